// Round 1
// baseline (6438.013 us; speedup 1.0000x reference)
//
#include <hip/hip_runtime.h>
#include <hip/hip_bf16.h>
#include <math.h>

// Problem constants
#define BB 2
#define TT 2048
#define DD 1024
#define HH 16
#define DK 64
#define HD 1024   // H*DK
#define KCONV 4

__device__ __forceinline__ float sigmoidf_(float x) { return 1.0f / (1.0f + expf(-x)); }
__device__ __forceinline__ float siluf_(float x) { return x * sigmoidf_(x); }

// ---------------------------------------------------------------------------
// Generic tiled fp32 GEMM: C[M,N] = A[M,K] @ B[K,N], all row-major.
// 64x64 tile, BK=16, 256 threads, 4x4 micro-tile per thread.
// ---------------------------------------------------------------------------
#define GTS 64
#define GBK 16
__global__ __launch_bounds__(256) void gemm_k(const float* __restrict__ A,
                                              const float* __restrict__ Bm,
                                              float* __restrict__ C,
                                              int M, int N, int Kd) {
    __shared__ __align__(16) float a_s[GBK][GTS];  // [k][m]  (A staged transposed)
    __shared__ __align__(16) float b_s[GBK][GTS];  // [k][n]

    const int tid = threadIdx.x;
    const int tx = tid & 15;        // 0..15 -> n
    const int ty = tid >> 4;        // 0..15 -> m
    const int n0 = blockIdx.x * GTS;
    const int m0 = blockIdx.y * GTS;

    // A loader: thread -> (row lr 0..63, k-chunk lc 0..3)
    const int lr = tid >> 2;
    const int lc = tid & 3;
    // B loader: thread -> (k-row br 0..15, n-chunk bc 0..15)
    const int br = tid >> 4;
    const int bc = tid & 15;

    float acc[4][4];
#pragma unroll
    for (int i = 0; i < 4; ++i)
#pragma unroll
        for (int j = 0; j < 4; ++j) acc[i][j] = 0.0f;

    for (int k0 = 0; k0 < Kd; k0 += GBK) {
        float4 av = *(const float4*)&A[(size_t)(m0 + lr) * Kd + k0 + lc * 4];
        float4 bv = *(const float4*)&Bm[(size_t)(k0 + br) * N + n0 + bc * 4];
        __syncthreads();
        a_s[lc * 4 + 0][lr] = av.x;
        a_s[lc * 4 + 1][lr] = av.y;
        a_s[lc * 4 + 2][lr] = av.z;
        a_s[lc * 4 + 3][lr] = av.w;
        *(float4*)&b_s[br][bc * 4] = bv;
        __syncthreads();
#pragma unroll
        for (int kk = 0; kk < GBK; ++kk) {
            float4 a4 = *(const float4*)&a_s[kk][ty * 4];
            float4 b4 = *(const float4*)&b_s[kk][tx * 4];
            const float aa[4] = {a4.x, a4.y, a4.z, a4.w};
            const float bb[4] = {b4.x, b4.y, b4.z, b4.w};
#pragma unroll
            for (int i = 0; i < 4; ++i)
#pragma unroll
                for (int j = 0; j < 4; ++j) acc[i][j] += aa[i] * bb[j];
        }
    }

#pragma unroll
    for (int i = 0; i < 4; ++i) {
        float4 r = make_float4(acc[i][0], acc[i][1], acc[i][2], acc[i][3]);
        *(float4*)&C[(size_t)(m0 + ty * 4 + i) * N + n0 + tx * 4] = r;
    }
}

// ---------------------------------------------------------------------------
// g / beta kernel: per row (b*T+t) compute 16 dots vs Wa (-> g via softplus)
// and 16 dots vs Wb (-> beta via sigmoid). One block per row, 256 threads.
// ---------------------------------------------------------------------------
__global__ __launch_bounds__(256) void gbeta_k(const float* __restrict__ x,
                                               const float* __restrict__ Wa,
                                               const float* __restrict__ Wb,
                                               const float* __restrict__ A_log,
                                               const float* __restrict__ dt_bias,
                                               float* __restrict__ g,
                                               float* __restrict__ beta) {
    __shared__ __align__(16) float xs[DD];
    const int row = blockIdx.x;  // b*T + t
    const int tid = threadIdx.x;

    *(float4*)&xs[tid * 4] = *(const float4*)&x[(size_t)row * DD + tid * 4];
    __syncthreads();

    const int out = tid >> 3;   // 0..31
    const int part = tid & 7;   // 0..7
    const int h = out & 15;
    const float* W = (out < 16) ? Wa : Wb;

    float s = 0.0f;
#pragma unroll 4
    for (int i = 0; i < 128; ++i) {
        int ie = (i + out * 16) & 127;   // rotate start per group to spread LDS banks
        int d = part * 128 + ie;
        s += xs[d] * W[(size_t)d * HH + h];
    }
    s += __shfl_down(s, 4);
    s += __shfl_down(s, 2);
    s += __shfl_down(s, 1);

    if (part == 0) {
        if (out < 16) {
            float v = s + dt_bias[h];
            float sp = (v > 20.0f) ? v : log1pf(expf(v));
            g[(size_t)row * HH + h] = -expf(A_log[h]) * sp;
        } else {
            beta[(size_t)row * HH + h] = sigmoidf_(s);
        }
    }
}

// ---------------------------------------------------------------------------
// Sequential gated delta-rule scan. One block (1 wave, 64 lanes) per (b,h).
// Lane = v-column; state h[k][lane] lives in 64 VGPRs.
// Short conv (K=4) + silu + l2norm fused into chunk staging.
// ---------------------------------------------------------------------------
__global__ __launch_bounds__(64, 1) void scan_k(const float* __restrict__ q_pre,
                                                const float* __restrict__ k_pre,
                                                const float* __restrict__ v_pre,
                                                const float* __restrict__ cq,
                                                const float* __restrict__ ck,
                                                const float* __restrict__ cv,
                                                const float* __restrict__ g,
                                                const float* __restrict__ beta,
                                                float* __restrict__ o) {
    const int bh = blockIdx.x;       // b*H + h
    const int b = bh >> 4;
    const int h = bh & 15;
    const int lane = threadIdx.x;    // 0..63 (one wave)
    const int ch = h * DK + lane;    // channel in [0,1024)

    __shared__ __align__(16) float q_s[64 * 64];
    __shared__ __align__(16) float k_s[64 * 64];
    __shared__ __align__(16) float v_s[64 * 64];
    __shared__ float eg_s[64];
    __shared__ float be_s[64];

    // depthwise conv weights for this channel (K=4 -> one float4 row)
    const float4 wq4 = *(const float4*)&cq[ch * 4];
    const float4 wk4 = *(const float4*)&ck[ch * 4];
    const float4 wv4 = *(const float4*)&cv[ch * 4];
    const float wq[4] = {wq4.x, wq4.y, wq4.z, wq4.w};
    const float wk[4] = {wk4.x, wk4.y, wk4.z, wk4.w};
    const float wv[4] = {wv4.x, wv4.y, wv4.z, wv4.w};

    float hst[DK];
#pragma unroll
    for (int i = 0; i < DK; ++i) hst[i] = 0.0f;

    const float qscale = 0.125f;  // DK^-0.5

    for (int c0 = 0; c0 < TT; c0 += 64) {
        // stage decay / beta for the chunk (coalesced: lane = t within chunk)
        {
            size_t gi = ((size_t)b * TT + c0 + lane) * HH + h;
            eg_s[lane] = expf(g[gi]);
            be_s[lane] = beta[gi];
        }
        // stage q/k/v with conv + silu + l2norm
#pragma unroll 1
        for (int tt = 0; tt < 64; ++tt) {
            const int t = c0 + tt;
            float qa = 0.0f, ka = 0.0f, va = 0.0f;
#pragma unroll
            for (int j = 0; j < 4; ++j) {
                int ts = t - 3 + j;
                if (ts >= 0) {
                    size_t bi = ((size_t)b * TT + ts) * HD + ch;
                    qa += q_pre[bi] * wq[j];
                    ka += k_pre[bi] * wk[j];
                    va += v_pre[bi] * wv[j];
                }
            }
            qa = siluf_(qa);
            ka = siluf_(ka);
            va = siluf_(va);

            float qs2 = qa * qa;
            float ks2 = ka * ka;
#pragma unroll
            for (int s = 32; s > 0; s >>= 1) {
                qs2 += __shfl_xor(qs2, s);
                ks2 += __shfl_xor(ks2, s);
            }
            q_s[tt * 64 + lane] = qa * rsqrtf(qs2 + 1e-6f) * qscale;
            k_s[tt * 64 + lane] = ka * rsqrtf(ks2 + 1e-6f);
            v_s[tt * 64 + lane] = va;
        }
        __syncthreads();

        // sequential inner steps
#pragma unroll 1
        for (int tt = 0; tt < 64; ++tt) {
            const float* ks = &k_s[tt * 64];
            const float* qs = &q_s[tt * 64];
            const float eg = eg_s[tt];
            const float bt = be_s[tt];

            float kv = 0.0f;
#pragma unroll
            for (int j = 0; j < DK; ++j) kv += ks[j] * hst[j];

            const float vadj = (v_s[tt * 64 + lane] - eg * kv) * bt;

            float ot = 0.0f;
#pragma unroll
            for (int j = 0; j < DK; ++j) {
                float hn = eg * hst[j] + ks[j] * vadj;
                hst[j] = hn;
                ot += qs[j] * hn;
            }
            o[(((size_t)b * TT + c0 + tt) * HH + h) * DK + lane] = ot;
        }
        __syncthreads();
    }
}

// ---------------------------------------------------------------------------
// Gated RMSNorm: o2 = (o * rsqrt(mean(o^2)+eps) * rms_w) * silu(gate)
// One 64-lane wave per (b,t,h); 4 waves per block.
// ---------------------------------------------------------------------------
__global__ __launch_bounds__(256) void gnorm_k(const float* __restrict__ o_scan,
                                               const float* __restrict__ gate,
                                               const float* __restrict__ rms_w,
                                               float* __restrict__ o2) {
    const int tid = threadIdx.x;
    const int grp = tid >> 6;
    const int lane = tid & 63;
    const int bth = blockIdx.x * 4 + grp;   // (b*T+t)*H + h
    const int h = bth & 15;
    const int row = bth >> 4;               // b*T + t

    float ov = o_scan[(size_t)bth * DK + lane];
    float s = ov * ov;
#pragma unroll
    for (int sh = 32; sh > 0; sh >>= 1) s += __shfl_xor(s, sh);
    float r = rsqrtf(s * (1.0f / 64.0f) + 1e-5f);

    float gt = gate[(size_t)row * HD + h * DK + lane];
    o2[(size_t)row * HD + h * DK + lane] = ov * r * rms_w[lane] * siluf_(gt);
}

// ---------------------------------------------------------------------------
extern "C" void kernel_launch(void* const* d_in, const int* in_sizes, int n_in,
                              void* d_out, int out_size, void* d_ws, size_t ws_size,
                              hipStream_t stream) {
    (void)in_sizes; (void)n_in; (void)out_size; (void)ws_size;

    const float* x       = (const float*)d_in[0];
    const float* Wq      = (const float*)d_in[1];
    const float* Wk      = (const float*)d_in[2];
    const float* Wv      = (const float*)d_in[3];
    const float* Wa      = (const float*)d_in[4];
    const float* Wb      = (const float*)d_in[5];
    const float* Wg      = (const float*)d_in[6];
    const float* Wo      = (const float*)d_in[7];
    const float* conv_q  = (const float*)d_in[8];
    const float* conv_k  = (const float*)d_in[9];
    const float* conv_v  = (const float*)d_in[10];
    const float* A_log   = (const float*)d_in[11];
    const float* dt_bias = (const float*)d_in[12];
    const float* rms_w   = (const float*)d_in[13];
    float* out = (float*)d_out;

    float* ws = (float*)d_ws;
    const size_t NTOK = (size_t)BB * TT;          // 4096
    const size_t BIG = NTOK * HD;                 // 4 Mi floats
    float* q_pre  = ws + 0 * BIG;
    float* k_pre  = ws + 1 * BIG;
    float* v_pre  = ws + 2 * BIG;
    float* gatep  = ws + 3 * BIG;
    float* o_scan = ws + 4 * BIG;
    float* gbuf   = ws + 5 * BIG;
    float* bbuf   = gbuf + NTOK * HH;
    float* o2     = q_pre;  // reuse: q_pre fully consumed by scan_k before gnorm_k

    dim3 gg(HD / GTS, (NTOK) / GTS);  // (16, 64)

    gemm_k<<<gg, 256, 0, stream>>>(x, Wq, q_pre, (int)NTOK, HD, DD);
    gemm_k<<<gg, 256, 0, stream>>>(x, Wk, k_pre, (int)NTOK, HD, DD);
    gemm_k<<<gg, 256, 0, stream>>>(x, Wv, v_pre, (int)NTOK, HD, DD);
    gemm_k<<<gg, 256, 0, stream>>>(x, Wg, gatep, (int)NTOK, HD, DD);

    gbeta_k<<<(int)NTOK, 256, 0, stream>>>(x, Wa, Wb, A_log, dt_bias, gbuf, bbuf);

    scan_k<<<BB * HH, 64, 0, stream>>>(q_pre, k_pre, v_pre, conv_q, conv_k, conv_v,
                                       gbuf, bbuf, o_scan);

    gnorm_k<<<(int)(NTOK * HH / 4), 256, 0, stream>>>(o_scan, gatep, rms_w, o2);

    gemm_k<<<gg, 256, 0, stream>>>(o2, Wo, out, (int)NTOK, HD, DD);
}

// Round 2
// 1857.095 us; speedup vs baseline: 3.4667x; 3.4667x over previous
//
#include <hip/hip_runtime.h>
#include <hip/hip_bf16.h>
#include <math.h>

// Problem constants
#define BB 2
#define TT 2048
#define DD 1024
#define HH 16
#define DK 64
#define HD 1024   // H*DK
#define NC 32     // chunks per sequence (TT/64)
#define CL 64     // chunk length
#define PAD 68    // padded LDS row stride (floats) to break stride-64 bank conflicts

__device__ __forceinline__ float sigmoidf_(float x) { return 1.0f / (1.0f + expf(-x)); }
__device__ __forceinline__ float siluf_(float x) { return x * sigmoidf_(x); }
__device__ __forceinline__ void f4a(const float4 v, float* o) { o[0]=v.x; o[1]=v.y; o[2]=v.z; o[3]=v.w; }

// ---------------------------------------------------------------------------
// Generic tiled fp32 GEMM: C[M,N] = A[M,K] @ B[K,N], all row-major.
// ---------------------------------------------------------------------------
#define GTS 64
#define GBK 16
__global__ __launch_bounds__(256) void gemm_k(const float* __restrict__ A,
                                              const float* __restrict__ Bm,
                                              float* __restrict__ C,
                                              int M, int N, int Kd) {
    __shared__ __align__(16) float a_s[GBK][GTS];
    __shared__ __align__(16) float b_s[GBK][GTS];

    const int tid = threadIdx.x;
    const int tx = tid & 15;
    const int ty = tid >> 4;
    const int n0 = blockIdx.x * GTS;
    const int m0 = blockIdx.y * GTS;

    const int lr = tid >> 2;
    const int lc = tid & 3;
    const int br = tid >> 4;
    const int bc = tid & 15;

    float acc[4][4];
#pragma unroll
    for (int i = 0; i < 4; ++i)
#pragma unroll
        for (int j = 0; j < 4; ++j) acc[i][j] = 0.0f;

    for (int k0 = 0; k0 < Kd; k0 += GBK) {
        float4 av = *(const float4*)&A[(size_t)(m0 + lr) * Kd + k0 + lc * 4];
        float4 bv = *(const float4*)&Bm[(size_t)(k0 + br) * N + n0 + bc * 4];
        __syncthreads();
        a_s[lc * 4 + 0][lr] = av.x;
        a_s[lc * 4 + 1][lr] = av.y;
        a_s[lc * 4 + 2][lr] = av.z;
        a_s[lc * 4 + 3][lr] = av.w;
        *(float4*)&b_s[br][bc * 4] = bv;
        __syncthreads();
#pragma unroll
        for (int kk = 0; kk < GBK; ++kk) {
            float4 a4 = *(const float4*)&a_s[kk][ty * 4];
            float4 b4 = *(const float4*)&b_s[kk][tx * 4];
            const float aa[4] = {a4.x, a4.y, a4.z, a4.w};
            const float bb[4] = {b4.x, b4.y, b4.z, b4.w};
#pragma unroll
            for (int i = 0; i < 4; ++i)
#pragma unroll
                for (int j = 0; j < 4; ++j) acc[i][j] += aa[i] * bb[j];
        }
    }

#pragma unroll
    for (int i = 0; i < 4; ++i) {
        float4 r = make_float4(acc[i][0], acc[i][1], acc[i][2], acc[i][3]);
        *(float4*)&C[(size_t)(m0 + ty * 4 + i) * N + n0 + tx * 4] = r;
    }
}

// ---------------------------------------------------------------------------
// g / beta kernel (unchanged from R0)
// ---------------------------------------------------------------------------
__global__ __launch_bounds__(256) void gbeta_k(const float* __restrict__ x,
                                               const float* __restrict__ Wa,
                                               const float* __restrict__ Wb,
                                               const float* __restrict__ A_log,
                                               const float* __restrict__ dt_bias,
                                               float* __restrict__ g,
                                               float* __restrict__ beta) {
    __shared__ __align__(16) float xs[DD];
    const int row = blockIdx.x;
    const int tid = threadIdx.x;

    *(float4*)&xs[tid * 4] = *(const float4*)&x[(size_t)row * DD + tid * 4];
    __syncthreads();

    const int out = tid >> 3;
    const int part = tid & 7;
    const int h = out & 15;
    const float* W = (out < 16) ? Wa : Wb;

    float s = 0.0f;
#pragma unroll 4
    for (int i = 0; i < 128; ++i) {
        int ie = (i + out * 16) & 127;
        int d = part * 128 + ie;
        s += xs[d] * W[(size_t)d * HH + h];
    }
    s += __shfl_down(s, 4);
    s += __shfl_down(s, 2);
    s += __shfl_down(s, 1);

    if (part == 0) {
        if (out < 16) {
            float v = s + dt_bias[h];
            float sp = (v > 20.0f) ? v : log1pf(expf(v));
            g[(size_t)row * HH + h] = -expf(A_log[h]) * sp;
        } else {
            beta[(size_t)row * HH + h] = sigmoidf_(s);
        }
    }
}

// ---------------------------------------------------------------------------
// Phase A1: per (bh,chunk) stage normalized q,k (conv+silu+l2norm) and cumsum(g).
// grid = 1024 (bh*NC + c), block = 64 (lane = dk).
// ---------------------------------------------------------------------------
__global__ __launch_bounds__(64) void stage_k(const float* __restrict__ q_pre,
                                              const float* __restrict__ k_pre,
                                              const float* __restrict__ cq,
                                              const float* __restrict__ ck,
                                              const float* __restrict__ g,
                                              float* __restrict__ Qc,
                                              float* __restrict__ Kc,
                                              float* __restrict__ bcum) {
    const int blk = blockIdx.x;
    const int bh = blk >> 5;
    const int c = blk & 31;
    const int b = bh >> 4;
    const int h = bh & 15;
    const int lane = threadIdx.x;
    const int ch = h * DK + lane;

    const float4 wq4 = *(const float4*)&cq[ch * 4];
    const float4 wk4 = *(const float4*)&ck[ch * 4];

    float qw0 = 0, qw1 = 0, qw2 = 0, kw0 = 0, kw1 = 0, kw2 = 0;
    {
        const int t0 = c * CL;
        if (t0 - 3 >= 0) { size_t bi = ((size_t)b * TT + t0 - 3) * HD + ch; qw0 = q_pre[bi]; kw0 = k_pre[bi]; }
        if (t0 - 2 >= 0) { size_t bi = ((size_t)b * TT + t0 - 2) * HD + ch; qw1 = q_pre[bi]; kw1 = k_pre[bi]; }
        if (t0 - 1 >= 0) { size_t bi = ((size_t)b * TT + t0 - 1) * HD + ch; qw2 = q_pre[bi]; kw2 = k_pre[bi]; }
    }
    float* Qo = Qc + (size_t)blk * 4096;
    float* Ko = Kc + (size_t)blk * 4096;

    for (int tt = 0; tt < CL; ++tt) {
        const int t = c * CL + tt;
        const size_t bi = ((size_t)b * TT + t) * HD + ch;
        const float qc_ = q_pre[bi];
        const float kc_ = k_pre[bi];
        float qa = qw0 * wq4.x + qw1 * wq4.y + qw2 * wq4.z + qc_ * wq4.w;
        float ka = kw0 * wk4.x + kw1 * wk4.y + kw2 * wk4.z + kc_ * wk4.w;
        qw0 = qw1; qw1 = qw2; qw2 = qc_;
        kw0 = kw1; kw1 = kw2; kw2 = kc_;
        qa = siluf_(qa);
        ka = siluf_(ka);
        float qs2 = qa * qa, ks2 = ka * ka;
#pragma unroll
        for (int s = 32; s > 0; s >>= 1) {
            qs2 += __shfl_xor(qs2, s);
            ks2 += __shfl_xor(ks2, s);
        }
        Qo[tt * 64 + lane] = qa * rsqrtf(qs2 + 1e-6f) * 0.125f;
        Ko[tt * 64 + lane] = ka * rsqrtf(ks2 + 1e-6f);
    }

    // inclusive prefix sum of g within chunk
    float cum = g[((size_t)b * TT + c * CL + lane) * HH + h];
#pragma unroll
    for (int s = 1; s < 64; s <<= 1) {
        float u = __shfl_up(cum, s);
        if (lane >= s) cum += u;
    }
    bcum[(size_t)blk * 64 + lane] = cum;
}

// ---------------------------------------------------------------------------
// Phase A2: per (bh,chunk): build A = strict-lower(beta_t e^{b_t-b_s} k_t.k_s),
// forward-substitute (I+A)^{-1} on R_v = beta*V (v conv done here) and
// R_k = beta e^{b} K. Writes Wv, Wk. grid = 1024, block = 256.
// ---------------------------------------------------------------------------
__global__ __launch_bounds__(256) void prep_k(const float* __restrict__ Kc,
                                              const float* __restrict__ v_pre,
                                              const float* __restrict__ cv,
                                              const float* __restrict__ bcum,
                                              const float* __restrict__ bbuf,
                                              float* __restrict__ Wv,
                                              float* __restrict__ Wk) {
    __shared__ __align__(16) float k_s[CL * PAD];
    __shared__ __align__(16) float wv_s[CL * PAD];
    __shared__ __align__(16) float wk_s[CL * PAD];
    __shared__ __align__(16) float A_s[CL * PAD];
    __shared__ float b_s[CL], beta_s[CL], bk_s[CL];

    const int blk = blockIdx.x;
    const int bh = blk >> 5;
    const int c = blk & 31;
    const int b = bh >> 4;
    const int h = bh & 15;
    const int tid = threadIdx.x;

    if (tid < 64) {
        float bv = bcum[(size_t)blk * 64 + tid];
        float be = bbuf[((size_t)b * TT + c * CL + tid) * HH + tid * 0 + h];
        b_s[tid] = bv;
        beta_s[tid] = be;
        bk_s[tid] = be * __expf(bv);
    }
    __syncthreads();

    // load K (and scaled copy into wk_s)
    const float4* Kg = (const float4*)(Kc + (size_t)blk * 4096);
#pragma unroll
    for (int i = 0; i < 4; ++i) {
        int f = tid + i * 256;
        int t = f >> 4;
        int d = t * PAD + (f & 15) * 4;
        float4 kv = Kg[f];
        *(float4*)&k_s[d] = kv;
        float sk = bk_s[t];
        *(float4*)&wk_s[d] = make_float4(kv.x * sk, kv.y * sk, kv.z * sk, kv.w * sk);
    }

    // v: conv + silu + *beta, staged directly into wv_s
    {
        const int lane = tid & 63;
        const int q4 = tid >> 6;          // 0..3 -> rows q4*16 .. q4*16+15
        const int ch = h * DK + lane;
        const float4 wv4 = *(const float4*)&cv[ch * 4];
        const int T0 = c * CL + q4 * 16;
        float w0 = 0, w1 = 0, w2 = 0;
        if (T0 - 3 >= 0) w0 = v_pre[((size_t)b * TT + T0 - 3) * HD + ch];
        if (T0 - 2 >= 0) w1 = v_pre[((size_t)b * TT + T0 - 2) * HD + ch];
        if (T0 - 1 >= 0) w2 = v_pre[((size_t)b * TT + T0 - 1) * HD + ch];
#pragma unroll 1
        for (int i = 0; i < 16; ++i) {
            const int t = T0 + i;
            const float vc_ = v_pre[((size_t)b * TT + t) * HD + ch];
            float va = w0 * wv4.x + w1 * wv4.y + w2 * wv4.z + vc_ * wv4.w;
            w0 = w1; w1 = w2; w2 = vc_;
            va = siluf_(va);
            wv_s[(q4 * 16 + i) * PAD + lane] = va * beta_s[q4 * 16 + i];
        }
    }
    __syncthreads();

    // A[t][s] = beta_t e^{b_t-b_s} (k_t . k_s) for s<t, else 0
    {
        const int t0 = (tid >> 4) * 4, s0 = (tid & 15) * 4;
        float acc[4][4] = {};
        for (int kk = 0; kk < 64; kk += 4) {
            float ta[4][4], sb[4][4];
#pragma unroll
            for (int i = 0; i < 4; ++i) f4a(*(const float4*)&k_s[(t0 + i) * PAD + kk], ta[i]);
#pragma unroll
            for (int j = 0; j < 4; ++j) f4a(*(const float4*)&k_s[(s0 + j) * PAD + kk], sb[j]);
#pragma unroll
            for (int i = 0; i < 4; ++i)
#pragma unroll
                for (int j = 0; j < 4; ++j)
#pragma unroll
                    for (int m = 0; m < 4; ++m) acc[i][j] += ta[i][m] * sb[j][m];
        }
#pragma unroll
        for (int i = 0; i < 4; ++i)
#pragma unroll
            for (int j = 0; j < 4; ++j) {
                const int t = t0 + i, s = s0 + j;
                A_s[t * PAD + s] = (s < t) ? acc[i][j] * beta_s[t] * __expf(b_s[t] - b_s[s]) : 0.0f;
            }
    }
    __syncthreads();

    // forward substitution, in place: wave0 -> wv_s, wave1 -> wk_s
    {
        const int wv = tid >> 6;
        const int lane = tid & 63;
        if (wv < 2) {
            float* W = (wv == 0) ? wv_s : wk_s;
#pragma unroll 1
            for (int t = 1; t < 64; ++t) {
                float w = W[t * PAD + lane];
#pragma unroll 1
                for (int s = 0; s < t; ++s) w -= A_s[t * PAD + s] * W[s * PAD + lane];
                W[t * PAD + lane] = w;
            }
        }
    }
    __syncthreads();

    // write Wv, Wk
    float4* Wvg = (float4*)(Wv + (size_t)blk * 4096);
    float4* Wkg = (float4*)(Wk + (size_t)blk * 4096);
#pragma unroll
    for (int i = 0; i < 4; ++i) {
        int f = tid + i * 256;
        int d = (f >> 4) * PAD + (f & 15) * 4;
        Wvg[f] = *(float4*)&wv_s[d];
        Wkg[f] = *(float4*)&wk_s[d];
    }
}

// ---------------------------------------------------------------------------
// Phase B: sequential chunk recurrence per (bh). Writes chunk-start states Hst
// and W = Wv - Wk h0 (over the Wv buffer). grid = 32, block = 256.
// ---------------------------------------------------------------------------
__global__ __launch_bounds__(256) void state_k(const float* __restrict__ Kc,
                                               float* __restrict__ Wio,   // in: Wv, out: W
                                               const float* __restrict__ Wk,
                                               const float* __restrict__ bcum,
                                               float* __restrict__ Hst) {
    __shared__ __align__(16) float h_s[CL * PAD];
    __shared__ __align__(16) float w_s[CL * PAD];
    __shared__ __align__(16) float x_s[CL * PAD];
    __shared__ float e_s[CL];

    const int bh = blockIdx.x;
    const int tid = threadIdx.x;
    const int r0 = (tid >> 4) * 4;   // tile rows
    const int v0 = (tid & 15) * 4;   // tile cols

#pragma unroll
    for (int i = 0; i < 4; ++i) {
        int f = tid + i * 256;
        int d = (f >> 4) * PAD + (f & 15) * 4;
        *(float4*)&h_s[d] = make_float4(0, 0, 0, 0);
    }
    __syncthreads();

    for (int c = 0; c < NC; ++c) {
        const size_t blk = (size_t)bh * NC + c;
        // (a) write chunk-start state; stage Wk; decay scalars
        float4* Hg = (float4*)(Hst + blk * 4096);
        const float4* Wkg = (const float4*)(Wk + blk * 4096);
#pragma unroll
        for (int i = 0; i < 4; ++i) {
            int f = tid + i * 256;
            int d = (f >> 4) * PAD + (f & 15) * 4;
            Hg[f] = *(float4*)&h_s[d];
            *(float4*)&x_s[d] = Wkg[f];
        }
        const float bC = bcum[blk * 64 + 63];
        if (tid < 64) e_s[tid] = __expf(bC - bcum[blk * 64 + tid]);
        __syncthreads();

        // (b) W = Wv - Wk @ h0
        float acc[4][4];
        {
            const float4* Wvg = (const float4*)(Wio + blk * 4096);
#pragma unroll
            for (int i = 0; i < 4; ++i) f4a(Wvg[(r0 + i) * 16 + (v0 >> 2)], acc[i]);
            for (int kk = 0; kk < 64; kk += 4) {
                float a[4][4], hb[4][4];
#pragma unroll
                for (int i = 0; i < 4; ++i) f4a(*(const float4*)&x_s[(r0 + i) * PAD + kk], a[i]);
#pragma unroll
                for (int m = 0; m < 4; ++m) f4a(*(const float4*)&h_s[(kk + m) * PAD + v0], hb[m]);
#pragma unroll
                for (int i = 0; i < 4; ++i)
#pragma unroll
                    for (int m = 0; m < 4; ++m)
#pragma unroll
                        for (int j = 0; j < 4; ++j) acc[i][j] -= a[i][m] * hb[m][j];
            }
        }
        __syncthreads();
        // (c) store W (LDS + global); stage K
        {
            float4* Wg = (float4*)(Wio + blk * 4096);
            const float4* Kg = (const float4*)(Kc + blk * 4096);
#pragma unroll
            for (int i = 0; i < 4; ++i) {
                float4 r = make_float4(acc[i][0], acc[i][1], acc[i][2], acc[i][3]);
                *(float4*)&w_s[(r0 + i) * PAD + v0] = r;
                Wg[(r0 + i) * 16 + (v0 >> 2)] = r;
            }
#pragma unroll
            for (int i = 0; i < 4; ++i) {
                int f = tid + i * 256;
                int d = (f >> 4) * PAD + (f & 15) * 4;
                *(float4*)&x_s[d] = Kg[f];
            }
        }
        __syncthreads();
        // (d) h' = e^{bC} h + Ktilde^T W
        {
            const float eb = __expf(bC);
#pragma unroll
            for (int i = 0; i < 4; ++i)
#pragma unroll
                for (int j = 0; j < 4; ++j) acc[i][j] = eb * h_s[(r0 + i) * PAD + v0 + j];
            for (int ss = 0; ss < 64; ss += 4) {
                float kf[4][4], wb[4][4];
#pragma unroll
                for (int m = 0; m < 4; ++m) {
                    f4a(*(const float4*)&x_s[(ss + m) * PAD + r0], kf[m]);
                    f4a(*(const float4*)&w_s[(ss + m) * PAD + v0], wb[m]);
                    const float e = e_s[ss + m];
#pragma unroll
                    for (int i = 0; i < 4; ++i) kf[m][i] *= e;
                }
#pragma unroll
                for (int i = 0; i < 4; ++i)
#pragma unroll
                    for (int m = 0; m < 4; ++m)
#pragma unroll
                        for (int j = 0; j < 4; ++j) acc[i][j] += kf[m][i] * wb[m][j];
            }
        }
        __syncthreads();
#pragma unroll
        for (int i = 0; i < 4; ++i)
            *(float4*)&h_s[(r0 + i) * PAD + v0] =
                make_float4(acc[i][0], acc[i][1], acc[i][2], acc[i][3]);
        __syncthreads();
    }
}

// ---------------------------------------------------------------------------
// Phase C: per (bh,chunk) outputs: O = (QK^T ⊙ M)W + diag(e^{b_t}) Q h0.
// grid = 1024, block = 256. LDS arrays stride 64 (4 x 16KB -> 2 blocks/CU).
// ---------------------------------------------------------------------------
__global__ __launch_bounds__(256) void out_k(const float* __restrict__ Qc,
                                             const float* __restrict__ Kc,
                                             const float* __restrict__ Wb_,
                                             const float* __restrict__ Hst,
                                             const float* __restrict__ bcum,
                                             float* __restrict__ o_scan) {
    __shared__ __align__(16) float q_s[4096];
    __shared__ __align__(16) float k_s[4096];   // K, then S
    __shared__ __align__(16) float h_s[4096];
    __shared__ __align__(16) float w_s[4096];
    __shared__ float b_s[64];

    const int blk = blockIdx.x;
    const int bh = blk >> 5;
    const int c = blk & 31;
    const int b = bh >> 4;
    const int h = bh & 15;
    const int tid = threadIdx.x;

    if (tid < 64) b_s[tid] = bcum[(size_t)blk * 64 + tid];
    {
        const float4* Qg = (const float4*)(Qc + (size_t)blk * 4096);
        const float4* Kg = (const float4*)(Kc + (size_t)blk * 4096);
        const float4* Hg = (const float4*)(Hst + (size_t)blk * 4096);
        const float4* Wg = (const float4*)(Wb_ + (size_t)blk * 4096);
#pragma unroll
        for (int i = 0; i < 4; ++i) {
            int f = tid + i * 256;
            ((float4*)q_s)[f] = Qg[f];
            ((float4*)k_s)[f] = Kg[f];
            ((float4*)h_s)[f] = Hg[f];
            ((float4*)w_s)[f] = Wg[f];
        }
    }
    __syncthreads();

    // S = (Q K^T) ⊙ exp(b_t - b_s) [s<=t]  -> overwrite k_s
    {
        const int t0 = (tid >> 4) * 4, s0 = (tid & 15) * 4;
        float acc[4][4] = {};
        for (int kk = 0; kk < 64; kk += 4) {
            float qa[4][4], kb[4][4];
#pragma unroll
            for (int i = 0; i < 4; ++i) f4a(*(const float4*)&q_s[(t0 + i) * 64 + kk], qa[i]);
#pragma unroll
            for (int j = 0; j < 4; ++j) f4a(*(const float4*)&k_s[(s0 + j) * 64 + kk], kb[j]);
#pragma unroll
            for (int i = 0; i < 4; ++i)
#pragma unroll
                for (int j = 0; j < 4; ++j)
#pragma unroll
                    for (int m = 0; m < 4; ++m) acc[i][j] += qa[i][m] * kb[j][m];
        }
        __syncthreads();   // all Q,K reads done before overwrite
#pragma unroll
        for (int i = 0; i < 4; ++i)
#pragma unroll
            for (int j = 0; j < 4; ++j) {
                const int t = t0 + i, s = s0 + j;
                k_s[t * 64 + s] = (s <= t) ? acc[i][j] * __expf(b_s[t] - b_s[s]) : 0.0f;
            }
    }
    // scale q rows by e^{b_t} (q reads for S finished before the sync above)
#pragma unroll
    for (int i = 0; i < 16; ++i) {
        int e = tid + i * 256;
        q_s[e] *= __expf(b_s[e >> 6]);
    }
    __syncthreads();

    // O = S @ W + Qs @ H
    {
        const int t0 = (tid >> 4) * 4, v0 = (tid & 15) * 4;
        float acc[4][4] = {};
        for (int ss = 0; ss < 64; ss += 4) {
            float sa[4][4], wb[4][4];
#pragma unroll
            for (int i = 0; i < 4; ++i) f4a(*(const float4*)&k_s[(t0 + i) * 64 + ss], sa[i]);
#pragma unroll
            for (int m = 0; m < 4; ++m) f4a(*(const float4*)&w_s[(ss + m) * 64 + v0], wb[m]);
#pragma unroll
            for (int i = 0; i < 4; ++i)
#pragma unroll
                for (int m = 0; m < 4; ++m)
#pragma unroll
                    for (int j = 0; j < 4; ++j) acc[i][j] += sa[i][m] * wb[m][j];
        }
        for (int kk = 0; kk < 64; kk += 4) {
            float qa[4][4], hb[4][4];
#pragma unroll
            for (int i = 0; i < 4; ++i) f4a(*(const float4*)&q_s[(t0 + i) * 64 + kk], qa[i]);
#pragma unroll
            for (int m = 0; m < 4; ++m) f4a(*(const float4*)&h_s[(kk + m) * 64 + v0], hb[m]);
#pragma unroll
            for (int i = 0; i < 4; ++i)
#pragma unroll
                for (int m = 0; m < 4; ++m)
#pragma unroll
                    for (int j = 0; j < 4; ++j) acc[i][j] += qa[i][m] * hb[m][j];
        }
#pragma unroll
        for (int i = 0; i < 4; ++i) {
            const int t = c * CL + t0 + i;
            *(float4*)&o_scan[(((size_t)b * TT + t) * HH + h) * DK + v0] =
                make_float4(acc[i][0], acc[i][1], acc[i][2], acc[i][3]);
        }
    }
}

// ---------------------------------------------------------------------------
// Gated RMSNorm (unchanged)
// ---------------------------------------------------------------------------
__global__ __launch_bounds__(256) void gnorm_k(const float* __restrict__ o_scan,
                                               const float* __restrict__ gate,
                                               const float* __restrict__ rms_w,
                                               float* __restrict__ o2) {
    const int tid = threadIdx.x;
    const int grp = tid >> 6;
    const int lane = tid & 63;
    const int bth = blockIdx.x * 4 + grp;
    const int h = bth & 15;
    const int row = bth >> 4;

    float ov = o_scan[(size_t)bth * DK + lane];
    float s = ov * ov;
#pragma unroll
    for (int sh = 32; sh > 0; sh >>= 1) s += __shfl_xor(s, sh);
    float r = rsqrtf(s * (1.0f / 64.0f) + 1e-5f);

    float gt = gate[(size_t)row * HD + h * DK + lane];
    o2[(size_t)row * HD + h * DK + lane] = ov * r * rms_w[lane] * siluf_(gt);
}

// ---------------------------------------------------------------------------
extern "C" void kernel_launch(void* const* d_in, const int* in_sizes, int n_in,
                              void* d_out, int out_size, void* d_ws, size_t ws_size,
                              hipStream_t stream) {
    (void)in_sizes; (void)n_in; (void)out_size; (void)ws_size;

    const float* x       = (const float*)d_in[0];
    const float* Wq      = (const float*)d_in[1];
    const float* Wk_     = (const float*)d_in[2];
    const float* Wv_     = (const float*)d_in[3];
    const float* Wa      = (const float*)d_in[4];
    const float* Wb      = (const float*)d_in[5];
    const float* Wg      = (const float*)d_in[6];
    const float* Wo      = (const float*)d_in[7];
    const float* conv_q  = (const float*)d_in[8];
    const float* conv_k  = (const float*)d_in[9];
    const float* conv_v  = (const float*)d_in[10];
    const float* A_log   = (const float*)d_in[11];
    const float* dt_bias = (const float*)d_in[12];
    const float* rms_w   = (const float*)d_in[13];
    float* out = (float*)d_out;

    float* ws = (float*)d_ws;
    const size_t NTOK = (size_t)BB * TT;     // 4096
    const size_t BIG = NTOK * HD;            // 4 Mi floats

    float* q_pre = ws + 0 * BIG;
    float* k_pre = ws + 1 * BIG;
    float* v_pre = ws + 2 * BIG;
    float* gatep = ws + 3 * BIG;
    float* Qc    = ws + 4 * BIG;
    float* Kc    = ws + 5 * BIG;
    float* gbuf  = ws + 6 * BIG;
    float* bbuf  = gbuf + NTOK * HH;
    float* bcumb = bbuf + NTOK * HH;

    // aliases (stream-ordered lifetimes):
    float* Wvb    = q_pre;   // prep_k writes after stage_k's last q_pre read; becomes W in state_k
    float* Wkb    = k_pre;   // prep_k writes after stage_k's last k_pre read
    float* Hst    = v_pre;   // state_k writes after prep_k's last v_pre read
    float* o_scan = k_pre;   // out_k writes after state_k's last Wk read
    float* o2     = Qc;      // gnorm writes after out_k's last Qc read

    dim3 gg(HD / GTS, NTOK / GTS);

    gemm_k<<<gg, 256, 0, stream>>>(x, Wq, q_pre, (int)NTOK, HD, DD);
    gemm_k<<<gg, 256, 0, stream>>>(x, Wk_, k_pre, (int)NTOK, HD, DD);
    gemm_k<<<gg, 256, 0, stream>>>(x, Wv_, v_pre, (int)NTOK, HD, DD);
    gemm_k<<<gg, 256, 0, stream>>>(x, Wg, gatep, (int)NTOK, HD, DD);

    gbeta_k<<<(int)NTOK, 256, 0, stream>>>(x, Wa, Wb, A_log, dt_bias, gbuf, bbuf);

    stage_k<<<BB * HH * NC, 64, 0, stream>>>(q_pre, k_pre, conv_q, conv_k, gbuf,
                                             Qc, Kc, bcumb);

    prep_k<<<BB * HH * NC, 256, 0, stream>>>(Kc, v_pre, conv_v, bcumb, bbuf, Wvb, Wkb);

    state_k<<<BB * HH, 256, 0, stream>>>(Kc, Wvb, Wkb, bcumb, Hst);

    out_k<<<BB * HH * NC, 256, 0, stream>>>(Qc, Kc, Wvb, Hst, bcumb, o_scan);

    gnorm_k<<<(int)(NTOK * HH / 4), 256, 0, stream>>>(o_scan, gatep, rms_w, o2);

    gemm_k<<<gg, 256, 0, stream>>>(o2, Wo, out, (int)NTOK, HD, DD);
}

// Round 3
// 1427.913 us; speedup vs baseline: 4.5087x; 1.3006x over previous
//
#include <hip/hip_runtime.h>
#include <hip/hip_bf16.h>
#include <math.h>
#include <stdint.h>

// Problem constants
#define BB 2
#define TT 2048
#define DD 1024
#define HH 16
#define DK 64
#define HD 1024   // H*DK
#define NC 32     // chunks per sequence (TT/64)
#define CL 64     // chunk length
#define PAD 68    // padded LDS row stride (floats) to break stride-64 bank conflicts

typedef short bf16x8 __attribute__((ext_vector_type(8)));     // 8 bf16 (4 VGPRs)
typedef float f32x4 __attribute__((ext_vector_type(4)));      // MFMA acc
typedef unsigned short u16x8 __attribute__((ext_vector_type(8)));
typedef unsigned short u16x4 __attribute__((ext_vector_type(4)));

#define GAS __attribute__((address_space(1)))
#define LAS __attribute__((address_space(3)))

__device__ __forceinline__ float sigmoidf_(float x) { return 1.0f / (1.0f + expf(-x)); }
__device__ __forceinline__ float siluf_(float x) { return x * sigmoidf_(x); }
__device__ __forceinline__ void f4a(const float4 v, float* o) { o[0]=v.x; o[1]=v.y; o[2]=v.z; o[3]=v.w; }

// round-to-nearest-even fp32 -> bf16
__device__ __forceinline__ unsigned short f2bf(float f) {
    unsigned int u = __builtin_bit_cast(unsigned int, f);
    u = (u + 0x7fffu + ((u >> 16) & 1u)) >> 16;
    return (unsigned short)u;
}

// ---------------------------------------------------------------------------
// Cast x (fp32) -> bf16, flat. grid*block*8 == count.
// ---------------------------------------------------------------------------
__global__ __launch_bounds__(256) void castx_k(const float* __restrict__ src,
                                               unsigned short* __restrict__ dst) {
    const size_t idx = (size_t)blockIdx.x * 256 + threadIdx.x;
    float4 a = *(const float4*)&src[idx * 8];
    float4 b = *(const float4*)&src[idx * 8 + 4];
    u16x8 o;
    o[0] = f2bf(a.x); o[1] = f2bf(a.y); o[2] = f2bf(a.z); o[3] = f2bf(a.w);
    o[4] = f2bf(b.x); o[5] = f2bf(b.y); o[6] = f2bf(b.z); o[7] = f2bf(b.w);
    *(u16x8*)&dst[idx * 8] = o;
}

// ---------------------------------------------------------------------------
// Transpose+cast weight: W[K=1024][N=1024] fp32 -> Wt[N][K] bf16.
// 64x64 LDS tile, 256 threads.
// ---------------------------------------------------------------------------
__global__ __launch_bounds__(256) void castw_k(const float* __restrict__ W,
                                               unsigned short* __restrict__ Wt) {
    __shared__ float t_s[64][65];
    const int tid = threadIdx.x;
    const int rr = tid >> 4;     // 0..15
    const int cc = tid & 15;     // 0..15
    const int r0 = blockIdx.y * 64;   // k block
    const int c0 = blockIdx.x * 64;   // n block
#pragma unroll
    for (int i = 0; i < 4; ++i) {
        const int row = rr + i * 16;
        float4 v = *(const float4*)&W[(size_t)(r0 + row) * 1024 + c0 + cc * 4];
        t_s[row][cc * 4 + 0] = v.x;
        t_s[row][cc * 4 + 1] = v.y;
        t_s[row][cc * 4 + 2] = v.z;
        t_s[row][cc * 4 + 3] = v.w;
    }
    __syncthreads();
#pragma unroll
    for (int i = 0; i < 4; ++i) {
        const int nr = rr + i * 16;          // n within tile
        u16x4 o;
#pragma unroll
        for (int d = 0; d < 4; ++d) o[d] = f2bf(t_s[cc * 4 + d][nr]);
        *(u16x4*)&Wt[(size_t)(c0 + nr) * 1024 + r0 + cc * 4] = o;
    }
}

// ---------------------------------------------------------------------------
// bf16 MFMA GEMM (m97 structure): C[M,N] fp32 = A[M,K]bf16 @ Bt[N,K]bf16^T.
// 128x128 tile, BK=32, 256 threads (4 waves, each a 64x64 quadrant of 4x4
// 16x16x32 MFMA tiles). global_load_lds width=16 staging, unpadded [row][32]
// LDS (wave-uniform base + lane*16 requirement).
// ---------------------------------------------------------------------------
__global__ __launch_bounds__(256) void gemm_bf16_k(const unsigned short* __restrict__ A,
                                                   const unsigned short* __restrict__ Bt,
                                                   float* __restrict__ C,
                                                   int M, int N, int Kd) {
    __shared__ unsigned short a_s[128 * 32];
    __shared__ unsigned short b_s[128 * 32];

    const int tid = threadIdx.x;
    const int wave = tid >> 6;
    const int lane = tid & 63;
    const int m0 = blockIdx.y * 128;
    const int n0 = blockIdx.x * 128;

    const int quad = lane >> 4;
    const int l16 = lane & 15;
    const int wr = wave >> 1;     // wave quadrant row (0/1)
    const int wc = wave & 1;      // wave quadrant col (0/1)

    // staging: lane covers row srow (4 lanes/row), 16B segment sseg
    const int srow = lane >> 2;   // 0..15 within a 16-row region
    const int sseg = lane & 3;

    f32x4 acc[4][4];
#pragma unroll
    for (int i = 0; i < 4; ++i)
#pragma unroll
        for (int j = 0; j < 4; ++j) acc[i][j] = (f32x4){0.f, 0.f, 0.f, 0.f};

    for (int k0 = 0; k0 < Kd; k0 += 32) {
        __syncthreads();   // previous iter's LDS reads done before overwrite
#pragma unroll
        for (int c = 0; c < 2; ++c) {
            const int region = wave * 2 + c;       // 0..7
            const int r0t = region * 16;
            const int ra = r0t + srow;
            const unsigned short* ga = A + (size_t)(m0 + ra) * Kd + k0 + sseg * 8;
            const unsigned short* gb = Bt + (size_t)(n0 + ra) * Kd + k0 + sseg * 8;
            __builtin_amdgcn_global_load_lds((const GAS unsigned int*)ga,
                                             (LAS unsigned int*)&a_s[r0t * 32], 16, 0, 0);
            __builtin_amdgcn_global_load_lds((const GAS unsigned int*)gb,
                                             (LAS unsigned int*)&b_s[r0t * 32], 16, 0, 0);
        }
        __syncthreads();   // drains vmcnt(0): staged data visible

        bf16x8 af[4], bfr[4];
#pragma unroll
        for (int i = 0; i < 4; ++i)
            af[i] = *(const bf16x8*)&a_s[(wr * 64 + i * 16 + l16) * 32 + quad * 8];
#pragma unroll
        for (int j = 0; j < 4; ++j)
            bfr[j] = *(const bf16x8*)&b_s[(wc * 64 + j * 16 + l16) * 32 + quad * 8];
#pragma unroll
        for (int i = 0; i < 4; ++i)
#pragma unroll
            for (int j = 0; j < 4; ++j)
                acc[i][j] = __builtin_amdgcn_mfma_f32_16x16x32_bf16(af[i], bfr[j], acc[i][j], 0, 0, 0);
    }

    // epilogue: C/D layout col=lane&15, row=quad*4+reg
#pragma unroll
    for (int i = 0; i < 4; ++i)
#pragma unroll
        for (int j = 0; j < 4; ++j) {
            const int col = n0 + wc * 64 + j * 16 + l16;
#pragma unroll
            for (int r = 0; r < 4; ++r) {
                const int row = m0 + wr * 64 + i * 16 + quad * 4 + r;
                C[(size_t)row * N + col] = acc[i][j][r];
            }
        }
}

// ---------------------------------------------------------------------------
// g / beta kernel (unchanged)
// ---------------------------------------------------------------------------
__global__ __launch_bounds__(256) void gbeta_k(const float* __restrict__ x,
                                               const float* __restrict__ Wa,
                                               const float* __restrict__ Wb,
                                               const float* __restrict__ A_log,
                                               const float* __restrict__ dt_bias,
                                               float* __restrict__ g,
                                               float* __restrict__ beta) {
    __shared__ __align__(16) float xs[DD];
    const int row = blockIdx.x;
    const int tid = threadIdx.x;

    *(float4*)&xs[tid * 4] = *(const float4*)&x[(size_t)row * DD + tid * 4];
    __syncthreads();

    const int out = tid >> 3;
    const int part = tid & 7;
    const int h = out & 15;
    const float* W = (out < 16) ? Wa : Wb;

    float s = 0.0f;
#pragma unroll 4
    for (int i = 0; i < 128; ++i) {
        int ie = (i + out * 16) & 127;
        int d = part * 128 + ie;
        s += xs[d] * W[(size_t)d * HH + h];
    }
    s += __shfl_down(s, 4);
    s += __shfl_down(s, 2);
    s += __shfl_down(s, 1);

    if (part == 0) {
        if (out < 16) {
            float v = s + dt_bias[h];
            float sp = (v > 20.0f) ? v : log1pf(expf(v));
            g[(size_t)row * HH + h] = -expf(A_log[h]) * sp;
        } else {
            beta[(size_t)row * HH + h] = sigmoidf_(s);
        }
    }
}

// ---------------------------------------------------------------------------
// Phase A1: stage normalized q,k (conv+silu+l2norm) and cumsum(g). (unchanged)
// ---------------------------------------------------------------------------
__global__ __launch_bounds__(64) void stage_k(const float* __restrict__ q_pre,
                                              const float* __restrict__ k_pre,
                                              const float* __restrict__ cq,
                                              const float* __restrict__ ck,
                                              const float* __restrict__ g,
                                              float* __restrict__ Qc,
                                              float* __restrict__ Kc,
                                              float* __restrict__ bcum) {
    const int blk = blockIdx.x;
    const int bh = blk >> 5;
    const int c = blk & 31;
    const int b = bh >> 4;
    const int h = bh & 15;
    const int lane = threadIdx.x;
    const int ch = h * DK + lane;

    const float4 wq4 = *(const float4*)&cq[ch * 4];
    const float4 wk4 = *(const float4*)&ck[ch * 4];

    float qw0 = 0, qw1 = 0, qw2 = 0, kw0 = 0, kw1 = 0, kw2 = 0;
    {
        const int t0 = c * CL;
        if (t0 - 3 >= 0) { size_t bi = ((size_t)b * TT + t0 - 3) * HD + ch; qw0 = q_pre[bi]; kw0 = k_pre[bi]; }
        if (t0 - 2 >= 0) { size_t bi = ((size_t)b * TT + t0 - 2) * HD + ch; qw1 = q_pre[bi]; kw1 = k_pre[bi]; }
        if (t0 - 1 >= 0) { size_t bi = ((size_t)b * TT + t0 - 1) * HD + ch; qw2 = q_pre[bi]; kw2 = k_pre[bi]; }
    }
    float* Qo = Qc + (size_t)blk * 4096;
    float* Ko = Kc + (size_t)blk * 4096;

    for (int tt = 0; tt < CL; ++tt) {
        const int t = c * CL + tt;
        const size_t bi = ((size_t)b * TT + t) * HD + ch;
        const float qc_ = q_pre[bi];
        const float kc_ = k_pre[bi];
        float qa = qw0 * wq4.x + qw1 * wq4.y + qw2 * wq4.z + qc_ * wq4.w;
        float ka = kw0 * wk4.x + kw1 * wk4.y + kw2 * wk4.z + kc_ * wk4.w;
        qw0 = qw1; qw1 = qw2; qw2 = qc_;
        kw0 = kw1; kw1 = kw2; kw2 = kc_;
        qa = siluf_(qa);
        ka = siluf_(ka);
        float qs2 = qa * qa, ks2 = ka * ka;
#pragma unroll
        for (int s = 32; s > 0; s >>= 1) {
            qs2 += __shfl_xor(qs2, s);
            ks2 += __shfl_xor(ks2, s);
        }
        Qo[tt * 64 + lane] = qa * rsqrtf(qs2 + 1e-6f) * 0.125f;
        Ko[tt * 64 + lane] = ka * rsqrtf(ks2 + 1e-6f);
    }

    float cum = g[((size_t)b * TT + c * CL + lane) * HH + h];
#pragma unroll
    for (int s = 1; s < 64; s <<= 1) {
        float u = __shfl_up(cum, s);
        if (lane >= s) cum += u;
    }
    bcum[(size_t)blk * 64 + lane] = cum;
}

// ---------------------------------------------------------------------------
// Phase A2 (unchanged this round; round-3 target)
// ---------------------------------------------------------------------------
__global__ __launch_bounds__(256) void prep_k(const float* __restrict__ Kc,
                                              const float* __restrict__ v_pre,
                                              const float* __restrict__ cv,
                                              const float* __restrict__ bcum,
                                              const float* __restrict__ bbuf,
                                              float* __restrict__ Wv,
                                              float* __restrict__ Wk) {
    __shared__ __align__(16) float k_s[CL * PAD];
    __shared__ __align__(16) float wv_s[CL * PAD];
    __shared__ __align__(16) float wk_s[CL * PAD];
    __shared__ __align__(16) float A_s[CL * PAD];
    __shared__ float b_s[CL], beta_s[CL], bk_s[CL];

    const int blk = blockIdx.x;
    const int bh = blk >> 5;
    const int c = blk & 31;
    const int b = bh >> 4;
    const int h = bh & 15;
    const int tid = threadIdx.x;

    if (tid < 64) {
        float bv = bcum[(size_t)blk * 64 + tid];
        float be = bbuf[((size_t)b * TT + c * CL + tid) * HH + h];
        b_s[tid] = bv;
        beta_s[tid] = be;
        bk_s[tid] = be * __expf(bv);
    }
    __syncthreads();

    const float4* Kg = (const float4*)(Kc + (size_t)blk * 4096);
#pragma unroll
    for (int i = 0; i < 4; ++i) {
        int f = tid + i * 256;
        int t = f >> 4;
        int d = t * PAD + (f & 15) * 4;
        float4 kv = Kg[f];
        *(float4*)&k_s[d] = kv;
        float sk = bk_s[t];
        *(float4*)&wk_s[d] = make_float4(kv.x * sk, kv.y * sk, kv.z * sk, kv.w * sk);
    }

    {
        const int lane = tid & 63;
        const int q4 = tid >> 6;
        const int ch = h * DK + lane;
        const float4 wv4 = *(const float4*)&cv[ch * 4];
        const int T0 = c * CL + q4 * 16;
        float w0 = 0, w1 = 0, w2 = 0;
        if (T0 - 3 >= 0) w0 = v_pre[((size_t)b * TT + T0 - 3) * HD + ch];
        if (T0 - 2 >= 0) w1 = v_pre[((size_t)b * TT + T0 - 2) * HD + ch];
        if (T0 - 1 >= 0) w2 = v_pre[((size_t)b * TT + T0 - 1) * HD + ch];
#pragma unroll 1
        for (int i = 0; i < 16; ++i) {
            const int t = T0 + i;
            const float vc_ = v_pre[((size_t)b * TT + t) * HD + ch];
            float va = w0 * wv4.x + w1 * wv4.y + w2 * wv4.z + vc_ * wv4.w;
            w0 = w1; w1 = w2; w2 = vc_;
            va = siluf_(va);
            wv_s[(q4 * 16 + i) * PAD + lane] = va * beta_s[q4 * 16 + i];
        }
    }
    __syncthreads();

    {
        const int t0 = (tid >> 4) * 4, s0 = (tid & 15) * 4;
        float acc[4][4] = {};
        for (int kk = 0; kk < 64; kk += 4) {
            float ta[4][4], sb[4][4];
#pragma unroll
            for (int i = 0; i < 4; ++i) f4a(*(const float4*)&k_s[(t0 + i) * PAD + kk], ta[i]);
#pragma unroll
            for (int j = 0; j < 4; ++j) f4a(*(const float4*)&k_s[(s0 + j) * PAD + kk], sb[j]);
#pragma unroll
            for (int i = 0; i < 4; ++i)
#pragma unroll
                for (int j = 0; j < 4; ++j)
#pragma unroll
                    for (int m = 0; m < 4; ++m) acc[i][j] += ta[i][m] * sb[j][m];
        }
#pragma unroll
        for (int i = 0; i < 4; ++i)
#pragma unroll
            for (int j = 0; j < 4; ++j) {
                const int t = t0 + i, s = s0 + j;
                A_s[t * PAD + s] = (s < t) ? acc[i][j] * beta_s[t] * __expf(b_s[t] - b_s[s]) : 0.0f;
            }
    }
    __syncthreads();

    {
        const int wv = tid >> 6;
        const int lane = tid & 63;
        if (wv < 2) {
            float* W = (wv == 0) ? wv_s : wk_s;
#pragma unroll 1
            for (int t = 1; t < 64; ++t) {
                float w = W[t * PAD + lane];
#pragma unroll 1
                for (int s = 0; s < t; ++s) w -= A_s[t * PAD + s] * W[s * PAD + lane];
                W[t * PAD + lane] = w;
            }
        }
    }
    __syncthreads();

    float4* Wvg = (float4*)(Wv + (size_t)blk * 4096);
    float4* Wkg = (float4*)(Wk + (size_t)blk * 4096);
#pragma unroll
    for (int i = 0; i < 4; ++i) {
        int f = tid + i * 256;
        int d = (f >> 4) * PAD + (f & 15) * 4;
        Wvg[f] = *(float4*)&wv_s[d];
        Wkg[f] = *(float4*)&wk_s[d];
    }
}

// ---------------------------------------------------------------------------
// Phase B: sequential chunk recurrence (unchanged)
// ---------------------------------------------------------------------------
__global__ __launch_bounds__(256) void state_k(const float* __restrict__ Kc,
                                               float* __restrict__ Wio,
                                               const float* __restrict__ Wk,
                                               const float* __restrict__ bcum,
                                               float* __restrict__ Hst) {
    __shared__ __align__(16) float h_s[CL * PAD];
    __shared__ __align__(16) float w_s[CL * PAD];
    __shared__ __align__(16) float x_s[CL * PAD];
    __shared__ float e_s[CL];

    const int bh = blockIdx.x;
    const int tid = threadIdx.x;
    const int r0 = (tid >> 4) * 4;
    const int v0 = (tid & 15) * 4;

#pragma unroll
    for (int i = 0; i < 4; ++i) {
        int f = tid + i * 256;
        int d = (f >> 4) * PAD + (f & 15) * 4;
        *(float4*)&h_s[d] = make_float4(0, 0, 0, 0);
    }
    __syncthreads();

    for (int c = 0; c < NC; ++c) {
        const size_t blk = (size_t)bh * NC + c;
        float4* Hg = (float4*)(Hst + blk * 4096);
        const float4* Wkg = (const float4*)(Wk + blk * 4096);
#pragma unroll
        for (int i = 0; i < 4; ++i) {
            int f = tid + i * 256;
            int d = (f >> 4) * PAD + (f & 15) * 4;
            Hg[f] = *(float4*)&h_s[d];
            *(float4*)&x_s[d] = Wkg[f];
        }
        const float bC = bcum[blk * 64 + 63];
        if (tid < 64) e_s[tid] = __expf(bC - bcum[blk * 64 + tid]);
        __syncthreads();

        float acc[4][4];
        {
            const float4* Wvg = (const float4*)(Wio + blk * 4096);
#pragma unroll
            for (int i = 0; i < 4; ++i) f4a(Wvg[(r0 + i) * 16 + (v0 >> 2)], acc[i]);
            for (int kk = 0; kk < 64; kk += 4) {
                float a[4][4], hb[4][4];
#pragma unroll
                for (int i = 0; i < 4; ++i) f4a(*(const float4*)&x_s[(r0 + i) * PAD + kk], a[i]);
#pragma unroll
                for (int m = 0; m < 4; ++m) f4a(*(const float4*)&h_s[(kk + m) * PAD + v0], hb[m]);
#pragma unroll
                for (int i = 0; i < 4; ++i)
#pragma unroll
                    for (int m = 0; m < 4; ++m)
#pragma unroll
                        for (int j = 0; j < 4; ++j) acc[i][j] -= a[i][m] * hb[m][j];
            }
        }
        __syncthreads();
        {
            float4* Wg = (float4*)(Wio + blk * 4096);
            const float4* Kg = (const float4*)(Kc + blk * 4096);
#pragma unroll
            for (int i = 0; i < 4; ++i) {
                float4 r = make_float4(acc[i][0], acc[i][1], acc[i][2], acc[i][3]);
                *(float4*)&w_s[(r0 + i) * PAD + v0] = r;
                Wg[(r0 + i) * 16 + (v0 >> 2)] = r;
            }
#pragma unroll
            for (int i = 0; i < 4; ++i) {
                int f = tid + i * 256;
                int d = (f >> 4) * PAD + (f & 15) * 4;
                *(float4*)&x_s[d] = Kg[f];
            }
        }
        __syncthreads();
        {
            const float eb = __expf(bC);
#pragma unroll
            for (int i = 0; i < 4; ++i)
#pragma unroll
                for (int j = 0; j < 4; ++j) acc[i][j] = eb * h_s[(r0 + i) * PAD + v0 + j];
            for (int ss = 0; ss < 64; ss += 4) {
                float kf[4][4], wb[4][4];
#pragma unroll
                for (int m = 0; m < 4; ++m) {
                    f4a(*(const float4*)&x_s[(ss + m) * PAD + r0], kf[m]);
                    f4a(*(const float4*)&w_s[(ss + m) * PAD + v0], wb[m]);
                    const float e = e_s[ss + m];
#pragma unroll
                    for (int i = 0; i < 4; ++i) kf[m][i] *= e;
                }
#pragma unroll
                for (int i = 0; i < 4; ++i)
#pragma unroll
                    for (int m = 0; m < 4; ++m)
#pragma unroll
                        for (int j = 0; j < 4; ++j) acc[i][j] += kf[m][i] * wb[m][j];
            }
        }
        __syncthreads();
#pragma unroll
        for (int i = 0; i < 4; ++i)
            *(float4*)&h_s[(r0 + i) * PAD + v0] =
                make_float4(acc[i][0], acc[i][1], acc[i][2], acc[i][3]);
        __syncthreads();
    }
}

// ---------------------------------------------------------------------------
// Phase C: per (bh,chunk) outputs (unchanged)
// ---------------------------------------------------------------------------
__global__ __launch_bounds__(256) void out_k(const float* __restrict__ Qc,
                                             const float* __restrict__ Kc,
                                             const float* __restrict__ Wb_,
                                             const float* __restrict__ Hst,
                                             const float* __restrict__ bcum,
                                             float* __restrict__ o_scan) {
    __shared__ __align__(16) float q_s[4096];
    __shared__ __align__(16) float k_s[4096];
    __shared__ __align__(16) float h_s[4096];
    __shared__ __align__(16) float w_s[4096];
    __shared__ float b_s[64];

    const int blk = blockIdx.x;
    const int bh = blk >> 5;
    const int c = blk & 31;
    const int b = bh >> 4;
    const int h = bh & 15;
    const int tid = threadIdx.x;

    if (tid < 64) b_s[tid] = bcum[(size_t)blk * 64 + tid];
    {
        const float4* Qg = (const float4*)(Qc + (size_t)blk * 4096);
        const float4* Kg = (const float4*)(Kc + (size_t)blk * 4096);
        const float4* Hg = (const float4*)(Hst + (size_t)blk * 4096);
        const float4* Wg = (const float4*)(Wb_ + (size_t)blk * 4096);
#pragma unroll
        for (int i = 0; i < 4; ++i) {
            int f = tid + i * 256;
            ((float4*)q_s)[f] = Qg[f];
            ((float4*)k_s)[f] = Kg[f];
            ((float4*)h_s)[f] = Hg[f];
            ((float4*)w_s)[f] = Wg[f];
        }
    }
    __syncthreads();

    {
        const int t0 = (tid >> 4) * 4, s0 = (tid & 15) * 4;
        float acc[4][4] = {};
        for (int kk = 0; kk < 64; kk += 4) {
            float qa[4][4], kb[4][4];
#pragma unroll
            for (int i = 0; i < 4; ++i) f4a(*(const float4*)&q_s[(t0 + i) * 64 + kk], qa[i]);
#pragma unroll
            for (int j = 0; j < 4; ++j) f4a(*(const float4*)&k_s[(s0 + j) * 64 + kk], kb[j]);
#pragma unroll
            for (int i = 0; i < 4; ++i)
#pragma unroll
                for (int j = 0; j < 4; ++j)
#pragma unroll
                    for (int m = 0; m < 4; ++m) acc[i][j] += qa[i][m] * kb[j][m];
        }
        __syncthreads();
#pragma unroll
        for (int i = 0; i < 4; ++i)
#pragma unroll
            for (int j = 0; j < 4; ++j) {
                const int t = t0 + i, s = s0 + j;
                k_s[t * 64 + s] = (s <= t) ? acc[i][j] * __expf(b_s[t] - b_s[s]) : 0.0f;
            }
    }
#pragma unroll
    for (int i = 0; i < 16; ++i) {
        int e = tid + i * 256;
        q_s[e] *= __expf(b_s[e >> 6]);
    }
    __syncthreads();

    {
        const int t0 = (tid >> 4) * 4, v0 = (tid & 15) * 4;
        float acc[4][4] = {};
        for (int ss = 0; ss < 64; ss += 4) {
            float sa[4][4], wb[4][4];
#pragma unroll
            for (int i = 0; i < 4; ++i) f4a(*(const float4*)&k_s[(t0 + i) * 64 + ss], sa[i]);
#pragma unroll
            for (int m = 0; m < 4; ++m) f4a(*(const float4*)&w_s[(ss + m) * 64 + v0], wb[m]);
#pragma unroll
            for (int i = 0; i < 4; ++i)
#pragma unroll
                for (int m = 0; m < 4; ++m)
#pragma unroll
                    for (int j = 0; j < 4; ++j) acc[i][j] += sa[i][m] * wb[m][j];
        }
        for (int kk = 0; kk < 64; kk += 4) {
            float qa[4][4], hb[4][4];
#pragma unroll
            for (int i = 0; i < 4; ++i) f4a(*(const float4*)&q_s[(t0 + i) * 64 + kk], qa[i]);
#pragma unroll
            for (int m = 0; m < 4; ++m) f4a(*(const float4*)&h_s[(kk + m) * 64 + v0], hb[m]);
#pragma unroll
            for (int i = 0; i < 4; ++i)
#pragma unroll
                for (int m = 0; m < 4; ++m)
#pragma unroll
                    for (int j = 0; j < 4; ++j) acc[i][j] += qa[i][m] * hb[m][j];
        }
#pragma unroll
        for (int i = 0; i < 4; ++i) {
            const int t = c * CL + t0 + i;
            *(float4*)&o_scan[(((size_t)b * TT + t) * HH + h) * DK + v0] =
                make_float4(acc[i][0], acc[i][1], acc[i][2], acc[i][3]);
        }
    }
}

// ---------------------------------------------------------------------------
// Gated RMSNorm -> bf16 output (feeds final MFMA GEMM)
// ---------------------------------------------------------------------------
__global__ __launch_bounds__(256) void gnorm_k(const float* __restrict__ o_scan,
                                               const float* __restrict__ gate,
                                               const float* __restrict__ rms_w,
                                               unsigned short* __restrict__ o2) {
    const int tid = threadIdx.x;
    const int grp = tid >> 6;
    const int lane = tid & 63;
    const int bth = blockIdx.x * 4 + grp;
    const int h = bth & 15;
    const int row = bth >> 4;

    float ov = o_scan[(size_t)bth * DK + lane];
    float s = ov * ov;
#pragma unroll
    for (int sh = 32; sh > 0; sh >>= 1) s += __shfl_xor(s, sh);
    float r = rsqrtf(s * (1.0f / 64.0f) + 1e-5f);

    float gt = gate[(size_t)row * HD + h * DK + lane];
    o2[(size_t)row * HD + h * DK + lane] = f2bf(ov * r * rms_w[lane] * siluf_(gt));
}

// ---------------------------------------------------------------------------
extern "C" void kernel_launch(void* const* d_in, const int* in_sizes, int n_in,
                              void* d_out, int out_size, void* d_ws, size_t ws_size,
                              hipStream_t stream) {
    (void)in_sizes; (void)n_in; (void)out_size; (void)ws_size;

    const float* x       = (const float*)d_in[0];
    const float* Wq      = (const float*)d_in[1];
    const float* Wk_     = (const float*)d_in[2];
    const float* Wv_     = (const float*)d_in[3];
    const float* Wa      = (const float*)d_in[4];
    const float* Wb      = (const float*)d_in[5];
    const float* Wg      = (const float*)d_in[6];
    const float* Wo      = (const float*)d_in[7];
    const float* conv_q  = (const float*)d_in[8];
    const float* conv_k  = (const float*)d_in[9];
    const float* conv_v  = (const float*)d_in[10];
    const float* A_log   = (const float*)d_in[11];
    const float* dt_bias = (const float*)d_in[12];
    const float* rms_w   = (const float*)d_in[13];
    float* out = (float*)d_out;

    float* ws = (float*)d_ws;
    const size_t NTOK = (size_t)BB * TT;     // 4096
    const size_t BIG = NTOK * HD;            // 4 Mi floats

    float* q_pre = ws + 0 * BIG;
    float* k_pre = ws + 1 * BIG;
    float* v_pre = ws + 2 * BIG;
    float* gatep = ws + 3 * BIG;
    float* Qc    = ws + 4 * BIG;
    float* Kc    = ws + 5 * BIG;
    float* gbuf  = ws + 6 * BIG;
    float* bbuf  = gbuf + NTOK * HH;
    float* bcumb = bbuf + NTOK * HH;

    // bf16 buffers after the fp32 region
    unsigned short* xb  = (unsigned short*)(bcumb + NTOK * CL);  // bcumb is NTOK*16.. conservative: place after largest small
    // NOTE: bcumb holds NTOK/CL*... actually BB*HH*NC*64 = 65536 floats = NTOK*HH
    xb = (unsigned short*)(bcumb + NTOK * HH);
    unsigned short* wqt = xb + (size_t)NTOK * DD;        // 4Mi ushort = 8 MB
    unsigned short* wkt = wqt + (size_t)DD * HD;
    unsigned short* wvt = wkt + (size_t)DD * HD;
    unsigned short* wgt = wvt + (size_t)DD * HD;
    unsigned short* wot = wgt + (size_t)DD * HD;

    // aliases (stream-ordered lifetimes):
    float* Wvb    = q_pre;
    float* Wkb    = k_pre;
    float* Hst    = v_pre;
    float* o_scan = k_pre;
    unsigned short* o2b = (unsigned short*)Qc;  // gnorm writes after out_k's last Qc read

    // casts
    castx_k<<<(int)(NTOK * DD / (256 * 8)), 256, 0, stream>>>(x, xb);
    dim3 tg(16, 16);
    castw_k<<<tg, 256, 0, stream>>>(Wq, wqt);
    castw_k<<<tg, 256, 0, stream>>>(Wk_, wkt);
    castw_k<<<tg, 256, 0, stream>>>(Wv_, wvt);
    castw_k<<<tg, 256, 0, stream>>>(Wg, wgt);
    castw_k<<<tg, 256, 0, stream>>>(Wo, wot);

    // projections: [4096,1024] = xb @ Wt^T
    dim3 gg(HD / 128, NTOK / 128);   // (8, 32)
    gemm_bf16_k<<<gg, 256, 0, stream>>>(xb, wqt, q_pre, (int)NTOK, HD, DD);
    gemm_bf16_k<<<gg, 256, 0, stream>>>(xb, wkt, k_pre, (int)NTOK, HD, DD);
    gemm_bf16_k<<<gg, 256, 0, stream>>>(xb, wvt, v_pre, (int)NTOK, HD, DD);
    gemm_bf16_k<<<gg, 256, 0, stream>>>(xb, wgt, gatep, (int)NTOK, HD, DD);

    gbeta_k<<<(int)NTOK, 256, 0, stream>>>(x, Wa, Wb, A_log, dt_bias, gbuf, bbuf);

    stage_k<<<BB * HH * NC, 64, 0, stream>>>(q_pre, k_pre, conv_q, conv_k, gbuf,
                                             Qc, Kc, bcumb);

    prep_k<<<BB * HH * NC, 256, 0, stream>>>(Kc, v_pre, conv_v, bcumb, bbuf, Wvb, Wkb);

    state_k<<<BB * HH, 256, 0, stream>>>(Kc, Wvb, Wkb, bcumb, Hst);

    out_k<<<BB * HH * NC, 256, 0, stream>>>(Qc, Kc, Wvb, Hst, bcumb, o_scan);

    gnorm_k<<<(int)(NTOK * HH / 4), 256, 0, stream>>>(o_scan, gatep, rms_w, o2b);

    gemm_bf16_k<<<gg, 256, 0, stream>>>(o2b, wot, out, (int)NTOK, HD, DD);
}

// Round 4
// 1136.118 us; speedup vs baseline: 5.6667x; 1.2568x over previous
//
#include <hip/hip_runtime.h>
#include <hip/hip_bf16.h>
#include <math.h>
#include <stdint.h>

// Problem constants
#define BB 2
#define TT 2048
#define DD 1024
#define HH 16
#define DK 64
#define HD 1024   // H*DK
#define NC 32     // chunks per sequence (TT/64)
#define CL 64     // chunk length
#define PAD 68    // padded LDS row stride (floats) to break stride-64 bank conflicts

typedef short bf16x8 __attribute__((ext_vector_type(8)));     // 8 bf16 (4 VGPRs)
typedef float f32x4 __attribute__((ext_vector_type(4)));      // MFMA acc
typedef unsigned short u16x8 __attribute__((ext_vector_type(8)));
typedef unsigned short u16x4 __attribute__((ext_vector_type(4)));

#define GAS __attribute__((address_space(1)))
#define LAS __attribute__((address_space(3)))

__device__ __forceinline__ float sigmoidf_(float x) { return 1.0f / (1.0f + expf(-x)); }
__device__ __forceinline__ float siluf_(float x) { return x * sigmoidf_(x); }
__device__ __forceinline__ void f4a(const float4 v, float* o) { o[0]=v.x; o[1]=v.y; o[2]=v.z; o[3]=v.w; }

// round-to-nearest-even fp32 -> bf16
__device__ __forceinline__ unsigned short f2bf(float f) {
    unsigned int u = __builtin_bit_cast(unsigned int, f);
    u = (u + 0x7fffu + ((u >> 16) & 1u)) >> 16;
    return (unsigned short)u;
}

// ---------------------------------------------------------------------------
// Cast x (fp32) -> bf16, flat.
// ---------------------------------------------------------------------------
__global__ __launch_bounds__(256) void castx_k(const float* __restrict__ src,
                                               unsigned short* __restrict__ dst) {
    const size_t idx = (size_t)blockIdx.x * 256 + threadIdx.x;
    float4 a = *(const float4*)&src[idx * 8];
    float4 b = *(const float4*)&src[idx * 8 + 4];
    u16x8 o;
    o[0] = f2bf(a.x); o[1] = f2bf(a.y); o[2] = f2bf(a.z); o[3] = f2bf(a.w);
    o[4] = f2bf(b.x); o[5] = f2bf(b.y); o[6] = f2bf(b.z); o[7] = f2bf(b.w);
    *(u16x8*)&dst[idx * 8] = o;
}

// ---------------------------------------------------------------------------
// Transpose+cast weight: W[K=1024][N=1024] fp32 -> Wt[N][K] bf16.
// ---------------------------------------------------------------------------
__global__ __launch_bounds__(256) void castw_k(const float* __restrict__ W,
                                               unsigned short* __restrict__ Wt) {
    __shared__ float t_s[64][65];
    const int tid = threadIdx.x;
    const int rr = tid >> 4;
    const int cc = tid & 15;
    const int r0 = blockIdx.y * 64;
    const int c0 = blockIdx.x * 64;
#pragma unroll
    for (int i = 0; i < 4; ++i) {
        const int row = rr + i * 16;
        float4 v = *(const float4*)&W[(size_t)(r0 + row) * 1024 + c0 + cc * 4];
        t_s[row][cc * 4 + 0] = v.x;
        t_s[row][cc * 4 + 1] = v.y;
        t_s[row][cc * 4 + 2] = v.z;
        t_s[row][cc * 4 + 3] = v.w;
    }
    __syncthreads();
#pragma unroll
    for (int i = 0; i < 4; ++i) {
        const int nr = rr + i * 16;
        u16x4 o;
#pragma unroll
        for (int d = 0; d < 4; ++d) o[d] = f2bf(t_s[cc * 4 + d][nr]);
        *(u16x4*)&Wt[(size_t)(c0 + nr) * 1024 + r0 + cc * 4] = o;
    }
}

// ---------------------------------------------------------------------------
// bf16 MFMA GEMM (m97 structure), unchanged from R2.
// ---------------------------------------------------------------------------
__global__ __launch_bounds__(256) void gemm_bf16_k(const unsigned short* __restrict__ A,
                                                   const unsigned short* __restrict__ Bt,
                                                   float* __restrict__ C,
                                                   int M, int N, int Kd) {
    __shared__ unsigned short a_s[128 * 32];
    __shared__ unsigned short b_s[128 * 32];

    const int tid = threadIdx.x;
    const int wave = tid >> 6;
    const int lane = tid & 63;
    const int m0 = blockIdx.y * 128;
    const int n0 = blockIdx.x * 128;

    const int quad = lane >> 4;
    const int l16 = lane & 15;
    const int wr = wave >> 1;
    const int wc = wave & 1;

    const int srow = lane >> 2;
    const int sseg = lane & 3;

    f32x4 acc[4][4];
#pragma unroll
    for (int i = 0; i < 4; ++i)
#pragma unroll
        for (int j = 0; j < 4; ++j) acc[i][j] = (f32x4){0.f, 0.f, 0.f, 0.f};

    for (int k0 = 0; k0 < Kd; k0 += 32) {
        __syncthreads();
#pragma unroll
        for (int c = 0; c < 2; ++c) {
            const int region = wave * 2 + c;
            const int r0t = region * 16;
            const int ra = r0t + srow;
            const unsigned short* ga = A + (size_t)(m0 + ra) * Kd + k0 + sseg * 8;
            const unsigned short* gb = Bt + (size_t)(n0 + ra) * Kd + k0 + sseg * 8;
            __builtin_amdgcn_global_load_lds((const GAS unsigned int*)ga,
                                             (LAS unsigned int*)&a_s[r0t * 32], 16, 0, 0);
            __builtin_amdgcn_global_load_lds((const GAS unsigned int*)gb,
                                             (LAS unsigned int*)&b_s[r0t * 32], 16, 0, 0);
        }
        __syncthreads();

        bf16x8 af[4], bfr[4];
#pragma unroll
        for (int i = 0; i < 4; ++i)
            af[i] = *(const bf16x8*)&a_s[(wr * 64 + i * 16 + l16) * 32 + quad * 8];
#pragma unroll
        for (int j = 0; j < 4; ++j)
            bfr[j] = *(const bf16x8*)&b_s[(wc * 64 + j * 16 + l16) * 32 + quad * 8];
#pragma unroll
        for (int i = 0; i < 4; ++i)
#pragma unroll
            for (int j = 0; j < 4; ++j)
                acc[i][j] = __builtin_amdgcn_mfma_f32_16x16x32_bf16(af[i], bfr[j], acc[i][j], 0, 0, 0);
    }

#pragma unroll
    for (int i = 0; i < 4; ++i)
#pragma unroll
        for (int j = 0; j < 4; ++j) {
            const int col = n0 + wc * 64 + j * 16 + l16;
#pragma unroll
            for (int r = 0; r < 4; ++r) {
                const int row = m0 + wr * 64 + i * 16 + quad * 4 + r;
                C[(size_t)row * N + col] = acc[i][j][r];
            }
        }
}

// ---------------------------------------------------------------------------
// g / beta kernel (unchanged)
// ---------------------------------------------------------------------------
__global__ __launch_bounds__(256) void gbeta_k(const float* __restrict__ x,
                                               const float* __restrict__ Wa,
                                               const float* __restrict__ Wb,
                                               const float* __restrict__ A_log,
                                               const float* __restrict__ dt_bias,
                                               float* __restrict__ g,
                                               float* __restrict__ beta) {
    __shared__ __align__(16) float xs[DD];
    const int row = blockIdx.x;
    const int tid = threadIdx.x;

    *(float4*)&xs[tid * 4] = *(const float4*)&x[(size_t)row * DD + tid * 4];
    __syncthreads();

    const int out = tid >> 3;
    const int part = tid & 7;
    const int h = out & 15;
    const float* W = (out < 16) ? Wa : Wb;

    float s = 0.0f;
#pragma unroll 4
    for (int i = 0; i < 128; ++i) {
        int ie = (i + out * 16) & 127;
        int d = part * 128 + ie;
        s += xs[d] * W[(size_t)d * HH + h];
    }
    s += __shfl_down(s, 4);
    s += __shfl_down(s, 2);
    s += __shfl_down(s, 1);

    if (part == 0) {
        if (out < 16) {
            float v = s + dt_bias[h];
            float sp = (v > 20.0f) ? v : log1pf(expf(v));
            g[(size_t)row * HH + h] = -expf(A_log[h]) * sp;
        } else {
            beta[(size_t)row * HH + h] = sigmoidf_(s);
        }
    }
}

// ---------------------------------------------------------------------------
// Phase A1: stage normalized q,k (conv+silu+l2norm) and cumsum(g). (unchanged)
// ---------------------------------------------------------------------------
__global__ __launch_bounds__(64) void stage_k(const float* __restrict__ q_pre,
                                              const float* __restrict__ k_pre,
                                              const float* __restrict__ cq,
                                              const float* __restrict__ ck,
                                              const float* __restrict__ g,
                                              float* __restrict__ Qc,
                                              float* __restrict__ Kc,
                                              float* __restrict__ bcum) {
    const int blk = blockIdx.x;
    const int bh = blk >> 5;
    const int c = blk & 31;
    const int b = bh >> 4;
    const int h = bh & 15;
    const int lane = threadIdx.x;
    const int ch = h * DK + lane;

    const float4 wq4 = *(const float4*)&cq[ch * 4];
    const float4 wk4 = *(const float4*)&ck[ch * 4];

    float qw0 = 0, qw1 = 0, qw2 = 0, kw0 = 0, kw1 = 0, kw2 = 0;
    {
        const int t0 = c * CL;
        if (t0 - 3 >= 0) { size_t bi = ((size_t)b * TT + t0 - 3) * HD + ch; qw0 = q_pre[bi]; kw0 = k_pre[bi]; }
        if (t0 - 2 >= 0) { size_t bi = ((size_t)b * TT + t0 - 2) * HD + ch; qw1 = q_pre[bi]; kw1 = k_pre[bi]; }
        if (t0 - 1 >= 0) { size_t bi = ((size_t)b * TT + t0 - 1) * HD + ch; qw2 = q_pre[bi]; kw2 = k_pre[bi]; }
    }
    float* Qo = Qc + (size_t)blk * 4096;
    float* Ko = Kc + (size_t)blk * 4096;

    for (int tt = 0; tt < CL; ++tt) {
        const int t = c * CL + tt;
        const size_t bi = ((size_t)b * TT + t) * HD + ch;
        const float qc_ = q_pre[bi];
        const float kc_ = k_pre[bi];
        float qa = qw0 * wq4.x + qw1 * wq4.y + qw2 * wq4.z + qc_ * wq4.w;
        float ka = kw0 * wk4.x + kw1 * wk4.y + kw2 * wk4.z + kc_ * wk4.w;
        qw0 = qw1; qw1 = qw2; qw2 = qc_;
        kw0 = kw1; kw1 = kw2; kw2 = kc_;
        qa = siluf_(qa);
        ka = siluf_(ka);
        float qs2 = qa * qa, ks2 = ka * ka;
#pragma unroll
        for (int s = 32; s > 0; s >>= 1) {
            qs2 += __shfl_xor(qs2, s);
            ks2 += __shfl_xor(ks2, s);
        }
        Qo[tt * 64 + lane] = qa * rsqrtf(qs2 + 1e-6f) * 0.125f;
        Ko[tt * 64 + lane] = ka * rsqrtf(ks2 + 1e-6f);
    }

    float cum = g[((size_t)b * TT + c * CL + lane) * HH + h];
#pragma unroll
    for (int s = 1; s < 64; s <<= 1) {
        float u = __shfl_up(cum, s);
        if (lane >= s) cum += u;
    }
    bcum[(size_t)blk * 64 + lane] = cum;
}

// ---------------------------------------------------------------------------
// Phase A2 REWRITTEN: blocked triangular solve.
//  - A = strict-lower(beta_t e^{b_t-b_s} k_t.k_s)
//  - invert the four 16x16 unit-lower diagonal blocks in parallel (wave 0,
//    lane=(block,col), 15-step serial depth)
//  - per 16-row block: dense update R_i -= A[i,<i] @ W  (256 thr, 8 cols ea),
//    then W_i = T_i @ R_i (dense 16x16x128). Low reg pressure, no spill.
// ---------------------------------------------------------------------------
__global__ __launch_bounds__(256) void prep_k(const float* __restrict__ Kc,
                                              const float* __restrict__ v_pre,
                                              const float* __restrict__ cv,
                                              const float* __restrict__ bcum,
                                              const float* __restrict__ bbuf,
                                              float* __restrict__ Wv,
                                              float* __restrict__ Wk) {
    __shared__ __align__(16) float k_s[CL * PAD];
    __shared__ __align__(16) float wv_s[CL * PAD];
    __shared__ __align__(16) float wk_s[CL * PAD];
    __shared__ __align__(16) float A_s[CL * PAD];
    __shared__ float T_s[4][16 * 17];
    __shared__ float b_s[CL], beta_s[CL], bk_s[CL];

    const int blk = blockIdx.x;
    const int bh = blk >> 5;
    const int c = blk & 31;
    const int b = bh >> 4;
    const int h = bh & 15;
    const int tid = threadIdx.x;

    if (tid < 64) {
        float bv = bcum[(size_t)blk * 64 + tid];
        float be = bbuf[((size_t)b * TT + c * CL + tid) * HH + h];
        b_s[tid] = bv;
        beta_s[tid] = be;
        bk_s[tid] = be * __expf(bv);
    }
    __syncthreads();

    // stage K and Rk = diag(beta e^b) K
    {
        const float4* Kg = (const float4*)(Kc + (size_t)blk * 4096);
#pragma unroll
        for (int i = 0; i < 4; ++i) {
            int f = tid + i * 256;
            int t = f >> 4;
            int d = t * PAD + (f & 15) * 4;
            float4 kv = Kg[f];
            *(float4*)&k_s[d] = kv;
            float sk = bk_s[t];
            *(float4*)&wk_s[d] = make_float4(kv.x * sk, kv.y * sk, kv.z * sk, kv.w * sk);
        }
    }

    // Rv = beta * silu(conv(v))
    {
        const int lane = tid & 63;
        const int q4 = tid >> 6;
        const int ch = h * DK + lane;
        const float4 wv4 = *(const float4*)&cv[ch * 4];
        const int T0 = c * CL + q4 * 16;
        float w0 = 0, w1 = 0, w2 = 0;
        if (T0 - 3 >= 0) w0 = v_pre[((size_t)b * TT + T0 - 3) * HD + ch];
        if (T0 - 2 >= 0) w1 = v_pre[((size_t)b * TT + T0 - 2) * HD + ch];
        if (T0 - 1 >= 0) w2 = v_pre[((size_t)b * TT + T0 - 1) * HD + ch];
#pragma unroll 1
        for (int i = 0; i < 16; ++i) {
            const int t = T0 + i;
            const float vc_ = v_pre[((size_t)b * TT + t) * HD + ch];
            float va = w0 * wv4.x + w1 * wv4.y + w2 * wv4.z + vc_ * wv4.w;
            w0 = w1; w1 = w2; w2 = vc_;
            va = siluf_(va);
            wv_s[(q4 * 16 + i) * PAD + lane] = va * beta_s[q4 * 16 + i];
        }
    }
    __syncthreads();

    // A matrix (strict lower, zeros elsewhere)
    {
        const int t0 = (tid >> 4) * 4, s0 = (tid & 15) * 4;
        float acc[4][4] = {};
        for (int kk = 0; kk < 64; kk += 4) {
            float ta[4][4], sb[4][4];
#pragma unroll
            for (int i = 0; i < 4; ++i) f4a(*(const float4*)&k_s[(t0 + i) * PAD + kk], ta[i]);
#pragma unroll
            for (int j = 0; j < 4; ++j) f4a(*(const float4*)&k_s[(s0 + j) * PAD + kk], sb[j]);
#pragma unroll
            for (int i = 0; i < 4; ++i)
#pragma unroll
                for (int j = 0; j < 4; ++j)
#pragma unroll
                    for (int m = 0; m < 4; ++m) acc[i][j] += ta[i][m] * sb[j][m];
        }
#pragma unroll
        for (int i = 0; i < 4; ++i)
#pragma unroll
            for (int j = 0; j < 4; ++j) {
                const int t = t0 + i, s = s0 + j;
                A_s[t * PAD + s] = (s < t) ? acc[i][j] * beta_s[t] * __expf(b_s[t] - b_s[s]) : 0.0f;
            }
    }
    __syncthreads();

    // invert 4 diagonal 16x16 unit-lower blocks: lane = d*16 + col
    if (tid < 64) {
        const int d = tid >> 4;
        const int col = tid & 15;
        const int base = d * 16;
        float tcol[16];
#pragma unroll
        for (int s = 0; s < 16; ++s) tcol[s] = (s == col) ? 1.0f : 0.0f;
#pragma unroll
        for (int t = 1; t < 16; ++t) {
            float a = 0.0f;
#pragma unroll
            for (int s = 0; s < 16; ++s)
                if (s < t) a += A_s[(base + t) * PAD + base + s] * tcol[s];
            tcol[t] -= a;
        }
#pragma unroll
        for (int t = 0; t < 16; ++t) T_s[d][t * 17 + col] = tcol[t];
    }
    __syncthreads();

    // blocked solve over 4 row-blocks x 128 RHS columns (wv | wk)
    {
        const int r = tid >> 4;          // row within block, 0..15
        const int cg = tid & 15;         // col group
        float* Wc = (cg < 8) ? wv_s : wk_s;
        const int cc = (cg & 7) * 8;     // 8 columns per thread

        for (int tb = 0; tb < 4; ++tb) {
            const int t = tb * 16 + r;
            if (tb > 0) {
                float acc[8];
                f4a(*(const float4*)&Wc[t * PAD + cc], acc);
                f4a(*(const float4*)&Wc[t * PAD + cc + 4], acc + 4);
#pragma unroll 2
                for (int s = 0; s < tb * 16; ++s) {
                    const float a = A_s[t * PAD + s];
                    float wr[8];
                    f4a(*(const float4*)&Wc[s * PAD + cc], wr);
                    f4a(*(const float4*)&Wc[s * PAD + cc + 4], wr + 4);
#pragma unroll
                    for (int u = 0; u < 8; ++u) acc[u] -= a * wr[u];
                }
                *(float4*)&Wc[t * PAD + cc] = make_float4(acc[0], acc[1], acc[2], acc[3]);
                *(float4*)&Wc[t * PAD + cc + 4] = make_float4(acc[4], acc[5], acc[6], acc[7]);
            }
            __syncthreads();
            // W_block = T[tb] @ R_block (read phase -> regs)
            float acc2[8] = {};
#pragma unroll 4
            for (int s = 0; s < 16; ++s) {
                const float tv = T_s[tb][r * 17 + s];
                float wr[8];
                f4a(*(const float4*)&Wc[(tb * 16 + s) * PAD + cc], wr);
                f4a(*(const float4*)&Wc[(tb * 16 + s) * PAD + cc + 4], wr + 4);
#pragma unroll
                for (int u = 0; u < 8; ++u) acc2[u] += tv * wr[u];
            }
            __syncthreads();   // all reads of the block done before overwrite
            *(float4*)&Wc[t * PAD + cc] = make_float4(acc2[0], acc2[1], acc2[2], acc2[3]);
            *(float4*)&Wc[t * PAD + cc + 4] = make_float4(acc2[4], acc2[5], acc2[6], acc2[7]);
            __syncthreads();
        }
    }

    // write out
    float4* Wvg = (float4*)(Wv + (size_t)blk * 4096);
    float4* Wkg = (float4*)(Wk + (size_t)blk * 4096);
#pragma unroll
    for (int i = 0; i < 4; ++i) {
        int f = tid + i * 256;
        int d = (f >> 4) * PAD + (f & 15) * 4;
        Wvg[f] = *(float4*)&wv_s[d];
        Wkg[f] = *(float4*)&wk_s[d];
    }
}

// ---------------------------------------------------------------------------
// Phase B: sequential chunk recurrence (unchanged)
// ---------------------------------------------------------------------------
__global__ __launch_bounds__(256) void state_k(const float* __restrict__ Kc,
                                               float* __restrict__ Wio,
                                               const float* __restrict__ Wk,
                                               const float* __restrict__ bcum,
                                               float* __restrict__ Hst) {
    __shared__ __align__(16) float h_s[CL * PAD];
    __shared__ __align__(16) float w_s[CL * PAD];
    __shared__ __align__(16) float x_s[CL * PAD];
    __shared__ float e_s[CL];

    const int bh = blockIdx.x;
    const int tid = threadIdx.x;
    const int r0 = (tid >> 4) * 4;
    const int v0 = (tid & 15) * 4;

#pragma unroll
    for (int i = 0; i < 4; ++i) {
        int f = tid + i * 256;
        int d = (f >> 4) * PAD + (f & 15) * 4;
        *(float4*)&h_s[d] = make_float4(0, 0, 0, 0);
    }
    __syncthreads();

    for (int c = 0; c < NC; ++c) {
        const size_t blk = (size_t)bh * NC + c;
        float4* Hg = (float4*)(Hst + blk * 4096);
        const float4* Wkg = (const float4*)(Wk + blk * 4096);
#pragma unroll
        for (int i = 0; i < 4; ++i) {
            int f = tid + i * 256;
            int d = (f >> 4) * PAD + (f & 15) * 4;
            Hg[f] = *(float4*)&h_s[d];
            *(float4*)&x_s[d] = Wkg[f];
        }
        const float bC = bcum[blk * 64 + 63];
        if (tid < 64) e_s[tid] = __expf(bC - bcum[blk * 64 + tid]);
        __syncthreads();

        float acc[4][4];
        {
            const float4* Wvg = (const float4*)(Wio + blk * 4096);
#pragma unroll
            for (int i = 0; i < 4; ++i) f4a(Wvg[(r0 + i) * 16 + (v0 >> 2)], acc[i]);
            for (int kk = 0; kk < 64; kk += 4) {
                float a[4][4], hb[4][4];
#pragma unroll
                for (int i = 0; i < 4; ++i) f4a(*(const float4*)&x_s[(r0 + i) * PAD + kk], a[i]);
#pragma unroll
                for (int m = 0; m < 4; ++m) f4a(*(const float4*)&h_s[(kk + m) * PAD + v0], hb[m]);
#pragma unroll
                for (int i = 0; i < 4; ++i)
#pragma unroll
                    for (int m = 0; m < 4; ++m)
#pragma unroll
                        for (int j = 0; j < 4; ++j) acc[i][j] -= a[i][m] * hb[m][j];
            }
        }
        __syncthreads();
        {
            float4* Wg = (float4*)(Wio + blk * 4096);
            const float4* Kg = (const float4*)(Kc + blk * 4096);
#pragma unroll
            for (int i = 0; i < 4; ++i) {
                float4 r = make_float4(acc[i][0], acc[i][1], acc[i][2], acc[i][3]);
                *(float4*)&w_s[(r0 + i) * PAD + v0] = r;
                Wg[(r0 + i) * 16 + (v0 >> 2)] = r;
            }
#pragma unroll
            for (int i = 0; i < 4; ++i) {
                int f = tid + i * 256;
                int d = (f >> 4) * PAD + (f & 15) * 4;
                *(float4*)&x_s[d] = Kg[f];
            }
        }
        __syncthreads();
        {
            const float eb = __expf(bC);
#pragma unroll
            for (int i = 0; i < 4; ++i)
#pragma unroll
                for (int j = 0; j < 4; ++j) acc[i][j] = eb * h_s[(r0 + i) * PAD + v0 + j];
            for (int ss = 0; ss < 64; ss += 4) {
                float kf[4][4], wb[4][4];
#pragma unroll
                for (int m = 0; m < 4; ++m) {
                    f4a(*(const float4*)&x_s[(ss + m) * PAD + r0], kf[m]);
                    f4a(*(const float4*)&w_s[(ss + m) * PAD + v0], wb[m]);
                    const float e = e_s[ss + m];
#pragma unroll
                    for (int i = 0; i < 4; ++i) kf[m][i] *= e;
                }
#pragma unroll
                for (int i = 0; i < 4; ++i)
#pragma unroll
                    for (int m = 0; m < 4; ++m)
#pragma unroll
                        for (int j = 0; j < 4; ++j) acc[i][j] += kf[m][i] * wb[m][j];
            }
        }
        __syncthreads();
#pragma unroll
        for (int i = 0; i < 4; ++i)
            *(float4*)&h_s[(r0 + i) * PAD + v0] =
                make_float4(acc[i][0], acc[i][1], acc[i][2], acc[i][3]);
        __syncthreads();
    }
}

// ---------------------------------------------------------------------------
// Phase C: per (bh,chunk) outputs (unchanged)
// ---------------------------------------------------------------------------
__global__ __launch_bounds__(256) void out_k(const float* __restrict__ Qc,
                                             const float* __restrict__ Kc,
                                             const float* __restrict__ Wb_,
                                             const float* __restrict__ Hst,
                                             const float* __restrict__ bcum,
                                             float* __restrict__ o_scan) {
    __shared__ __align__(16) float q_s[4096];
    __shared__ __align__(16) float k_s[4096];
    __shared__ __align__(16) float h_s[4096];
    __shared__ __align__(16) float w_s[4096];
    __shared__ float b_s[64];

    const int blk = blockIdx.x;
    const int bh = blk >> 5;
    const int c = blk & 31;
    const int b = bh >> 4;
    const int h = bh & 15;
    const int tid = threadIdx.x;

    if (tid < 64) b_s[tid] = bcum[(size_t)blk * 64 + tid];
    {
        const float4* Qg = (const float4*)(Qc + (size_t)blk * 4096);
        const float4* Kg = (const float4*)(Kc + (size_t)blk * 4096);
        const float4* Hg = (const float4*)(Hst + (size_t)blk * 4096);
        const float4* Wg = (const float4*)(Wb_ + (size_t)blk * 4096);
#pragma unroll
        for (int i = 0; i < 4; ++i) {
            int f = tid + i * 256;
            ((float4*)q_s)[f] = Qg[f];
            ((float4*)k_s)[f] = Kg[f];
            ((float4*)h_s)[f] = Hg[f];
            ((float4*)w_s)[f] = Wg[f];
        }
    }
    __syncthreads();

    {
        const int t0 = (tid >> 4) * 4, s0 = (tid & 15) * 4;
        float acc[4][4] = {};
        for (int kk = 0; kk < 64; kk += 4) {
            float qa[4][4], kb[4][4];
#pragma unroll
            for (int i = 0; i < 4; ++i) f4a(*(const float4*)&q_s[(t0 + i) * 64 + kk], qa[i]);
#pragma unroll
            for (int j = 0; j < 4; ++j) f4a(*(const float4*)&k_s[(s0 + j) * 64 + kk], kb[j]);
#pragma unroll
            for (int i = 0; i < 4; ++i)
#pragma unroll
                for (int j = 0; j < 4; ++j)
#pragma unroll
                    for (int m = 0; m < 4; ++m) acc[i][j] += qa[i][m] * kb[j][m];
        }
        __syncthreads();
#pragma unroll
        for (int i = 0; i < 4; ++i)
#pragma unroll
            for (int j = 0; j < 4; ++j) {
                const int t = t0 + i, s = s0 + j;
                k_s[t * 64 + s] = (s <= t) ? acc[i][j] * __expf(b_s[t] - b_s[s]) : 0.0f;
            }
    }
#pragma unroll
    for (int i = 0; i < 16; ++i) {
        int e = tid + i * 256;
        q_s[e] *= __expf(b_s[e >> 6]);
    }
    __syncthreads();

    {
        const int t0 = (tid >> 4) * 4, v0 = (tid & 15) * 4;
        float acc[4][4] = {};
        for (int ss = 0; ss < 64; ss += 4) {
            float sa[4][4], wb[4][4];
#pragma unroll
            for (int i = 0; i < 4; ++i) f4a(*(const float4*)&k_s[(t0 + i) * 64 + ss], sa[i]);
#pragma unroll
            for (int m = 0; m < 4; ++m) f4a(*(const float4*)&w_s[(ss + m) * 64 + v0], wb[m]);
#pragma unroll
            for (int i = 0; i < 4; ++i)
#pragma unroll
                for (int m = 0; m < 4; ++m)
#pragma unroll
                    for (int j = 0; j < 4; ++j) acc[i][j] += sa[i][m] * wb[m][j];
        }
        for (int kk = 0; kk < 64; kk += 4) {
            float qa[4][4], hb[4][4];
#pragma unroll
            for (int i = 0; i < 4; ++i) f4a(*(const float4*)&q_s[(t0 + i) * 64 + kk], qa[i]);
#pragma unroll
            for (int m = 0; m < 4; ++m) f4a(*(const float4*)&h_s[(kk + m) * 64 + v0], hb[m]);
#pragma unroll
            for (int i = 0; i < 4; ++i)
#pragma unroll
                for (int m = 0; m < 4; ++m)
#pragma unroll
                    for (int j = 0; j < 4; ++j) acc[i][j] += qa[i][m] * hb[m][j];
        }
#pragma unroll
        for (int i = 0; i < 4; ++i) {
            const int t = c * CL + t0 + i;
            *(float4*)&o_scan[(((size_t)b * TT + t) * HH + h) * DK + v0] =
                make_float4(acc[i][0], acc[i][1], acc[i][2], acc[i][3]);
        }
    }
}

// ---------------------------------------------------------------------------
// Gated RMSNorm -> bf16 output (feeds final MFMA GEMM)
// ---------------------------------------------------------------------------
__global__ __launch_bounds__(256) void gnorm_k(const float* __restrict__ o_scan,
                                               const float* __restrict__ gate,
                                               const float* __restrict__ rms_w,
                                               unsigned short* __restrict__ o2) {
    const int tid = threadIdx.x;
    const int grp = tid >> 6;
    const int lane = tid & 63;
    const int bth = blockIdx.x * 4 + grp;
    const int h = bth & 15;
    const int row = bth >> 4;

    float ov = o_scan[(size_t)bth * DK + lane];
    float s = ov * ov;
#pragma unroll
    for (int sh = 32; sh > 0; sh >>= 1) s += __shfl_xor(s, sh);
    float r = rsqrtf(s * (1.0f / 64.0f) + 1e-5f);

    float gt = gate[(size_t)row * HD + h * DK + lane];
    o2[(size_t)row * HD + h * DK + lane] = f2bf(ov * r * rms_w[lane] * siluf_(gt));
}

// ---------------------------------------------------------------------------
extern "C" void kernel_launch(void* const* d_in, const int* in_sizes, int n_in,
                              void* d_out, int out_size, void* d_ws, size_t ws_size,
                              hipStream_t stream) {
    (void)in_sizes; (void)n_in; (void)out_size; (void)ws_size;

    const float* x       = (const float*)d_in[0];
    const float* Wq      = (const float*)d_in[1];
    const float* Wk_     = (const float*)d_in[2];
    const float* Wv_     = (const float*)d_in[3];
    const float* Wa      = (const float*)d_in[4];
    const float* Wb      = (const float*)d_in[5];
    const float* Wg      = (const float*)d_in[6];
    const float* Wo      = (const float*)d_in[7];
    const float* conv_q  = (const float*)d_in[8];
    const float* conv_k  = (const float*)d_in[9];
    const float* conv_v  = (const float*)d_in[10];
    const float* A_log   = (const float*)d_in[11];
    const float* dt_bias = (const float*)d_in[12];
    const float* rms_w   = (const float*)d_in[13];
    float* out = (float*)d_out;

    float* ws = (float*)d_ws;
    const size_t NTOK = (size_t)BB * TT;     // 4096
    const size_t BIG = NTOK * HD;            // 4 Mi floats

    float* q_pre = ws + 0 * BIG;
    float* k_pre = ws + 1 * BIG;
    float* v_pre = ws + 2 * BIG;
    float* gatep = ws + 3 * BIG;
    float* Qc    = ws + 4 * BIG;
    float* Kc    = ws + 5 * BIG;
    float* gbuf  = ws + 6 * BIG;
    float* bbuf  = gbuf + NTOK * HH;
    float* bcumb = bbuf + NTOK * HH;

    // bf16 buffers after the fp32 region (bcumb = BB*HH*NC*64 = NTOK*HH floats)
    unsigned short* xb  = (unsigned short*)(bcumb + NTOK * HH);
    unsigned short* wqt = xb + (size_t)NTOK * DD;
    unsigned short* wkt = wqt + (size_t)DD * HD;
    unsigned short* wvt = wkt + (size_t)DD * HD;
    unsigned short* wgt = wvt + (size_t)DD * HD;
    unsigned short* wot = wgt + (size_t)DD * HD;

    // aliases (stream-ordered lifetimes):
    float* Wvb    = q_pre;
    float* Wkb    = k_pre;
    float* Hst    = v_pre;
    float* o_scan = k_pre;
    unsigned short* o2b = (unsigned short*)Qc;

    // casts
    castx_k<<<(int)(NTOK * DD / (256 * 8)), 256, 0, stream>>>(x, xb);
    dim3 tg(16, 16);
    castw_k<<<tg, 256, 0, stream>>>(Wq, wqt);
    castw_k<<<tg, 256, 0, stream>>>(Wk_, wkt);
    castw_k<<<tg, 256, 0, stream>>>(Wv_, wvt);
    castw_k<<<tg, 256, 0, stream>>>(Wg, wgt);
    castw_k<<<tg, 256, 0, stream>>>(Wo, wot);

    // projections
    dim3 gg(HD / 128, NTOK / 128);   // (8, 32)
    gemm_bf16_k<<<gg, 256, 0, stream>>>(xb, wqt, q_pre, (int)NTOK, HD, DD);
    gemm_bf16_k<<<gg, 256, 0, stream>>>(xb, wkt, k_pre, (int)NTOK, HD, DD);
    gemm_bf16_k<<<gg, 256, 0, stream>>>(xb, wvt, v_pre, (int)NTOK, HD, DD);
    gemm_bf16_k<<<gg, 256, 0, stream>>>(xb, wgt, gatep, (int)NTOK, HD, DD);

    gbeta_k<<<(int)NTOK, 256, 0, stream>>>(x, Wa, Wb, A_log, dt_bias, gbuf, bbuf);

    stage_k<<<BB * HH * NC, 64, 0, stream>>>(q_pre, k_pre, conv_q, conv_k, gbuf,
                                             Qc, Kc, bcumb);

    prep_k<<<BB * HH * NC, 256, 0, stream>>>(Kc, v_pre, conv_v, bcumb, bbuf, Wvb, Wkb);

    state_k<<<BB * HH, 256, 0, stream>>>(Kc, Wvb, Wkb, bcumb, Hst);

    out_k<<<BB * HH * NC, 256, 0, stream>>>(Qc, Kc, Wvb, Hst, bcumb, o_scan);

    gnorm_k<<<(int)(NTOK * HH / 4), 256, 0, stream>>>(o_scan, gatep, rms_w, o2b);

    gemm_bf16_k<<<gg, 256, 0, stream>>>(o2b, wot, out, (int)NTOK, HD, DD);
}

// Round 5
// 944.909 us; speedup vs baseline: 6.8134x; 1.2024x over previous
//
#include <hip/hip_runtime.h>
#include <hip/hip_bf16.h>
#include <math.h>
#include <stdint.h>

// Problem constants
#define BB 2
#define TT 2048
#define DD 1024
#define HH 16
#define DK 64
#define HD 1024   // H*DK
#define NC 32     // chunks per sequence (TT/64)
#define CL 64     // chunk length
#define PAD 68    // padded LDS row stride (floats) to break stride-64 bank conflicts

typedef short bf16x8 __attribute__((ext_vector_type(8)));     // 8 bf16 (4 VGPRs)
typedef float f32x4 __attribute__((ext_vector_type(4)));      // MFMA acc
typedef unsigned short u16x8 __attribute__((ext_vector_type(8)));
typedef unsigned short u16x4 __attribute__((ext_vector_type(4)));

#define GAS __attribute__((address_space(1)))
#define LAS __attribute__((address_space(3)))

__device__ __forceinline__ float sigmoidf_(float x) { return 1.0f / (1.0f + expf(-x)); }
__device__ __forceinline__ float siluf_(float x) { return x * sigmoidf_(x); }
__device__ __forceinline__ void f4a(const float4 v, float* o) { o[0]=v.x; o[1]=v.y; o[2]=v.z; o[3]=v.w; }

// round-to-nearest-even fp32 -> bf16
__device__ __forceinline__ unsigned short f2bf(float f) {
    unsigned int u = __builtin_bit_cast(unsigned int, f);
    u = (u + 0x7fffu + ((u >> 16) & 1u)) >> 16;
    return (unsigned short)u;
}

// ---------------------------------------------------------------------------
// Cast x (fp32) -> bf16, flat.
// ---------------------------------------------------------------------------
__global__ __launch_bounds__(256) void castx_k(const float* __restrict__ src,
                                               unsigned short* __restrict__ dst) {
    const size_t idx = (size_t)blockIdx.x * 256 + threadIdx.x;
    float4 a = *(const float4*)&src[idx * 8];
    float4 b = *(const float4*)&src[idx * 8 + 4];
    u16x8 o;
    o[0] = f2bf(a.x); o[1] = f2bf(a.y); o[2] = f2bf(a.z); o[3] = f2bf(a.w);
    o[4] = f2bf(b.x); o[5] = f2bf(b.y); o[6] = f2bf(b.z); o[7] = f2bf(b.w);
    *(u16x8*)&dst[idx * 8] = o;
}

// ---------------------------------------------------------------------------
// Transpose+cast weight: W[K=1024][N=1024] fp32 -> Wt[N][K] bf16.
// ---------------------------------------------------------------------------
__global__ __launch_bounds__(256) void castw_k(const float* __restrict__ W,
                                               unsigned short* __restrict__ Wt) {
    __shared__ float t_s[64][65];
    const int tid = threadIdx.x;
    const int rr = tid >> 4;
    const int cc = tid & 15;
    const int r0 = blockIdx.y * 64;
    const int c0 = blockIdx.x * 64;
#pragma unroll
    for (int i = 0; i < 4; ++i) {
        const int row = rr + i * 16;
        float4 v = *(const float4*)&W[(size_t)(r0 + row) * 1024 + c0 + cc * 4];
        t_s[row][cc * 4 + 0] = v.x;
        t_s[row][cc * 4 + 1] = v.y;
        t_s[row][cc * 4 + 2] = v.z;
        t_s[row][cc * 4 + 3] = v.w;
    }
    __syncthreads();
#pragma unroll
    for (int i = 0; i < 4; ++i) {
        const int nr = rr + i * 16;
        u16x4 o;
#pragma unroll
        for (int d = 0; d < 4; ++d) o[d] = f2bf(t_s[cc * 4 + d][nr]);
        *(u16x4*)&Wt[(size_t)(c0 + nr) * 1024 + r0 + cc * 4] = o;
    }
}

// ---------------------------------------------------------------------------
// bf16 MFMA GEMM (m97 structure), unchanged.
// ---------------------------------------------------------------------------
__global__ __launch_bounds__(256) void gemm_bf16_k(const unsigned short* __restrict__ A,
                                                   const unsigned short* __restrict__ Bt,
                                                   float* __restrict__ C,
                                                   int M, int N, int Kd) {
    __shared__ unsigned short a_s[128 * 32];
    __shared__ unsigned short b_s[128 * 32];

    const int tid = threadIdx.x;
    const int wave = tid >> 6;
    const int lane = tid & 63;
    const int m0 = blockIdx.y * 128;
    const int n0 = blockIdx.x * 128;

    const int quad = lane >> 4;
    const int l16 = lane & 15;
    const int wr = wave >> 1;
    const int wc = wave & 1;

    const int srow = lane >> 2;
    const int sseg = lane & 3;

    f32x4 acc[4][4];
#pragma unroll
    for (int i = 0; i < 4; ++i)
#pragma unroll
        for (int j = 0; j < 4; ++j) acc[i][j] = (f32x4){0.f, 0.f, 0.f, 0.f};

    for (int k0 = 0; k0 < Kd; k0 += 32) {
        __syncthreads();
#pragma unroll
        for (int c = 0; c < 2; ++c) {
            const int region = wave * 2 + c;
            const int r0t = region * 16;
            const int ra = r0t + srow;
            const unsigned short* ga = A + (size_t)(m0 + ra) * Kd + k0 + sseg * 8;
            const unsigned short* gb = Bt + (size_t)(n0 + ra) * Kd + k0 + sseg * 8;
            __builtin_amdgcn_global_load_lds((const GAS unsigned int*)ga,
                                             (LAS unsigned int*)&a_s[r0t * 32], 16, 0, 0);
            __builtin_amdgcn_global_load_lds((const GAS unsigned int*)gb,
                                             (LAS unsigned int*)&b_s[r0t * 32], 16, 0, 0);
        }
        __syncthreads();

        bf16x8 af[4], bfr[4];
#pragma unroll
        for (int i = 0; i < 4; ++i)
            af[i] = *(const bf16x8*)&a_s[(wr * 64 + i * 16 + l16) * 32 + quad * 8];
#pragma unroll
        for (int j = 0; j < 4; ++j)
            bfr[j] = *(const bf16x8*)&b_s[(wc * 64 + j * 16 + l16) * 32 + quad * 8];
#pragma unroll
        for (int i = 0; i < 4; ++i)
#pragma unroll
            for (int j = 0; j < 4; ++j)
                acc[i][j] = __builtin_amdgcn_mfma_f32_16x16x32_bf16(af[i], bfr[j], acc[i][j], 0, 0, 0);
    }

#pragma unroll
    for (int i = 0; i < 4; ++i)
#pragma unroll
        for (int j = 0; j < 4; ++j) {
            const int col = n0 + wc * 64 + j * 16 + l16;
#pragma unroll
            for (int r = 0; r < 4; ++r) {
                const int row = m0 + wr * 64 + i * 16 + quad * 4 + r;
                C[(size_t)row * N + col] = acc[i][j][r];
            }
        }
}

// ---------------------------------------------------------------------------
// g / beta kernel — REWRITTEN access pattern (R4).
// Was: rotated LDS indexing -> 2-bank aliasing, 6.3e7 conflicts, 327 us.
// Now: thread (out=tid>>3, part=tid&7) reads float4 at d = i*32 + part*4:
// 8 distinct float4 addrs/wave cover banks 0..31 exactly once; the 8
// out-groups broadcast. Reduce over part with 3 shfl_xor.
// ---------------------------------------------------------------------------
__global__ __launch_bounds__(256) void gbeta_k(const float* __restrict__ x,
                                               const float* __restrict__ Wa,
                                               const float* __restrict__ Wb,
                                               const float* __restrict__ A_log,
                                               const float* __restrict__ dt_bias,
                                               float* __restrict__ g,
                                               float* __restrict__ beta) {
    __shared__ __align__(16) float xs[DD];
    const int row = blockIdx.x;
    const int tid = threadIdx.x;

    *(float4*)&xs[tid * 4] = *(const float4*)&x[(size_t)row * DD + tid * 4];
    __syncthreads();

    const int out = tid >> 3;   // 0..31
    const int part = tid & 7;   // 0..7
    const int h = out & 15;
    const float* W = (out < 16) ? Wa : Wb;

    float s = 0.0f;
#pragma unroll 8
    for (int i = 0; i < 32; ++i) {
        const int d = i * 32 + part * 4;
        float4 xv = *(const float4*)&xs[d];
        s += xv.x * W[(size_t)(d + 0) * HH + h];
        s += xv.y * W[(size_t)(d + 1) * HH + h];
        s += xv.z * W[(size_t)(d + 2) * HH + h];
        s += xv.w * W[(size_t)(d + 3) * HH + h];
    }
    s += __shfl_xor(s, 1);
    s += __shfl_xor(s, 2);
    s += __shfl_xor(s, 4);

    if (part == 0) {
        if (out < 16) {
            float v = s + dt_bias[h];
            float sp = (v > 20.0f) ? v : log1pf(expf(v));
            g[(size_t)row * HH + h] = -expf(A_log[h]) * sp;
        } else {
            beta[(size_t)row * HH + h] = sigmoidf_(s);
        }
    }
}

// ---------------------------------------------------------------------------
// Phase A1: stage normalized q,k (conv+silu+l2norm) and cumsum(g). (unchanged)
// ---------------------------------------------------------------------------
__global__ __launch_bounds__(64) void stage_k(const float* __restrict__ q_pre,
                                              const float* __restrict__ k_pre,
                                              const float* __restrict__ cq,
                                              const float* __restrict__ ck,
                                              const float* __restrict__ g,
                                              float* __restrict__ Qc,
                                              float* __restrict__ Kc,
                                              float* __restrict__ bcum) {
    const int blk = blockIdx.x;
    const int bh = blk >> 5;
    const int c = blk & 31;
    const int b = bh >> 4;
    const int h = bh & 15;
    const int lane = threadIdx.x;
    const int ch = h * DK + lane;

    const float4 wq4 = *(const float4*)&cq[ch * 4];
    const float4 wk4 = *(const float4*)&ck[ch * 4];

    float qw0 = 0, qw1 = 0, qw2 = 0, kw0 = 0, kw1 = 0, kw2 = 0;
    {
        const int t0 = c * CL;
        if (t0 - 3 >= 0) { size_t bi = ((size_t)b * TT + t0 - 3) * HD + ch; qw0 = q_pre[bi]; kw0 = k_pre[bi]; }
        if (t0 - 2 >= 0) { size_t bi = ((size_t)b * TT + t0 - 2) * HD + ch; qw1 = q_pre[bi]; kw1 = k_pre[bi]; }
        if (t0 - 1 >= 0) { size_t bi = ((size_t)b * TT + t0 - 1) * HD + ch; qw2 = q_pre[bi]; kw2 = k_pre[bi]; }
    }
    float* Qo = Qc + (size_t)blk * 4096;
    float* Ko = Kc + (size_t)blk * 4096;

    for (int tt = 0; tt < CL; ++tt) {
        const int t = c * CL + tt;
        const size_t bi = ((size_t)b * TT + t) * HD + ch;
        const float qc_ = q_pre[bi];
        const float kc_ = k_pre[bi];
        float qa = qw0 * wq4.x + qw1 * wq4.y + qw2 * wq4.z + qc_ * wq4.w;
        float ka = kw0 * wk4.x + kw1 * wk4.y + kw2 * wk4.z + kc_ * wk4.w;
        qw0 = qw1; qw1 = qw2; qw2 = qc_;
        kw0 = kw1; kw1 = kw2; kw2 = kc_;
        qa = siluf_(qa);
        ka = siluf_(ka);
        float qs2 = qa * qa, ks2 = ka * ka;
#pragma unroll
        for (int s = 32; s > 0; s >>= 1) {
            qs2 += __shfl_xor(qs2, s);
            ks2 += __shfl_xor(ks2, s);
        }
        Qo[tt * 64 + lane] = qa * rsqrtf(qs2 + 1e-6f) * 0.125f;
        Ko[tt * 64 + lane] = ka * rsqrtf(ks2 + 1e-6f);
    }

    float cum = g[((size_t)b * TT + c * CL + lane) * HH + h];
#pragma unroll
    for (int s = 1; s < 64; s <<= 1) {
        float u = __shfl_up(cum, s);
        if (lane >= s) cum += u;
    }
    bcum[(size_t)blk * 64 + lane] = cum;
}

// ---------------------------------------------------------------------------
// Phase A2: blocked triangular solve (unchanged from R3)
// ---------------------------------------------------------------------------
__global__ __launch_bounds__(256) void prep_k(const float* __restrict__ Kc,
                                              const float* __restrict__ v_pre,
                                              const float* __restrict__ cv,
                                              const float* __restrict__ bcum,
                                              const float* __restrict__ bbuf,
                                              float* __restrict__ Wv,
                                              float* __restrict__ Wk) {
    __shared__ __align__(16) float k_s[CL * PAD];
    __shared__ __align__(16) float wv_s[CL * PAD];
    __shared__ __align__(16) float wk_s[CL * PAD];
    __shared__ __align__(16) float A_s[CL * PAD];
    __shared__ float T_s[4][16 * 17];
    __shared__ float b_s[CL], beta_s[CL], bk_s[CL];

    const int blk = blockIdx.x;
    const int bh = blk >> 5;
    const int c = blk & 31;
    const int b = bh >> 4;
    const int h = bh & 15;
    const int tid = threadIdx.x;

    if (tid < 64) {
        float bv = bcum[(size_t)blk * 64 + tid];
        float be = bbuf[((size_t)b * TT + c * CL + tid) * HH + h];
        b_s[tid] = bv;
        beta_s[tid] = be;
        bk_s[tid] = be * __expf(bv);
    }
    __syncthreads();

    {
        const float4* Kg = (const float4*)(Kc + (size_t)blk * 4096);
#pragma unroll
        for (int i = 0; i < 4; ++i) {
            int f = tid + i * 256;
            int t = f >> 4;
            int d = t * PAD + (f & 15) * 4;
            float4 kv = Kg[f];
            *(float4*)&k_s[d] = kv;
            float sk = bk_s[t];
            *(float4*)&wk_s[d] = make_float4(kv.x * sk, kv.y * sk, kv.z * sk, kv.w * sk);
        }
    }

    {
        const int lane = tid & 63;
        const int q4 = tid >> 6;
        const int ch = h * DK + lane;
        const float4 wv4 = *(const float4*)&cv[ch * 4];
        const int T0 = c * CL + q4 * 16;
        float w0 = 0, w1 = 0, w2 = 0;
        if (T0 - 3 >= 0) w0 = v_pre[((size_t)b * TT + T0 - 3) * HD + ch];
        if (T0 - 2 >= 0) w1 = v_pre[((size_t)b * TT + T0 - 2) * HD + ch];
        if (T0 - 1 >= 0) w2 = v_pre[((size_t)b * TT + T0 - 1) * HD + ch];
#pragma unroll 1
        for (int i = 0; i < 16; ++i) {
            const int t = T0 + i;
            const float vc_ = v_pre[((size_t)b * TT + t) * HD + ch];
            float va = w0 * wv4.x + w1 * wv4.y + w2 * wv4.z + vc_ * wv4.w;
            w0 = w1; w1 = w2; w2 = vc_;
            va = siluf_(va);
            wv_s[(q4 * 16 + i) * PAD + lane] = va * beta_s[q4 * 16 + i];
        }
    }
    __syncthreads();

    {
        const int t0 = (tid >> 4) * 4, s0 = (tid & 15) * 4;
        float acc[4][4] = {};
        for (int kk = 0; kk < 64; kk += 4) {
            float ta[4][4], sb[4][4];
#pragma unroll
            for (int i = 0; i < 4; ++i) f4a(*(const float4*)&k_s[(t0 + i) * PAD + kk], ta[i]);
#pragma unroll
            for (int j = 0; j < 4; ++j) f4a(*(const float4*)&k_s[(s0 + j) * PAD + kk], sb[j]);
#pragma unroll
            for (int i = 0; i < 4; ++i)
#pragma unroll
                for (int j = 0; j < 4; ++j)
#pragma unroll
                    for (int m = 0; m < 4; ++m) acc[i][j] += ta[i][m] * sb[j][m];
        }
#pragma unroll
        for (int i = 0; i < 4; ++i)
#pragma unroll
            for (int j = 0; j < 4; ++j) {
                const int t = t0 + i, s = s0 + j;
                A_s[t * PAD + s] = (s < t) ? acc[i][j] * beta_s[t] * __expf(b_s[t] - b_s[s]) : 0.0f;
            }
    }
    __syncthreads();

    if (tid < 64) {
        const int d = tid >> 4;
        const int col = tid & 15;
        const int base = d * 16;
        float tcol[16];
#pragma unroll
        for (int s = 0; s < 16; ++s) tcol[s] = (s == col) ? 1.0f : 0.0f;
#pragma unroll
        for (int t = 1; t < 16; ++t) {
            float a = 0.0f;
#pragma unroll
            for (int s = 0; s < 16; ++s)
                if (s < t) a += A_s[(base + t) * PAD + base + s] * tcol[s];
            tcol[t] -= a;
        }
#pragma unroll
        for (int t = 0; t < 16; ++t) T_s[d][t * 17 + col] = tcol[t];
    }
    __syncthreads();

    {
        const int r = tid >> 4;
        const int cg = tid & 15;
        float* Wc = (cg < 8) ? wv_s : wk_s;
        const int cc = (cg & 7) * 8;

        for (int tb = 0; tb < 4; ++tb) {
            const int t = tb * 16 + r;
            if (tb > 0) {
                float acc[8];
                f4a(*(const float4*)&Wc[t * PAD + cc], acc);
                f4a(*(const float4*)&Wc[t * PAD + cc + 4], acc + 4);
#pragma unroll 2
                for (int s = 0; s < tb * 16; ++s) {
                    const float a = A_s[t * PAD + s];
                    float wr[8];
                    f4a(*(const float4*)&Wc[s * PAD + cc], wr);
                    f4a(*(const float4*)&Wc[s * PAD + cc + 4], wr + 4);
#pragma unroll
                    for (int u = 0; u < 8; ++u) acc[u] -= a * wr[u];
                }
                *(float4*)&Wc[t * PAD + cc] = make_float4(acc[0], acc[1], acc[2], acc[3]);
                *(float4*)&Wc[t * PAD + cc + 4] = make_float4(acc[4], acc[5], acc[6], acc[7]);
            }
            __syncthreads();
            float acc2[8] = {};
#pragma unroll 4
            for (int s = 0; s < 16; ++s) {
                const float tv = T_s[tb][r * 17 + s];
                float wr[8];
                f4a(*(const float4*)&Wc[(tb * 16 + s) * PAD + cc], wr);
                f4a(*(const float4*)&Wc[(tb * 16 + s) * PAD + cc + 4], wr + 4);
#pragma unroll
                for (int u = 0; u < 8; ++u) acc2[u] += tv * wr[u];
            }
            __syncthreads();
            *(float4*)&Wc[t * PAD + cc] = make_float4(acc2[0], acc2[1], acc2[2], acc2[3]);
            *(float4*)&Wc[t * PAD + cc + 4] = make_float4(acc2[4], acc2[5], acc2[6], acc2[7]);
            __syncthreads();
        }
    }

    float4* Wvg = (float4*)(Wv + (size_t)blk * 4096);
    float4* Wkg = (float4*)(Wk + (size_t)blk * 4096);
#pragma unroll
    for (int i = 0; i < 4; ++i) {
        int f = tid + i * 256;
        int d = (f >> 4) * PAD + (f & 15) * 4;
        Wvg[f] = *(float4*)&wv_s[d];
        Wkg[f] = *(float4*)&wk_s[d];
    }
}

// ---------------------------------------------------------------------------
// Phase B: sequential chunk recurrence (unchanged)
// ---------------------------------------------------------------------------
__global__ __launch_bounds__(256) void state_k(const float* __restrict__ Kc,
                                               float* __restrict__ Wio,
                                               const float* __restrict__ Wk,
                                               const float* __restrict__ bcum,
                                               float* __restrict__ Hst) {
    __shared__ __align__(16) float h_s[CL * PAD];
    __shared__ __align__(16) float w_s[CL * PAD];
    __shared__ __align__(16) float x_s[CL * PAD];
    __shared__ float e_s[CL];

    const int bh = blockIdx.x;
    const int tid = threadIdx.x;
    const int r0 = (tid >> 4) * 4;
    const int v0 = (tid & 15) * 4;

#pragma unroll
    for (int i = 0; i < 4; ++i) {
        int f = tid + i * 256;
        int d = (f >> 4) * PAD + (f & 15) * 4;
        *(float4*)&h_s[d] = make_float4(0, 0, 0, 0);
    }
    __syncthreads();

    for (int c = 0; c < NC; ++c) {
        const size_t blk = (size_t)bh * NC + c;
        float4* Hg = (float4*)(Hst + blk * 4096);
        const float4* Wkg = (const float4*)(Wk + blk * 4096);
#pragma unroll
        for (int i = 0; i < 4; ++i) {
            int f = tid + i * 256;
            int d = (f >> 4) * PAD + (f & 15) * 4;
            Hg[f] = *(float4*)&h_s[d];
            *(float4*)&x_s[d] = Wkg[f];
        }
        const float bC = bcum[blk * 64 + 63];
        if (tid < 64) e_s[tid] = __expf(bC - bcum[blk * 64 + tid]);
        __syncthreads();

        float acc[4][4];
        {
            const float4* Wvg = (const float4*)(Wio + blk * 4096);
#pragma unroll
            for (int i = 0; i < 4; ++i) f4a(Wvg[(r0 + i) * 16 + (v0 >> 2)], acc[i]);
            for (int kk = 0; kk < 64; kk += 4) {
                float a[4][4], hb[4][4];
#pragma unroll
                for (int i = 0; i < 4; ++i) f4a(*(const float4*)&x_s[(r0 + i) * PAD + kk], a[i]);
#pragma unroll
                for (int m = 0; m < 4; ++m) f4a(*(const float4*)&h_s[(kk + m) * PAD + v0], hb[m]);
#pragma unroll
                for (int i = 0; i < 4; ++i)
#pragma unroll
                    for (int m = 0; m < 4; ++m)
#pragma unroll
                        for (int j = 0; j < 4; ++j) acc[i][j] -= a[i][m] * hb[m][j];
            }
        }
        __syncthreads();
        {
            float4* Wg = (float4*)(Wio + blk * 4096);
            const float4* Kg = (const float4*)(Kc + blk * 4096);
#pragma unroll
            for (int i = 0; i < 4; ++i) {
                float4 r = make_float4(acc[i][0], acc[i][1], acc[i][2], acc[i][3]);
                *(float4*)&w_s[(r0 + i) * PAD + v0] = r;
                Wg[(r0 + i) * 16 + (v0 >> 2)] = r;
            }
#pragma unroll
            for (int i = 0; i < 4; ++i) {
                int f = tid + i * 256;
                int d = (f >> 4) * PAD + (f & 15) * 4;
                *(float4*)&x_s[d] = Kg[f];
            }
        }
        __syncthreads();
        {
            const float eb = __expf(bC);
#pragma unroll
            for (int i = 0; i < 4; ++i)
#pragma unroll
                for (int j = 0; j < 4; ++j) acc[i][j] = eb * h_s[(r0 + i) * PAD + v0 + j];
            for (int ss = 0; ss < 64; ss += 4) {
                float kf[4][4], wb[4][4];
#pragma unroll
                for (int m = 0; m < 4; ++m) {
                    f4a(*(const float4*)&x_s[(ss + m) * PAD + r0], kf[m]);
                    f4a(*(const float4*)&w_s[(ss + m) * PAD + v0], wb[m]);
                    const float e = e_s[ss + m];
#pragma unroll
                    for (int i = 0; i < 4; ++i) kf[m][i] *= e;
                }
#pragma unroll
                for (int i = 0; i < 4; ++i)
#pragma unroll
                    for (int m = 0; m < 4; ++m)
#pragma unroll
                        for (int j = 0; j < 4; ++j) acc[i][j] += kf[m][i] * wb[m][j];
            }
        }
        __syncthreads();
#pragma unroll
        for (int i = 0; i < 4; ++i)
            *(float4*)&h_s[(r0 + i) * PAD + v0] =
                make_float4(acc[i][0], acc[i][1], acc[i][2], acc[i][3]);
        __syncthreads();
    }
}

// ---------------------------------------------------------------------------
// Phase C: per (bh,chunk) outputs (unchanged)
// ---------------------------------------------------------------------------
__global__ __launch_bounds__(256) void out_k(const float* __restrict__ Qc,
                                             const float* __restrict__ Kc,
                                             const float* __restrict__ Wb_,
                                             const float* __restrict__ Hst,
                                             const float* __restrict__ bcum,
                                             float* __restrict__ o_scan) {
    __shared__ __align__(16) float q_s[4096];
    __shared__ __align__(16) float k_s[4096];
    __shared__ __align__(16) float h_s[4096];
    __shared__ __align__(16) float w_s[4096];
    __shared__ float b_s[64];

    const int blk = blockIdx.x;
    const int bh = blk >> 5;
    const int c = blk & 31;
    const int b = bh >> 4;
    const int h = bh & 15;
    const int tid = threadIdx.x;

    if (tid < 64) b_s[tid] = bcum[(size_t)blk * 64 + tid];
    {
        const float4* Qg = (const float4*)(Qc + (size_t)blk * 4096);
        const float4* Kg = (const float4*)(Kc + (size_t)blk * 4096);
        const float4* Hg = (const float4*)(Hst + (size_t)blk * 4096);
        const float4* Wg = (const float4*)(Wb_ + (size_t)blk * 4096);
#pragma unroll
        for (int i = 0; i < 4; ++i) {
            int f = tid + i * 256;
            ((float4*)q_s)[f] = Qg[f];
            ((float4*)k_s)[f] = Kg[f];
            ((float4*)h_s)[f] = Hg[f];
            ((float4*)w_s)[f] = Wg[f];
        }
    }
    __syncthreads();

    {
        const int t0 = (tid >> 4) * 4, s0 = (tid & 15) * 4;
        float acc[4][4] = {};
        for (int kk = 0; kk < 64; kk += 4) {
            float qa[4][4], kb[4][4];
#pragma unroll
            for (int i = 0; i < 4; ++i) f4a(*(const float4*)&q_s[(t0 + i) * 64 + kk], qa[i]);
#pragma unroll
            for (int j = 0; j < 4; ++j) f4a(*(const float4*)&k_s[(s0 + j) * 64 + kk], kb[j]);
#pragma unroll
            for (int i = 0; i < 4; ++i)
#pragma unroll
                for (int j = 0; j < 4; ++j)
#pragma unroll
                    for (int m = 0; m < 4; ++m) acc[i][j] += qa[i][m] * kb[j][m];
        }
        __syncthreads();
#pragma unroll
        for (int i = 0; i < 4; ++i)
#pragma unroll
            for (int j = 0; j < 4; ++j) {
                const int t = t0 + i, s = s0 + j;
                k_s[t * 64 + s] = (s <= t) ? acc[i][j] * __expf(b_s[t] - b_s[s]) : 0.0f;
            }
    }
#pragma unroll
    for (int i = 0; i < 16; ++i) {
        int e = tid + i * 256;
        q_s[e] *= __expf(b_s[e >> 6]);
    }
    __syncthreads();

    {
        const int t0 = (tid >> 4) * 4, v0 = (tid & 15) * 4;
        float acc[4][4] = {};
        for (int ss = 0; ss < 64; ss += 4) {
            float sa[4][4], wb[4][4];
#pragma unroll
            for (int i = 0; i < 4; ++i) f4a(*(const float4*)&k_s[(t0 + i) * 64 + ss], sa[i]);
#pragma unroll
            for (int m = 0; m < 4; ++m) f4a(*(const float4*)&w_s[(ss + m) * 64 + v0], wb[m]);
#pragma unroll
            for (int i = 0; i < 4; ++i)
#pragma unroll
                for (int m = 0; m < 4; ++m)
#pragma unroll
                    for (int j = 0; j < 4; ++j) acc[i][j] += sa[i][m] * wb[m][j];
        }
        for (int kk = 0; kk < 64; kk += 4) {
            float qa[4][4], hb[4][4];
#pragma unroll
            for (int i = 0; i < 4; ++i) f4a(*(const float4*)&q_s[(t0 + i) * 64 + kk], qa[i]);
#pragma unroll
            for (int m = 0; m < 4; ++m) f4a(*(const float4*)&h_s[(kk + m) * 64 + v0], hb[m]);
#pragma unroll
            for (int i = 0; i < 4; ++i)
#pragma unroll
                for (int m = 0; m < 4; ++m)
#pragma unroll
                    for (int j = 0; j < 4; ++j) acc[i][j] += qa[i][m] * hb[m][j];
        }
#pragma unroll
        for (int i = 0; i < 4; ++i) {
            const int t = c * CL + t0 + i;
            *(float4*)&o_scan[(((size_t)b * TT + t) * HH + h) * DK + v0] =
                make_float4(acc[i][0], acc[i][1], acc[i][2], acc[i][3]);
        }
    }
}

// ---------------------------------------------------------------------------
// Gated RMSNorm -> bf16 output (unchanged)
// ---------------------------------------------------------------------------
__global__ __launch_bounds__(256) void gnorm_k(const float* __restrict__ o_scan,
                                               const float* __restrict__ gate,
                                               const float* __restrict__ rms_w,
                                               unsigned short* __restrict__ o2) {
    const int tid = threadIdx.x;
    const int grp = tid >> 6;
    const int lane = tid & 63;
    const int bth = blockIdx.x * 4 + grp;
    const int h = bth & 15;
    const int row = bth >> 4;

    float ov = o_scan[(size_t)bth * DK + lane];
    float s = ov * ov;
#pragma unroll
    for (int sh = 32; sh > 0; sh >>= 1) s += __shfl_xor(s, sh);
    float r = rsqrtf(s * (1.0f / 64.0f) + 1e-5f);

    float gt = gate[(size_t)row * HD + h * DK + lane];
    o2[(size_t)row * HD + h * DK + lane] = f2bf(ov * r * rms_w[lane] * siluf_(gt));
}

// ---------------------------------------------------------------------------
extern "C" void kernel_launch(void* const* d_in, const int* in_sizes, int n_in,
                              void* d_out, int out_size, void* d_ws, size_t ws_size,
                              hipStream_t stream) {
    (void)in_sizes; (void)n_in; (void)out_size; (void)ws_size;

    const float* x       = (const float*)d_in[0];
    const float* Wq      = (const float*)d_in[1];
    const float* Wk_     = (const float*)d_in[2];
    const float* Wv_     = (const float*)d_in[3];
    const float* Wa      = (const float*)d_in[4];
    const float* Wb      = (const float*)d_in[5];
    const float* Wg      = (const float*)d_in[6];
    const float* Wo      = (const float*)d_in[7];
    const float* conv_q  = (const float*)d_in[8];
    const float* conv_k  = (const float*)d_in[9];
    const float* conv_v  = (const float*)d_in[10];
    const float* A_log   = (const float*)d_in[11];
    const float* dt_bias = (const float*)d_in[12];
    const float* rms_w   = (const float*)d_in[13];
    float* out = (float*)d_out;

    float* ws = (float*)d_ws;
    const size_t NTOK = (size_t)BB * TT;     // 4096
    const size_t BIG = NTOK * HD;            // 4 Mi floats

    float* q_pre = ws + 0 * BIG;
    float* k_pre = ws + 1 * BIG;
    float* v_pre = ws + 2 * BIG;
    float* gatep = ws + 3 * BIG;
    float* Qc    = ws + 4 * BIG;
    float* Kc    = ws + 5 * BIG;
    float* gbuf  = ws + 6 * BIG;
    float* bbuf  = gbuf + NTOK * HH;
    float* bcumb = bbuf + NTOK * HH;

    // bf16 buffers after the fp32 region
    unsigned short* xb  = (unsigned short*)(bcumb + NTOK * HH);
    unsigned short* wqt = xb + (size_t)NTOK * DD;
    unsigned short* wkt = wqt + (size_t)DD * HD;
    unsigned short* wvt = wkt + (size_t)DD * HD;
    unsigned short* wgt = wvt + (size_t)DD * HD;
    unsigned short* wot = wgt + (size_t)DD * HD;

    // aliases (stream-ordered lifetimes):
    float* Wvb    = q_pre;
    float* Wkb    = k_pre;
    float* Hst    = v_pre;
    float* o_scan = k_pre;
    unsigned short* o2b = (unsigned short*)Qc;

    // casts
    castx_k<<<(int)(NTOK * DD / (256 * 8)), 256, 0, stream>>>(x, xb);
    dim3 tg(16, 16);
    castw_k<<<tg, 256, 0, stream>>>(Wq, wqt);
    castw_k<<<tg, 256, 0, stream>>>(Wk_, wkt);
    castw_k<<<tg, 256, 0, stream>>>(Wv_, wvt);
    castw_k<<<tg, 256, 0, stream>>>(Wg, wgt);
    castw_k<<<tg, 256, 0, stream>>>(Wo, wot);

    // projections
    dim3 gg(HD / 128, NTOK / 128);   // (8, 32)
    gemm_bf16_k<<<gg, 256, 0, stream>>>(xb, wqt, q_pre, (int)NTOK, HD, DD);
    gemm_bf16_k<<<gg, 256, 0, stream>>>(xb, wkt, k_pre, (int)NTOK, HD, DD);
    gemm_bf16_k<<<gg, 256, 0, stream>>>(xb, wvt, v_pre, (int)NTOK, HD, DD);
    gemm_bf16_k<<<gg, 256, 0, stream>>>(xb, wgt, gatep, (int)NTOK, HD, DD);

    gbeta_k<<<(int)NTOK, 256, 0, stream>>>(x, Wa, Wb, A_log, dt_bias, gbuf, bbuf);

    stage_k<<<BB * HH * NC, 64, 0, stream>>>(q_pre, k_pre, conv_q, conv_k, gbuf,
                                             Qc, Kc, bcumb);

    prep_k<<<BB * HH * NC, 256, 0, stream>>>(Kc, v_pre, conv_v, bcumb, bbuf, Wvb, Wkb);

    state_k<<<BB * HH, 256, 0, stream>>>(Kc, Wvb, Wkb, bcumb, Hst);

    out_k<<<BB * HH * NC, 256, 0, stream>>>(Qc, Kc, Wvb, Hst, bcumb, o_scan);

    gnorm_k<<<(int)(NTOK * HH / 4), 256, 0, stream>>>(o_scan, gatep, rms_w, o2b);

    gemm_bf16_k<<<gg, 256, 0, stream>>>(o2b, wot, out, (int)NTOK, HD, DD);
}

// Round 6
// 796.830 us; speedup vs baseline: 8.0795x; 1.1858x over previous
//
#include <hip/hip_runtime.h>
#include <hip/hip_bf16.h>
#include <math.h>
#include <stdint.h>

// Problem constants
#define BB 2
#define TT 2048
#define DD 1024
#define HH 16
#define DK 64
#define HD 1024   // H*DK
#define NC 32     // chunks per sequence (TT/64)
#define CL 64     // chunk length
#define PAD 68    // padded LDS row stride (floats) to break stride-64 bank conflicts

typedef short bf16x8 __attribute__((ext_vector_type(8)));     // 8 bf16 (4 VGPRs)
typedef float f32x4 __attribute__((ext_vector_type(4)));      // MFMA acc
typedef unsigned short u16x8 __attribute__((ext_vector_type(8)));
typedef unsigned short u16x4 __attribute__((ext_vector_type(4)));

#define GAS __attribute__((address_space(1)))
#define LAS __attribute__((address_space(3)))

#define DOT4(a, b) ((a).x*(b).x + (a).y*(b).y + (a).z*(b).z + (a).w*(b).w)

__device__ __forceinline__ float sigmoidf_(float x) { return 1.0f / (1.0f + expf(-x)); }
__device__ __forceinline__ float siluf_(float x) { return x * sigmoidf_(x); }
__device__ __forceinline__ void f4a(const float4 v, float* o) { o[0]=v.x; o[1]=v.y; o[2]=v.z; o[3]=v.w; }

// round-to-nearest-even fp32 -> bf16
__device__ __forceinline__ unsigned short f2bf(float f) {
    unsigned int u = __builtin_bit_cast(unsigned int, f);
    u = (u + 0x7fffu + ((u >> 16) & 1u)) >> 16;
    return (unsigned short)u;
}

// ---------------------------------------------------------------------------
// Cast x (fp32) -> bf16, flat.
// ---------------------------------------------------------------------------
__global__ __launch_bounds__(256) void castx_k(const float* __restrict__ src,
                                               unsigned short* __restrict__ dst) {
    const size_t idx = (size_t)blockIdx.x * 256 + threadIdx.x;
    float4 a = *(const float4*)&src[idx * 8];
    float4 b = *(const float4*)&src[idx * 8 + 4];
    u16x8 o;
    o[0] = f2bf(a.x); o[1] = f2bf(a.y); o[2] = f2bf(a.z); o[3] = f2bf(a.w);
    o[4] = f2bf(b.x); o[5] = f2bf(b.y); o[6] = f2bf(b.z); o[7] = f2bf(b.w);
    *(u16x8*)&dst[idx * 8] = o;
}

// ---------------------------------------------------------------------------
// Transpose+cast weight: W[K=1024][N=1024] fp32 -> Wt[N][K] bf16.
// ---------------------------------------------------------------------------
__global__ __launch_bounds__(256) void castw_k(const float* __restrict__ W,
                                               unsigned short* __restrict__ Wt) {
    __shared__ float t_s[64][65];
    const int tid = threadIdx.x;
    const int rr = tid >> 4;
    const int cc = tid & 15;
    const int r0 = blockIdx.y * 64;
    const int c0 = blockIdx.x * 64;
#pragma unroll
    for (int i = 0; i < 4; ++i) {
        const int row = rr + i * 16;
        float4 v = *(const float4*)&W[(size_t)(r0 + row) * 1024 + c0 + cc * 4];
        t_s[row][cc * 4 + 0] = v.x;
        t_s[row][cc * 4 + 1] = v.y;
        t_s[row][cc * 4 + 2] = v.z;
        t_s[row][cc * 4 + 3] = v.w;
    }
    __syncthreads();
#pragma unroll
    for (int i = 0; i < 4; ++i) {
        const int nr = rr + i * 16;
        u16x4 o;
#pragma unroll
        for (int d = 0; d < 4; ++d) o[d] = f2bf(t_s[cc * 4 + d][nr]);
        *(u16x4*)&Wt[(size_t)(c0 + nr) * 1024 + r0 + cc * 4] = o;
    }
}

// ---------------------------------------------------------------------------
// bf16 MFMA GEMM (m97 structure), unchanged.
// ---------------------------------------------------------------------------
__global__ __launch_bounds__(256) void gemm_bf16_k(const unsigned short* __restrict__ A,
                                                   const unsigned short* __restrict__ Bt,
                                                   float* __restrict__ C,
                                                   int M, int N, int Kd) {
    __shared__ unsigned short a_s[128 * 32];
    __shared__ unsigned short b_s[128 * 32];

    const int tid = threadIdx.x;
    const int wave = tid >> 6;
    const int lane = tid & 63;
    const int m0 = blockIdx.y * 128;
    const int n0 = blockIdx.x * 128;

    const int quad = lane >> 4;
    const int l16 = lane & 15;
    const int wr = wave >> 1;
    const int wc = wave & 1;

    const int srow = lane >> 2;
    const int sseg = lane & 3;

    f32x4 acc[4][4];
#pragma unroll
    for (int i = 0; i < 4; ++i)
#pragma unroll
        for (int j = 0; j < 4; ++j) acc[i][j] = (f32x4){0.f, 0.f, 0.f, 0.f};

    for (int k0 = 0; k0 < Kd; k0 += 32) {
        __syncthreads();
#pragma unroll
        for (int c = 0; c < 2; ++c) {
            const int region = wave * 2 + c;
            const int r0t = region * 16;
            const int ra = r0t + srow;
            const unsigned short* ga = A + (size_t)(m0 + ra) * Kd + k0 + sseg * 8;
            const unsigned short* gb = Bt + (size_t)(n0 + ra) * Kd + k0 + sseg * 8;
            __builtin_amdgcn_global_load_lds((const GAS unsigned int*)ga,
                                             (LAS unsigned int*)&a_s[r0t * 32], 16, 0, 0);
            __builtin_amdgcn_global_load_lds((const GAS unsigned int*)gb,
                                             (LAS unsigned int*)&b_s[r0t * 32], 16, 0, 0);
        }
        __syncthreads();

        bf16x8 af[4], bfr[4];
#pragma unroll
        for (int i = 0; i < 4; ++i)
            af[i] = *(const bf16x8*)&a_s[(wr * 64 + i * 16 + l16) * 32 + quad * 8];
#pragma unroll
        for (int j = 0; j < 4; ++j)
            bfr[j] = *(const bf16x8*)&b_s[(wc * 64 + j * 16 + l16) * 32 + quad * 8];
#pragma unroll
        for (int i = 0; i < 4; ++i)
#pragma unroll
            for (int j = 0; j < 4; ++j)
                acc[i][j] = __builtin_amdgcn_mfma_f32_16x16x32_bf16(af[i], bfr[j], acc[i][j], 0, 0, 0);
    }

#pragma unroll
    for (int i = 0; i < 4; ++i)
#pragma unroll
        for (int j = 0; j < 4; ++j) {
            const int col = n0 + wc * 64 + j * 16 + l16;
#pragma unroll
            for (int r = 0; r < 4; ++r) {
                const int row = m0 + wr * 64 + i * 16 + quad * 4 + r;
                C[(size_t)row * N + col] = acc[i][j][r];
            }
        }
}

// ---------------------------------------------------------------------------
// g / beta kernel (R4 version, unchanged)
// ---------------------------------------------------------------------------
__global__ __launch_bounds__(256) void gbeta_k(const float* __restrict__ x,
                                               const float* __restrict__ Wa,
                                               const float* __restrict__ Wb,
                                               const float* __restrict__ A_log,
                                               const float* __restrict__ dt_bias,
                                               float* __restrict__ g,
                                               float* __restrict__ beta) {
    __shared__ __align__(16) float xs[DD];
    const int row = blockIdx.x;
    const int tid = threadIdx.x;

    *(float4*)&xs[tid * 4] = *(const float4*)&x[(size_t)row * DD + tid * 4];
    __syncthreads();

    const int out = tid >> 3;   // 0..31
    const int part = tid & 7;   // 0..7
    const int h = out & 15;
    const float* W = (out < 16) ? Wa : Wb;

    float s = 0.0f;
#pragma unroll 8
    for (int i = 0; i < 32; ++i) {
        const int d = i * 32 + part * 4;
        float4 xv = *(const float4*)&xs[d];
        s += xv.x * W[(size_t)(d + 0) * HH + h];
        s += xv.y * W[(size_t)(d + 1) * HH + h];
        s += xv.z * W[(size_t)(d + 2) * HH + h];
        s += xv.w * W[(size_t)(d + 3) * HH + h];
    }
    s += __shfl_xor(s, 1);
    s += __shfl_xor(s, 2);
    s += __shfl_xor(s, 4);

    if (part == 0) {
        if (out < 16) {
            float v = s + dt_bias[h];
            float sp = (v > 20.0f) ? v : log1pf(expf(v));
            g[(size_t)row * HH + h] = -expf(A_log[h]) * sp;
        } else {
            beta[(size_t)row * HH + h] = sigmoidf_(s);
        }
    }
}

// ---------------------------------------------------------------------------
// Phase A1: stage normalized q,k (conv+silu+l2norm) and cumsum(g). (unchanged)
// ---------------------------------------------------------------------------
__global__ __launch_bounds__(64) void stage_k(const float* __restrict__ q_pre,
                                              const float* __restrict__ k_pre,
                                              const float* __restrict__ cq,
                                              const float* __restrict__ ck,
                                              const float* __restrict__ g,
                                              float* __restrict__ Qc,
                                              float* __restrict__ Kc,
                                              float* __restrict__ bcum) {
    const int blk = blockIdx.x;
    const int bh = blk >> 5;
    const int c = blk & 31;
    const int b = bh >> 4;
    const int h = bh & 15;
    const int lane = threadIdx.x;
    const int ch = h * DK + lane;

    const float4 wq4 = *(const float4*)&cq[ch * 4];
    const float4 wk4 = *(const float4*)&ck[ch * 4];

    float qw0 = 0, qw1 = 0, qw2 = 0, kw0 = 0, kw1 = 0, kw2 = 0;
    {
        const int t0 = c * CL;
        if (t0 - 3 >= 0) { size_t bi = ((size_t)b * TT + t0 - 3) * HD + ch; qw0 = q_pre[bi]; kw0 = k_pre[bi]; }
        if (t0 - 2 >= 0) { size_t bi = ((size_t)b * TT + t0 - 2) * HD + ch; qw1 = q_pre[bi]; kw1 = k_pre[bi]; }
        if (t0 - 1 >= 0) { size_t bi = ((size_t)b * TT + t0 - 1) * HD + ch; qw2 = q_pre[bi]; kw2 = k_pre[bi]; }
    }
    float* Qo = Qc + (size_t)blk * 4096;
    float* Ko = Kc + (size_t)blk * 4096;

    for (int tt = 0; tt < CL; ++tt) {
        const int t = c * CL + tt;
        const size_t bi = ((size_t)b * TT + t) * HD + ch;
        const float qc_ = q_pre[bi];
        const float kc_ = k_pre[bi];
        float qa = qw0 * wq4.x + qw1 * wq4.y + qw2 * wq4.z + qc_ * wq4.w;
        float ka = kw0 * wk4.x + kw1 * wk4.y + kw2 * wk4.z + kc_ * wk4.w;
        qw0 = qw1; qw1 = qw2; qw2 = qc_;
        kw0 = kw1; kw1 = kw2; kw2 = kc_;
        qa = siluf_(qa);
        ka = siluf_(ka);
        float qs2 = qa * qa, ks2 = ka * ka;
#pragma unroll
        for (int s = 32; s > 0; s >>= 1) {
            qs2 += __shfl_xor(qs2, s);
            ks2 += __shfl_xor(ks2, s);
        }
        Qo[tt * 64 + lane] = qa * rsqrtf(qs2 + 1e-6f) * 0.125f;
        Ko[tt * 64 + lane] = ka * rsqrtf(ks2 + 1e-6f);
    }

    float cum = g[((size_t)b * TT + c * CL + lane) * HH + h];
#pragma unroll
    for (int s = 1; s < 64; s <<= 1) {
        float u = __shfl_up(cum, s);
        if (lane >= s) cum += u;
    }
    bcum[(size_t)blk * 64 + lane] = cum;
}

// ---------------------------------------------------------------------------
// Phase A2 (R5): scratch-free rewrite. Same blocked triangular solve as R3,
// but all hot loops use NAMED float4 temporaries (no float[] locals written
// through pointers) — prior versions carried ~225 MB of HBM scratch traffic
// (FETCH+WRITE ~296 MB vs ~70 MB logical) from unpromoted allocas.
// ---------------------------------------------------------------------------
__global__ __launch_bounds__(256) void prep_k(const float* __restrict__ Kc,
                                              const float* __restrict__ v_pre,
                                              const float* __restrict__ cv,
                                              const float* __restrict__ bcum,
                                              const float* __restrict__ bbuf,
                                              float* __restrict__ Wv,
                                              float* __restrict__ Wk) {
    __shared__ __align__(16) float k_s[CL * PAD];
    __shared__ __align__(16) float wv_s[CL * PAD];
    __shared__ __align__(16) float wk_s[CL * PAD];
    __shared__ __align__(16) float A_s[CL * PAD];
    __shared__ float T_s[4][16 * 17];
    __shared__ float b_s[CL], beta_s[CL], bk_s[CL];

    const int blk = blockIdx.x;
    const int bh = blk >> 5;
    const int c = blk & 31;
    const int b = bh >> 4;
    const int h = bh & 15;
    const int tid = threadIdx.x;

    if (tid < 64) {
        float bv = bcum[(size_t)blk * 64 + tid];
        float be = bbuf[((size_t)b * TT + c * CL + tid) * HH + h];
        b_s[tid] = bv;
        beta_s[tid] = be;
        bk_s[tid] = be * __expf(bv);
    }
    __syncthreads();

    // stage K and Rk = diag(beta e^b) K
    {
        const float4* Kg = (const float4*)(Kc + (size_t)blk * 4096);
#pragma unroll
        for (int i = 0; i < 4; ++i) {
            int f = tid + i * 256;
            int t = f >> 4;
            int d = t * PAD + (f & 15) * 4;
            float4 kv = Kg[f];
            *(float4*)&k_s[d] = kv;
            float sk = bk_s[t];
            *(float4*)&wk_s[d] = make_float4(kv.x * sk, kv.y * sk, kv.z * sk, kv.w * sk);
        }
    }

    // Rv = beta * silu(conv(v))
    {
        const int lane = tid & 63;
        const int q4 = tid >> 6;
        const int ch = h * DK + lane;
        const float4 wv4 = *(const float4*)&cv[ch * 4];
        const int T0 = c * CL + q4 * 16;
        float w0 = 0, w1 = 0, w2 = 0;
        if (T0 - 3 >= 0) w0 = v_pre[((size_t)b * TT + T0 - 3) * HD + ch];
        if (T0 - 2 >= 0) w1 = v_pre[((size_t)b * TT + T0 - 2) * HD + ch];
        if (T0 - 1 >= 0) w2 = v_pre[((size_t)b * TT + T0 - 1) * HD + ch];
#pragma unroll 1
        for (int i = 0; i < 16; ++i) {
            const int t = T0 + i;
            const float vc_ = v_pre[((size_t)b * TT + t) * HD + ch];
            float va = w0 * wv4.x + w1 * wv4.y + w2 * wv4.z + vc_ * wv4.w;
            w0 = w1; w1 = w2; w2 = vc_;
            va = siluf_(va);
            wv_s[(q4 * 16 + i) * PAD + lane] = va * beta_s[q4 * 16 + i];
        }
    }
    __syncthreads();

    // A = strict-lower(beta_t e^{b_t-b_s} k_t.k_s) — named float4 temps only
    {
        const int t0 = (tid >> 4) * 4, s0 = (tid & 15) * 4;
        float acc[4][4] = {};   // constant-indexed only (fully unrolled)
        for (int kk = 0; kk < 64; kk += 4) {
            float4 ta0 = *(const float4*)&k_s[(t0 + 0) * PAD + kk];
            float4 ta1 = *(const float4*)&k_s[(t0 + 1) * PAD + kk];
            float4 ta2 = *(const float4*)&k_s[(t0 + 2) * PAD + kk];
            float4 ta3 = *(const float4*)&k_s[(t0 + 3) * PAD + kk];
            float4 sb0 = *(const float4*)&k_s[(s0 + 0) * PAD + kk];
            float4 sb1 = *(const float4*)&k_s[(s0 + 1) * PAD + kk];
            float4 sb2 = *(const float4*)&k_s[(s0 + 2) * PAD + kk];
            float4 sb3 = *(const float4*)&k_s[(s0 + 3) * PAD + kk];
            acc[0][0] += DOT4(ta0, sb0); acc[0][1] += DOT4(ta0, sb1);
            acc[0][2] += DOT4(ta0, sb2); acc[0][3] += DOT4(ta0, sb3);
            acc[1][0] += DOT4(ta1, sb0); acc[1][1] += DOT4(ta1, sb1);
            acc[1][2] += DOT4(ta1, sb2); acc[1][3] += DOT4(ta1, sb3);
            acc[2][0] += DOT4(ta2, sb0); acc[2][1] += DOT4(ta2, sb1);
            acc[2][2] += DOT4(ta2, sb2); acc[2][3] += DOT4(ta2, sb3);
            acc[3][0] += DOT4(ta3, sb0); acc[3][1] += DOT4(ta3, sb1);
            acc[3][2] += DOT4(ta3, sb2); acc[3][3] += DOT4(ta3, sb3);
        }
#pragma unroll
        for (int i = 0; i < 4; ++i)
#pragma unroll
            for (int j = 0; j < 4; ++j) {
                const int t = t0 + i, s = s0 + j;
                A_s[t * PAD + s] = (s < t) ? acc[i][j] * beta_s[t] * __expf(b_s[t] - b_s[s]) : 0.0f;
            }
    }
    __syncthreads();

    // invert 4 diagonal 16x16 unit-lower blocks (constant-indexed tcol)
    if (tid < 64) {
        const int d = tid >> 4;
        const int col = tid & 15;
        const int base = d * 16;
        float tcol[16];
#pragma unroll
        for (int s = 0; s < 16; ++s) tcol[s] = (s == col) ? 1.0f : 0.0f;
#pragma unroll
        for (int t = 1; t < 16; ++t) {
            float a = 0.0f;
#pragma unroll
            for (int s = 0; s < 16; ++s)
                if (s < t) a += A_s[(base + t) * PAD + base + s] * tcol[s];
            tcol[t] -= a;
        }
#pragma unroll
        for (int t = 0; t < 16; ++t) T_s[d][t * 17 + col] = tcol[t];
    }
    __syncthreads();

    // blocked solve: named float4 accumulators, no local arrays
    {
        const int r = tid >> 4;          // row within block, 0..15
        const int cg = tid & 15;         // col group
        float* Wc = (cg < 8) ? wv_s : wk_s;
        const int cc = (cg & 7) * 8;     // 8 columns per thread

        for (int tb = 0; tb < 4; ++tb) {
            const int t = tb * 16 + r;
            if (tb > 0) {
                float4 lo = *(const float4*)&Wc[t * PAD + cc];
                float4 hi = *(const float4*)&Wc[t * PAD + cc + 4];
#pragma unroll 4
                for (int s = 0; s < tb * 16; ++s) {
                    const float a = A_s[t * PAD + s];
                    float4 wlo = *(const float4*)&Wc[s * PAD + cc];
                    float4 whi = *(const float4*)&Wc[s * PAD + cc + 4];
                    lo.x -= a * wlo.x; lo.y -= a * wlo.y; lo.z -= a * wlo.z; lo.w -= a * wlo.w;
                    hi.x -= a * whi.x; hi.y -= a * whi.y; hi.z -= a * whi.z; hi.w -= a * whi.w;
                }
                *(float4*)&Wc[t * PAD + cc] = lo;
                *(float4*)&Wc[t * PAD + cc + 4] = hi;
            }
            __syncthreads();
            float4 alo = make_float4(0, 0, 0, 0);
            float4 ahi = make_float4(0, 0, 0, 0);
#pragma unroll 4
            for (int s = 0; s < 16; ++s) {
                const float tv = T_s[tb][r * 17 + s];
                float4 wlo = *(const float4*)&Wc[(tb * 16 + s) * PAD + cc];
                float4 whi = *(const float4*)&Wc[(tb * 16 + s) * PAD + cc + 4];
                alo.x += tv * wlo.x; alo.y += tv * wlo.y; alo.z += tv * wlo.z; alo.w += tv * wlo.w;
                ahi.x += tv * whi.x; ahi.y += tv * whi.y; ahi.z += tv * whi.z; ahi.w += tv * whi.w;
            }
            __syncthreads();   // all reads of the block done before overwrite
            *(float4*)&Wc[t * PAD + cc] = alo;
            *(float4*)&Wc[t * PAD + cc + 4] = ahi;
            __syncthreads();
        }
    }

    // write out
    float4* Wvg = (float4*)(Wv + (size_t)blk * 4096);
    float4* Wkg = (float4*)(Wk + (size_t)blk * 4096);
#pragma unroll
    for (int i = 0; i < 4; ++i) {
        int f = tid + i * 256;
        int d = (f >> 4) * PAD + (f & 15) * 4;
        Wvg[f] = *(float4*)&wv_s[d];
        Wkg[f] = *(float4*)&wk_s[d];
    }
}

// ---------------------------------------------------------------------------
// Phase B: sequential chunk recurrence (unchanged)
// ---------------------------------------------------------------------------
__global__ __launch_bounds__(256) void state_k(const float* __restrict__ Kc,
                                               float* __restrict__ Wio,
                                               const float* __restrict__ Wk,
                                               const float* __restrict__ bcum,
                                               float* __restrict__ Hst) {
    __shared__ __align__(16) float h_s[CL * PAD];
    __shared__ __align__(16) float w_s[CL * PAD];
    __shared__ __align__(16) float x_s[CL * PAD];
    __shared__ float e_s[CL];

    const int bh = blockIdx.x;
    const int tid = threadIdx.x;
    const int r0 = (tid >> 4) * 4;
    const int v0 = (tid & 15) * 4;

#pragma unroll
    for (int i = 0; i < 4; ++i) {
        int f = tid + i * 256;
        int d = (f >> 4) * PAD + (f & 15) * 4;
        *(float4*)&h_s[d] = make_float4(0, 0, 0, 0);
    }
    __syncthreads();

    for (int c = 0; c < NC; ++c) {
        const size_t blk = (size_t)bh * NC + c;
        float4* Hg = (float4*)(Hst + blk * 4096);
        const float4* Wkg = (const float4*)(Wk + blk * 4096);
#pragma unroll
        for (int i = 0; i < 4; ++i) {
            int f = tid + i * 256;
            int d = (f >> 4) * PAD + (f & 15) * 4;
            Hg[f] = *(float4*)&h_s[d];
            *(float4*)&x_s[d] = Wkg[f];
        }
        const float bC = bcum[blk * 64 + 63];
        if (tid < 64) e_s[tid] = __expf(bC - bcum[blk * 64 + tid]);
        __syncthreads();

        float acc[4][4];
        {
            const float4* Wvg = (const float4*)(Wio + blk * 4096);
#pragma unroll
            for (int i = 0; i < 4; ++i) f4a(Wvg[(r0 + i) * 16 + (v0 >> 2)], acc[i]);
            for (int kk = 0; kk < 64; kk += 4) {
                float a[4][4], hb[4][4];
#pragma unroll
                for (int i = 0; i < 4; ++i) f4a(*(const float4*)&x_s[(r0 + i) * PAD + kk], a[i]);
#pragma unroll
                for (int m = 0; m < 4; ++m) f4a(*(const float4*)&h_s[(kk + m) * PAD + v0], hb[m]);
#pragma unroll
                for (int i = 0; i < 4; ++i)
#pragma unroll
                    for (int m = 0; m < 4; ++m)
#pragma unroll
                        for (int j = 0; j < 4; ++j) acc[i][j] -= a[i][m] * hb[m][j];
            }
        }
        __syncthreads();
        {
            float4* Wg = (float4*)(Wio + blk * 4096);
            const float4* Kg = (const float4*)(Kc + blk * 4096);
#pragma unroll
            for (int i = 0; i < 4; ++i) {
                float4 r = make_float4(acc[i][0], acc[i][1], acc[i][2], acc[i][3]);
                *(float4*)&w_s[(r0 + i) * PAD + v0] = r;
                Wg[(r0 + i) * 16 + (v0 >> 2)] = r;
            }
#pragma unroll
            for (int i = 0; i < 4; ++i) {
                int f = tid + i * 256;
                int d = (f >> 4) * PAD + (f & 15) * 4;
                *(float4*)&x_s[d] = Kg[f];
            }
        }
        __syncthreads();
        {
            const float eb = __expf(bC);
#pragma unroll
            for (int i = 0; i < 4; ++i)
#pragma unroll
                for (int j = 0; j < 4; ++j) acc[i][j] = eb * h_s[(r0 + i) * PAD + v0 + j];
            for (int ss = 0; ss < 64; ss += 4) {
                float kf[4][4], wb[4][4];
#pragma unroll
                for (int m = 0; m < 4; ++m) {
                    f4a(*(const float4*)&x_s[(ss + m) * PAD + r0], kf[m]);
                    f4a(*(const float4*)&w_s[(ss + m) * PAD + v0], wb[m]);
                    const float e = e_s[ss + m];
#pragma unroll
                    for (int i = 0; i < 4; ++i) kf[m][i] *= e;
                }
#pragma unroll
                for (int i = 0; i < 4; ++i)
#pragma unroll
                    for (int m = 0; m < 4; ++m)
#pragma unroll
                        for (int j = 0; j < 4; ++j) acc[i][j] += kf[m][i] * wb[m][j];
            }
        }
        __syncthreads();
#pragma unroll
        for (int i = 0; i < 4; ++i)
            *(float4*)&h_s[(r0 + i) * PAD + v0] =
                make_float4(acc[i][0], acc[i][1], acc[i][2], acc[i][3]);
        __syncthreads();
    }
}

// ---------------------------------------------------------------------------
// Phase C: per (bh,chunk) outputs (unchanged)
// ---------------------------------------------------------------------------
__global__ __launch_bounds__(256) void out_k(const float* __restrict__ Qc,
                                             const float* __restrict__ Kc,
                                             const float* __restrict__ Wb_,
                                             const float* __restrict__ Hst,
                                             const float* __restrict__ bcum,
                                             float* __restrict__ o_scan) {
    __shared__ __align__(16) float q_s[4096];
    __shared__ __align__(16) float k_s[4096];
    __shared__ __align__(16) float h_s[4096];
    __shared__ __align__(16) float w_s[4096];
    __shared__ float b_s[64];

    const int blk = blockIdx.x;
    const int bh = blk >> 5;
    const int c = blk & 31;
    const int b = bh >> 4;
    const int h = bh & 15;
    const int tid = threadIdx.x;

    if (tid < 64) b_s[tid] = bcum[(size_t)blk * 64 + tid];
    {
        const float4* Qg = (const float4*)(Qc + (size_t)blk * 4096);
        const float4* Kg = (const float4*)(Kc + (size_t)blk * 4096);
        const float4* Hg = (const float4*)(Hst + (size_t)blk * 4096);
        const float4* Wg = (const float4*)(Wb_ + (size_t)blk * 4096);
#pragma unroll
        for (int i = 0; i < 4; ++i) {
            int f = tid + i * 256;
            ((float4*)q_s)[f] = Qg[f];
            ((float4*)k_s)[f] = Kg[f];
            ((float4*)h_s)[f] = Hg[f];
            ((float4*)w_s)[f] = Wg[f];
        }
    }
    __syncthreads();

    {
        const int t0 = (tid >> 4) * 4, s0 = (tid & 15) * 4;
        float acc[4][4] = {};
        for (int kk = 0; kk < 64; kk += 4) {
            float qa[4][4], kb[4][4];
#pragma unroll
            for (int i = 0; i < 4; ++i) f4a(*(const float4*)&q_s[(t0 + i) * 64 + kk], qa[i]);
#pragma unroll
            for (int j = 0; j < 4; ++j) f4a(*(const float4*)&k_s[(s0 + j) * 64 + kk], kb[j]);
#pragma unroll
            for (int i = 0; i < 4; ++i)
#pragma unroll
                for (int j = 0; j < 4; ++j)
#pragma unroll
                    for (int m = 0; m < 4; ++m) acc[i][j] += qa[i][m] * kb[j][m];
        }
        __syncthreads();
#pragma unroll
        for (int i = 0; i < 4; ++i)
#pragma unroll
            for (int j = 0; j < 4; ++j) {
                const int t = t0 + i, s = s0 + j;
                k_s[t * 64 + s] = (s <= t) ? acc[i][j] * __expf(b_s[t] - b_s[s]) : 0.0f;
            }
    }
#pragma unroll
    for (int i = 0; i < 16; ++i) {
        int e = tid + i * 256;
        q_s[e] *= __expf(b_s[e >> 6]);
    }
    __syncthreads();

    {
        const int t0 = (tid >> 4) * 4, v0 = (tid & 15) * 4;
        float acc[4][4] = {};
        for (int ss = 0; ss < 64; ss += 4) {
            float sa[4][4], wb[4][4];
#pragma unroll
            for (int i = 0; i < 4; ++i) f4a(*(const float4*)&k_s[(t0 + i) * 64 + ss], sa[i]);
#pragma unroll
            for (int m = 0; m < 4; ++m) f4a(*(const float4*)&w_s[(ss + m) * 64 + v0], wb[m]);
#pragma unroll
            for (int i = 0; i < 4; ++i)
#pragma unroll
                for (int m = 0; m < 4; ++m)
#pragma unroll
                    for (int j = 0; j < 4; ++j) acc[i][j] += sa[i][m] * wb[m][j];
        }
        for (int kk = 0; kk < 64; kk += 4) {
            float qa[4][4], hb[4][4];
#pragma unroll
            for (int i = 0; i < 4; ++i) f4a(*(const float4*)&q_s[(t0 + i) * 64 + kk], qa[i]);
#pragma unroll
            for (int m = 0; m < 4; ++m) f4a(*(const float4*)&h_s[(kk + m) * 64 + v0], hb[m]);
#pragma unroll
            for (int i = 0; i < 4; ++i)
#pragma unroll
                for (int m = 0; m < 4; ++m)
#pragma unroll
                    for (int j = 0; j < 4; ++j) acc[i][j] += qa[i][m] * hb[m][j];
        }
#pragma unroll
        for (int i = 0; i < 4; ++i) {
            const int t = c * CL + t0 + i;
            *(float4*)&o_scan[(((size_t)b * TT + t) * HH + h) * DK + v0] =
                make_float4(acc[i][0], acc[i][1], acc[i][2], acc[i][3]);
        }
    }
}

// ---------------------------------------------------------------------------
// Gated RMSNorm -> bf16 output (unchanged)
// ---------------------------------------------------------------------------
__global__ __launch_bounds__(256) void gnorm_k(const float* __restrict__ o_scan,
                                               const float* __restrict__ gate,
                                               const float* __restrict__ rms_w,
                                               unsigned short* __restrict__ o2) {
    const int tid = threadIdx.x;
    const int grp = tid >> 6;
    const int lane = tid & 63;
    const int bth = blockIdx.x * 4 + grp;
    const int h = bth & 15;
    const int row = bth >> 4;

    float ov = o_scan[(size_t)bth * DK + lane];
    float s = ov * ov;
#pragma unroll
    for (int sh = 32; sh > 0; sh >>= 1) s += __shfl_xor(s, sh);
    float r = rsqrtf(s * (1.0f / 64.0f) + 1e-5f);

    float gt = gate[(size_t)row * HD + h * DK + lane];
    o2[(size_t)row * HD + h * DK + lane] = f2bf(ov * r * rms_w[lane] * siluf_(gt));
}

// ---------------------------------------------------------------------------
extern "C" void kernel_launch(void* const* d_in, const int* in_sizes, int n_in,
                              void* d_out, int out_size, void* d_ws, size_t ws_size,
                              hipStream_t stream) {
    (void)in_sizes; (void)n_in; (void)out_size; (void)ws_size;

    const float* x       = (const float*)d_in[0];
    const float* Wq      = (const float*)d_in[1];
    const float* Wk_     = (const float*)d_in[2];
    const float* Wv_     = (const float*)d_in[3];
    const float* Wa      = (const float*)d_in[4];
    const float* Wb      = (const float*)d_in[5];
    const float* Wg      = (const float*)d_in[6];
    const float* Wo      = (const float*)d_in[7];
    const float* conv_q  = (const float*)d_in[8];
    const float* conv_k  = (const float*)d_in[9];
    const float* conv_v  = (const float*)d_in[10];
    const float* A_log   = (const float*)d_in[11];
    const float* dt_bias = (const float*)d_in[12];
    const float* rms_w   = (const float*)d_in[13];
    float* out = (float*)d_out;

    float* ws = (float*)d_ws;
    const size_t NTOK = (size_t)BB * TT;     // 4096
    const size_t BIG = NTOK * HD;            // 4 Mi floats

    float* q_pre = ws + 0 * BIG;
    float* k_pre = ws + 1 * BIG;
    float* v_pre = ws + 2 * BIG;
    float* gatep = ws + 3 * BIG;
    float* Qc    = ws + 4 * BIG;
    float* Kc    = ws + 5 * BIG;
    float* gbuf  = ws + 6 * BIG;
    float* bbuf  = gbuf + NTOK * HH;
    float* bcumb = bbuf + NTOK * HH;

    // bf16 buffers after the fp32 region
    unsigned short* xb  = (unsigned short*)(bcumb + NTOK * HH);
    unsigned short* wqt = xb + (size_t)NTOK * DD;
    unsigned short* wkt = wqt + (size_t)DD * HD;
    unsigned short* wvt = wkt + (size_t)DD * HD;
    unsigned short* wgt = wvt + (size_t)DD * HD;
    unsigned short* wot = wgt + (size_t)DD * HD;

    // aliases (stream-ordered lifetimes):
    float* Wvb    = q_pre;
    float* Wkb    = k_pre;
    float* Hst    = v_pre;
    float* o_scan = k_pre;
    unsigned short* o2b = (unsigned short*)Qc;

    // casts
    castx_k<<<(int)(NTOK * DD / (256 * 8)), 256, 0, stream>>>(x, xb);
    dim3 tg(16, 16);
    castw_k<<<tg, 256, 0, stream>>>(Wq, wqt);
    castw_k<<<tg, 256, 0, stream>>>(Wk_, wkt);
    castw_k<<<tg, 256, 0, stream>>>(Wv_, wvt);
    castw_k<<<tg, 256, 0, stream>>>(Wg, wgt);
    castw_k<<<tg, 256, 0, stream>>>(Wo, wot);

    // projections
    dim3 gg(HD / 128, NTOK / 128);   // (8, 32)
    gemm_bf16_k<<<gg, 256, 0, stream>>>(xb, wqt, q_pre, (int)NTOK, HD, DD);
    gemm_bf16_k<<<gg, 256, 0, stream>>>(xb, wkt, k_pre, (int)NTOK, HD, DD);
    gemm_bf16_k<<<gg, 256, 0, stream>>>(xb, wvt, v_pre, (int)NTOK, HD, DD);
    gemm_bf16_k<<<gg, 256, 0, stream>>>(xb, wgt, gatep, (int)NTOK, HD, DD);

    gbeta_k<<<(int)NTOK, 256, 0, stream>>>(x, Wa, Wb, A_log, dt_bias, gbuf, bbuf);

    stage_k<<<BB * HH * NC, 64, 0, stream>>>(q_pre, k_pre, conv_q, conv_k, gbuf,
                                             Qc, Kc, bcumb);

    prep_k<<<BB * HH * NC, 256, 0, stream>>>(Kc, v_pre, conv_v, bcumb, bbuf, Wvb, Wkb);

    state_k<<<BB * HH, 256, 0, stream>>>(Kc, Wvb, Wkb, bcumb, Hst);

    out_k<<<BB * HH * NC, 256, 0, stream>>>(Qc, Kc, Wvb, Hst, bcumb, o_scan);

    gnorm_k<<<(int)(NTOK * HH / 4), 256, 0, stream>>>(o_scan, gatep, rms_w, o2b);

    gemm_bf16_k<<<gg, 256, 0, stream>>>(o2b, wot, out, (int)NTOK, HD, DD);
}

// Round 7
// 729.136 us; speedup vs baseline: 8.8296x; 1.0928x over previous
//
#include <hip/hip_runtime.h>
#include <hip/hip_bf16.h>
#include <math.h>
#include <stdint.h>

// Problem constants
#define BB 2
#define TT 2048
#define DD 1024
#define HH 16
#define DK 64
#define HD 1024   // H*DK
#define NC 32     // chunks per sequence (TT/64)
#define CL 64     // chunk length
#define PAD 68    // padded LDS row stride (floats) to break stride-64 bank conflicts

typedef short bf16x8 __attribute__((ext_vector_type(8)));     // 8 bf16 (4 VGPRs)
typedef float f32x4 __attribute__((ext_vector_type(4)));      // MFMA acc
typedef unsigned short u16x8 __attribute__((ext_vector_type(8)));
typedef unsigned short u16x4 __attribute__((ext_vector_type(4)));

#define GAS __attribute__((address_space(1)))
#define LAS __attribute__((address_space(3)))

#define DOT4(a, b) ((a).x*(b).x + (a).y*(b).y + (a).z*(b).z + (a).w*(b).w)

// acc[i][j] += kf[i-component] * wv[j-component]   (one contraction step)
#define OUT16(acc, kf, wv) \
    acc[0][0] += kf.x * wv.x; acc[0][1] += kf.x * wv.y; acc[0][2] += kf.x * wv.z; acc[0][3] += kf.x * wv.w; \
    acc[1][0] += kf.y * wv.x; acc[1][1] += kf.y * wv.y; acc[1][2] += kf.y * wv.z; acc[1][3] += kf.y * wv.w; \
    acc[2][0] += kf.z * wv.x; acc[2][1] += kf.z * wv.y; acc[2][2] += kf.z * wv.z; acc[2][3] += kf.z * wv.w; \
    acc[3][0] += kf.w * wv.x; acc[3][1] += kf.w * wv.y; acc[3][2] += kf.w * wv.z; acc[3][3] += kf.w * wv.w;

// acc[i][j] -= wa_i.c * hv[j]   (c = component selecting m)
#define WSUB(c, hv) \
    acc[0][0] -= wa0.c * hv.x; acc[0][1] -= wa0.c * hv.y; acc[0][2] -= wa0.c * hv.z; acc[0][3] -= wa0.c * hv.w; \
    acc[1][0] -= wa1.c * hv.x; acc[1][1] -= wa1.c * hv.y; acc[1][2] -= wa1.c * hv.z; acc[1][3] -= wa1.c * hv.w; \
    acc[2][0] -= wa2.c * hv.x; acc[2][1] -= wa2.c * hv.y; acc[2][2] -= wa2.c * hv.z; acc[2][3] -= wa2.c * hv.w; \
    acc[3][0] -= wa3.c * hv.x; acc[3][1] -= wa3.c * hv.y; acc[3][2] -= wa3.c * hv.z; acc[3][3] -= wa3.c * hv.w;

__device__ __forceinline__ float sigmoidf_(float x) { return 1.0f / (1.0f + expf(-x)); }
__device__ __forceinline__ float siluf_(float x) { return x * sigmoidf_(x); }
__device__ __forceinline__ void f4a(const float4 v, float* o) { o[0]=v.x; o[1]=v.y; o[2]=v.z; o[3]=v.w; }

// round-to-nearest-even fp32 -> bf16
__device__ __forceinline__ unsigned short f2bf(float f) {
    unsigned int u = __builtin_bit_cast(unsigned int, f);
    u = (u + 0x7fffu + ((u >> 16) & 1u)) >> 16;
    return (unsigned short)u;
}

// ---------------------------------------------------------------------------
// Cast x (fp32) -> bf16, flat.
// ---------------------------------------------------------------------------
__global__ __launch_bounds__(256) void castx_k(const float* __restrict__ src,
                                               unsigned short* __restrict__ dst) {
    const size_t idx = (size_t)blockIdx.x * 256 + threadIdx.x;
    float4 a = *(const float4*)&src[idx * 8];
    float4 b = *(const float4*)&src[idx * 8 + 4];
    u16x8 o;
    o[0] = f2bf(a.x); o[1] = f2bf(a.y); o[2] = f2bf(a.z); o[3] = f2bf(a.w);
    o[4] = f2bf(b.x); o[5] = f2bf(b.y); o[6] = f2bf(b.z); o[7] = f2bf(b.w);
    *(u16x8*)&dst[idx * 8] = o;
}

// ---------------------------------------------------------------------------
// Transpose+cast weight: W[K=1024][N=1024] fp32 -> Wt[N][K] bf16.
// ---------------------------------------------------------------------------
__global__ __launch_bounds__(256) void castw_k(const float* __restrict__ W,
                                               unsigned short* __restrict__ Wt) {
    __shared__ float t_s[64][65];
    const int tid = threadIdx.x;
    const int rr = tid >> 4;
    const int cc = tid & 15;
    const int r0 = blockIdx.y * 64;
    const int c0 = blockIdx.x * 64;
#pragma unroll
    for (int i = 0; i < 4; ++i) {
        const int row = rr + i * 16;
        float4 v = *(const float4*)&W[(size_t)(r0 + row) * 1024 + c0 + cc * 4];
        t_s[row][cc * 4 + 0] = v.x;
        t_s[row][cc * 4 + 1] = v.y;
        t_s[row][cc * 4 + 2] = v.z;
        t_s[row][cc * 4 + 3] = v.w;
    }
    __syncthreads();
#pragma unroll
    for (int i = 0; i < 4; ++i) {
        const int nr = rr + i * 16;
        u16x4 o;
#pragma unroll
        for (int d = 0; d < 4; ++d) o[d] = f2bf(t_s[cc * 4 + d][nr]);
        *(u16x4*)&Wt[(size_t)(c0 + nr) * 1024 + r0 + cc * 4] = o;
    }
}

// ---------------------------------------------------------------------------
// bf16 MFMA GEMM (m97 structure), unchanged.
// ---------------------------------------------------------------------------
__global__ __launch_bounds__(256) void gemm_bf16_k(const unsigned short* __restrict__ A,
                                                   const unsigned short* __restrict__ Bt,
                                                   float* __restrict__ C,
                                                   int M, int N, int Kd) {
    __shared__ unsigned short a_s[128 * 32];
    __shared__ unsigned short b_s[128 * 32];

    const int tid = threadIdx.x;
    const int wave = tid >> 6;
    const int lane = tid & 63;
    const int m0 = blockIdx.y * 128;
    const int n0 = blockIdx.x * 128;

    const int quad = lane >> 4;
    const int l16 = lane & 15;
    const int wr = wave >> 1;
    const int wc = wave & 1;

    const int srow = lane >> 2;
    const int sseg = lane & 3;

    f32x4 acc[4][4];
#pragma unroll
    for (int i = 0; i < 4; ++i)
#pragma unroll
        for (int j = 0; j < 4; ++j) acc[i][j] = (f32x4){0.f, 0.f, 0.f, 0.f};

    for (int k0 = 0; k0 < Kd; k0 += 32) {
        __syncthreads();
#pragma unroll
        for (int c = 0; c < 2; ++c) {
            const int region = wave * 2 + c;
            const int r0t = region * 16;
            const int ra = r0t + srow;
            const unsigned short* ga = A + (size_t)(m0 + ra) * Kd + k0 + sseg * 8;
            const unsigned short* gb = Bt + (size_t)(n0 + ra) * Kd + k0 + sseg * 8;
            __builtin_amdgcn_global_load_lds((const GAS unsigned int*)ga,
                                             (LAS unsigned int*)&a_s[r0t * 32], 16, 0, 0);
            __builtin_amdgcn_global_load_lds((const GAS unsigned int*)gb,
                                             (LAS unsigned int*)&b_s[r0t * 32], 16, 0, 0);
        }
        __syncthreads();

        bf16x8 af[4], bfr[4];
#pragma unroll
        for (int i = 0; i < 4; ++i)
            af[i] = *(const bf16x8*)&a_s[(wr * 64 + i * 16 + l16) * 32 + quad * 8];
#pragma unroll
        for (int j = 0; j < 4; ++j)
            bfr[j] = *(const bf16x8*)&b_s[(wc * 64 + j * 16 + l16) * 32 + quad * 8];
#pragma unroll
        for (int i = 0; i < 4; ++i)
#pragma unroll
            for (int j = 0; j < 4; ++j)
                acc[i][j] = __builtin_amdgcn_mfma_f32_16x16x32_bf16(af[i], bfr[j], acc[i][j], 0, 0, 0);
    }

#pragma unroll
    for (int i = 0; i < 4; ++i)
#pragma unroll
        for (int j = 0; j < 4; ++j) {
            const int col = n0 + wc * 64 + j * 16 + l16;
#pragma unroll
            for (int r = 0; r < 4; ++r) {
                const int row = m0 + wr * 64 + i * 16 + quad * 4 + r;
                C[(size_t)row * N + col] = acc[i][j][r];
            }
        }
}

// ---------------------------------------------------------------------------
// g / beta kernel (R4 version, unchanged)
// ---------------------------------------------------------------------------
__global__ __launch_bounds__(256) void gbeta_k(const float* __restrict__ x,
                                               const float* __restrict__ Wa,
                                               const float* __restrict__ Wb,
                                               const float* __restrict__ A_log,
                                               const float* __restrict__ dt_bias,
                                               float* __restrict__ g,
                                               float* __restrict__ beta) {
    __shared__ __align__(16) float xs[DD];
    const int row = blockIdx.x;
    const int tid = threadIdx.x;

    *(float4*)&xs[tid * 4] = *(const float4*)&x[(size_t)row * DD + tid * 4];
    __syncthreads();

    const int out = tid >> 3;   // 0..31
    const int part = tid & 7;   // 0..7
    const int h = out & 15;
    const float* W = (out < 16) ? Wa : Wb;

    float s = 0.0f;
#pragma unroll 8
    for (int i = 0; i < 32; ++i) {
        const int d = i * 32 + part * 4;
        float4 xv = *(const float4*)&xs[d];
        s += xv.x * W[(size_t)(d + 0) * HH + h];
        s += xv.y * W[(size_t)(d + 1) * HH + h];
        s += xv.z * W[(size_t)(d + 2) * HH + h];
        s += xv.w * W[(size_t)(d + 3) * HH + h];
    }
    s += __shfl_xor(s, 1);
    s += __shfl_xor(s, 2);
    s += __shfl_xor(s, 4);

    if (part == 0) {
        if (out < 16) {
            float v = s + dt_bias[h];
            float sp = (v > 20.0f) ? v : log1pf(expf(v));
            g[(size_t)row * HH + h] = -expf(A_log[h]) * sp;
        } else {
            beta[(size_t)row * HH + h] = sigmoidf_(s);
        }
    }
}

// ---------------------------------------------------------------------------
// Phase A1: stage normalized q,k (conv+silu+l2norm) and cumsum(g). (unchanged)
// ---------------------------------------------------------------------------
__global__ __launch_bounds__(64) void stage_k(const float* __restrict__ q_pre,
                                              const float* __restrict__ k_pre,
                                              const float* __restrict__ cq,
                                              const float* __restrict__ ck,
                                              const float* __restrict__ g,
                                              float* __restrict__ Qc,
                                              float* __restrict__ Kc,
                                              float* __restrict__ bcum) {
    const int blk = blockIdx.x;
    const int bh = blk >> 5;
    const int c = blk & 31;
    const int b = bh >> 4;
    const int h = bh & 15;
    const int lane = threadIdx.x;
    const int ch = h * DK + lane;

    const float4 wq4 = *(const float4*)&cq[ch * 4];
    const float4 wk4 = *(const float4*)&ck[ch * 4];

    float qw0 = 0, qw1 = 0, qw2 = 0, kw0 = 0, kw1 = 0, kw2 = 0;
    {
        const int t0 = c * CL;
        if (t0 - 3 >= 0) { size_t bi = ((size_t)b * TT + t0 - 3) * HD + ch; qw0 = q_pre[bi]; kw0 = k_pre[bi]; }
        if (t0 - 2 >= 0) { size_t bi = ((size_t)b * TT + t0 - 2) * HD + ch; qw1 = q_pre[bi]; kw1 = k_pre[bi]; }
        if (t0 - 1 >= 0) { size_t bi = ((size_t)b * TT + t0 - 1) * HD + ch; qw2 = q_pre[bi]; kw2 = k_pre[bi]; }
    }
    float* Qo = Qc + (size_t)blk * 4096;
    float* Ko = Kc + (size_t)blk * 4096;

    for (int tt = 0; tt < CL; ++tt) {
        const int t = c * CL + tt;
        const size_t bi = ((size_t)b * TT + t) * HD + ch;
        const float qc_ = q_pre[bi];
        const float kc_ = k_pre[bi];
        float qa = qw0 * wq4.x + qw1 * wq4.y + qw2 * wq4.z + qc_ * wq4.w;
        float ka = kw0 * wk4.x + kw1 * wk4.y + kw2 * wk4.z + kc_ * wk4.w;
        qw0 = qw1; qw1 = qw2; qw2 = qc_;
        kw0 = kw1; kw1 = kw2; kw2 = kc_;
        qa = siluf_(qa);
        ka = siluf_(ka);
        float qs2 = qa * qa, ks2 = ka * ka;
#pragma unroll
        for (int s = 32; s > 0; s >>= 1) {
            qs2 += __shfl_xor(qs2, s);
            ks2 += __shfl_xor(ks2, s);
        }
        Qo[tt * 64 + lane] = qa * rsqrtf(qs2 + 1e-6f) * 0.125f;
        Ko[tt * 64 + lane] = ka * rsqrtf(ks2 + 1e-6f);
    }

    float cum = g[((size_t)b * TT + c * CL + lane) * HH + h];
#pragma unroll
    for (int s = 1; s < 64; s <<= 1) {
        float u = __shfl_up(cum, s);
        if (lane >= s) cum += u;
    }
    bcum[(size_t)blk * 64 + lane] = cum;
}

// ---------------------------------------------------------------------------
// Phase A2 (R5): scratch-free blocked triangular solve (unchanged)
// ---------------------------------------------------------------------------
__global__ __launch_bounds__(256) void prep_k(const float* __restrict__ Kc,
                                              const float* __restrict__ v_pre,
                                              const float* __restrict__ cv,
                                              const float* __restrict__ bcum,
                                              const float* __restrict__ bbuf,
                                              float* __restrict__ Wv,
                                              float* __restrict__ Wk) {
    __shared__ __align__(16) float k_s[CL * PAD];
    __shared__ __align__(16) float wv_s[CL * PAD];
    __shared__ __align__(16) float wk_s[CL * PAD];
    __shared__ __align__(16) float A_s[CL * PAD];
    __shared__ float T_s[4][16 * 17];
    __shared__ float b_s[CL], beta_s[CL], bk_s[CL];

    const int blk = blockIdx.x;
    const int bh = blk >> 5;
    const int c = blk & 31;
    const int b = bh >> 4;
    const int h = bh & 15;
    const int tid = threadIdx.x;

    if (tid < 64) {
        float bv = bcum[(size_t)blk * 64 + tid];
        float be = bbuf[((size_t)b * TT + c * CL + tid) * HH + h];
        b_s[tid] = bv;
        beta_s[tid] = be;
        bk_s[tid] = be * __expf(bv);
    }
    __syncthreads();

    {
        const float4* Kg = (const float4*)(Kc + (size_t)blk * 4096);
#pragma unroll
        for (int i = 0; i < 4; ++i) {
            int f = tid + i * 256;
            int t = f >> 4;
            int d = t * PAD + (f & 15) * 4;
            float4 kv = Kg[f];
            *(float4*)&k_s[d] = kv;
            float sk = bk_s[t];
            *(float4*)&wk_s[d] = make_float4(kv.x * sk, kv.y * sk, kv.z * sk, kv.w * sk);
        }
    }

    {
        const int lane = tid & 63;
        const int q4 = tid >> 6;
        const int ch = h * DK + lane;
        const float4 wv4 = *(const float4*)&cv[ch * 4];
        const int T0 = c * CL + q4 * 16;
        float w0 = 0, w1 = 0, w2 = 0;
        if (T0 - 3 >= 0) w0 = v_pre[((size_t)b * TT + T0 - 3) * HD + ch];
        if (T0 - 2 >= 0) w1 = v_pre[((size_t)b * TT + T0 - 2) * HD + ch];
        if (T0 - 1 >= 0) w2 = v_pre[((size_t)b * TT + T0 - 1) * HD + ch];
#pragma unroll 1
        for (int i = 0; i < 16; ++i) {
            const int t = T0 + i;
            const float vc_ = v_pre[((size_t)b * TT + t) * HD + ch];
            float va = w0 * wv4.x + w1 * wv4.y + w2 * wv4.z + vc_ * wv4.w;
            w0 = w1; w1 = w2; w2 = vc_;
            va = siluf_(va);
            wv_s[(q4 * 16 + i) * PAD + lane] = va * beta_s[q4 * 16 + i];
        }
    }
    __syncthreads();

    {
        const int t0 = (tid >> 4) * 4, s0 = (tid & 15) * 4;
        float acc[4][4] = {};
        for (int kk = 0; kk < 64; kk += 4) {
            float4 ta0 = *(const float4*)&k_s[(t0 + 0) * PAD + kk];
            float4 ta1 = *(const float4*)&k_s[(t0 + 1) * PAD + kk];
            float4 ta2 = *(const float4*)&k_s[(t0 + 2) * PAD + kk];
            float4 ta3 = *(const float4*)&k_s[(t0 + 3) * PAD + kk];
            float4 sb0 = *(const float4*)&k_s[(s0 + 0) * PAD + kk];
            float4 sb1 = *(const float4*)&k_s[(s0 + 1) * PAD + kk];
            float4 sb2 = *(const float4*)&k_s[(s0 + 2) * PAD + kk];
            float4 sb3 = *(const float4*)&k_s[(s0 + 3) * PAD + kk];
            acc[0][0] += DOT4(ta0, sb0); acc[0][1] += DOT4(ta0, sb1);
            acc[0][2] += DOT4(ta0, sb2); acc[0][3] += DOT4(ta0, sb3);
            acc[1][0] += DOT4(ta1, sb0); acc[1][1] += DOT4(ta1, sb1);
            acc[1][2] += DOT4(ta1, sb2); acc[1][3] += DOT4(ta1, sb3);
            acc[2][0] += DOT4(ta2, sb0); acc[2][1] += DOT4(ta2, sb1);
            acc[2][2] += DOT4(ta2, sb2); acc[2][3] += DOT4(ta2, sb3);
            acc[3][0] += DOT4(ta3, sb0); acc[3][1] += DOT4(ta3, sb1);
            acc[3][2] += DOT4(ta3, sb2); acc[3][3] += DOT4(ta3, sb3);
        }
#pragma unroll
        for (int i = 0; i < 4; ++i)
#pragma unroll
            for (int j = 0; j < 4; ++j) {
                const int t = t0 + i, s = s0 + j;
                A_s[t * PAD + s] = (s < t) ? acc[i][j] * beta_s[t] * __expf(b_s[t] - b_s[s]) : 0.0f;
            }
    }
    __syncthreads();

    if (tid < 64) {
        const int d = tid >> 4;
        const int col = tid & 15;
        const int base = d * 16;
        float tcol[16];
#pragma unroll
        for (int s = 0; s < 16; ++s) tcol[s] = (s == col) ? 1.0f : 0.0f;
#pragma unroll
        for (int t = 1; t < 16; ++t) {
            float a = 0.0f;
#pragma unroll
            for (int s = 0; s < 16; ++s)
                if (s < t) a += A_s[(base + t) * PAD + base + s] * tcol[s];
            tcol[t] -= a;
        }
#pragma unroll
        for (int t = 0; t < 16; ++t) T_s[d][t * 17 + col] = tcol[t];
    }
    __syncthreads();

    {
        const int r = tid >> 4;
        const int cg = tid & 15;
        float* Wc = (cg < 8) ? wv_s : wk_s;
        const int cc = (cg & 7) * 8;

        for (int tb = 0; tb < 4; ++tb) {
            const int t = tb * 16 + r;
            if (tb > 0) {
                float4 lo = *(const float4*)&Wc[t * PAD + cc];
                float4 hi = *(const float4*)&Wc[t * PAD + cc + 4];
#pragma unroll 4
                for (int s = 0; s < tb * 16; ++s) {
                    const float a = A_s[t * PAD + s];
                    float4 wlo = *(const float4*)&Wc[s * PAD + cc];
                    float4 whi = *(const float4*)&Wc[s * PAD + cc + 4];
                    lo.x -= a * wlo.x; lo.y -= a * wlo.y; lo.z -= a * wlo.z; lo.w -= a * wlo.w;
                    hi.x -= a * whi.x; hi.y -= a * whi.y; hi.z -= a * whi.z; hi.w -= a * whi.w;
                }
                *(float4*)&Wc[t * PAD + cc] = lo;
                *(float4*)&Wc[t * PAD + cc + 4] = hi;
            }
            __syncthreads();
            float4 alo = make_float4(0, 0, 0, 0);
            float4 ahi = make_float4(0, 0, 0, 0);
#pragma unroll 4
            for (int s = 0; s < 16; ++s) {
                const float tv = T_s[tb][r * 17 + s];
                float4 wlo = *(const float4*)&Wc[(tb * 16 + s) * PAD + cc];
                float4 whi = *(const float4*)&Wc[(tb * 16 + s) * PAD + cc + 4];
                alo.x += tv * wlo.x; alo.y += tv * wlo.y; alo.z += tv * wlo.z; alo.w += tv * wlo.w;
                ahi.x += tv * whi.x; ahi.y += tv * whi.y; ahi.z += tv * whi.z; ahi.w += tv * whi.w;
            }
            __syncthreads();
            *(float4*)&Wc[t * PAD + cc] = alo;
            *(float4*)&Wc[t * PAD + cc + 4] = ahi;
            __syncthreads();
        }
    }

    float4* Wvg = (float4*)(Wv + (size_t)blk * 4096);
    float4* Wkg = (float4*)(Wk + (size_t)blk * 4096);
#pragma unroll
    for (int i = 0; i < 4; ++i) {
        int f = tid + i * 256;
        int d = (f >> 4) * PAD + (f & 15) * 4;
        Wvg[f] = *(float4*)&wv_s[d];
        Wkg[f] = *(float4*)&wk_s[d];
    }
}

// ---------------------------------------------------------------------------
// NEW (R6) Phase B1: per (bh,chunk) chunk-transition operators, fully parallel.
//   A_c = e^{bC} I - K~^T Wk_c   (64x64)
//   B_c = K~^T Wv_c              (64x64),  K~[t] = e^{bC-b_t} K[t]
// grid = 1024, block = 256.
// ---------------------------------------------------------------------------
__global__ __launch_bounds__(256) void ab_k(const float* __restrict__ Kc,
                                            const float* __restrict__ Wv,
                                            const float* __restrict__ Wk,
                                            const float* __restrict__ bcum,
                                            float* __restrict__ Ab,
                                            float* __restrict__ Bb) {
    __shared__ __align__(16) float kt_s[CL * PAD];
    __shared__ __align__(16) float wk_s[CL * PAD];
    __shared__ __align__(16) float wv_s[CL * PAD];
    __shared__ float e_s[CL];
    __shared__ float ebC_s;

    const int blk = blockIdx.x;
    const int tid = threadIdx.x;

    if (tid < 64) {
        float bC = bcum[(size_t)blk * 64 + 63];
        e_s[tid] = __expf(bC - bcum[(size_t)blk * 64 + tid]);
        if (tid == 63) ebC_s = __expf(bC);
    }
    __syncthreads();

    {
        const float4* Kg = (const float4*)(Kc + (size_t)blk * 4096);
        const float4* Wkg = (const float4*)(Wk + (size_t)blk * 4096);
        const float4* Wvg = (const float4*)(Wv + (size_t)blk * 4096);
#pragma unroll
        for (int i = 0; i < 4; ++i) {
            int f = tid + i * 256;
            int t = f >> 4;
            int d = t * PAD + (f & 15) * 4;
            float4 kv = Kg[f];
            float e = e_s[t];
            *(float4*)&kt_s[d] = make_float4(kv.x * e, kv.y * e, kv.z * e, kv.w * e);
            *(float4*)&wk_s[d] = Wkg[f];
            *(float4*)&wv_s[d] = Wvg[f];
        }
    }
    __syncthreads();

    const int k0 = (tid >> 4) * 4, m0 = (tid & 15) * 4;
    float aA[4][4] = {};
    float aB[4][4] = {};
    for (int ss = 0; ss < 64; ss += 4) {
        float4 kf0 = *(const float4*)&kt_s[(ss + 0) * PAD + k0];
        float4 kf1 = *(const float4*)&kt_s[(ss + 1) * PAD + k0];
        float4 kf2 = *(const float4*)&kt_s[(ss + 2) * PAD + k0];
        float4 kf3 = *(const float4*)&kt_s[(ss + 3) * PAD + k0];
        float4 wa0 = *(const float4*)&wk_s[(ss + 0) * PAD + m0];
        float4 wa1 = *(const float4*)&wk_s[(ss + 1) * PAD + m0];
        float4 wa2 = *(const float4*)&wk_s[(ss + 2) * PAD + m0];
        float4 wa3 = *(const float4*)&wk_s[(ss + 3) * PAD + m0];
        float4 wb0 = *(const float4*)&wv_s[(ss + 0) * PAD + m0];
        float4 wb1 = *(const float4*)&wv_s[(ss + 1) * PAD + m0];
        float4 wb2 = *(const float4*)&wv_s[(ss + 2) * PAD + m0];
        float4 wb3 = *(const float4*)&wv_s[(ss + 3) * PAD + m0];
        OUT16(aA, kf0, wa0); OUT16(aA, kf1, wa1); OUT16(aA, kf2, wa2); OUT16(aA, kf3, wa3);
        OUT16(aB, kf0, wb0); OUT16(aB, kf1, wb1); OUT16(aB, kf2, wb2); OUT16(aB, kf3, wb3);
    }

    const float ebC = ebC_s;
    float* Ag = Ab + (size_t)blk * 4096;
    float* Bg = Bb + (size_t)blk * 4096;
#pragma unroll
    for (int i = 0; i < 4; ++i) {
        const int kk = k0 + i;
        float4 av = make_float4(-aA[i][0], -aA[i][1], -aA[i][2], -aA[i][3]);
        if (kk - m0 == 0) av.x += ebC;
        if (kk - m0 == 1) av.y += ebC;
        if (kk - m0 == 2) av.z += ebC;
        if (kk - m0 == 3) av.w += ebC;
        *(float4*)&Ag[kk * 64 + m0] = av;
        *(float4*)&Bg[kk * 64 + m0] = make_float4(aB[i][0], aB[i][1], aB[i][2], aB[i][3]);
    }
}

// ---------------------------------------------------------------------------
// NEW (R6) Phase B2: serial chunk recurrence h' = A_c h + B_c, v-split 8-way.
// grid = 32 bh x 8 vsplit = 256 blocks, 64 threads (one wave). Thread = k-row;
// A row in registers (double-buffered from global); h slice in 2KB LDS
// (broadcast reads). Writes chunk-start states Hst.
// ---------------------------------------------------------------------------
__global__ __launch_bounds__(64) void hrec_k(const float* __restrict__ Ab,
                                             const float* __restrict__ Bb,
                                             float* __restrict__ Hst) {
    const int bh = blockIdx.x >> 3;
    const int vs = blockIdx.x & 7;
    const int k = threadIdx.x;

    __shared__ float h_s[8][64];
#pragma unroll
    for (int j = 0; j < 8; ++j) h_s[j][k] = 0.0f;

    float h0 = 0, h1 = 0, h2 = 0, h3 = 0, h4 = 0, h5 = 0, h6 = 0, h7 = 0;

    const float* Abase = Ab + (size_t)bh * NC * 4096 + k * 64;
    const float* Bbase = Bb + (size_t)bh * NC * 4096 + k * 64 + vs * 8;

    float4 an[16];
#pragma unroll
    for (int q = 0; q < 16; ++q) an[q] = *(const float4*)&Abase[q * 4];
    float4 bn0 = *(const float4*)&Bbase[0];
    float4 bn1 = *(const float4*)&Bbase[4];
    __syncthreads();

    for (int c = 0; c < NC; ++c) {
        float4 ac[16];
#pragma unroll
        for (int q = 0; q < 16; ++q) ac[q] = an[q];
        float4 b0 = bn0, b1 = bn1;
        if (c + 1 < NC) {
            const float* An = Abase + (size_t)(c + 1) * 4096;
            const float* Bn = Bbase + (size_t)(c + 1) * 4096;
#pragma unroll
            for (int q = 0; q < 16; ++q) an[q] = *(const float4*)&An[q * 4];
            bn0 = *(const float4*)&Bn[0];
            bn1 = *(const float4*)&Bn[4];
        }

        // write chunk-start state h0 (state at entry of chunk c)
        float* Hg = Hst + ((size_t)bh * NC + c) * 4096 + k * 64 + vs * 8;
        *(float4*)&Hg[0] = make_float4(h0, h1, h2, h3);
        *(float4*)&Hg[4] = make_float4(h4, h5, h6, h7);

        // h' = A h + B
        float a0 = b0.x, a1 = b0.y, a2 = b0.z, a3 = b0.w;
        float a4 = b1.x, a5 = b1.y, a6 = b1.z, a7 = b1.w;
#pragma unroll
        for (int m4 = 0; m4 < 16; ++m4) {
            float4 av = ac[m4];
            float4 hv0 = *(const float4*)&h_s[0][m4 * 4];
            float4 hv1 = *(const float4*)&h_s[1][m4 * 4];
            float4 hv2 = *(const float4*)&h_s[2][m4 * 4];
            float4 hv3 = *(const float4*)&h_s[3][m4 * 4];
            float4 hv4 = *(const float4*)&h_s[4][m4 * 4];
            float4 hv5 = *(const float4*)&h_s[5][m4 * 4];
            float4 hv6 = *(const float4*)&h_s[6][m4 * 4];
            float4 hv7 = *(const float4*)&h_s[7][m4 * 4];
            a0 += DOT4(av, hv0); a1 += DOT4(av, hv1);
            a2 += DOT4(av, hv2); a3 += DOT4(av, hv3);
            a4 += DOT4(av, hv4); a5 += DOT4(av, hv5);
            a6 += DOT4(av, hv6); a7 += DOT4(av, hv7);
        }
        __syncthreads();
        h0 = a0; h1 = a1; h2 = a2; h3 = a3;
        h4 = a4; h5 = a5; h6 = a6; h7 = a7;
        h_s[0][k] = h0; h_s[1][k] = h1; h_s[2][k] = h2; h_s[3][k] = h3;
        h_s[4][k] = h4; h_s[5][k] = h5; h_s[6][k] = h6; h_s[7][k] = h7;
        __syncthreads();
    }
}

// ---------------------------------------------------------------------------
// NEW (R6) Phase B3: W_c = Wv_c - Wk_c h0_c (in place over Wv), fully parallel.
// grid = 1024, block = 256.
// ---------------------------------------------------------------------------
__global__ __launch_bounds__(256) void wfix_k(const float* __restrict__ Wk,
                                              const float* __restrict__ Hst,
                                              float* __restrict__ Wio) {
    __shared__ __align__(16) float wk_s[CL * PAD];
    __shared__ __align__(16) float h_s[CL * PAD];

    const int blk = blockIdx.x;
    const int tid = threadIdx.x;

    {
        const float4* Wkg = (const float4*)(Wk + (size_t)blk * 4096);
        const float4* Hg = (const float4*)(Hst + (size_t)blk * 4096);
#pragma unroll
        for (int i = 0; i < 4; ++i) {
            int f = tid + i * 256;
            int d = (f >> 4) * PAD + (f & 15) * 4;
            *(float4*)&wk_s[d] = Wkg[f];
            *(float4*)&h_s[d] = Hg[f];
        }
    }
    __syncthreads();

    const int t0 = (tid >> 4) * 4, v0 = (tid & 15) * 4;
    float* Wg = Wio + (size_t)blk * 4096;

    float acc[4][4];
#pragma unroll
    for (int i = 0; i < 4; ++i) {
        float4 wv = *(const float4*)&Wg[(t0 + i) * 64 + v0];
        acc[i][0] = wv.x; acc[i][1] = wv.y; acc[i][2] = wv.z; acc[i][3] = wv.w;
    }
    for (int kk = 0; kk < 64; kk += 4) {
        float4 wa0 = *(const float4*)&wk_s[(t0 + 0) * PAD + kk];
        float4 wa1 = *(const float4*)&wk_s[(t0 + 1) * PAD + kk];
        float4 wa2 = *(const float4*)&wk_s[(t0 + 2) * PAD + kk];
        float4 wa3 = *(const float4*)&wk_s[(t0 + 3) * PAD + kk];
        float4 hb0 = *(const float4*)&h_s[(kk + 0) * PAD + v0];
        float4 hb1 = *(const float4*)&h_s[(kk + 1) * PAD + v0];
        float4 hb2 = *(const float4*)&h_s[(kk + 2) * PAD + v0];
        float4 hb3 = *(const float4*)&h_s[(kk + 3) * PAD + v0];
        WSUB(x, hb0); WSUB(y, hb1); WSUB(z, hb2); WSUB(w, hb3);
    }
#pragma unroll
    for (int i = 0; i < 4; ++i)
        *(float4*)&Wg[(t0 + i) * 64 + v0] =
            make_float4(acc[i][0], acc[i][1], acc[i][2], acc[i][3]);
}

// ---------------------------------------------------------------------------
// Phase C: per (bh,chunk) outputs (unchanged from R6)
// ---------------------------------------------------------------------------
__global__ __launch_bounds__(256) void out_k(const float* __restrict__ Qc,
                                             const float* __restrict__ Kc,
                                             const float* __restrict__ Wb_,
                                             const float* __restrict__ Hst,
                                             const float* __restrict__ bcum,
                                             float* __restrict__ o_scan) {
    __shared__ __align__(16) float q_s[4096];
    __shared__ __align__(16) float k_s[4096];
    __shared__ __align__(16) float h_s[4096];
    __shared__ __align__(16) float w_s[4096];
    __shared__ float b_s[64];

    const int blk = blockIdx.x;
    const int bh = blk >> 5;
    const int c = blk & 31;
    const int b = bh >> 4;
    const int h = bh & 15;
    const int tid = threadIdx.x;

    if (tid < 64) b_s[tid] = bcum[(size_t)blk * 64 + tid];
    {
        const float4* Qg = (const float4*)(Qc + (size_t)blk * 4096);
        const float4* Kg = (const float4*)(Kc + (size_t)blk * 4096);
        const float4* Hg = (const float4*)(Hst + (size_t)blk * 4096);
        const float4* Wg = (const float4*)(Wb_ + (size_t)blk * 4096);
#pragma unroll
        for (int i = 0; i < 4; ++i) {
            int f = tid + i * 256;
            ((float4*)q_s)[f] = Qg[f];
            ((float4*)k_s)[f] = Kg[f];
            ((float4*)h_s)[f] = Hg[f];
            ((float4*)w_s)[f] = Wg[f];
        }
    }
    __syncthreads();

    {
        const int t0 = (tid >> 4) * 4, s0 = (tid & 15) * 4;
        float acc[4][4] = {};
        for (int kk = 0; kk < 64; kk += 4) {
            float qa[4][4], kb[4][4];
#pragma unroll
            for (int i = 0; i < 4; ++i) f4a(*(const float4*)&q_s[(t0 + i) * 64 + kk], qa[i]);
#pragma unroll
            for (int j = 0; j < 4; ++j) f4a(*(const float4*)&k_s[(s0 + j) * 64 + kk], kb[j]);
#pragma unroll
            for (int i = 0; i < 4; ++i)
#pragma unroll
                for (int j = 0; j < 4; ++j)
#pragma unroll
                    for (int m = 0; m < 4; ++m) acc[i][j] += qa[i][m] * kb[j][m];
        }
        __syncthreads();
#pragma unroll
        for (int i = 0; i < 4; ++i)
#pragma unroll
            for (int j = 0; j < 4; ++j) {
                const int t = t0 + i, s = s0 + j;
                k_s[t * 64 + s] = (s <= t) ? acc[i][j] * __expf(b_s[t] - b_s[s]) : 0.0f;
            }
    }
#pragma unroll
    for (int i = 0; i < 16; ++i) {
        int e = tid + i * 256;
        q_s[e] *= __expf(b_s[e >> 6]);
    }
    __syncthreads();

    {
        const int t0 = (tid >> 4) * 4, v0 = (tid & 15) * 4;
        float acc[4][4] = {};
        for (int ss = 0; ss < 64; ss += 4) {
            float sa[4][4], wb[4][4];
#pragma unroll
            for (int i = 0; i < 4; ++i) f4a(*(const float4*)&k_s[(t0 + i) * 64 + ss], sa[i]);
#pragma unroll
            for (int m = 0; m < 4; ++m) f4a(*(const float4*)&w_s[(ss + m) * 64 + v0], wb[m]);
#pragma unroll
            for (int i = 0; i < 4; ++i)
#pragma unroll
                for (int m = 0; m < 4; ++m)
#pragma unroll
                    for (int j = 0; j < 4; ++j) acc[i][j] += sa[i][m] * wb[m][j];
        }
        for (int kk = 0; kk < 64; kk += 4) {
            float qa[4][4], hb[4][4];
#pragma unroll
            for (int i = 0; i < 4; ++i) f4a(*(const float4*)&q_s[(t0 + i) * 64 + kk], qa[i]);
#pragma unroll
            for (int m = 0; m < 4; ++m) f4a(*(const float4*)&h_s[(kk + m) * 64 + v0], hb[m]);
#pragma unroll
            for (int i = 0; i < 4; ++i)
#pragma unroll
                for (int m = 0; m < 4; ++m)
#pragma unroll
                    for (int j = 0; j < 4; ++j) acc[i][j] += qa[i][m] * hb[m][j];
        }
#pragma unroll
        for (int i = 0; i < 4; ++i) {
            const int t = c * CL + t0 + i;
            *(float4*)&o_scan[(((size_t)b * TT + t) * HH + h) * DK + v0] =
                make_float4(acc[i][0], acc[i][1], acc[i][2], acc[i][3]);
        }
    }
}

// ---------------------------------------------------------------------------
// Gated RMSNorm -> bf16 output (unchanged)
// ---------------------------------------------------------------------------
__global__ __launch_bounds__(256) void gnorm_k(const float* __restrict__ o_scan,
                                               const float* __restrict__ gate,
                                               const float* __restrict__ rms_w,
                                               unsigned short* __restrict__ o2) {
    const int tid = threadIdx.x;
    const int grp = tid >> 6;
    const int lane = tid & 63;
    const int bth = blockIdx.x * 4 + grp;
    const int h = bth & 15;
    const int row = bth >> 4;

    float ov = o_scan[(size_t)bth * DK + lane];
    float s = ov * ov;
#pragma unroll
    for (int sh = 32; sh > 0; sh >>= 1) s += __shfl_xor(s, sh);
    float r = rsqrtf(s * (1.0f / 64.0f) + 1e-5f);

    float gt = gate[(size_t)row * HD + h * DK + lane];
    o2[(size_t)row * HD + h * DK + lane] = f2bf(ov * r * rms_w[lane] * siluf_(gt));
}

// ---------------------------------------------------------------------------
extern "C" void kernel_launch(void* const* d_in, const int* in_sizes, int n_in,
                              void* d_out, int out_size, void* d_ws, size_t ws_size,
                              hipStream_t stream) {
    (void)in_sizes; (void)n_in; (void)out_size; (void)ws_size;

    const float* x       = (const float*)d_in[0];
    const float* Wq      = (const float*)d_in[1];
    const float* Wk_     = (const float*)d_in[2];
    const float* Wv_     = (const float*)d_in[3];
    const float* Wa      = (const float*)d_in[4];
    const float* Wb      = (const float*)d_in[5];
    const float* Wg      = (const float*)d_in[6];
    const float* Wo      = (const float*)d_in[7];
    const float* conv_q  = (const float*)d_in[8];
    const float* conv_k  = (const float*)d_in[9];
    const float* conv_v  = (const float*)d_in[10];
    const float* A_log   = (const float*)d_in[11];
    const float* dt_bias = (const float*)d_in[12];
    const float* rms_w   = (const float*)d_in[13];
    float* out = (float*)d_out;

    float* ws = (float*)d_ws;
    const size_t NTOK = (size_t)BB * TT;     // 4096
    const size_t BIG = NTOK * HD;            // 4 Mi floats

    float* q_pre = ws + 0 * BIG;
    float* k_pre = ws + 1 * BIG;
    float* v_pre = ws + 2 * BIG;
    float* gatep = ws + 3 * BIG;
    float* Qc    = ws + 4 * BIG;
    float* Kc    = ws + 5 * BIG;
    float* gbuf  = ws + 6 * BIG;
    float* bbuf  = gbuf + NTOK * HH;
    float* bcumb = bbuf + NTOK * HH;

    // bf16 buffers after the fp32 region
    unsigned short* xb  = (unsigned short*)(bcumb + NTOK * HH);
    unsigned short* wqt = xb + (size_t)NTOK * DD;
    unsigned short* wkt = wqt + (size_t)DD * HD;
    unsigned short* wvt = wkt + (size_t)DD * HD;
    unsigned short* wgt = wvt + (size_t)DD * HD;
    unsigned short* wot = wgt + (size_t)DD * HD;

    // new fp32 buffers after bf16 region (R6): Bb + Hst (32 MB)
    float* Bbuf = (float*)(wot + (size_t)DD * HD);
    float* HstB = Bbuf + BIG;

    // aliases (stream-ordered lifetimes):
    float* Wvb    = q_pre;   // prep_k out; wfix_k rewrites in place to W
    float* Wkb    = k_pre;
    float* Abuf   = v_pre;   // ab_k out (v_pre dead after prep_k)
    float* o_scan = v_pre;   // out_k out (Abuf dead after hrec_k)
    unsigned short* o2b = (unsigned short*)Qc;

    // casts
    castx_k<<<(int)(NTOK * DD / (256 * 8)), 256, 0, stream>>>(x, xb);
    dim3 tg(16, 16);
    castw_k<<<tg, 256, 0, stream>>>(Wq, wqt);
    castw_k<<<tg, 256, 0, stream>>>(Wk_, wkt);
    castw_k<<<tg, 256, 0, stream>>>(Wv_, wvt);
    castw_k<<<tg, 256, 0, stream>>>(Wg, wgt);
    castw_k<<<tg, 256, 0, stream>>>(Wo, wot);

    // projections
    dim3 gg(HD / 128, NTOK / 128);   // (8, 32)
    gemm_bf16_k<<<gg, 256, 0, stream>>>(xb, wqt, q_pre, (int)NTOK, HD, DD);
    gemm_bf16_k<<<gg, 256, 0, stream>>>(xb, wkt, k_pre, (int)NTOK, HD, DD);
    gemm_bf16_k<<<gg, 256, 0, stream>>>(xb, wvt, v_pre, (int)NTOK, HD, DD);
    gemm_bf16_k<<<gg, 256, 0, stream>>>(xb, wgt, gatep, (int)NTOK, HD, DD);

    gbeta_k<<<(int)NTOK, 256, 0, stream>>>(x, Wa, Wb, A_log, dt_bias, gbuf, bbuf);

    stage_k<<<BB * HH * NC, 64, 0, stream>>>(q_pre, k_pre, conv_q, conv_k, gbuf,
                                             Qc, Kc, bcumb);

    prep_k<<<BB * HH * NC, 256, 0, stream>>>(Kc, v_pre, conv_v, bcumb, bbuf, Wvb, Wkb);

    // chunked state recurrence, decomposed:
    ab_k<<<BB * HH * NC, 256, 0, stream>>>(Kc, Wvb, Wkb, bcumb, Abuf, Bbuf);
    hrec_k<<<BB * HH * 8, 64, 0, stream>>>(Abuf, Bbuf, HstB);
    wfix_k<<<BB * HH * NC, 256, 0, stream>>>(Wkb, HstB, Wvb);

    out_k<<<BB * HH * NC, 256, 0, stream>>>(Qc, Kc, Wvb, HstB, bcumb, o_scan);

    gnorm_k<<<(int)(NTOK * HH / 4), 256, 0, stream>>>(o_scan, gatep, rms_w, o2b);

    gemm_bf16_k<<<gg, 256, 0, stream>>>(o2b, wot, out, (int)NTOK, HD, DD);
}

// Round 8
// 638.246 us; speedup vs baseline: 10.0870x; 1.1424x over previous
//
#include <hip/hip_runtime.h>
#include <hip/hip_bf16.h>
#include <math.h>
#include <stdint.h>

// Problem constants
#define BB 2
#define TT 2048
#define DD 1024
#define HH 16
#define DK 64
#define HD 1024   // H*DK
#define NC 32     // chunks per sequence (TT/64)
#define CL 64     // chunk length
#define PAD 68    // padded LDS row stride (floats) to break stride-64 bank conflicts

typedef short bf16x8 __attribute__((ext_vector_type(8)));     // 8 bf16 (4 VGPRs)
typedef float f32x4 __attribute__((ext_vector_type(4)));      // MFMA acc
typedef unsigned short u16x8 __attribute__((ext_vector_type(8)));
typedef unsigned short u16x4 __attribute__((ext_vector_type(4)));

#define GAS __attribute__((address_space(1)))
#define LAS __attribute__((address_space(3)))

#define DOT4(a, b) ((a).x*(b).x + (a).y*(b).y + (a).z*(b).z + (a).w*(b).w)

// acc[i][j] += kf[i-component] * wv[j-component]   (one contraction step)
#define OUT16(acc, kf, wv) \
    acc[0][0] += kf.x * wv.x; acc[0][1] += kf.x * wv.y; acc[0][2] += kf.x * wv.z; acc[0][3] += kf.x * wv.w; \
    acc[1][0] += kf.y * wv.x; acc[1][1] += kf.y * wv.y; acc[1][2] += kf.y * wv.z; acc[1][3] += kf.y * wv.w; \
    acc[2][0] += kf.z * wv.x; acc[2][1] += kf.z * wv.y; acc[2][2] += kf.z * wv.z; acc[2][3] += kf.z * wv.w; \
    acc[3][0] += kf.w * wv.x; acc[3][1] += kf.w * wv.y; acc[3][2] += kf.w * wv.z; acc[3][3] += kf.w * wv.w;

// acc[i][j] -= wa_i.c * hv[j]   (c = component selecting m)
#define WSUB(c, hv) \
    acc[0][0] -= wa0.c * hv.x; acc[0][1] -= wa0.c * hv.y; acc[0][2] -= wa0.c * hv.z; acc[0][3] -= wa0.c * hv.w; \
    acc[1][0] -= wa1.c * hv.x; acc[1][1] -= wa1.c * hv.y; acc[1][2] -= wa1.c * hv.z; acc[1][3] -= wa1.c * hv.w; \
    acc[2][0] -= wa2.c * hv.x; acc[2][1] -= wa2.c * hv.y; acc[2][2] -= wa2.c * hv.z; acc[2][3] -= wa2.c * hv.w; \
    acc[3][0] -= wa3.c * hv.x; acc[3][1] -= wa3.c * hv.y; acc[3][2] -= wa3.c * hv.z; acc[3][3] -= wa3.c * hv.w;

// acc[i][j] += sa_i.c * wv[j]   (c = component selecting the contraction idx)
#define ACC16(c, wv) \
    acc[0][0] += sa0.c * wv.x; acc[0][1] += sa0.c * wv.y; acc[0][2] += sa0.c * wv.z; acc[0][3] += sa0.c * wv.w; \
    acc[1][0] += sa1.c * wv.x; acc[1][1] += sa1.c * wv.y; acc[1][2] += sa1.c * wv.z; acc[1][3] += sa1.c * wv.w; \
    acc[2][0] += sa2.c * wv.x; acc[2][1] += sa2.c * wv.y; acc[2][2] += sa2.c * wv.z; acc[2][3] += sa2.c * wv.w; \
    acc[3][0] += sa3.c * wv.x; acc[3][1] += sa3.c * wv.y; acc[3][2] += sa3.c * wv.z; acc[3][3] += sa3.c * wv.w;

__device__ __forceinline__ float sigmoidf_(float x) { return 1.0f / (1.0f + expf(-x)); }
__device__ __forceinline__ float siluf_(float x) { return x * sigmoidf_(x); }

// round-to-nearest-even fp32 -> bf16
__device__ __forceinline__ unsigned short f2bf(float f) {
    unsigned int u = __builtin_bit_cast(unsigned int, f);
    u = (u + 0x7fffu + ((u >> 16) & 1u)) >> 16;
    return (unsigned short)u;
}

// ---------------------------------------------------------------------------
// Cast x (fp32) -> bf16, flat.
// ---------------------------------------------------------------------------
__global__ __launch_bounds__(256) void castx_k(const float* __restrict__ src,
                                               unsigned short* __restrict__ dst) {
    const size_t idx = (size_t)blockIdx.x * 256 + threadIdx.x;
    float4 a = *(const float4*)&src[idx * 8];
    float4 b = *(const float4*)&src[idx * 8 + 4];
    u16x8 o;
    o[0] = f2bf(a.x); o[1] = f2bf(a.y); o[2] = f2bf(a.z); o[3] = f2bf(a.w);
    o[4] = f2bf(b.x); o[5] = f2bf(b.y); o[6] = f2bf(b.z); o[7] = f2bf(b.w);
    *(u16x8*)&dst[idx * 8] = o;
}

// ---------------------------------------------------------------------------
// Transpose+cast weight: W[K=1024][N=1024] fp32 -> Wt[N][K] bf16.
// ---------------------------------------------------------------------------
__global__ __launch_bounds__(256) void castw_k(const float* __restrict__ W,
                                               unsigned short* __restrict__ Wt) {
    __shared__ float t_s[64][65];
    const int tid = threadIdx.x;
    const int rr = tid >> 4;
    const int cc = tid & 15;
    const int r0 = blockIdx.y * 64;
    const int c0 = blockIdx.x * 64;
#pragma unroll
    for (int i = 0; i < 4; ++i) {
        const int row = rr + i * 16;
        float4 v = *(const float4*)&W[(size_t)(r0 + row) * 1024 + c0 + cc * 4];
        t_s[row][cc * 4 + 0] = v.x;
        t_s[row][cc * 4 + 1] = v.y;
        t_s[row][cc * 4 + 2] = v.z;
        t_s[row][cc * 4 + 3] = v.w;
    }
    __syncthreads();
#pragma unroll
    for (int i = 0; i < 4; ++i) {
        const int nr = rr + i * 16;
        u16x4 o;
#pragma unroll
        for (int d = 0; d < 4; ++d) o[d] = f2bf(t_s[cc * 4 + d][nr]);
        *(u16x4*)&Wt[(size_t)(c0 + nr) * 1024 + r0 + cc * 4] = o;
    }
}

// ---------------------------------------------------------------------------
// bf16 MFMA GEMM (m97 structure), unchanged.
// ---------------------------------------------------------------------------
__global__ __launch_bounds__(256) void gemm_bf16_k(const unsigned short* __restrict__ A,
                                                   const unsigned short* __restrict__ Bt,
                                                   float* __restrict__ C,
                                                   int M, int N, int Kd) {
    __shared__ unsigned short a_s[128 * 32];
    __shared__ unsigned short b_s[128 * 32];

    const int tid = threadIdx.x;
    const int wave = tid >> 6;
    const int lane = tid & 63;
    const int m0 = blockIdx.y * 128;
    const int n0 = blockIdx.x * 128;

    const int quad = lane >> 4;
    const int l16 = lane & 15;
    const int wr = wave >> 1;
    const int wc = wave & 1;

    const int srow = lane >> 2;
    const int sseg = lane & 3;

    f32x4 acc[4][4];
#pragma unroll
    for (int i = 0; i < 4; ++i)
#pragma unroll
        for (int j = 0; j < 4; ++j) acc[i][j] = (f32x4){0.f, 0.f, 0.f, 0.f};

    for (int k0 = 0; k0 < Kd; k0 += 32) {
        __syncthreads();
#pragma unroll
        for (int c = 0; c < 2; ++c) {
            const int region = wave * 2 + c;
            const int r0t = region * 16;
            const int ra = r0t + srow;
            const unsigned short* ga = A + (size_t)(m0 + ra) * Kd + k0 + sseg * 8;
            const unsigned short* gb = Bt + (size_t)(n0 + ra) * Kd + k0 + sseg * 8;
            __builtin_amdgcn_global_load_lds((const GAS unsigned int*)ga,
                                             (LAS unsigned int*)&a_s[r0t * 32], 16, 0, 0);
            __builtin_amdgcn_global_load_lds((const GAS unsigned int*)gb,
                                             (LAS unsigned int*)&b_s[r0t * 32], 16, 0, 0);
        }
        __syncthreads();

        bf16x8 af[4], bfr[4];
#pragma unroll
        for (int i = 0; i < 4; ++i)
            af[i] = *(const bf16x8*)&a_s[(wr * 64 + i * 16 + l16) * 32 + quad * 8];
#pragma unroll
        for (int j = 0; j < 4; ++j)
            bfr[j] = *(const bf16x8*)&b_s[(wc * 64 + j * 16 + l16) * 32 + quad * 8];
#pragma unroll
        for (int i = 0; i < 4; ++i)
#pragma unroll
            for (int j = 0; j < 4; ++j)
                acc[i][j] = __builtin_amdgcn_mfma_f32_16x16x32_bf16(af[i], bfr[j], acc[i][j], 0, 0, 0);
    }

#pragma unroll
    for (int i = 0; i < 4; ++i)
#pragma unroll
        for (int j = 0; j < 4; ++j) {
            const int col = n0 + wc * 64 + j * 16 + l16;
#pragma unroll
            for (int r = 0; r < 4; ++r) {
                const int row = m0 + wr * 64 + i * 16 + quad * 4 + r;
                C[(size_t)row * N + col] = acc[i][j][r];
            }
        }
}

// ---------------------------------------------------------------------------
// g / beta kernel (R4 version, unchanged)
// ---------------------------------------------------------------------------
__global__ __launch_bounds__(256) void gbeta_k(const float* __restrict__ x,
                                               const float* __restrict__ Wa,
                                               const float* __restrict__ Wb,
                                               const float* __restrict__ A_log,
                                               const float* __restrict__ dt_bias,
                                               float* __restrict__ g,
                                               float* __restrict__ beta) {
    __shared__ __align__(16) float xs[DD];
    const int row = blockIdx.x;
    const int tid = threadIdx.x;

    *(float4*)&xs[tid * 4] = *(const float4*)&x[(size_t)row * DD + tid * 4];
    __syncthreads();

    const int out = tid >> 3;   // 0..31
    const int part = tid & 7;   // 0..7
    const int h = out & 15;
    const float* W = (out < 16) ? Wa : Wb;

    float s = 0.0f;
#pragma unroll 8
    for (int i = 0; i < 32; ++i) {
        const int d = i * 32 + part * 4;
        float4 xv = *(const float4*)&xs[d];
        s += xv.x * W[(size_t)(d + 0) * HH + h];
        s += xv.y * W[(size_t)(d + 1) * HH + h];
        s += xv.z * W[(size_t)(d + 2) * HH + h];
        s += xv.w * W[(size_t)(d + 3) * HH + h];
    }
    s += __shfl_xor(s, 1);
    s += __shfl_xor(s, 2);
    s += __shfl_xor(s, 4);

    if (part == 0) {
        if (out < 16) {
            float v = s + dt_bias[h];
            float sp = (v > 20.0f) ? v : log1pf(expf(v));
            g[(size_t)row * HH + h] = -expf(A_log[h]) * sp;
        } else {
            beta[(size_t)row * HH + h] = sigmoidf_(s);
        }
    }
}

// ---------------------------------------------------------------------------
// Phase A1: stage normalized q,k (conv+silu+l2norm) and cumsum(g). (unchanged)
// ---------------------------------------------------------------------------
__global__ __launch_bounds__(64) void stage_k(const float* __restrict__ q_pre,
                                              const float* __restrict__ k_pre,
                                              const float* __restrict__ cq,
                                              const float* __restrict__ ck,
                                              const float* __restrict__ g,
                                              float* __restrict__ Qc,
                                              float* __restrict__ Kc,
                                              float* __restrict__ bcum) {
    const int blk = blockIdx.x;
    const int bh = blk >> 5;
    const int c = blk & 31;
    const int b = bh >> 4;
    const int h = bh & 15;
    const int lane = threadIdx.x;
    const int ch = h * DK + lane;

    const float4 wq4 = *(const float4*)&cq[ch * 4];
    const float4 wk4 = *(const float4*)&ck[ch * 4];

    float qw0 = 0, qw1 = 0, qw2 = 0, kw0 = 0, kw1 = 0, kw2 = 0;
    {
        const int t0 = c * CL;
        if (t0 - 3 >= 0) { size_t bi = ((size_t)b * TT + t0 - 3) * HD + ch; qw0 = q_pre[bi]; kw0 = k_pre[bi]; }
        if (t0 - 2 >= 0) { size_t bi = ((size_t)b * TT + t0 - 2) * HD + ch; qw1 = q_pre[bi]; kw1 = k_pre[bi]; }
        if (t0 - 1 >= 0) { size_t bi = ((size_t)b * TT + t0 - 1) * HD + ch; qw2 = q_pre[bi]; kw2 = k_pre[bi]; }
    }
    float* Qo = Qc + (size_t)blk * 4096;
    float* Ko = Kc + (size_t)blk * 4096;

    for (int tt = 0; tt < CL; ++tt) {
        const int t = c * CL + tt;
        const size_t bi = ((size_t)b * TT + t) * HD + ch;
        const float qc_ = q_pre[bi];
        const float kc_ = k_pre[bi];
        float qa = qw0 * wq4.x + qw1 * wq4.y + qw2 * wq4.z + qc_ * wq4.w;
        float ka = kw0 * wk4.x + kw1 * wk4.y + kw2 * wk4.z + kc_ * wk4.w;
        qw0 = qw1; qw1 = qw2; qw2 = qc_;
        kw0 = kw1; kw1 = kw2; kw2 = kc_;
        qa = siluf_(qa);
        ka = siluf_(ka);
        float qs2 = qa * qa, ks2 = ka * ka;
#pragma unroll
        for (int s = 32; s > 0; s >>= 1) {
            qs2 += __shfl_xor(qs2, s);
            ks2 += __shfl_xor(ks2, s);
        }
        Qo[tt * 64 + lane] = qa * rsqrtf(qs2 + 1e-6f) * 0.125f;
        Ko[tt * 64 + lane] = ka * rsqrtf(ks2 + 1e-6f);
    }

    float cum = g[((size_t)b * TT + c * CL + lane) * HH + h];
#pragma unroll
    for (int s = 1; s < 64; s <<= 1) {
        float u = __shfl_up(cum, s);
        if (lane >= s) cum += u;
    }
    bcum[(size_t)blk * 64 + lane] = cum;
}

// ---------------------------------------------------------------------------
// Phase A2 (R5): scratch-free blocked triangular solve (unchanged)
// ---------------------------------------------------------------------------
__global__ __launch_bounds__(256) void prep_k(const float* __restrict__ Kc,
                                              const float* __restrict__ v_pre,
                                              const float* __restrict__ cv,
                                              const float* __restrict__ bcum,
                                              const float* __restrict__ bbuf,
                                              float* __restrict__ Wv,
                                              float* __restrict__ Wk) {
    __shared__ __align__(16) float k_s[CL * PAD];
    __shared__ __align__(16) float wv_s[CL * PAD];
    __shared__ __align__(16) float wk_s[CL * PAD];
    __shared__ __align__(16) float A_s[CL * PAD];
    __shared__ float T_s[4][16 * 17];
    __shared__ float b_s[CL], beta_s[CL], bk_s[CL];

    const int blk = blockIdx.x;
    const int bh = blk >> 5;
    const int c = blk & 31;
    const int b = bh >> 4;
    const int h = bh & 15;
    const int tid = threadIdx.x;

    if (tid < 64) {
        float bv = bcum[(size_t)blk * 64 + tid];
        float be = bbuf[((size_t)b * TT + c * CL + tid) * HH + h];
        b_s[tid] = bv;
        beta_s[tid] = be;
        bk_s[tid] = be * __expf(bv);
    }
    __syncthreads();

    {
        const float4* Kg = (const float4*)(Kc + (size_t)blk * 4096);
#pragma unroll
        for (int i = 0; i < 4; ++i) {
            int f = tid + i * 256;
            int t = f >> 4;
            int d = t * PAD + (f & 15) * 4;
            float4 kv = Kg[f];
            *(float4*)&k_s[d] = kv;
            float sk = bk_s[t];
            *(float4*)&wk_s[d] = make_float4(kv.x * sk, kv.y * sk, kv.z * sk, kv.w * sk);
        }
    }

    {
        const int lane = tid & 63;
        const int q4 = tid >> 6;
        const int ch = h * DK + lane;
        const float4 wv4 = *(const float4*)&cv[ch * 4];
        const int T0 = c * CL + q4 * 16;
        float w0 = 0, w1 = 0, w2 = 0;
        if (T0 - 3 >= 0) w0 = v_pre[((size_t)b * TT + T0 - 3) * HD + ch];
        if (T0 - 2 >= 0) w1 = v_pre[((size_t)b * TT + T0 - 2) * HD + ch];
        if (T0 - 1 >= 0) w2 = v_pre[((size_t)b * TT + T0 - 1) * HD + ch];
#pragma unroll 1
        for (int i = 0; i < 16; ++i) {
            const int t = T0 + i;
            const float vc_ = v_pre[((size_t)b * TT + t) * HD + ch];
            float va = w0 * wv4.x + w1 * wv4.y + w2 * wv4.z + vc_ * wv4.w;
            w0 = w1; w1 = w2; w2 = vc_;
            va = siluf_(va);
            wv_s[(q4 * 16 + i) * PAD + lane] = va * beta_s[q4 * 16 + i];
        }
    }
    __syncthreads();

    {
        const int t0 = (tid >> 4) * 4, s0 = (tid & 15) * 4;
        float acc[4][4] = {};
        for (int kk = 0; kk < 64; kk += 4) {
            float4 ta0 = *(const float4*)&k_s[(t0 + 0) * PAD + kk];
            float4 ta1 = *(const float4*)&k_s[(t0 + 1) * PAD + kk];
            float4 ta2 = *(const float4*)&k_s[(t0 + 2) * PAD + kk];
            float4 ta3 = *(const float4*)&k_s[(t0 + 3) * PAD + kk];
            float4 sb0 = *(const float4*)&k_s[(s0 + 0) * PAD + kk];
            float4 sb1 = *(const float4*)&k_s[(s0 + 1) * PAD + kk];
            float4 sb2 = *(const float4*)&k_s[(s0 + 2) * PAD + kk];
            float4 sb3 = *(const float4*)&k_s[(s0 + 3) * PAD + kk];
            acc[0][0] += DOT4(ta0, sb0); acc[0][1] += DOT4(ta0, sb1);
            acc[0][2] += DOT4(ta0, sb2); acc[0][3] += DOT4(ta0, sb3);
            acc[1][0] += DOT4(ta1, sb0); acc[1][1] += DOT4(ta1, sb1);
            acc[1][2] += DOT4(ta1, sb2); acc[1][3] += DOT4(ta1, sb3);
            acc[2][0] += DOT4(ta2, sb0); acc[2][1] += DOT4(ta2, sb1);
            acc[2][2] += DOT4(ta2, sb2); acc[2][3] += DOT4(ta2, sb3);
            acc[3][0] += DOT4(ta3, sb0); acc[3][1] += DOT4(ta3, sb1);
            acc[3][2] += DOT4(ta3, sb2); acc[3][3] += DOT4(ta3, sb3);
        }
#pragma unroll
        for (int i = 0; i < 4; ++i)
#pragma unroll
            for (int j = 0; j < 4; ++j) {
                const int t = t0 + i, s = s0 + j;
                A_s[t * PAD + s] = (s < t) ? acc[i][j] * beta_s[t] * __expf(b_s[t] - b_s[s]) : 0.0f;
            }
    }
    __syncthreads();

    if (tid < 64) {
        const int d = tid >> 4;
        const int col = tid & 15;
        const int base = d * 16;
        float tcol[16];
#pragma unroll
        for (int s = 0; s < 16; ++s) tcol[s] = (s == col) ? 1.0f : 0.0f;
#pragma unroll
        for (int t = 1; t < 16; ++t) {
            float a = 0.0f;
#pragma unroll
            for (int s = 0; s < 16; ++s)
                if (s < t) a += A_s[(base + t) * PAD + base + s] * tcol[s];
            tcol[t] -= a;
        }
#pragma unroll
        for (int t = 0; t < 16; ++t) T_s[d][t * 17 + col] = tcol[t];
    }
    __syncthreads();

    {
        const int r = tid >> 4;
        const int cg = tid & 15;
        float* Wc = (cg < 8) ? wv_s : wk_s;
        const int cc = (cg & 7) * 8;

        for (int tb = 0; tb < 4; ++tb) {
            const int t = tb * 16 + r;
            if (tb > 0) {
                float4 lo = *(const float4*)&Wc[t * PAD + cc];
                float4 hi = *(const float4*)&Wc[t * PAD + cc + 4];
#pragma unroll 4
                for (int s = 0; s < tb * 16; ++s) {
                    const float a = A_s[t * PAD + s];
                    float4 wlo = *(const float4*)&Wc[s * PAD + cc];
                    float4 whi = *(const float4*)&Wc[s * PAD + cc + 4];
                    lo.x -= a * wlo.x; lo.y -= a * wlo.y; lo.z -= a * wlo.z; lo.w -= a * wlo.w;
                    hi.x -= a * whi.x; hi.y -= a * whi.y; hi.z -= a * whi.z; hi.w -= a * whi.w;
                }
                *(float4*)&Wc[t * PAD + cc] = lo;
                *(float4*)&Wc[t * PAD + cc + 4] = hi;
            }
            __syncthreads();
            float4 alo = make_float4(0, 0, 0, 0);
            float4 ahi = make_float4(0, 0, 0, 0);
#pragma unroll 4
            for (int s = 0; s < 16; ++s) {
                const float tv = T_s[tb][r * 17 + s];
                float4 wlo = *(const float4*)&Wc[(tb * 16 + s) * PAD + cc];
                float4 whi = *(const float4*)&Wc[(tb * 16 + s) * PAD + cc + 4];
                alo.x += tv * wlo.x; alo.y += tv * wlo.y; alo.z += tv * wlo.z; alo.w += tv * wlo.w;
                ahi.x += tv * whi.x; ahi.y += tv * whi.y; ahi.z += tv * whi.z; ahi.w += tv * whi.w;
            }
            __syncthreads();
            *(float4*)&Wc[t * PAD + cc] = alo;
            *(float4*)&Wc[t * PAD + cc + 4] = ahi;
            __syncthreads();
        }
    }

    float4* Wvg = (float4*)(Wv + (size_t)blk * 4096);
    float4* Wkg = (float4*)(Wk + (size_t)blk * 4096);
#pragma unroll
    for (int i = 0; i < 4; ++i) {
        int f = tid + i * 256;
        int d = (f >> 4) * PAD + (f & 15) * 4;
        Wvg[f] = *(float4*)&wv_s[d];
        Wkg[f] = *(float4*)&wk_s[d];
    }
}

// ---------------------------------------------------------------------------
// Phase B1: chunk-transition operators A_c, B_c (unchanged from R6)
// ---------------------------------------------------------------------------
__global__ __launch_bounds__(256) void ab_k(const float* __restrict__ Kc,
                                            const float* __restrict__ Wv,
                                            const float* __restrict__ Wk,
                                            const float* __restrict__ bcum,
                                            float* __restrict__ Ab,
                                            float* __restrict__ Bb) {
    __shared__ __align__(16) float kt_s[CL * PAD];
    __shared__ __align__(16) float wk_s[CL * PAD];
    __shared__ __align__(16) float wv_s[CL * PAD];
    __shared__ float e_s[CL];
    __shared__ float ebC_s;

    const int blk = blockIdx.x;
    const int tid = threadIdx.x;

    if (tid < 64) {
        float bC = bcum[(size_t)blk * 64 + 63];
        e_s[tid] = __expf(bC - bcum[(size_t)blk * 64 + tid]);
        if (tid == 63) ebC_s = __expf(bC);
    }
    __syncthreads();

    {
        const float4* Kg = (const float4*)(Kc + (size_t)blk * 4096);
        const float4* Wkg = (const float4*)(Wk + (size_t)blk * 4096);
        const float4* Wvg = (const float4*)(Wv + (size_t)blk * 4096);
#pragma unroll
        for (int i = 0; i < 4; ++i) {
            int f = tid + i * 256;
            int t = f >> 4;
            int d = t * PAD + (f & 15) * 4;
            float4 kv = Kg[f];
            float e = e_s[t];
            *(float4*)&kt_s[d] = make_float4(kv.x * e, kv.y * e, kv.z * e, kv.w * e);
            *(float4*)&wk_s[d] = Wkg[f];
            *(float4*)&wv_s[d] = Wvg[f];
        }
    }
    __syncthreads();

    const int k0 = (tid >> 4) * 4, m0 = (tid & 15) * 4;
    float aA[4][4] = {};
    float aB[4][4] = {};
    for (int ss = 0; ss < 64; ss += 4) {
        float4 kf0 = *(const float4*)&kt_s[(ss + 0) * PAD + k0];
        float4 kf1 = *(const float4*)&kt_s[(ss + 1) * PAD + k0];
        float4 kf2 = *(const float4*)&kt_s[(ss + 2) * PAD + k0];
        float4 kf3 = *(const float4*)&kt_s[(ss + 3) * PAD + k0];
        float4 wa0 = *(const float4*)&wk_s[(ss + 0) * PAD + m0];
        float4 wa1 = *(const float4*)&wk_s[(ss + 1) * PAD + m0];
        float4 wa2 = *(const float4*)&wk_s[(ss + 2) * PAD + m0];
        float4 wa3 = *(const float4*)&wk_s[(ss + 3) * PAD + m0];
        float4 wb0 = *(const float4*)&wv_s[(ss + 0) * PAD + m0];
        float4 wb1 = *(const float4*)&wv_s[(ss + 1) * PAD + m0];
        float4 wb2 = *(const float4*)&wv_s[(ss + 2) * PAD + m0];
        float4 wb3 = *(const float4*)&wv_s[(ss + 3) * PAD + m0];
        OUT16(aA, kf0, wa0); OUT16(aA, kf1, wa1); OUT16(aA, kf2, wa2); OUT16(aA, kf3, wa3);
        OUT16(aB, kf0, wb0); OUT16(aB, kf1, wb1); OUT16(aB, kf2, wb2); OUT16(aB, kf3, wb3);
    }

    const float ebC = ebC_s;
    float* Ag = Ab + (size_t)blk * 4096;
    float* Bg = Bb + (size_t)blk * 4096;
#pragma unroll
    for (int i = 0; i < 4; ++i) {
        const int kk = k0 + i;
        float4 av = make_float4(-aA[i][0], -aA[i][1], -aA[i][2], -aA[i][3]);
        if (kk - m0 == 0) av.x += ebC;
        if (kk - m0 == 1) av.y += ebC;
        if (kk - m0 == 2) av.z += ebC;
        if (kk - m0 == 3) av.w += ebC;
        *(float4*)&Ag[kk * 64 + m0] = av;
        *(float4*)&Bg[kk * 64 + m0] = make_float4(aB[i][0], aB[i][1], aB[i][2], aB[i][3]);
    }
}

// ---------------------------------------------------------------------------
// Phase B2: serial chunk recurrence h' = A_c h + B_c (unchanged from R6)
// ---------------------------------------------------------------------------
__global__ __launch_bounds__(64) void hrec_k(const float* __restrict__ Ab,
                                             const float* __restrict__ Bb,
                                             float* __restrict__ Hst) {
    const int bh = blockIdx.x >> 3;
    const int vs = blockIdx.x & 7;
    const int k = threadIdx.x;

    __shared__ float h_s[8][64];
#pragma unroll
    for (int j = 0; j < 8; ++j) h_s[j][k] = 0.0f;

    float h0 = 0, h1 = 0, h2 = 0, h3 = 0, h4 = 0, h5 = 0, h6 = 0, h7 = 0;

    const float* Abase = Ab + (size_t)bh * NC * 4096 + k * 64;
    const float* Bbase = Bb + (size_t)bh * NC * 4096 + k * 64 + vs * 8;

    float4 an[16];
#pragma unroll
    for (int q = 0; q < 16; ++q) an[q] = *(const float4*)&Abase[q * 4];
    float4 bn0 = *(const float4*)&Bbase[0];
    float4 bn1 = *(const float4*)&Bbase[4];
    __syncthreads();

    for (int c = 0; c < NC; ++c) {
        float4 ac[16];
#pragma unroll
        for (int q = 0; q < 16; ++q) ac[q] = an[q];
        float4 b0 = bn0, b1 = bn1;
        if (c + 1 < NC) {
            const float* An = Abase + (size_t)(c + 1) * 4096;
            const float* Bn = Bbase + (size_t)(c + 1) * 4096;
#pragma unroll
            for (int q = 0; q < 16; ++q) an[q] = *(const float4*)&An[q * 4];
            bn0 = *(const float4*)&Bn[0];
            bn1 = *(const float4*)&Bn[4];
        }

        float* Hg = Hst + ((size_t)bh * NC + c) * 4096 + k * 64 + vs * 8;
        *(float4*)&Hg[0] = make_float4(h0, h1, h2, h3);
        *(float4*)&Hg[4] = make_float4(h4, h5, h6, h7);

        float a0 = b0.x, a1 = b0.y, a2 = b0.z, a3 = b0.w;
        float a4 = b1.x, a5 = b1.y, a6 = b1.z, a7 = b1.w;
#pragma unroll
        for (int m4 = 0; m4 < 16; ++m4) {
            float4 av = ac[m4];
            float4 hv0 = *(const float4*)&h_s[0][m4 * 4];
            float4 hv1 = *(const float4*)&h_s[1][m4 * 4];
            float4 hv2 = *(const float4*)&h_s[2][m4 * 4];
            float4 hv3 = *(const float4*)&h_s[3][m4 * 4];
            float4 hv4 = *(const float4*)&h_s[4][m4 * 4];
            float4 hv5 = *(const float4*)&h_s[5][m4 * 4];
            float4 hv6 = *(const float4*)&h_s[6][m4 * 4];
            float4 hv7 = *(const float4*)&h_s[7][m4 * 4];
            a0 += DOT4(av, hv0); a1 += DOT4(av, hv1);
            a2 += DOT4(av, hv2); a3 += DOT4(av, hv3);
            a4 += DOT4(av, hv4); a5 += DOT4(av, hv5);
            a6 += DOT4(av, hv6); a7 += DOT4(av, hv7);
        }
        __syncthreads();
        h0 = a0; h1 = a1; h2 = a2; h3 = a3;
        h4 = a4; h5 = a5; h6 = a6; h7 = a7;
        h_s[0][k] = h0; h_s[1][k] = h1; h_s[2][k] = h2; h_s[3][k] = h3;
        h_s[4][k] = h4; h_s[5][k] = h5; h_s[6][k] = h6; h_s[7][k] = h7;
        __syncthreads();
    }
}

// ---------------------------------------------------------------------------
// Phase B3: W_c = Wv_c - Wk_c h0_c (unchanged from R6)
// ---------------------------------------------------------------------------
__global__ __launch_bounds__(256) void wfix_k(const float* __restrict__ Wk,
                                              const float* __restrict__ Hst,
                                              float* __restrict__ Wio) {
    __shared__ __align__(16) float wk_s[CL * PAD];
    __shared__ __align__(16) float h_s[CL * PAD];

    const int blk = blockIdx.x;
    const int tid = threadIdx.x;

    {
        const float4* Wkg = (const float4*)(Wk + (size_t)blk * 4096);
        const float4* Hg = (const float4*)(Hst + (size_t)blk * 4096);
#pragma unroll
        for (int i = 0; i < 4; ++i) {
            int f = tid + i * 256;
            int d = (f >> 4) * PAD + (f & 15) * 4;
            *(float4*)&wk_s[d] = Wkg[f];
            *(float4*)&h_s[d] = Hg[f];
        }
    }
    __syncthreads();

    const int t0 = (tid >> 4) * 4, v0 = (tid & 15) * 4;
    float* Wg = Wio + (size_t)blk * 4096;

    float acc[4][4];
#pragma unroll
    for (int i = 0; i < 4; ++i) {
        float4 wv = *(const float4*)&Wg[(t0 + i) * 64 + v0];
        acc[i][0] = wv.x; acc[i][1] = wv.y; acc[i][2] = wv.z; acc[i][3] = wv.w;
    }
    for (int kk = 0; kk < 64; kk += 4) {
        float4 wa0 = *(const float4*)&wk_s[(t0 + 0) * PAD + kk];
        float4 wa1 = *(const float4*)&wk_s[(t0 + 1) * PAD + kk];
        float4 wa2 = *(const float4*)&wk_s[(t0 + 2) * PAD + kk];
        float4 wa3 = *(const float4*)&wk_s[(t0 + 3) * PAD + kk];
        float4 hb0 = *(const float4*)&h_s[(kk + 0) * PAD + v0];
        float4 hb1 = *(const float4*)&h_s[(kk + 1) * PAD + v0];
        float4 hb2 = *(const float4*)&h_s[(kk + 2) * PAD + v0];
        float4 hb3 = *(const float4*)&h_s[(kk + 3) * PAD + v0];
        WSUB(x, hb0); WSUB(y, hb1); WSUB(z, hb2); WSUB(w, hb3);
    }
#pragma unroll
    for (int i = 0; i < 4; ++i)
        *(float4*)&Wg[(t0 + i) * 64 + v0] =
            make_float4(acc[i][0], acc[i][1], acc[i][2], acc[i][3]);
}

// ---------------------------------------------------------------------------
// Phase C (R7): scratch-free + PAD-strided LDS rewrite.
// Was: f4a local arrays (VGPR=256, WRITE 101MB vs 16MB logical = spill) and
// stride-64 LDS (1.9e7 bank conflicts). Now: named float4 temps only,
// PAD=68 LDS stride, same algebra.
// ---------------------------------------------------------------------------
__global__ __launch_bounds__(256) void out_k(const float* __restrict__ Qc,
                                             const float* __restrict__ Kc,
                                             const float* __restrict__ Wb_,
                                             const float* __restrict__ Hst,
                                             const float* __restrict__ bcum,
                                             float* __restrict__ o_scan) {
    __shared__ __align__(16) float q_s[CL * PAD];
    __shared__ __align__(16) float s_s[CL * PAD];   // K, then S
    __shared__ __align__(16) float h_s[CL * PAD];
    __shared__ __align__(16) float w_s[CL * PAD];
    __shared__ float b_s[64];

    const int blk = blockIdx.x;
    const int bh = blk >> 5;
    const int c = blk & 31;
    const int b = bh >> 4;
    const int h = bh & 15;
    const int tid = threadIdx.x;

    if (tid < 64) b_s[tid] = bcum[(size_t)blk * 64 + tid];
    {
        const float4* Qg = (const float4*)(Qc + (size_t)blk * 4096);
        const float4* Kg = (const float4*)(Kc + (size_t)blk * 4096);
        const float4* Hg = (const float4*)(Hst + (size_t)blk * 4096);
        const float4* Wg = (const float4*)(Wb_ + (size_t)blk * 4096);
#pragma unroll
        for (int i = 0; i < 4; ++i) {
            int f = tid + i * 256;
            int d = (f >> 4) * PAD + (f & 15) * 4;
            *(float4*)&q_s[d] = Qg[f];
            *(float4*)&s_s[d] = Kg[f];
            *(float4*)&h_s[d] = Hg[f];
            *(float4*)&w_s[d] = Wg[f];
        }
    }
    __syncthreads();

    // Phase 1: S = (Q K^T) ⊙ exp(b_t - b_s) [s<=t], overwrite s_s
    {
        const int t0 = (tid >> 4) * 4, s0 = (tid & 15) * 4;
        float acc[4][4] = {};
        for (int kk = 0; kk < 64; kk += 4) {
            float4 ta0 = *(const float4*)&q_s[(t0 + 0) * PAD + kk];
            float4 ta1 = *(const float4*)&q_s[(t0 + 1) * PAD + kk];
            float4 ta2 = *(const float4*)&q_s[(t0 + 2) * PAD + kk];
            float4 ta3 = *(const float4*)&q_s[(t0 + 3) * PAD + kk];
            float4 sb0 = *(const float4*)&s_s[(s0 + 0) * PAD + kk];
            float4 sb1 = *(const float4*)&s_s[(s0 + 1) * PAD + kk];
            float4 sb2 = *(const float4*)&s_s[(s0 + 2) * PAD + kk];
            float4 sb3 = *(const float4*)&s_s[(s0 + 3) * PAD + kk];
            acc[0][0] += DOT4(ta0, sb0); acc[0][1] += DOT4(ta0, sb1);
            acc[0][2] += DOT4(ta0, sb2); acc[0][3] += DOT4(ta0, sb3);
            acc[1][0] += DOT4(ta1, sb0); acc[1][1] += DOT4(ta1, sb1);
            acc[1][2] += DOT4(ta1, sb2); acc[1][3] += DOT4(ta1, sb3);
            acc[2][0] += DOT4(ta2, sb0); acc[2][1] += DOT4(ta2, sb1);
            acc[2][2] += DOT4(ta2, sb2); acc[2][3] += DOT4(ta2, sb3);
            acc[3][0] += DOT4(ta3, sb0); acc[3][1] += DOT4(ta3, sb1);
            acc[3][2] += DOT4(ta3, sb2); acc[3][3] += DOT4(ta3, sb3);
        }
        __syncthreads();   // all Q,K reads done before overwrite
#pragma unroll
        for (int i = 0; i < 4; ++i)
#pragma unroll
            for (int j = 0; j < 4; ++j) {
                const int t = t0 + i, s = s0 + j;
                s_s[t * PAD + s] = (s <= t) ? acc[i][j] * __expf(b_s[t] - b_s[s]) : 0.0f;
            }
    }
    // scale q rows by e^{b_t}
#pragma unroll
    for (int i = 0; i < 16; ++i) {
        const int e = tid + i * 256;
        const int t = e >> 6;
        q_s[t * PAD + (e & 63)] *= __expf(b_s[t]);
    }
    __syncthreads();

    // Phase 2: O = S @ W + Qs @ H
    {
        const int t0 = (tid >> 4) * 4, v0 = (tid & 15) * 4;
        float acc[4][4] = {};
        for (int ss = 0; ss < 64; ss += 4) {
            float4 sa0 = *(const float4*)&s_s[(t0 + 0) * PAD + ss];
            float4 sa1 = *(const float4*)&s_s[(t0 + 1) * PAD + ss];
            float4 sa2 = *(const float4*)&s_s[(t0 + 2) * PAD + ss];
            float4 sa3 = *(const float4*)&s_s[(t0 + 3) * PAD + ss];
            float4 wb0 = *(const float4*)&w_s[(ss + 0) * PAD + v0];
            float4 wb1 = *(const float4*)&w_s[(ss + 1) * PAD + v0];
            float4 wb2 = *(const float4*)&w_s[(ss + 2) * PAD + v0];
            float4 wb3 = *(const float4*)&w_s[(ss + 3) * PAD + v0];
            ACC16(x, wb0); ACC16(y, wb1); ACC16(z, wb2); ACC16(w, wb3);
        }
        for (int kk = 0; kk < 64; kk += 4) {
            float4 sa0 = *(const float4*)&q_s[(t0 + 0) * PAD + kk];
            float4 sa1 = *(const float4*)&q_s[(t0 + 1) * PAD + kk];
            float4 sa2 = *(const float4*)&q_s[(t0 + 2) * PAD + kk];
            float4 sa3 = *(const float4*)&q_s[(t0 + 3) * PAD + kk];
            float4 wb0 = *(const float4*)&h_s[(kk + 0) * PAD + v0];
            float4 wb1 = *(const float4*)&h_s[(kk + 1) * PAD + v0];
            float4 wb2 = *(const float4*)&h_s[(kk + 2) * PAD + v0];
            float4 wb3 = *(const float4*)&h_s[(kk + 3) * PAD + v0];
            ACC16(x, wb0); ACC16(y, wb1); ACC16(z, wb2); ACC16(w, wb3);
        }
#pragma unroll
        for (int i = 0; i < 4; ++i) {
            const int t = c * CL + t0 + i;
            *(float4*)&o_scan[(((size_t)b * TT + t) * HH + h) * DK + v0] =
                make_float4(acc[i][0], acc[i][1], acc[i][2], acc[i][3]);
        }
    }
}

// ---------------------------------------------------------------------------
// Gated RMSNorm -> bf16 output (unchanged)
// ---------------------------------------------------------------------------
__global__ __launch_bounds__(256) void gnorm_k(const float* __restrict__ o_scan,
                                               const float* __restrict__ gate,
                                               const float* __restrict__ rms_w,
                                               unsigned short* __restrict__ o2) {
    const int tid = threadIdx.x;
    const int grp = tid >> 6;
    const int lane = tid & 63;
    const int bth = blockIdx.x * 4 + grp;
    const int h = bth & 15;
    const int row = bth >> 4;

    float ov = o_scan[(size_t)bth * DK + lane];
    float s = ov * ov;
#pragma unroll
    for (int sh = 32; sh > 0; sh >>= 1) s += __shfl_xor(s, sh);
    float r = rsqrtf(s * (1.0f / 64.0f) + 1e-5f);

    float gt = gate[(size_t)row * HD + h * DK + lane];
    o2[(size_t)row * HD + h * DK + lane] = f2bf(ov * r * rms_w[lane] * siluf_(gt));
}

// ---------------------------------------------------------------------------
extern "C" void kernel_launch(void* const* d_in, const int* in_sizes, int n_in,
                              void* d_out, int out_size, void* d_ws, size_t ws_size,
                              hipStream_t stream) {
    (void)in_sizes; (void)n_in; (void)out_size; (void)ws_size;

    const float* x       = (const float*)d_in[0];
    const float* Wq      = (const float*)d_in[1];
    const float* Wk_     = (const float*)d_in[2];
    const float* Wv_     = (const float*)d_in[3];
    const float* Wa      = (const float*)d_in[4];
    const float* Wb      = (const float*)d_in[5];
    const float* Wg      = (const float*)d_in[6];
    const float* Wo      = (const float*)d_in[7];
    const float* conv_q  = (const float*)d_in[8];
    const float* conv_k  = (const float*)d_in[9];
    const float* conv_v  = (const float*)d_in[10];
    const float* A_log   = (const float*)d_in[11];
    const float* dt_bias = (const float*)d_in[12];
    const float* rms_w   = (const float*)d_in[13];
    float* out = (float*)d_out;

    float* ws = (float*)d_ws;
    const size_t NTOK = (size_t)BB * TT;     // 4096
    const size_t BIG = NTOK * HD;            // 4 Mi floats

    float* q_pre = ws + 0 * BIG;
    float* k_pre = ws + 1 * BIG;
    float* v_pre = ws + 2 * BIG;
    float* gatep = ws + 3 * BIG;
    float* Qc    = ws + 4 * BIG;
    float* Kc    = ws + 5 * BIG;
    float* gbuf  = ws + 6 * BIG;
    float* bbuf  = gbuf + NTOK * HH;
    float* bcumb = bbuf + NTOK * HH;

    // bf16 buffers after the fp32 region
    unsigned short* xb  = (unsigned short*)(bcumb + NTOK * HH);
    unsigned short* wqt = xb + (size_t)NTOK * DD;
    unsigned short* wkt = wqt + (size_t)DD * HD;
    unsigned short* wvt = wkt + (size_t)DD * HD;
    unsigned short* wgt = wvt + (size_t)DD * HD;
    unsigned short* wot = wgt + (size_t)DD * HD;

    // fp32 buffers after bf16 region: Bb + Hst (32 MB)
    float* Bbuf = (float*)(wot + (size_t)DD * HD);
    float* HstB = Bbuf + BIG;

    // aliases (stream-ordered lifetimes):
    float* Wvb    = q_pre;   // prep_k out; wfix_k rewrites in place to W
    float* Wkb    = k_pre;
    float* Abuf   = v_pre;   // ab_k out (v_pre dead after prep_k)
    float* o_scan = v_pre;   // out_k out (Abuf dead after hrec_k)
    unsigned short* o2b = (unsigned short*)Qc;

    // casts
    castx_k<<<(int)(NTOK * DD / (256 * 8)), 256, 0, stream>>>(x, xb);
    dim3 tg(16, 16);
    castw_k<<<tg, 256, 0, stream>>>(Wq, wqt);
    castw_k<<<tg, 256, 0, stream>>>(Wk_, wkt);
    castw_k<<<tg, 256, 0, stream>>>(Wv_, wvt);
    castw_k<<<tg, 256, 0, stream>>>(Wg, wgt);
    castw_k<<<tg, 256, 0, stream>>>(Wo, wot);

    // projections
    dim3 gg(HD / 128, NTOK / 128);   // (8, 32)
    gemm_bf16_k<<<gg, 256, 0, stream>>>(xb, wqt, q_pre, (int)NTOK, HD, DD);
    gemm_bf16_k<<<gg, 256, 0, stream>>>(xb, wkt, k_pre, (int)NTOK, HD, DD);
    gemm_bf16_k<<<gg, 256, 0, stream>>>(xb, wvt, v_pre, (int)NTOK, HD, DD);
    gemm_bf16_k<<<gg, 256, 0, stream>>>(xb, wgt, gatep, (int)NTOK, HD, DD);

    gbeta_k<<<(int)NTOK, 256, 0, stream>>>(x, Wa, Wb, A_log, dt_bias, gbuf, bbuf);

    stage_k<<<BB * HH * NC, 64, 0, stream>>>(q_pre, k_pre, conv_q, conv_k, gbuf,
                                             Qc, Kc, bcumb);

    prep_k<<<BB * HH * NC, 256, 0, stream>>>(Kc, v_pre, conv_v, bcumb, bbuf, Wvb, Wkb);

    // chunked state recurrence, decomposed:
    ab_k<<<BB * HH * NC, 256, 0, stream>>>(Kc, Wvb, Wkb, bcumb, Abuf, Bbuf);
    hrec_k<<<BB * HH * 8, 64, 0, stream>>>(Abuf, Bbuf, HstB);
    wfix_k<<<BB * HH * NC, 256, 0, stream>>>(Wkb, HstB, Wvb);

    out_k<<<BB * HH * NC, 256, 0, stream>>>(Qc, Kc, Wvb, HstB, bcumb, o_scan);

    gnorm_k<<<(int)(NTOK * HH / 4), 256, 0, stream>>>(o_scan, gatep, rms_w, o2b);

    gemm_bf16_k<<<gg, 256, 0, stream>>>(o2b, wot, out, (int)NTOK, HD, DD);
}

// Round 9
// 546.779 us; speedup vs baseline: 11.7744x; 1.1673x over previous
//
#include <hip/hip_runtime.h>
#include <hip/hip_bf16.h>
#include <math.h>
#include <stdint.h>

// Problem constants
#define BB 2
#define TT 2048
#define DD 1024
#define HH 16
#define DK 64
#define HD 1024   // H*DK
#define NC 32     // chunks per sequence (TT/64)
#define CL 64     // chunk length
#define PAD 68    // padded LDS row stride (floats) to break stride-64 bank conflicts

typedef short bf16x8 __attribute__((ext_vector_type(8)));     // 8 bf16 (4 VGPRs)
typedef float f32x4 __attribute__((ext_vector_type(4)));      // MFMA acc
typedef unsigned short u16x8 __attribute__((ext_vector_type(8)));
typedef unsigned short u16x4 __attribute__((ext_vector_type(4)));

#define GAS __attribute__((address_space(1)))
#define LAS __attribute__((address_space(3)))

#define DOT4(a, b) ((a).x*(b).x + (a).y*(b).y + (a).z*(b).z + (a).w*(b).w)

// acc[i][j] += kf[i-component] * wv[j-component]   (one contraction step)
#define OUT16(acc, kf, wv) \
    acc[0][0] += kf.x * wv.x; acc[0][1] += kf.x * wv.y; acc[0][2] += kf.x * wv.z; acc[0][3] += kf.x * wv.w; \
    acc[1][0] += kf.y * wv.x; acc[1][1] += kf.y * wv.y; acc[1][2] += kf.y * wv.z; acc[1][3] += kf.y * wv.w; \
    acc[2][0] += kf.z * wv.x; acc[2][1] += kf.z * wv.y; acc[2][2] += kf.z * wv.z; acc[2][3] += kf.z * wv.w; \
    acc[3][0] += kf.w * wv.x; acc[3][1] += kf.w * wv.y; acc[3][2] += kf.w * wv.z; acc[3][3] += kf.w * wv.w;

// acc[i][j] -= wa_i.c * hv[j]   (c = component selecting m)
#define WSUB(c, hv) \
    acc[0][0] -= wa0.c * hv.x; acc[0][1] -= wa0.c * hv.y; acc[0][2] -= wa0.c * hv.z; acc[0][3] -= wa0.c * hv.w; \
    acc[1][0] -= wa1.c * hv.x; acc[1][1] -= wa1.c * hv.y; acc[1][2] -= wa1.c * hv.z; acc[1][3] -= wa1.c * hv.w; \
    acc[2][0] -= wa2.c * hv.x; acc[2][1] -= wa2.c * hv.y; acc[2][2] -= wa2.c * hv.z; acc[2][3] -= wa2.c * hv.w; \
    acc[3][0] -= wa3.c * hv.x; acc[3][1] -= wa3.c * hv.y; acc[3][2] -= wa3.c * hv.z; acc[3][3] -= wa3.c * hv.w;

// acc[i][j] += sa_i.c * wv[j]   (c = component selecting the contraction idx)
#define ACC16(c, wv) \
    acc[0][0] += sa0.c * wv.x; acc[0][1] += sa0.c * wv.y; acc[0][2] += sa0.c * wv.z; acc[0][3] += sa0.c * wv.w; \
    acc[1][0] += sa1.c * wv.x; acc[1][1] += sa1.c * wv.y; acc[1][2] += sa1.c * wv.z; acc[1][3] += sa1.c * wv.w; \
    acc[2][0] += sa2.c * wv.x; acc[2][1] += sa2.c * wv.y; acc[2][2] += sa2.c * wv.z; acc[2][3] += sa2.c * wv.w; \
    acc[3][0] += sa3.c * wv.x; acc[3][1] += sa3.c * wv.y; acc[3][2] += sa3.c * wv.z; acc[3][3] += sa3.c * wv.w;

__device__ __forceinline__ float sigmoidf_(float x) { return 1.0f / (1.0f + expf(-x)); }
__device__ __forceinline__ float siluf_(float x) { return x * sigmoidf_(x); }

// round-to-nearest-even fp32 -> bf16
__device__ __forceinline__ unsigned short f2bf(float f) {
    unsigned int u = __builtin_bit_cast(unsigned int, f);
    u = (u + 0x7fffu + ((u >> 16) & 1u)) >> 16;
    return (unsigned short)u;
}

// ---------------------------------------------------------------------------
// Cast x (fp32) -> bf16, flat.
// ---------------------------------------------------------------------------
__global__ __launch_bounds__(256) void castx_k(const float* __restrict__ src,
                                               unsigned short* __restrict__ dst) {
    const size_t idx = (size_t)blockIdx.x * 256 + threadIdx.x;
    float4 a = *(const float4*)&src[idx * 8];
    float4 b = *(const float4*)&src[idx * 8 + 4];
    u16x8 o;
    o[0] = f2bf(a.x); o[1] = f2bf(a.y); o[2] = f2bf(a.z); o[3] = f2bf(a.w);
    o[4] = f2bf(b.x); o[5] = f2bf(b.y); o[6] = f2bf(b.z); o[7] = f2bf(b.w);
    *(u16x8*)&dst[idx * 8] = o;
}

// ---------------------------------------------------------------------------
// Transpose+cast weight: W[K=1024][N=1024] fp32 -> Wt[N][K] bf16.
// ---------------------------------------------------------------------------
__global__ __launch_bounds__(256) void castw_k(const float* __restrict__ W,
                                               unsigned short* __restrict__ Wt) {
    __shared__ float t_s[64][65];
    const int tid = threadIdx.x;
    const int rr = tid >> 4;
    const int cc = tid & 15;
    const int r0 = blockIdx.y * 64;
    const int c0 = blockIdx.x * 64;
#pragma unroll
    for (int i = 0; i < 4; ++i) {
        const int row = rr + i * 16;
        float4 v = *(const float4*)&W[(size_t)(r0 + row) * 1024 + c0 + cc * 4];
        t_s[row][cc * 4 + 0] = v.x;
        t_s[row][cc * 4 + 1] = v.y;
        t_s[row][cc * 4 + 2] = v.z;
        t_s[row][cc * 4 + 3] = v.w;
    }
    __syncthreads();
#pragma unroll
    for (int i = 0; i < 4; ++i) {
        const int nr = rr + i * 16;
        u16x4 o;
#pragma unroll
        for (int d = 0; d < 4; ++d) o[d] = f2bf(t_s[cc * 4 + d][nr]);
        *(u16x4*)&Wt[(size_t)(c0 + nr) * 1024 + r0 + cc * 4] = o;
    }
}

// ---------------------------------------------------------------------------
// NEW (R8): transpose Wa|Wb [1024][16] -> Wab_t [32][1024] fp32.
// grid = 32 (one output row), block = 256.
// ---------------------------------------------------------------------------
__global__ __launch_bounds__(256) void tw_k(const float* __restrict__ Wa,
                                            const float* __restrict__ Wb,
                                            float* __restrict__ Wt) {
    const int o = blockIdx.x;          // 0..31
    const int h = o & 15;
    const float* W = (o < 16) ? Wa : Wb;
    const int tid = threadIdx.x;
    float4 v;
    v.x = W[(size_t)(tid * 4 + 0) * HH + h];
    v.y = W[(size_t)(tid * 4 + 1) * HH + h];
    v.z = W[(size_t)(tid * 4 + 2) * HH + h];
    v.w = W[(size_t)(tid * 4 + 3) * HH + h];
    *(float4*)&Wt[(size_t)o * DD + tid * 4] = v;
}

// ---------------------------------------------------------------------------
// bf16 MFMA GEMM (m97 structure), unchanged.
// ---------------------------------------------------------------------------
__global__ __launch_bounds__(256) void gemm_bf16_k(const unsigned short* __restrict__ A,
                                                   const unsigned short* __restrict__ Bt,
                                                   float* __restrict__ C,
                                                   int M, int N, int Kd) {
    __shared__ unsigned short a_s[128 * 32];
    __shared__ unsigned short b_s[128 * 32];

    const int tid = threadIdx.x;
    const int wave = tid >> 6;
    const int lane = tid & 63;
    const int m0 = blockIdx.y * 128;
    const int n0 = blockIdx.x * 128;

    const int quad = lane >> 4;
    const int l16 = lane & 15;
    const int wr = wave >> 1;
    const int wc = wave & 1;

    const int srow = lane >> 2;
    const int sseg = lane & 3;

    f32x4 acc[4][4];
#pragma unroll
    for (int i = 0; i < 4; ++i)
#pragma unroll
        for (int j = 0; j < 4; ++j) acc[i][j] = (f32x4){0.f, 0.f, 0.f, 0.f};

    for (int k0 = 0; k0 < Kd; k0 += 32) {
        __syncthreads();
#pragma unroll
        for (int c = 0; c < 2; ++c) {
            const int region = wave * 2 + c;
            const int r0t = region * 16;
            const int ra = r0t + srow;
            const unsigned short* ga = A + (size_t)(m0 + ra) * Kd + k0 + sseg * 8;
            const unsigned short* gb = Bt + (size_t)(n0 + ra) * Kd + k0 + sseg * 8;
            __builtin_amdgcn_global_load_lds((const GAS unsigned int*)ga,
                                             (LAS unsigned int*)&a_s[r0t * 32], 16, 0, 0);
            __builtin_amdgcn_global_load_lds((const GAS unsigned int*)gb,
                                             (LAS unsigned int*)&b_s[r0t * 32], 16, 0, 0);
        }
        __syncthreads();

        bf16x8 af[4], bfr[4];
#pragma unroll
        for (int i = 0; i < 4; ++i)
            af[i] = *(const bf16x8*)&a_s[(wr * 64 + i * 16 + l16) * 32 + quad * 8];
#pragma unroll
        for (int j = 0; j < 4; ++j)
            bfr[j] = *(const bf16x8*)&b_s[(wc * 64 + j * 16 + l16) * 32 + quad * 8];
#pragma unroll
        for (int i = 0; i < 4; ++i)
#pragma unroll
            for (int j = 0; j < 4; ++j)
                acc[i][j] = __builtin_amdgcn_mfma_f32_16x16x32_bf16(af[i], bfr[j], acc[i][j], 0, 0, 0);
    }

#pragma unroll
    for (int i = 0; i < 4; ++i)
#pragma unroll
        for (int j = 0; j < 4; ++j) {
            const int col = n0 + wc * 64 + j * 16 + l16;
#pragma unroll
            for (int r = 0; r < 4; ++r) {
                const int row = m0 + wr * 64 + i * 16 + quad * 4 + r;
                C[(size_t)row * N + col] = acc[i][j][r];
            }
        }
}

// ---------------------------------------------------------------------------
// g / beta kernel (R8): register-blocked over 8 rows.
// Was: 128 scalar W loads/thread (VMEM-issue bound, 119 us). Now: W transposed
// (Wab_t[32][1024]), one float4 W load per K-step reused across 8 rows staged
// in LDS; d = i*32 + part*4 covers all 32 banks once (out-groups broadcast).
// grid = NTOK/8 = 512, block = 256.
// ---------------------------------------------------------------------------
__global__ __launch_bounds__(256) void gbeta_k(const float* __restrict__ x,
                                               const float* __restrict__ Wt,
                                               const float* __restrict__ A_log,
                                               const float* __restrict__ dt_bias,
                                               float* __restrict__ g,
                                               float* __restrict__ beta) {
    __shared__ __align__(16) float xs[8][DD];
    const int r0 = blockIdx.x * 8;
    const int tid = threadIdx.x;

    // stage 8 rows of x (8 x 4 KB)
#pragma unroll
    for (int i = 0; i < 8; ++i) {
        const int f = tid + i * 256;          // 0..2047
        const int r = f >> 8;                  // row 0..7
        const int col = (f & 255) * 4;
        *(float4*)&xs[r][col] = *(const float4*)&x[((size_t)r0 + r) * DD + col];
    }
    __syncthreads();

    const int out = tid >> 3;   // 0..31
    const int part = tid & 7;   // 0..7
    const int h = out & 15;
    const float* Wrow = Wt + (size_t)out * DD;

    float a0 = 0, a1 = 0, a2 = 0, a3 = 0, a4 = 0, a5 = 0, a6 = 0, a7 = 0;
#pragma unroll 4
    for (int i = 0; i < 32; ++i) {
        const int d = i * 32 + part * 4;
        const float4 wv = *(const float4*)&Wrow[d];
        float4 x0 = *(const float4*)&xs[0][d];
        float4 x1 = *(const float4*)&xs[1][d];
        float4 x2 = *(const float4*)&xs[2][d];
        float4 x3 = *(const float4*)&xs[3][d];
        float4 x4 = *(const float4*)&xs[4][d];
        float4 x5 = *(const float4*)&xs[5][d];
        float4 x6 = *(const float4*)&xs[6][d];
        float4 x7 = *(const float4*)&xs[7][d];
        a0 += DOT4(x0, wv); a1 += DOT4(x1, wv);
        a2 += DOT4(x2, wv); a3 += DOT4(x3, wv);
        a4 += DOT4(x4, wv); a5 += DOT4(x5, wv);
        a6 += DOT4(x6, wv); a7 += DOT4(x7, wv);
    }
#pragma unroll
    for (int s = 1; s <= 4; s <<= 1) {
        a0 += __shfl_xor(a0, s); a1 += __shfl_xor(a1, s);
        a2 += __shfl_xor(a2, s); a3 += __shfl_xor(a3, s);
        a4 += __shfl_xor(a4, s); a5 += __shfl_xor(a5, s);
        a6 += __shfl_xor(a6, s); a7 += __shfl_xor(a7, s);
    }

    if (part == 0) {
        float sv[8] = {a0, a1, a2, a3, a4, a5, a6, a7};
        if (out < 16) {
            const float ae = -expf(A_log[h]);
            const float db = dt_bias[h];
#pragma unroll
            for (int r = 0; r < 8; ++r) {
                float v = sv[r] + db;
                float sp = (v > 20.0f) ? v : log1pf(expf(v));
                g[((size_t)r0 + r) * HH + h] = ae * sp;
            }
        } else {
#pragma unroll
            for (int r = 0; r < 8; ++r)
                beta[((size_t)r0 + r) * HH + h] = sigmoidf_(sv[r]);
        }
    }
}

// ---------------------------------------------------------------------------
// Phase A1: stage normalized q,k (conv+silu+l2norm) and cumsum(g). (unchanged)
// ---------------------------------------------------------------------------
__global__ __launch_bounds__(64) void stage_k(const float* __restrict__ q_pre,
                                              const float* __restrict__ k_pre,
                                              const float* __restrict__ cq,
                                              const float* __restrict__ ck,
                                              const float* __restrict__ g,
                                              float* __restrict__ Qc,
                                              float* __restrict__ Kc,
                                              float* __restrict__ bcum) {
    const int blk = blockIdx.x;
    const int bh = blk >> 5;
    const int c = blk & 31;
    const int b = bh >> 4;
    const int h = bh & 15;
    const int lane = threadIdx.x;
    const int ch = h * DK + lane;

    const float4 wq4 = *(const float4*)&cq[ch * 4];
    const float4 wk4 = *(const float4*)&ck[ch * 4];

    float qw0 = 0, qw1 = 0, qw2 = 0, kw0 = 0, kw1 = 0, kw2 = 0;
    {
        const int t0 = c * CL;
        if (t0 - 3 >= 0) { size_t bi = ((size_t)b * TT + t0 - 3) * HD + ch; qw0 = q_pre[bi]; kw0 = k_pre[bi]; }
        if (t0 - 2 >= 0) { size_t bi = ((size_t)b * TT + t0 - 2) * HD + ch; qw1 = q_pre[bi]; kw1 = k_pre[bi]; }
        if (t0 - 1 >= 0) { size_t bi = ((size_t)b * TT + t0 - 1) * HD + ch; qw2 = q_pre[bi]; kw2 = k_pre[bi]; }
    }
    float* Qo = Qc + (size_t)blk * 4096;
    float* Ko = Kc + (size_t)blk * 4096;

    for (int tt = 0; tt < CL; ++tt) {
        const int t = c * CL + tt;
        const size_t bi = ((size_t)b * TT + t) * HD + ch;
        const float qc_ = q_pre[bi];
        const float kc_ = k_pre[bi];
        float qa = qw0 * wq4.x + qw1 * wq4.y + qw2 * wq4.z + qc_ * wq4.w;
        float ka = kw0 * wk4.x + kw1 * wk4.y + kw2 * wk4.z + kc_ * wk4.w;
        qw0 = qw1; qw1 = qw2; qw2 = qc_;
        kw0 = kw1; kw1 = kw2; kw2 = kc_;
        qa = siluf_(qa);
        ka = siluf_(ka);
        float qs2 = qa * qa, ks2 = ka * ka;
#pragma unroll
        for (int s = 32; s > 0; s >>= 1) {
            qs2 += __shfl_xor(qs2, s);
            ks2 += __shfl_xor(ks2, s);
        }
        Qo[tt * 64 + lane] = qa * rsqrtf(qs2 + 1e-6f) * 0.125f;
        Ko[tt * 64 + lane] = ka * rsqrtf(ks2 + 1e-6f);
    }

    float cum = g[((size_t)b * TT + c * CL + lane) * HH + h];
#pragma unroll
    for (int s = 1; s < 64; s <<= 1) {
        float u = __shfl_up(cum, s);
        if (lane >= s) cum += u;
    }
    bcum[(size_t)blk * 64 + lane] = cum;
}

// ---------------------------------------------------------------------------
// Phase A2 (R5): scratch-free blocked triangular solve (unchanged)
// ---------------------------------------------------------------------------
__global__ __launch_bounds__(256) void prep_k(const float* __restrict__ Kc,
                                              const float* __restrict__ v_pre,
                                              const float* __restrict__ cv,
                                              const float* __restrict__ bcum,
                                              const float* __restrict__ bbuf,
                                              float* __restrict__ Wv,
                                              float* __restrict__ Wk) {
    __shared__ __align__(16) float k_s[CL * PAD];
    __shared__ __align__(16) float wv_s[CL * PAD];
    __shared__ __align__(16) float wk_s[CL * PAD];
    __shared__ __align__(16) float A_s[CL * PAD];
    __shared__ float T_s[4][16 * 17];
    __shared__ float b_s[CL], beta_s[CL], bk_s[CL];

    const int blk = blockIdx.x;
    const int bh = blk >> 5;
    const int c = blk & 31;
    const int b = bh >> 4;
    const int h = bh & 15;
    const int tid = threadIdx.x;

    if (tid < 64) {
        float bv = bcum[(size_t)blk * 64 + tid];
        float be = bbuf[((size_t)b * TT + c * CL + tid) * HH + h];
        b_s[tid] = bv;
        beta_s[tid] = be;
        bk_s[tid] = be * __expf(bv);
    }
    __syncthreads();

    {
        const float4* Kg = (const float4*)(Kc + (size_t)blk * 4096);
#pragma unroll
        for (int i = 0; i < 4; ++i) {
            int f = tid + i * 256;
            int t = f >> 4;
            int d = t * PAD + (f & 15) * 4;
            float4 kv = Kg[f];
            *(float4*)&k_s[d] = kv;
            float sk = bk_s[t];
            *(float4*)&wk_s[d] = make_float4(kv.x * sk, kv.y * sk, kv.z * sk, kv.w * sk);
        }
    }

    {
        const int lane = tid & 63;
        const int q4 = tid >> 6;
        const int ch = h * DK + lane;
        const float4 wv4 = *(const float4*)&cv[ch * 4];
        const int T0 = c * CL + q4 * 16;
        float w0 = 0, w1 = 0, w2 = 0;
        if (T0 - 3 >= 0) w0 = v_pre[((size_t)b * TT + T0 - 3) * HD + ch];
        if (T0 - 2 >= 0) w1 = v_pre[((size_t)b * TT + T0 - 2) * HD + ch];
        if (T0 - 1 >= 0) w2 = v_pre[((size_t)b * TT + T0 - 1) * HD + ch];
#pragma unroll 1
        for (int i = 0; i < 16; ++i) {
            const int t = T0 + i;
            const float vc_ = v_pre[((size_t)b * TT + t) * HD + ch];
            float va = w0 * wv4.x + w1 * wv4.y + w2 * wv4.z + vc_ * wv4.w;
            w0 = w1; w1 = w2; w2 = vc_;
            va = siluf_(va);
            wv_s[(q4 * 16 + i) * PAD + lane] = va * beta_s[q4 * 16 + i];
        }
    }
    __syncthreads();

    {
        const int t0 = (tid >> 4) * 4, s0 = (tid & 15) * 4;
        float acc[4][4] = {};
        for (int kk = 0; kk < 64; kk += 4) {
            float4 ta0 = *(const float4*)&k_s[(t0 + 0) * PAD + kk];
            float4 ta1 = *(const float4*)&k_s[(t0 + 1) * PAD + kk];
            float4 ta2 = *(const float4*)&k_s[(t0 + 2) * PAD + kk];
            float4 ta3 = *(const float4*)&k_s[(t0 + 3) * PAD + kk];
            float4 sb0 = *(const float4*)&k_s[(s0 + 0) * PAD + kk];
            float4 sb1 = *(const float4*)&k_s[(s0 + 1) * PAD + kk];
            float4 sb2 = *(const float4*)&k_s[(s0 + 2) * PAD + kk];
            float4 sb3 = *(const float4*)&k_s[(s0 + 3) * PAD + kk];
            acc[0][0] += DOT4(ta0, sb0); acc[0][1] += DOT4(ta0, sb1);
            acc[0][2] += DOT4(ta0, sb2); acc[0][3] += DOT4(ta0, sb3);
            acc[1][0] += DOT4(ta1, sb0); acc[1][1] += DOT4(ta1, sb1);
            acc[1][2] += DOT4(ta1, sb2); acc[1][3] += DOT4(ta1, sb3);
            acc[2][0] += DOT4(ta2, sb0); acc[2][1] += DOT4(ta2, sb1);
            acc[2][2] += DOT4(ta2, sb2); acc[2][3] += DOT4(ta2, sb3);
            acc[3][0] += DOT4(ta3, sb0); acc[3][1] += DOT4(ta3, sb1);
            acc[3][2] += DOT4(ta3, sb2); acc[3][3] += DOT4(ta3, sb3);
        }
#pragma unroll
        for (int i = 0; i < 4; ++i)
#pragma unroll
            for (int j = 0; j < 4; ++j) {
                const int t = t0 + i, s = s0 + j;
                A_s[t * PAD + s] = (s < t) ? acc[i][j] * beta_s[t] * __expf(b_s[t] - b_s[s]) : 0.0f;
            }
    }
    __syncthreads();

    if (tid < 64) {
        const int d = tid >> 4;
        const int col = tid & 15;
        const int base = d * 16;
        float tcol[16];
#pragma unroll
        for (int s = 0; s < 16; ++s) tcol[s] = (s == col) ? 1.0f : 0.0f;
#pragma unroll
        for (int t = 1; t < 16; ++t) {
            float a = 0.0f;
#pragma unroll
            for (int s = 0; s < 16; ++s)
                if (s < t) a += A_s[(base + t) * PAD + base + s] * tcol[s];
            tcol[t] -= a;
        }
#pragma unroll
        for (int t = 0; t < 16; ++t) T_s[d][t * 17 + col] = tcol[t];
    }
    __syncthreads();

    {
        const int r = tid >> 4;
        const int cg = tid & 15;
        float* Wc = (cg < 8) ? wv_s : wk_s;
        const int cc = (cg & 7) * 8;

        for (int tb = 0; tb < 4; ++tb) {
            const int t = tb * 16 + r;
            if (tb > 0) {
                float4 lo = *(const float4*)&Wc[t * PAD + cc];
                float4 hi = *(const float4*)&Wc[t * PAD + cc + 4];
#pragma unroll 4
                for (int s = 0; s < tb * 16; ++s) {
                    const float a = A_s[t * PAD + s];
                    float4 wlo = *(const float4*)&Wc[s * PAD + cc];
                    float4 whi = *(const float4*)&Wc[s * PAD + cc + 4];
                    lo.x -= a * wlo.x; lo.y -= a * wlo.y; lo.z -= a * wlo.z; lo.w -= a * wlo.w;
                    hi.x -= a * whi.x; hi.y -= a * whi.y; hi.z -= a * whi.z; hi.w -= a * whi.w;
                }
                *(float4*)&Wc[t * PAD + cc] = lo;
                *(float4*)&Wc[t * PAD + cc + 4] = hi;
            }
            __syncthreads();
            float4 alo = make_float4(0, 0, 0, 0);
            float4 ahi = make_float4(0, 0, 0, 0);
#pragma unroll 4
            for (int s = 0; s < 16; ++s) {
                const float tv = T_s[tb][r * 17 + s];
                float4 wlo = *(const float4*)&Wc[(tb * 16 + s) * PAD + cc];
                float4 whi = *(const float4*)&Wc[(tb * 16 + s) * PAD + cc + 4];
                alo.x += tv * wlo.x; alo.y += tv * wlo.y; alo.z += tv * wlo.z; alo.w += tv * wlo.w;
                ahi.x += tv * whi.x; ahi.y += tv * whi.y; ahi.z += tv * whi.z; ahi.w += tv * whi.w;
            }
            __syncthreads();
            *(float4*)&Wc[t * PAD + cc] = alo;
            *(float4*)&Wc[t * PAD + cc + 4] = ahi;
            __syncthreads();
        }
    }

    float4* Wvg = (float4*)(Wv + (size_t)blk * 4096);
    float4* Wkg = (float4*)(Wk + (size_t)blk * 4096);
#pragma unroll
    for (int i = 0; i < 4; ++i) {
        int f = tid + i * 256;
        int d = (f >> 4) * PAD + (f & 15) * 4;
        Wvg[f] = *(float4*)&wv_s[d];
        Wkg[f] = *(float4*)&wk_s[d];
    }
}

// ---------------------------------------------------------------------------
// Phase B1: chunk-transition operators A_c, B_c (unchanged)
// ---------------------------------------------------------------------------
__global__ __launch_bounds__(256) void ab_k(const float* __restrict__ Kc,
                                            const float* __restrict__ Wv,
                                            const float* __restrict__ Wk,
                                            const float* __restrict__ bcum,
                                            float* __restrict__ Ab,
                                            float* __restrict__ Bb) {
    __shared__ __align__(16) float kt_s[CL * PAD];
    __shared__ __align__(16) float wk_s[CL * PAD];
    __shared__ __align__(16) float wv_s[CL * PAD];
    __shared__ float e_s[CL];
    __shared__ float ebC_s;

    const int blk = blockIdx.x;
    const int tid = threadIdx.x;

    if (tid < 64) {
        float bC = bcum[(size_t)blk * 64 + 63];
        e_s[tid] = __expf(bC - bcum[(size_t)blk * 64 + tid]);
        if (tid == 63) ebC_s = __expf(bC);
    }
    __syncthreads();

    {
        const float4* Kg = (const float4*)(Kc + (size_t)blk * 4096);
        const float4* Wkg = (const float4*)(Wk + (size_t)blk * 4096);
        const float4* Wvg = (const float4*)(Wv + (size_t)blk * 4096);
#pragma unroll
        for (int i = 0; i < 4; ++i) {
            int f = tid + i * 256;
            int t = f >> 4;
            int d = t * PAD + (f & 15) * 4;
            float4 kv = Kg[f];
            float e = e_s[t];
            *(float4*)&kt_s[d] = make_float4(kv.x * e, kv.y * e, kv.z * e, kv.w * e);
            *(float4*)&wk_s[d] = Wkg[f];
            *(float4*)&wv_s[d] = Wvg[f];
        }
    }
    __syncthreads();

    const int k0 = (tid >> 4) * 4, m0 = (tid & 15) * 4;
    float aA[4][4] = {};
    float aB[4][4] = {};
    for (int ss = 0; ss < 64; ss += 4) {
        float4 kf0 = *(const float4*)&kt_s[(ss + 0) * PAD + k0];
        float4 kf1 = *(const float4*)&kt_s[(ss + 1) * PAD + k0];
        float4 kf2 = *(const float4*)&kt_s[(ss + 2) * PAD + k0];
        float4 kf3 = *(const float4*)&kt_s[(ss + 3) * PAD + k0];
        float4 wa0 = *(const float4*)&wk_s[(ss + 0) * PAD + m0];
        float4 wa1 = *(const float4*)&wk_s[(ss + 1) * PAD + m0];
        float4 wa2 = *(const float4*)&wk_s[(ss + 2) * PAD + m0];
        float4 wa3 = *(const float4*)&wk_s[(ss + 3) * PAD + m0];
        float4 wb0 = *(const float4*)&wv_s[(ss + 0) * PAD + m0];
        float4 wb1 = *(const float4*)&wv_s[(ss + 1) * PAD + m0];
        float4 wb2 = *(const float4*)&wv_s[(ss + 2) * PAD + m0];
        float4 wb3 = *(const float4*)&wv_s[(ss + 3) * PAD + m0];
        OUT16(aA, kf0, wa0); OUT16(aA, kf1, wa1); OUT16(aA, kf2, wa2); OUT16(aA, kf3, wa3);
        OUT16(aB, kf0, wb0); OUT16(aB, kf1, wb1); OUT16(aB, kf2, wb2); OUT16(aB, kf3, wb3);
    }

    const float ebC = ebC_s;
    float* Ag = Ab + (size_t)blk * 4096;
    float* Bg = Bb + (size_t)blk * 4096;
#pragma unroll
    for (int i = 0; i < 4; ++i) {
        const int kk = k0 + i;
        float4 av = make_float4(-aA[i][0], -aA[i][1], -aA[i][2], -aA[i][3]);
        if (kk - m0 == 0) av.x += ebC;
        if (kk - m0 == 1) av.y += ebC;
        if (kk - m0 == 2) av.z += ebC;
        if (kk - m0 == 3) av.w += ebC;
        *(float4*)&Ag[kk * 64 + m0] = av;
        *(float4*)&Bg[kk * 64 + m0] = make_float4(aB[i][0], aB[i][1], aB[i][2], aB[i][3]);
    }
}

// ---------------------------------------------------------------------------
// Phase B2: serial chunk recurrence h' = A_c h + B_c (unchanged)
// ---------------------------------------------------------------------------
__global__ __launch_bounds__(64) void hrec_k(const float* __restrict__ Ab,
                                             const float* __restrict__ Bb,
                                             float* __restrict__ Hst) {
    const int bh = blockIdx.x >> 3;
    const int vs = blockIdx.x & 7;
    const int k = threadIdx.x;

    __shared__ float h_s[8][64];
#pragma unroll
    for (int j = 0; j < 8; ++j) h_s[j][k] = 0.0f;

    float h0 = 0, h1 = 0, h2 = 0, h3 = 0, h4 = 0, h5 = 0, h6 = 0, h7 = 0;

    const float* Abase = Ab + (size_t)bh * NC * 4096 + k * 64;
    const float* Bbase = Bb + (size_t)bh * NC * 4096 + k * 64 + vs * 8;

    float4 an[16];
#pragma unroll
    for (int q = 0; q < 16; ++q) an[q] = *(const float4*)&Abase[q * 4];
    float4 bn0 = *(const float4*)&Bbase[0];
    float4 bn1 = *(const float4*)&Bbase[4];
    __syncthreads();

    for (int c = 0; c < NC; ++c) {
        float4 ac[16];
#pragma unroll
        for (int q = 0; q < 16; ++q) ac[q] = an[q];
        float4 b0 = bn0, b1 = bn1;
        if (c + 1 < NC) {
            const float* An = Abase + (size_t)(c + 1) * 4096;
            const float* Bn = Bbase + (size_t)(c + 1) * 4096;
#pragma unroll
            for (int q = 0; q < 16; ++q) an[q] = *(const float4*)&An[q * 4];
            bn0 = *(const float4*)&Bn[0];
            bn1 = *(const float4*)&Bn[4];
        }

        float* Hg = Hst + ((size_t)bh * NC + c) * 4096 + k * 64 + vs * 8;
        *(float4*)&Hg[0] = make_float4(h0, h1, h2, h3);
        *(float4*)&Hg[4] = make_float4(h4, h5, h6, h7);

        float a0 = b0.x, a1 = b0.y, a2 = b0.z, a3 = b0.w;
        float a4 = b1.x, a5 = b1.y, a6 = b1.z, a7 = b1.w;
#pragma unroll
        for (int m4 = 0; m4 < 16; ++m4) {
            float4 av = ac[m4];
            float4 hv0 = *(const float4*)&h_s[0][m4 * 4];
            float4 hv1 = *(const float4*)&h_s[1][m4 * 4];
            float4 hv2 = *(const float4*)&h_s[2][m4 * 4];
            float4 hv3 = *(const float4*)&h_s[3][m4 * 4];
            float4 hv4 = *(const float4*)&h_s[4][m4 * 4];
            float4 hv5 = *(const float4*)&h_s[5][m4 * 4];
            float4 hv6 = *(const float4*)&h_s[6][m4 * 4];
            float4 hv7 = *(const float4*)&h_s[7][m4 * 4];
            a0 += DOT4(av, hv0); a1 += DOT4(av, hv1);
            a2 += DOT4(av, hv2); a3 += DOT4(av, hv3);
            a4 += DOT4(av, hv4); a5 += DOT4(av, hv5);
            a6 += DOT4(av, hv6); a7 += DOT4(av, hv7);
        }
        __syncthreads();
        h0 = a0; h1 = a1; h2 = a2; h3 = a3;
        h4 = a4; h5 = a5; h6 = a6; h7 = a7;
        h_s[0][k] = h0; h_s[1][k] = h1; h_s[2][k] = h2; h_s[3][k] = h3;
        h_s[4][k] = h4; h_s[5][k] = h5; h_s[6][k] = h6; h_s[7][k] = h7;
        __syncthreads();
    }
}

// ---------------------------------------------------------------------------
// Phase B3: W_c = Wv_c - Wk_c h0_c (unchanged)
// ---------------------------------------------------------------------------
__global__ __launch_bounds__(256) void wfix_k(const float* __restrict__ Wk,
                                              const float* __restrict__ Hst,
                                              float* __restrict__ Wio) {
    __shared__ __align__(16) float wk_s[CL * PAD];
    __shared__ __align__(16) float h_s[CL * PAD];

    const int blk = blockIdx.x;
    const int tid = threadIdx.x;

    {
        const float4* Wkg = (const float4*)(Wk + (size_t)blk * 4096);
        const float4* Hg = (const float4*)(Hst + (size_t)blk * 4096);
#pragma unroll
        for (int i = 0; i < 4; ++i) {
            int f = tid + i * 256;
            int d = (f >> 4) * PAD + (f & 15) * 4;
            *(float4*)&wk_s[d] = Wkg[f];
            *(float4*)&h_s[d] = Hg[f];
        }
    }
    __syncthreads();

    const int t0 = (tid >> 4) * 4, v0 = (tid & 15) * 4;
    float* Wg = Wio + (size_t)blk * 4096;

    float acc[4][4];
#pragma unroll
    for (int i = 0; i < 4; ++i) {
        float4 wv = *(const float4*)&Wg[(t0 + i) * 64 + v0];
        acc[i][0] = wv.x; acc[i][1] = wv.y; acc[i][2] = wv.z; acc[i][3] = wv.w;
    }
    for (int kk = 0; kk < 64; kk += 4) {
        float4 wa0 = *(const float4*)&wk_s[(t0 + 0) * PAD + kk];
        float4 wa1 = *(const float4*)&wk_s[(t0 + 1) * PAD + kk];
        float4 wa2 = *(const float4*)&wk_s[(t0 + 2) * PAD + kk];
        float4 wa3 = *(const float4*)&wk_s[(t0 + 3) * PAD + kk];
        float4 hb0 = *(const float4*)&h_s[(kk + 0) * PAD + v0];
        float4 hb1 = *(const float4*)&h_s[(kk + 1) * PAD + v0];
        float4 hb2 = *(const float4*)&h_s[(kk + 2) * PAD + v0];
        float4 hb3 = *(const float4*)&h_s[(kk + 3) * PAD + v0];
        WSUB(x, hb0); WSUB(y, hb1); WSUB(z, hb2); WSUB(w, hb3);
    }
#pragma unroll
    for (int i = 0; i < 4; ++i)
        *(float4*)&Wg[(t0 + i) * 64 + v0] =
            make_float4(acc[i][0], acc[i][1], acc[i][2], acc[i][3]);
}

// ---------------------------------------------------------------------------
// Phase C (R7): scratch-free + PAD-strided LDS (unchanged)
// ---------------------------------------------------------------------------
__global__ __launch_bounds__(256) void out_k(const float* __restrict__ Qc,
                                             const float* __restrict__ Kc,
                                             const float* __restrict__ Wb_,
                                             const float* __restrict__ Hst,
                                             const float* __restrict__ bcum,
                                             float* __restrict__ o_scan) {
    __shared__ __align__(16) float q_s[CL * PAD];
    __shared__ __align__(16) float s_s[CL * PAD];   // K, then S
    __shared__ __align__(16) float h_s[CL * PAD];
    __shared__ __align__(16) float w_s[CL * PAD];
    __shared__ float b_s[64];

    const int blk = blockIdx.x;
    const int bh = blk >> 5;
    const int c = blk & 31;
    const int b = bh >> 4;
    const int h = bh & 15;
    const int tid = threadIdx.x;

    if (tid < 64) b_s[tid] = bcum[(size_t)blk * 64 + tid];
    {
        const float4* Qg = (const float4*)(Qc + (size_t)blk * 4096);
        const float4* Kg = (const float4*)(Kc + (size_t)blk * 4096);
        const float4* Hg = (const float4*)(Hst + (size_t)blk * 4096);
        const float4* Wg = (const float4*)(Wb_ + (size_t)blk * 4096);
#pragma unroll
        for (int i = 0; i < 4; ++i) {
            int f = tid + i * 256;
            int d = (f >> 4) * PAD + (f & 15) * 4;
            *(float4*)&q_s[d] = Qg[f];
            *(float4*)&s_s[d] = Kg[f];
            *(float4*)&h_s[d] = Hg[f];
            *(float4*)&w_s[d] = Wg[f];
        }
    }
    __syncthreads();

    // Phase 1: S = (Q K^T) ⊙ exp(b_t - b_s) [s<=t], overwrite s_s
    {
        const int t0 = (tid >> 4) * 4, s0 = (tid & 15) * 4;
        float acc[4][4] = {};
        for (int kk = 0; kk < 64; kk += 4) {
            float4 ta0 = *(const float4*)&q_s[(t0 + 0) * PAD + kk];
            float4 ta1 = *(const float4*)&q_s[(t0 + 1) * PAD + kk];
            float4 ta2 = *(const float4*)&q_s[(t0 + 2) * PAD + kk];
            float4 ta3 = *(const float4*)&q_s[(t0 + 3) * PAD + kk];
            float4 sb0 = *(const float4*)&s_s[(s0 + 0) * PAD + kk];
            float4 sb1 = *(const float4*)&s_s[(s0 + 1) * PAD + kk];
            float4 sb2 = *(const float4*)&s_s[(s0 + 2) * PAD + kk];
            float4 sb3 = *(const float4*)&s_s[(s0 + 3) * PAD + kk];
            acc[0][0] += DOT4(ta0, sb0); acc[0][1] += DOT4(ta0, sb1);
            acc[0][2] += DOT4(ta0, sb2); acc[0][3] += DOT4(ta0, sb3);
            acc[1][0] += DOT4(ta1, sb0); acc[1][1] += DOT4(ta1, sb1);
            acc[1][2] += DOT4(ta1, sb2); acc[1][3] += DOT4(ta1, sb3);
            acc[2][0] += DOT4(ta2, sb0); acc[2][1] += DOT4(ta2, sb1);
            acc[2][2] += DOT4(ta2, sb2); acc[2][3] += DOT4(ta2, sb3);
            acc[3][0] += DOT4(ta3, sb0); acc[3][1] += DOT4(ta3, sb1);
            acc[3][2] += DOT4(ta3, sb2); acc[3][3] += DOT4(ta3, sb3);
        }
        __syncthreads();   // all Q,K reads done before overwrite
#pragma unroll
        for (int i = 0; i < 4; ++i)
#pragma unroll
            for (int j = 0; j < 4; ++j) {
                const int t = t0 + i, s = s0 + j;
                s_s[t * PAD + s] = (s <= t) ? acc[i][j] * __expf(b_s[t] - b_s[s]) : 0.0f;
            }
    }
    // scale q rows by e^{b_t}
#pragma unroll
    for (int i = 0; i < 16; ++i) {
        const int e = tid + i * 256;
        const int t = e >> 6;
        q_s[t * PAD + (e & 63)] *= __expf(b_s[t]);
    }
    __syncthreads();

    // Phase 2: O = S @ W + Qs @ H
    {
        const int t0 = (tid >> 4) * 4, v0 = (tid & 15) * 4;
        float acc[4][4] = {};
        for (int ss = 0; ss < 64; ss += 4) {
            float4 sa0 = *(const float4*)&s_s[(t0 + 0) * PAD + ss];
            float4 sa1 = *(const float4*)&s_s[(t0 + 1) * PAD + ss];
            float4 sa2 = *(const float4*)&s_s[(t0 + 2) * PAD + ss];
            float4 sa3 = *(const float4*)&s_s[(t0 + 3) * PAD + ss];
            float4 wb0 = *(const float4*)&w_s[(ss + 0) * PAD + v0];
            float4 wb1 = *(const float4*)&w_s[(ss + 1) * PAD + v0];
            float4 wb2 = *(const float4*)&w_s[(ss + 2) * PAD + v0];
            float4 wb3 = *(const float4*)&w_s[(ss + 3) * PAD + v0];
            ACC16(x, wb0); ACC16(y, wb1); ACC16(z, wb2); ACC16(w, wb3);
        }
        for (int kk = 0; kk < 64; kk += 4) {
            float4 sa0 = *(const float4*)&q_s[(t0 + 0) * PAD + kk];
            float4 sa1 = *(const float4*)&q_s[(t0 + 1) * PAD + kk];
            float4 sa2 = *(const float4*)&q_s[(t0 + 2) * PAD + kk];
            float4 sa3 = *(const float4*)&q_s[(t0 + 3) * PAD + kk];
            float4 wb0 = *(const float4*)&h_s[(kk + 0) * PAD + v0];
            float4 wb1 = *(const float4*)&h_s[(kk + 1) * PAD + v0];
            float4 wb2 = *(const float4*)&h_s[(kk + 2) * PAD + v0];
            float4 wb3 = *(const float4*)&h_s[(kk + 3) * PAD + v0];
            ACC16(x, wb0); ACC16(y, wb1); ACC16(z, wb2); ACC16(w, wb3);
        }
#pragma unroll
        for (int i = 0; i < 4; ++i) {
            const int t = c * CL + t0 + i;
            *(float4*)&o_scan[(((size_t)b * TT + t) * HH + h) * DK + v0] =
                make_float4(acc[i][0], acc[i][1], acc[i][2], acc[i][3]);
        }
    }
}

// ---------------------------------------------------------------------------
// Gated RMSNorm -> bf16 output (unchanged)
// ---------------------------------------------------------------------------
__global__ __launch_bounds__(256) void gnorm_k(const float* __restrict__ o_scan,
                                               const float* __restrict__ gate,
                                               const float* __restrict__ rms_w,
                                               unsigned short* __restrict__ o2) {
    const int tid = threadIdx.x;
    const int grp = tid >> 6;
    const int lane = tid & 63;
    const int bth = blockIdx.x * 4 + grp;
    const int h = bth & 15;
    const int row = bth >> 4;

    float ov = o_scan[(size_t)bth * DK + lane];
    float s = ov * ov;
#pragma unroll
    for (int sh = 32; sh > 0; sh >>= 1) s += __shfl_xor(s, sh);
    float r = rsqrtf(s * (1.0f / 64.0f) + 1e-5f);

    float gt = gate[(size_t)row * HD + h * DK + lane];
    o2[(size_t)row * HD + h * DK + lane] = f2bf(ov * r * rms_w[lane] * siluf_(gt));
}

// ---------------------------------------------------------------------------
extern "C" void kernel_launch(void* const* d_in, const int* in_sizes, int n_in,
                              void* d_out, int out_size, void* d_ws, size_t ws_size,
                              hipStream_t stream) {
    (void)in_sizes; (void)n_in; (void)out_size; (void)ws_size;

    const float* x       = (const float*)d_in[0];
    const float* Wq      = (const float*)d_in[1];
    const float* Wk_     = (const float*)d_in[2];
    const float* Wv_     = (const float*)d_in[3];
    const float* Wa      = (const float*)d_in[4];
    const float* Wb      = (const float*)d_in[5];
    const float* Wg      = (const float*)d_in[6];
    const float* Wo      = (const float*)d_in[7];
    const float* conv_q  = (const float*)d_in[8];
    const float* conv_k  = (const float*)d_in[9];
    const float* conv_v  = (const float*)d_in[10];
    const float* A_log   = (const float*)d_in[11];
    const float* dt_bias = (const float*)d_in[12];
    const float* rms_w   = (const float*)d_in[13];
    float* out = (float*)d_out;

    float* ws = (float*)d_ws;
    const size_t NTOK = (size_t)BB * TT;     // 4096
    const size_t BIG = NTOK * HD;            // 4 Mi floats

    float* q_pre = ws + 0 * BIG;
    float* k_pre = ws + 1 * BIG;
    float* v_pre = ws + 2 * BIG;
    float* gatep = ws + 3 * BIG;
    float* Qc    = ws + 4 * BIG;
    float* Kc    = ws + 5 * BIG;
    float* gbuf  = ws + 6 * BIG;
    float* bbuf  = gbuf + NTOK * HH;
    float* bcumb = bbuf + NTOK * HH;

    // bf16 buffers after the fp32 region
    unsigned short* xb  = (unsigned short*)(bcumb + NTOK * HH);
    unsigned short* wqt = xb + (size_t)NTOK * DD;
    unsigned short* wkt = wqt + (size_t)DD * HD;
    unsigned short* wvt = wkt + (size_t)DD * HD;
    unsigned short* wgt = wvt + (size_t)DD * HD;
    unsigned short* wot = wgt + (size_t)DD * HD;

    // fp32 buffers after bf16 region: Bb + Hst (32 MB) + Wab_t (128 KB)
    float* Bbuf = (float*)(wot + (size_t)DD * HD);
    float* HstB = Bbuf + BIG;
    float* Wabt = HstB + BIG;

    // aliases (stream-ordered lifetimes):
    float* Wvb    = q_pre;   // prep_k out; wfix_k rewrites in place to W
    float* Wkb    = k_pre;
    float* Abuf   = v_pre;   // ab_k out (v_pre dead after prep_k)
    float* o_scan = v_pre;   // out_k out (Abuf dead after hrec_k)
    unsigned short* o2b = (unsigned short*)Qc;

    // casts
    castx_k<<<(int)(NTOK * DD / (256 * 8)), 256, 0, stream>>>(x, xb);
    dim3 tg(16, 16);
    castw_k<<<tg, 256, 0, stream>>>(Wq, wqt);
    castw_k<<<tg, 256, 0, stream>>>(Wk_, wkt);
    castw_k<<<tg, 256, 0, stream>>>(Wv_, wvt);
    castw_k<<<tg, 256, 0, stream>>>(Wg, wgt);
    castw_k<<<tg, 256, 0, stream>>>(Wo, wot);
    tw_k<<<32, 256, 0, stream>>>(Wa, Wb, Wabt);

    // projections
    dim3 gg(HD / 128, NTOK / 128);   // (8, 32)
    gemm_bf16_k<<<gg, 256, 0, stream>>>(xb, wqt, q_pre, (int)NTOK, HD, DD);
    gemm_bf16_k<<<gg, 256, 0, stream>>>(xb, wkt, k_pre, (int)NTOK, HD, DD);
    gemm_bf16_k<<<gg, 256, 0, stream>>>(xb, wvt, v_pre, (int)NTOK, HD, DD);
    gemm_bf16_k<<<gg, 256, 0, stream>>>(xb, wgt, gatep, (int)NTOK, HD, DD);

    gbeta_k<<<(int)(NTOK / 8), 256, 0, stream>>>(x, Wabt, A_log, dt_bias, gbuf, bbuf);

    stage_k<<<BB * HH * NC, 64, 0, stream>>>(q_pre, k_pre, conv_q, conv_k, gbuf,
                                             Qc, Kc, bcumb);

    prep_k<<<BB * HH * NC, 256, 0, stream>>>(Kc, v_pre, conv_v, bcumb, bbuf, Wvb, Wkb);

    // chunked state recurrence, decomposed:
    ab_k<<<BB * HH * NC, 256, 0, stream>>>(Kc, Wvb, Wkb, bcumb, Abuf, Bbuf);
    hrec_k<<<BB * HH * 8, 64, 0, stream>>>(Abuf, Bbuf, HstB);
    wfix_k<<<BB * HH * NC, 256, 0, stream>>>(Wkb, HstB, Wvb);

    out_k<<<BB * HH * NC, 256, 0, stream>>>(Qc, Kc, Wvb, HstB, bcumb, o_scan);

    gnorm_k<<<(int)(NTOK * HH / 4), 256, 0, stream>>>(o_scan, gatep, rms_w, o2b);

    gemm_bf16_k<<<gg, 256, 0, stream>>>(o2b, wot, out, (int)NTOK, HD, DD);
}

// Round 10
// 520.897 us; speedup vs baseline: 12.3595x; 1.0497x over previous
//
#include <hip/hip_runtime.h>
#include <hip/hip_bf16.h>
#include <math.h>
#include <stdint.h>

// Problem constants
#define BB 2
#define TT 2048
#define DD 1024
#define HH 16
#define DK 64
#define HD 1024   // H*DK
#define NC 32     // chunks per sequence (TT/64)
#define CL 64     // chunk length
#define PAD 68    // padded LDS row stride (floats) to break stride-64 bank conflicts
#define VS 16     // v-splits in hrec_k

typedef short bf16x8 __attribute__((ext_vector_type(8)));     // 8 bf16 (4 VGPRs)
typedef float f32x4 __attribute__((ext_vector_type(4)));      // MFMA acc
typedef unsigned short u16x8 __attribute__((ext_vector_type(8)));
typedef unsigned short u16x4 __attribute__((ext_vector_type(4)));

#define GAS __attribute__((address_space(1)))
#define LAS __attribute__((address_space(3)))

#define DOT4(a, b) ((a).x*(b).x + (a).y*(b).y + (a).z*(b).z + (a).w*(b).w)

// acc[i][j] += kf[i-component] * wv[j-component]   (one contraction step)
#define OUT16(acc, kf, wv) \
    acc[0][0] += kf.x * wv.x; acc[0][1] += kf.x * wv.y; acc[0][2] += kf.x * wv.z; acc[0][3] += kf.x * wv.w; \
    acc[1][0] += kf.y * wv.x; acc[1][1] += kf.y * wv.y; acc[1][2] += kf.y * wv.z; acc[1][3] += kf.y * wv.w; \
    acc[2][0] += kf.z * wv.x; acc[2][1] += kf.z * wv.y; acc[2][2] += kf.z * wv.z; acc[2][3] += kf.z * wv.w; \
    acc[3][0] += kf.w * wv.x; acc[3][1] += kf.w * wv.y; acc[3][2] += kf.w * wv.z; acc[3][3] += kf.w * wv.w;

// acc[i][j] -= wa_i.c * hv[j]   (c = component selecting m)
#define WSUB(c, hv) \
    acc[0][0] -= wa0.c * hv.x; acc[0][1] -= wa0.c * hv.y; acc[0][2] -= wa0.c * hv.z; acc[0][3] -= wa0.c * hv.w; \
    acc[1][0] -= wa1.c * hv.x; acc[1][1] -= wa1.c * hv.y; acc[1][2] -= wa1.c * hv.z; acc[1][3] -= wa1.c * hv.w; \
    acc[2][0] -= wa2.c * hv.x; acc[2][1] -= wa2.c * hv.y; acc[2][2] -= wa2.c * hv.z; acc[2][3] -= wa2.c * hv.w; \
    acc[3][0] -= wa3.c * hv.x; acc[3][1] -= wa3.c * hv.y; acc[3][2] -= wa3.c * hv.z; acc[3][3] -= wa3.c * hv.w;

// acc[i][j] += sa_i.c * wv[j]   (c = component selecting the contraction idx)
#define ACC16(c, wv) \
    acc[0][0] += sa0.c * wv.x; acc[0][1] += sa0.c * wv.y; acc[0][2] += sa0.c * wv.z; acc[0][3] += sa0.c * wv.w; \
    acc[1][0] += sa1.c * wv.x; acc[1][1] += sa1.c * wv.y; acc[1][2] += sa1.c * wv.z; acc[1][3] += sa1.c * wv.w; \
    acc[2][0] += sa2.c * wv.x; acc[2][1] += sa2.c * wv.y; acc[2][2] += sa2.c * wv.z; acc[2][3] += sa2.c * wv.w; \
    acc[3][0] += sa3.c * wv.x; acc[3][1] += sa3.c * wv.y; acc[3][2] += sa3.c * wv.z; acc[3][3] += sa3.c * wv.w;

__device__ __forceinline__ float sigmoidf_(float x) { return 1.0f / (1.0f + expf(-x)); }
__device__ __forceinline__ float siluf_(float x) { return x * sigmoidf_(x); }

// round-to-nearest-even fp32 -> bf16
__device__ __forceinline__ unsigned short f2bf(float f) {
    unsigned int u = __builtin_bit_cast(unsigned int, f);
    u = (u + 0x7fffu + ((u >> 16) & 1u)) >> 16;
    return (unsigned short)u;
}

// ---------------------------------------------------------------------------
// Cast x (fp32) -> bf16, flat.
// ---------------------------------------------------------------------------
__global__ __launch_bounds__(256) void castx_k(const float* __restrict__ src,
                                               unsigned short* __restrict__ dst) {
    const size_t idx = (size_t)blockIdx.x * 256 + threadIdx.x;
    float4 a = *(const float4*)&src[idx * 8];
    float4 b = *(const float4*)&src[idx * 8 + 4];
    u16x8 o;
    o[0] = f2bf(a.x); o[1] = f2bf(a.y); o[2] = f2bf(a.z); o[3] = f2bf(a.w);
    o[4] = f2bf(b.x); o[5] = f2bf(b.y); o[6] = f2bf(b.z); o[7] = f2bf(b.w);
    *(u16x8*)&dst[idx * 8] = o;
}

// ---------------------------------------------------------------------------
// Transpose+cast weight: W[K=1024][N=1024] fp32 -> Wt[N][K] bf16.
// ---------------------------------------------------------------------------
__global__ __launch_bounds__(256) void castw_k(const float* __restrict__ W,
                                               unsigned short* __restrict__ Wt) {
    __shared__ float t_s[64][65];
    const int tid = threadIdx.x;
    const int rr = tid >> 4;
    const int cc = tid & 15;
    const int r0 = blockIdx.y * 64;
    const int c0 = blockIdx.x * 64;
#pragma unroll
    for (int i = 0; i < 4; ++i) {
        const int row = rr + i * 16;
        float4 v = *(const float4*)&W[(size_t)(r0 + row) * 1024 + c0 + cc * 4];
        t_s[row][cc * 4 + 0] = v.x;
        t_s[row][cc * 4 + 1] = v.y;
        t_s[row][cc * 4 + 2] = v.z;
        t_s[row][cc * 4 + 3] = v.w;
    }
    __syncthreads();
#pragma unroll
    for (int i = 0; i < 4; ++i) {
        const int nr = rr + i * 16;
        u16x4 o;
#pragma unroll
        for (int d = 0; d < 4; ++d) o[d] = f2bf(t_s[cc * 4 + d][nr]);
        *(u16x4*)&Wt[(size_t)(c0 + nr) * 1024 + r0 + cc * 4] = o;
    }
}

// ---------------------------------------------------------------------------
// transpose Wa|Wb [1024][16] -> Wab_t [32][1024] fp32 (R8)
// ---------------------------------------------------------------------------
__global__ __launch_bounds__(256) void tw_k(const float* __restrict__ Wa,
                                            const float* __restrict__ Wb,
                                            float* __restrict__ Wt) {
    const int o = blockIdx.x;          // 0..31
    const int h = o & 15;
    const float* W = (o < 16) ? Wa : Wb;
    const int tid = threadIdx.x;
    float4 v;
    v.x = W[(size_t)(tid * 4 + 0) * HH + h];
    v.y = W[(size_t)(tid * 4 + 1) * HH + h];
    v.z = W[(size_t)(tid * 4 + 2) * HH + h];
    v.w = W[(size_t)(tid * 4 + 3) * HH + h];
    *(float4*)&Wt[(size_t)o * DD + tid * 4] = v;
}

// ---------------------------------------------------------------------------
// bf16 MFMA GEMM (m97 structure), unchanged.
// ---------------------------------------------------------------------------
__global__ __launch_bounds__(256) void gemm_bf16_k(const unsigned short* __restrict__ A,
                                                   const unsigned short* __restrict__ Bt,
                                                   float* __restrict__ C,
                                                   int M, int N, int Kd) {
    __shared__ unsigned short a_s[128 * 32];
    __shared__ unsigned short b_s[128 * 32];

    const int tid = threadIdx.x;
    const int wave = tid >> 6;
    const int lane = tid & 63;
    const int m0 = blockIdx.y * 128;
    const int n0 = blockIdx.x * 128;

    const int quad = lane >> 4;
    const int l16 = lane & 15;
    const int wr = wave >> 1;
    const int wc = wave & 1;

    const int srow = lane >> 2;
    const int sseg = lane & 3;

    f32x4 acc[4][4];
#pragma unroll
    for (int i = 0; i < 4; ++i)
#pragma unroll
        for (int j = 0; j < 4; ++j) acc[i][j] = (f32x4){0.f, 0.f, 0.f, 0.f};

    for (int k0 = 0; k0 < Kd; k0 += 32) {
        __syncthreads();
#pragma unroll
        for (int c = 0; c < 2; ++c) {
            const int region = wave * 2 + c;
            const int r0t = region * 16;
            const int ra = r0t + srow;
            const unsigned short* ga = A + (size_t)(m0 + ra) * Kd + k0 + sseg * 8;
            const unsigned short* gb = Bt + (size_t)(n0 + ra) * Kd + k0 + sseg * 8;
            __builtin_amdgcn_global_load_lds((const GAS unsigned int*)ga,
                                             (LAS unsigned int*)&a_s[r0t * 32], 16, 0, 0);
            __builtin_amdgcn_global_load_lds((const GAS unsigned int*)gb,
                                             (LAS unsigned int*)&b_s[r0t * 32], 16, 0, 0);
        }
        __syncthreads();

        bf16x8 af[4], bfr[4];
#pragma unroll
        for (int i = 0; i < 4; ++i)
            af[i] = *(const bf16x8*)&a_s[(wr * 64 + i * 16 + l16) * 32 + quad * 8];
#pragma unroll
        for (int j = 0; j < 4; ++j)
            bfr[j] = *(const bf16x8*)&b_s[(wc * 64 + j * 16 + l16) * 32 + quad * 8];
#pragma unroll
        for (int i = 0; i < 4; ++i)
#pragma unroll
            for (int j = 0; j < 4; ++j)
                acc[i][j] = __builtin_amdgcn_mfma_f32_16x16x32_bf16(af[i], bfr[j], acc[i][j], 0, 0, 0);
    }

#pragma unroll
    for (int i = 0; i < 4; ++i)
#pragma unroll
        for (int j = 0; j < 4; ++j) {
            const int col = n0 + wc * 64 + j * 16 + l16;
#pragma unroll
            for (int r = 0; r < 4; ++r) {
                const int row = m0 + wr * 64 + i * 16 + quad * 4 + r;
                C[(size_t)row * N + col] = acc[i][j][r];
            }
        }
}

// ---------------------------------------------------------------------------
// g / beta kernel (R8, unchanged)
// ---------------------------------------------------------------------------
__global__ __launch_bounds__(256) void gbeta_k(const float* __restrict__ x,
                                               const float* __restrict__ Wt,
                                               const float* __restrict__ A_log,
                                               const float* __restrict__ dt_bias,
                                               float* __restrict__ g,
                                               float* __restrict__ beta) {
    __shared__ __align__(16) float xs[8][DD];
    const int r0 = blockIdx.x * 8;
    const int tid = threadIdx.x;

#pragma unroll
    for (int i = 0; i < 8; ++i) {
        const int f = tid + i * 256;
        const int r = f >> 8;
        const int col = (f & 255) * 4;
        *(float4*)&xs[r][col] = *(const float4*)&x[((size_t)r0 + r) * DD + col];
    }
    __syncthreads();

    const int out = tid >> 3;
    const int part = tid & 7;
    const int h = out & 15;
    const float* Wrow = Wt + (size_t)out * DD;

    float a0 = 0, a1 = 0, a2 = 0, a3 = 0, a4 = 0, a5 = 0, a6 = 0, a7 = 0;
#pragma unroll 4
    for (int i = 0; i < 32; ++i) {
        const int d = i * 32 + part * 4;
        const float4 wv = *(const float4*)&Wrow[d];
        float4 x0 = *(const float4*)&xs[0][d];
        float4 x1 = *(const float4*)&xs[1][d];
        float4 x2 = *(const float4*)&xs[2][d];
        float4 x3 = *(const float4*)&xs[3][d];
        float4 x4 = *(const float4*)&xs[4][d];
        float4 x5 = *(const float4*)&xs[5][d];
        float4 x6 = *(const float4*)&xs[6][d];
        float4 x7 = *(const float4*)&xs[7][d];
        a0 += DOT4(x0, wv); a1 += DOT4(x1, wv);
        a2 += DOT4(x2, wv); a3 += DOT4(x3, wv);
        a4 += DOT4(x4, wv); a5 += DOT4(x5, wv);
        a6 += DOT4(x6, wv); a7 += DOT4(x7, wv);
    }
#pragma unroll
    for (int s = 1; s <= 4; s <<= 1) {
        a0 += __shfl_xor(a0, s); a1 += __shfl_xor(a1, s);
        a2 += __shfl_xor(a2, s); a3 += __shfl_xor(a3, s);
        a4 += __shfl_xor(a4, s); a5 += __shfl_xor(a5, s);
        a6 += __shfl_xor(a6, s); a7 += __shfl_xor(a7, s);
    }

    if (part == 0) {
        float sv[8] = {a0, a1, a2, a3, a4, a5, a6, a7};
        if (out < 16) {
            const float ae = -expf(A_log[h]);
            const float db = dt_bias[h];
#pragma unroll
            for (int r = 0; r < 8; ++r) {
                float v = sv[r] + db;
                float sp = (v > 20.0f) ? v : log1pf(expf(v));
                g[((size_t)r0 + r) * HH + h] = ae * sp;
            }
        } else {
#pragma unroll
            for (int r = 0; r < 8; ++r)
                beta[((size_t)r0 + r) * HH + h] = sigmoidf_(sv[r]);
        }
    }
}

// ---------------------------------------------------------------------------
// Phase A1: stage normalized q,k (conv+silu+l2norm) and cumsum(g). (unchanged)
// ---------------------------------------------------------------------------
__global__ __launch_bounds__(64) void stage_k(const float* __restrict__ q_pre,
                                              const float* __restrict__ k_pre,
                                              const float* __restrict__ cq,
                                              const float* __restrict__ ck,
                                              const float* __restrict__ g,
                                              float* __restrict__ Qc,
                                              float* __restrict__ Kc,
                                              float* __restrict__ bcum) {
    const int blk = blockIdx.x;
    const int bh = blk >> 5;
    const int c = blk & 31;
    const int b = bh >> 4;
    const int h = bh & 15;
    const int lane = threadIdx.x;
    const int ch = h * DK + lane;

    const float4 wq4 = *(const float4*)&cq[ch * 4];
    const float4 wk4 = *(const float4*)&ck[ch * 4];

    float qw0 = 0, qw1 = 0, qw2 = 0, kw0 = 0, kw1 = 0, kw2 = 0;
    {
        const int t0 = c * CL;
        if (t0 - 3 >= 0) { size_t bi = ((size_t)b * TT + t0 - 3) * HD + ch; qw0 = q_pre[bi]; kw0 = k_pre[bi]; }
        if (t0 - 2 >= 0) { size_t bi = ((size_t)b * TT + t0 - 2) * HD + ch; qw1 = q_pre[bi]; kw1 = k_pre[bi]; }
        if (t0 - 1 >= 0) { size_t bi = ((size_t)b * TT + t0 - 1) * HD + ch; qw2 = q_pre[bi]; kw2 = k_pre[bi]; }
    }
    float* Qo = Qc + (size_t)blk * 4096;
    float* Ko = Kc + (size_t)blk * 4096;

    for (int tt = 0; tt < CL; ++tt) {
        const int t = c * CL + tt;
        const size_t bi = ((size_t)b * TT + t) * HD + ch;
        const float qc_ = q_pre[bi];
        const float kc_ = k_pre[bi];
        float qa = qw0 * wq4.x + qw1 * wq4.y + qw2 * wq4.z + qc_ * wq4.w;
        float ka = kw0 * wk4.x + kw1 * wk4.y + kw2 * wk4.z + kc_ * wk4.w;
        qw0 = qw1; qw1 = qw2; qw2 = qc_;
        kw0 = kw1; kw1 = kw2; kw2 = kc_;
        qa = siluf_(qa);
        ka = siluf_(ka);
        float qs2 = qa * qa, ks2 = ka * ka;
#pragma unroll
        for (int s = 32; s > 0; s >>= 1) {
            qs2 += __shfl_xor(qs2, s);
            ks2 += __shfl_xor(ks2, s);
        }
        Qo[tt * 64 + lane] = qa * rsqrtf(qs2 + 1e-6f) * 0.125f;
        Ko[tt * 64 + lane] = ka * rsqrtf(ks2 + 1e-6f);
    }

    float cum = g[((size_t)b * TT + c * CL + lane) * HH + h];
#pragma unroll
    for (int s = 1; s < 64; s <<= 1) {
        float u = __shfl_up(cum, s);
        if (lane >= s) cum += u;
    }
    bcum[(size_t)blk * 64 + lane] = cum;
}

// ---------------------------------------------------------------------------
// Phase A2 (R5): scratch-free blocked triangular solve (unchanged)
// ---------------------------------------------------------------------------
__global__ __launch_bounds__(256) void prep_k(const float* __restrict__ Kc,
                                              const float* __restrict__ v_pre,
                                              const float* __restrict__ cv,
                                              const float* __restrict__ bcum,
                                              const float* __restrict__ bbuf,
                                              float* __restrict__ Wv,
                                              float* __restrict__ Wk) {
    __shared__ __align__(16) float k_s[CL * PAD];
    __shared__ __align__(16) float wv_s[CL * PAD];
    __shared__ __align__(16) float wk_s[CL * PAD];
    __shared__ __align__(16) float A_s[CL * PAD];
    __shared__ float T_s[4][16 * 17];
    __shared__ float b_s[CL], beta_s[CL], bk_s[CL];

    const int blk = blockIdx.x;
    const int bh = blk >> 5;
    const int c = blk & 31;
    const int b = bh >> 4;
    const int h = bh & 15;
    const int tid = threadIdx.x;

    if (tid < 64) {
        float bv = bcum[(size_t)blk * 64 + tid];
        float be = bbuf[((size_t)b * TT + c * CL + tid) * HH + h];
        b_s[tid] = bv;
        beta_s[tid] = be;
        bk_s[tid] = be * __expf(bv);
    }
    __syncthreads();

    {
        const float4* Kg = (const float4*)(Kc + (size_t)blk * 4096);
#pragma unroll
        for (int i = 0; i < 4; ++i) {
            int f = tid + i * 256;
            int t = f >> 4;
            int d = t * PAD + (f & 15) * 4;
            float4 kv = Kg[f];
            *(float4*)&k_s[d] = kv;
            float sk = bk_s[t];
            *(float4*)&wk_s[d] = make_float4(kv.x * sk, kv.y * sk, kv.z * sk, kv.w * sk);
        }
    }

    {
        const int lane = tid & 63;
        const int q4 = tid >> 6;
        const int ch = h * DK + lane;
        const float4 wv4 = *(const float4*)&cv[ch * 4];
        const int T0 = c * CL + q4 * 16;
        float w0 = 0, w1 = 0, w2 = 0;
        if (T0 - 3 >= 0) w0 = v_pre[((size_t)b * TT + T0 - 3) * HD + ch];
        if (T0 - 2 >= 0) w1 = v_pre[((size_t)b * TT + T0 - 2) * HD + ch];
        if (T0 - 1 >= 0) w2 = v_pre[((size_t)b * TT + T0 - 1) * HD + ch];
#pragma unroll 1
        for (int i = 0; i < 16; ++i) {
            const int t = T0 + i;
            const float vc_ = v_pre[((size_t)b * TT + t) * HD + ch];
            float va = w0 * wv4.x + w1 * wv4.y + w2 * wv4.z + vc_ * wv4.w;
            w0 = w1; w1 = w2; w2 = vc_;
            va = siluf_(va);
            wv_s[(q4 * 16 + i) * PAD + lane] = va * beta_s[q4 * 16 + i];
        }
    }
    __syncthreads();

    {
        const int t0 = (tid >> 4) * 4, s0 = (tid & 15) * 4;
        float acc[4][4] = {};
        for (int kk = 0; kk < 64; kk += 4) {
            float4 ta0 = *(const float4*)&k_s[(t0 + 0) * PAD + kk];
            float4 ta1 = *(const float4*)&k_s[(t0 + 1) * PAD + kk];
            float4 ta2 = *(const float4*)&k_s[(t0 + 2) * PAD + kk];
            float4 ta3 = *(const float4*)&k_s[(t0 + 3) * PAD + kk];
            float4 sb0 = *(const float4*)&k_s[(s0 + 0) * PAD + kk];
            float4 sb1 = *(const float4*)&k_s[(s0 + 1) * PAD + kk];
            float4 sb2 = *(const float4*)&k_s[(s0 + 2) * PAD + kk];
            float4 sb3 = *(const float4*)&k_s[(s0 + 3) * PAD + kk];
            acc[0][0] += DOT4(ta0, sb0); acc[0][1] += DOT4(ta0, sb1);
            acc[0][2] += DOT4(ta0, sb2); acc[0][3] += DOT4(ta0, sb3);
            acc[1][0] += DOT4(ta1, sb0); acc[1][1] += DOT4(ta1, sb1);
            acc[1][2] += DOT4(ta1, sb2); acc[1][3] += DOT4(ta1, sb3);
            acc[2][0] += DOT4(ta2, sb0); acc[2][1] += DOT4(ta2, sb1);
            acc[2][2] += DOT4(ta2, sb2); acc[2][3] += DOT4(ta2, sb3);
            acc[3][0] += DOT4(ta3, sb0); acc[3][1] += DOT4(ta3, sb1);
            acc[3][2] += DOT4(ta3, sb2); acc[3][3] += DOT4(ta3, sb3);
        }
#pragma unroll
        for (int i = 0; i < 4; ++i)
#pragma unroll
            for (int j = 0; j < 4; ++j) {
                const int t = t0 + i, s = s0 + j;
                A_s[t * PAD + s] = (s < t) ? acc[i][j] * beta_s[t] * __expf(b_s[t] - b_s[s]) : 0.0f;
            }
    }
    __syncthreads();

    if (tid < 64) {
        const int d = tid >> 4;
        const int col = tid & 15;
        const int base = d * 16;
        float tcol[16];
#pragma unroll
        for (int s = 0; s < 16; ++s) tcol[s] = (s == col) ? 1.0f : 0.0f;
#pragma unroll
        for (int t = 1; t < 16; ++t) {
            float a = 0.0f;
#pragma unroll
            for (int s = 0; s < 16; ++s)
                if (s < t) a += A_s[(base + t) * PAD + base + s] * tcol[s];
            tcol[t] -= a;
        }
#pragma unroll
        for (int t = 0; t < 16; ++t) T_s[d][t * 17 + col] = tcol[t];
    }
    __syncthreads();

    {
        const int r = tid >> 4;
        const int cg = tid & 15;
        float* Wc = (cg < 8) ? wv_s : wk_s;
        const int cc = (cg & 7) * 8;

        for (int tb = 0; tb < 4; ++tb) {
            const int t = tb * 16 + r;
            if (tb > 0) {
                float4 lo = *(const float4*)&Wc[t * PAD + cc];
                float4 hi = *(const float4*)&Wc[t * PAD + cc + 4];
#pragma unroll 4
                for (int s = 0; s < tb * 16; ++s) {
                    const float a = A_s[t * PAD + s];
                    float4 wlo = *(const float4*)&Wc[s * PAD + cc];
                    float4 whi = *(const float4*)&Wc[s * PAD + cc + 4];
                    lo.x -= a * wlo.x; lo.y -= a * wlo.y; lo.z -= a * wlo.z; lo.w -= a * wlo.w;
                    hi.x -= a * whi.x; hi.y -= a * whi.y; hi.z -= a * whi.z; hi.w -= a * whi.w;
                }
                *(float4*)&Wc[t * PAD + cc] = lo;
                *(float4*)&Wc[t * PAD + cc + 4] = hi;
            }
            __syncthreads();
            float4 alo = make_float4(0, 0, 0, 0);
            float4 ahi = make_float4(0, 0, 0, 0);
#pragma unroll 4
            for (int s = 0; s < 16; ++s) {
                const float tv = T_s[tb][r * 17 + s];
                float4 wlo = *(const float4*)&Wc[(tb * 16 + s) * PAD + cc];
                float4 whi = *(const float4*)&Wc[(tb * 16 + s) * PAD + cc + 4];
                alo.x += tv * wlo.x; alo.y += tv * wlo.y; alo.z += tv * wlo.z; alo.w += tv * wlo.w;
                ahi.x += tv * whi.x; ahi.y += tv * whi.y; ahi.z += tv * whi.z; ahi.w += tv * whi.w;
            }
            __syncthreads();
            *(float4*)&Wc[t * PAD + cc] = alo;
            *(float4*)&Wc[t * PAD + cc + 4] = ahi;
            __syncthreads();
        }
    }

    float4* Wvg = (float4*)(Wv + (size_t)blk * 4096);
    float4* Wkg = (float4*)(Wk + (size_t)blk * 4096);
#pragma unroll
    for (int i = 0; i < 4; ++i) {
        int f = tid + i * 256;
        int d = (f >> 4) * PAD + (f & 15) * 4;
        Wvg[f] = *(float4*)&wv_s[d];
        Wkg[f] = *(float4*)&wk_s[d];
    }
}

// ---------------------------------------------------------------------------
// Phase B1: chunk-transition operators A_c, B_c (unchanged)
// ---------------------------------------------------------------------------
__global__ __launch_bounds__(256) void ab_k(const float* __restrict__ Kc,
                                            const float* __restrict__ Wv,
                                            const float* __restrict__ Wk,
                                            const float* __restrict__ bcum,
                                            float* __restrict__ Ab,
                                            float* __restrict__ Bb) {
    __shared__ __align__(16) float kt_s[CL * PAD];
    __shared__ __align__(16) float wk_s[CL * PAD];
    __shared__ __align__(16) float wv_s[CL * PAD];
    __shared__ float e_s[CL];
    __shared__ float ebC_s;

    const int blk = blockIdx.x;
    const int tid = threadIdx.x;

    if (tid < 64) {
        float bC = bcum[(size_t)blk * 64 + 63];
        e_s[tid] = __expf(bC - bcum[(size_t)blk * 64 + tid]);
        if (tid == 63) ebC_s = __expf(bC);
    }
    __syncthreads();

    {
        const float4* Kg = (const float4*)(Kc + (size_t)blk * 4096);
        const float4* Wkg = (const float4*)(Wk + (size_t)blk * 4096);
        const float4* Wvg = (const float4*)(Wv + (size_t)blk * 4096);
#pragma unroll
        for (int i = 0; i < 4; ++i) {
            int f = tid + i * 256;
            int t = f >> 4;
            int d = t * PAD + (f & 15) * 4;
            float4 kv = Kg[f];
            float e = e_s[t];
            *(float4*)&kt_s[d] = make_float4(kv.x * e, kv.y * e, kv.z * e, kv.w * e);
            *(float4*)&wk_s[d] = Wkg[f];
            *(float4*)&wv_s[d] = Wvg[f];
        }
    }
    __syncthreads();

    const int k0 = (tid >> 4) * 4, m0 = (tid & 15) * 4;
    float aA[4][4] = {};
    float aB[4][4] = {};
    for (int ss = 0; ss < 64; ss += 4) {
        float4 kf0 = *(const float4*)&kt_s[(ss + 0) * PAD + k0];
        float4 kf1 = *(const float4*)&kt_s[(ss + 1) * PAD + k0];
        float4 kf2 = *(const float4*)&kt_s[(ss + 2) * PAD + k0];
        float4 kf3 = *(const float4*)&kt_s[(ss + 3) * PAD + k0];
        float4 wa0 = *(const float4*)&wk_s[(ss + 0) * PAD + m0];
        float4 wa1 = *(const float4*)&wk_s[(ss + 1) * PAD + m0];
        float4 wa2 = *(const float4*)&wk_s[(ss + 2) * PAD + m0];
        float4 wa3 = *(const float4*)&wk_s[(ss + 3) * PAD + m0];
        float4 wb0 = *(const float4*)&wv_s[(ss + 0) * PAD + m0];
        float4 wb1 = *(const float4*)&wv_s[(ss + 1) * PAD + m0];
        float4 wb2 = *(const float4*)&wv_s[(ss + 2) * PAD + m0];
        float4 wb3 = *(const float4*)&wv_s[(ss + 3) * PAD + m0];
        OUT16(aA, kf0, wa0); OUT16(aA, kf1, wa1); OUT16(aA, kf2, wa2); OUT16(aA, kf3, wa3);
        OUT16(aB, kf0, wb0); OUT16(aB, kf1, wb1); OUT16(aB, kf2, wb2); OUT16(aB, kf3, wb3);
    }

    const float ebC = ebC_s;
    float* Ag = Ab + (size_t)blk * 4096;
    float* Bg = Bb + (size_t)blk * 4096;
#pragma unroll
    for (int i = 0; i < 4; ++i) {
        const int kk = k0 + i;
        float4 av = make_float4(-aA[i][0], -aA[i][1], -aA[i][2], -aA[i][3]);
        if (kk - m0 == 0) av.x += ebC;
        if (kk - m0 == 1) av.y += ebC;
        if (kk - m0 == 2) av.z += ebC;
        if (kk - m0 == 3) av.w += ebC;
        *(float4*)&Ag[kk * 64 + m0] = av;
        *(float4*)&Bg[kk * 64 + m0] = make_float4(aB[i][0], aB[i][1], aB[i][2], aB[i][3]);
    }
}

// ---------------------------------------------------------------------------
// Phase B2 (R9): serial chunk recurrence h' = A_c h + B_c.
// vs-major block index: bh = blk & 31, vs = blk >> 5 -> the VS blocks of one
// bh share indices ≡ bh (mod 32); under idx%8 XCD round-robin they land on
// ONE XCD, so A is fetched from HBM once per bh (was 8x dup, FETCH 98 MB).
// VS=16 -> 512 blocks = 2 waves/CU for latency hiding; 4 v-cols/thread.
// ---------------------------------------------------------------------------
__global__ __launch_bounds__(64) void hrec_k(const float* __restrict__ Ab,
                                             const float* __restrict__ Bb,
                                             float* __restrict__ Hst) {
    const int blk = blockIdx.x;
    const int bh = blk & 31;          // vs-major: same-bh blocks -> same XCD
    const int vs = blk >> 5;          // 0..VS-1
    const int k = threadIdx.x;

    __shared__ float h_s[4][64];
#pragma unroll
    for (int j = 0; j < 4; ++j) h_s[j][k] = 0.0f;

    float h0 = 0, h1 = 0, h2 = 0, h3 = 0;

    const float* Abase = Ab + (size_t)bh * NC * 4096 + k * 64;
    const float* Bbase = Bb + (size_t)bh * NC * 4096 + k * 64 + vs * 4;

    float4 an[16];
#pragma unroll
    for (int q = 0; q < 16; ++q) an[q] = *(const float4*)&Abase[q * 4];
    float4 bn = *(const float4*)&Bbase[0];
    __syncthreads();

    for (int c = 0; c < NC; ++c) {
        float4 ac[16];
#pragma unroll
        for (int q = 0; q < 16; ++q) ac[q] = an[q];
        float4 b0 = bn;
        if (c + 1 < NC) {
            const float* An = Abase + (size_t)(c + 1) * 4096;
            const float* Bn = Bbase + (size_t)(c + 1) * 4096;
#pragma unroll
            for (int q = 0; q < 16; ++q) an[q] = *(const float4*)&An[q * 4];
            bn = *(const float4*)&Bn[0];
        }

        // write chunk-start state
        float* Hg = Hst + ((size_t)bh * NC + c) * 4096 + k * 64 + vs * 4;
        *(float4*)&Hg[0] = make_float4(h0, h1, h2, h3);

        // h' = A h + B
        float a0 = b0.x, a1 = b0.y, a2 = b0.z, a3 = b0.w;
#pragma unroll
        for (int m4 = 0; m4 < 16; ++m4) {
            float4 av = ac[m4];
            float4 hv0 = *(const float4*)&h_s[0][m4 * 4];
            float4 hv1 = *(const float4*)&h_s[1][m4 * 4];
            float4 hv2 = *(const float4*)&h_s[2][m4 * 4];
            float4 hv3 = *(const float4*)&h_s[3][m4 * 4];
            a0 += DOT4(av, hv0); a1 += DOT4(av, hv1);
            a2 += DOT4(av, hv2); a3 += DOT4(av, hv3);
        }
        __syncthreads();
        h0 = a0; h1 = a1; h2 = a2; h3 = a3;
        h_s[0][k] = h0; h_s[1][k] = h1; h_s[2][k] = h2; h_s[3][k] = h3;
        __syncthreads();
    }
}

// ---------------------------------------------------------------------------
// Phase B3: W_c = Wv_c - Wk_c h0_c (unchanged)
// ---------------------------------------------------------------------------
__global__ __launch_bounds__(256) void wfix_k(const float* __restrict__ Wk,
                                              const float* __restrict__ Hst,
                                              float* __restrict__ Wio) {
    __shared__ __align__(16) float wk_s[CL * PAD];
    __shared__ __align__(16) float h_s[CL * PAD];

    const int blk = blockIdx.x;
    const int tid = threadIdx.x;

    {
        const float4* Wkg = (const float4*)(Wk + (size_t)blk * 4096);
        const float4* Hg = (const float4*)(Hst + (size_t)blk * 4096);
#pragma unroll
        for (int i = 0; i < 4; ++i) {
            int f = tid + i * 256;
            int d = (f >> 4) * PAD + (f & 15) * 4;
            *(float4*)&wk_s[d] = Wkg[f];
            *(float4*)&h_s[d] = Hg[f];
        }
    }
    __syncthreads();

    const int t0 = (tid >> 4) * 4, v0 = (tid & 15) * 4;
    float* Wg = Wio + (size_t)blk * 4096;

    float acc[4][4];
#pragma unroll
    for (int i = 0; i < 4; ++i) {
        float4 wv = *(const float4*)&Wg[(t0 + i) * 64 + v0];
        acc[i][0] = wv.x; acc[i][1] = wv.y; acc[i][2] = wv.z; acc[i][3] = wv.w;
    }
    for (int kk = 0; kk < 64; kk += 4) {
        float4 wa0 = *(const float4*)&wk_s[(t0 + 0) * PAD + kk];
        float4 wa1 = *(const float4*)&wk_s[(t0 + 1) * PAD + kk];
        float4 wa2 = *(const float4*)&wk_s[(t0 + 2) * PAD + kk];
        float4 wa3 = *(const float4*)&wk_s[(t0 + 3) * PAD + kk];
        float4 hb0 = *(const float4*)&h_s[(kk + 0) * PAD + v0];
        float4 hb1 = *(const float4*)&h_s[(kk + 1) * PAD + v0];
        float4 hb2 = *(const float4*)&h_s[(kk + 2) * PAD + v0];
        float4 hb3 = *(const float4*)&h_s[(kk + 3) * PAD + v0];
        WSUB(x, hb0); WSUB(y, hb1); WSUB(z, hb2); WSUB(w, hb3);
    }
#pragma unroll
    for (int i = 0; i < 4; ++i)
        *(float4*)&Wg[(t0 + i) * 64 + v0] =
            make_float4(acc[i][0], acc[i][1], acc[i][2], acc[i][3]);
}

// ---------------------------------------------------------------------------
// Phase C (R7): scratch-free + PAD-strided LDS (unchanged)
// ---------------------------------------------------------------------------
__global__ __launch_bounds__(256) void out_k(const float* __restrict__ Qc,
                                             const float* __restrict__ Kc,
                                             const float* __restrict__ Wb_,
                                             const float* __restrict__ Hst,
                                             const float* __restrict__ bcum,
                                             float* __restrict__ o_scan) {
    __shared__ __align__(16) float q_s[CL * PAD];
    __shared__ __align__(16) float s_s[CL * PAD];   // K, then S
    __shared__ __align__(16) float h_s[CL * PAD];
    __shared__ __align__(16) float w_s[CL * PAD];
    __shared__ float b_s[64];

    const int blk = blockIdx.x;
    const int bh = blk >> 5;
    const int c = blk & 31;
    const int b = bh >> 4;
    const int h = bh & 15;
    const int tid = threadIdx.x;

    if (tid < 64) b_s[tid] = bcum[(size_t)blk * 64 + tid];
    {
        const float4* Qg = (const float4*)(Qc + (size_t)blk * 4096);
        const float4* Kg = (const float4*)(Kc + (size_t)blk * 4096);
        const float4* Hg = (const float4*)(Hst + (size_t)blk * 4096);
        const float4* Wg = (const float4*)(Wb_ + (size_t)blk * 4096);
#pragma unroll
        for (int i = 0; i < 4; ++i) {
            int f = tid + i * 256;
            int d = (f >> 4) * PAD + (f & 15) * 4;
            *(float4*)&q_s[d] = Qg[f];
            *(float4*)&s_s[d] = Kg[f];
            *(float4*)&h_s[d] = Hg[f];
            *(float4*)&w_s[d] = Wg[f];
        }
    }
    __syncthreads();

    // Phase 1: S = (Q K^T) ⊙ exp(b_t - b_s) [s<=t], overwrite s_s
    {
        const int t0 = (tid >> 4) * 4, s0 = (tid & 15) * 4;
        float acc[4][4] = {};
        for (int kk = 0; kk < 64; kk += 4) {
            float4 ta0 = *(const float4*)&q_s[(t0 + 0) * PAD + kk];
            float4 ta1 = *(const float4*)&q_s[(t0 + 1) * PAD + kk];
            float4 ta2 = *(const float4*)&q_s[(t0 + 2) * PAD + kk];
            float4 ta3 = *(const float4*)&q_s[(t0 + 3) * PAD + kk];
            float4 sb0 = *(const float4*)&s_s[(s0 + 0) * PAD + kk];
            float4 sb1 = *(const float4*)&s_s[(s0 + 1) * PAD + kk];
            float4 sb2 = *(const float4*)&s_s[(s0 + 2) * PAD + kk];
            float4 sb3 = *(const float4*)&s_s[(s0 + 3) * PAD + kk];
            acc[0][0] += DOT4(ta0, sb0); acc[0][1] += DOT4(ta0, sb1);
            acc[0][2] += DOT4(ta0, sb2); acc[0][3] += DOT4(ta0, sb3);
            acc[1][0] += DOT4(ta1, sb0); acc[1][1] += DOT4(ta1, sb1);
            acc[1][2] += DOT4(ta1, sb2); acc[1][3] += DOT4(ta1, sb3);
            acc[2][0] += DOT4(ta2, sb0); acc[2][1] += DOT4(ta2, sb1);
            acc[2][2] += DOT4(ta2, sb2); acc[2][3] += DOT4(ta2, sb3);
            acc[3][0] += DOT4(ta3, sb0); acc[3][1] += DOT4(ta3, sb1);
            acc[3][2] += DOT4(ta3, sb2); acc[3][3] += DOT4(ta3, sb3);
        }
        __syncthreads();   // all Q,K reads done before overwrite
#pragma unroll
        for (int i = 0; i < 4; ++i)
#pragma unroll
            for (int j = 0; j < 4; ++j) {
                const int t = t0 + i, s = s0 + j;
                s_s[t * PAD + s] = (s <= t) ? acc[i][j] * __expf(b_s[t] - b_s[s]) : 0.0f;
            }
    }
    // scale q rows by e^{b_t}
#pragma unroll
    for (int i = 0; i < 16; ++i) {
        const int e = tid + i * 256;
        const int t = e >> 6;
        q_s[t * PAD + (e & 63)] *= __expf(b_s[t]);
    }
    __syncthreads();

    // Phase 2: O = S @ W + Qs @ H
    {
        const int t0 = (tid >> 4) * 4, v0 = (tid & 15) * 4;
        float acc[4][4] = {};
        for (int ss = 0; ss < 64; ss += 4) {
            float4 sa0 = *(const float4*)&s_s[(t0 + 0) * PAD + ss];
            float4 sa1 = *(const float4*)&s_s[(t0 + 1) * PAD + ss];
            float4 sa2 = *(const float4*)&s_s[(t0 + 2) * PAD + ss];
            float4 sa3 = *(const float4*)&s_s[(t0 + 3) * PAD + ss];
            float4 wb0 = *(const float4*)&w_s[(ss + 0) * PAD + v0];
            float4 wb1 = *(const float4*)&w_s[(ss + 1) * PAD + v0];
            float4 wb2 = *(const float4*)&w_s[(ss + 2) * PAD + v0];
            float4 wb3 = *(const float4*)&w_s[(ss + 3) * PAD + v0];
            ACC16(x, wb0); ACC16(y, wb1); ACC16(z, wb2); ACC16(w, wb3);
        }
        for (int kk = 0; kk < 64; kk += 4) {
            float4 sa0 = *(const float4*)&q_s[(t0 + 0) * PAD + kk];
            float4 sa1 = *(const float4*)&q_s[(t0 + 1) * PAD + kk];
            float4 sa2 = *(const float4*)&q_s[(t0 + 2) * PAD + kk];
            float4 sa3 = *(const float4*)&q_s[(t0 + 3) * PAD + kk];
            float4 wb0 = *(const float4*)&h_s[(kk + 0) * PAD + v0];
            float4 wb1 = *(const float4*)&h_s[(kk + 1) * PAD + v0];
            float4 wb2 = *(const float4*)&h_s[(kk + 2) * PAD + v0];
            float4 wb3 = *(const float4*)&h_s[(kk + 3) * PAD + v0];
            ACC16(x, wb0); ACC16(y, wb1); ACC16(z, wb2); ACC16(w, wb3);
        }
#pragma unroll
        for (int i = 0; i < 4; ++i) {
            const int t = c * CL + t0 + i;
            *(float4*)&o_scan[(((size_t)b * TT + t) * HH + h) * DK + v0] =
                make_float4(acc[i][0], acc[i][1], acc[i][2], acc[i][3]);
        }
    }
}

// ---------------------------------------------------------------------------
// Gated RMSNorm -> bf16 output (unchanged)
// ---------------------------------------------------------------------------
__global__ __launch_bounds__(256) void gnorm_k(const float* __restrict__ o_scan,
                                               const float* __restrict__ gate,
                                               const float* __restrict__ rms_w,
                                               unsigned short* __restrict__ o2) {
    const int tid = threadIdx.x;
    const int grp = tid >> 6;
    const int lane = tid & 63;
    const int bth = blockIdx.x * 4 + grp;
    const int h = bth & 15;
    const int row = bth >> 4;

    float ov = o_scan[(size_t)bth * DK + lane];
    float s = ov * ov;
#pragma unroll
    for (int sh = 32; sh > 0; sh >>= 1) s += __shfl_xor(s, sh);
    float r = rsqrtf(s * (1.0f / 64.0f) + 1e-5f);

    float gt = gate[(size_t)row * HD + h * DK + lane];
    o2[(size_t)row * HD + h * DK + lane] = f2bf(ov * r * rms_w[lane] * siluf_(gt));
}

// ---------------------------------------------------------------------------
extern "C" void kernel_launch(void* const* d_in, const int* in_sizes, int n_in,
                              void* d_out, int out_size, void* d_ws, size_t ws_size,
                              hipStream_t stream) {
    (void)in_sizes; (void)n_in; (void)out_size; (void)ws_size;

    const float* x       = (const float*)d_in[0];
    const float* Wq      = (const float*)d_in[1];
    const float* Wk_     = (const float*)d_in[2];
    const float* Wv_     = (const float*)d_in[3];
    const float* Wa      = (const float*)d_in[4];
    const float* Wb      = (const float*)d_in[5];
    const float* Wg      = (const float*)d_in[6];
    const float* Wo      = (const float*)d_in[7];
    const float* conv_q  = (const float*)d_in[8];
    const float* conv_k  = (const float*)d_in[9];
    const float* conv_v  = (const float*)d_in[10];
    const float* A_log   = (const float*)d_in[11];
    const float* dt_bias = (const float*)d_in[12];
    const float* rms_w   = (const float*)d_in[13];
    float* out = (float*)d_out;

    float* ws = (float*)d_ws;
    const size_t NTOK = (size_t)BB * TT;     // 4096
    const size_t BIG = NTOK * HD;            // 4 Mi floats

    float* q_pre = ws + 0 * BIG;
    float* k_pre = ws + 1 * BIG;
    float* v_pre = ws + 2 * BIG;
    float* gatep = ws + 3 * BIG;
    float* Qc    = ws + 4 * BIG;
    float* Kc    = ws + 5 * BIG;
    float* gbuf  = ws + 6 * BIG;
    float* bbuf  = gbuf + NTOK * HH;
    float* bcumb = bbuf + NTOK * HH;

    // bf16 buffers after the fp32 region
    unsigned short* xb  = (unsigned short*)(bcumb + NTOK * HH);
    unsigned short* wqt = xb + (size_t)NTOK * DD;
    unsigned short* wkt = wqt + (size_t)DD * HD;
    unsigned short* wvt = wkt + (size_t)DD * HD;
    unsigned short* wgt = wvt + (size_t)DD * HD;
    unsigned short* wot = wgt + (size_t)DD * HD;

    // fp32 buffers after bf16 region: Bb + Hst (32 MB) + Wab_t (128 KB)
    float* Bbuf = (float*)(wot + (size_t)DD * HD);
    float* HstB = Bbuf + BIG;
    float* Wabt = HstB + BIG;

    // aliases (stream-ordered lifetimes):
    float* Wvb    = q_pre;   // prep_k out; wfix_k rewrites in place to W
    float* Wkb    = k_pre;
    float* Abuf   = v_pre;   // ab_k out (v_pre dead after prep_k)
    float* o_scan = v_pre;   // out_k out (Abuf dead after hrec_k)
    unsigned short* o2b = (unsigned short*)Qc;

    // casts
    castx_k<<<(int)(NTOK * DD / (256 * 8)), 256, 0, stream>>>(x, xb);
    dim3 tg(16, 16);
    castw_k<<<tg, 256, 0, stream>>>(Wq, wqt);
    castw_k<<<tg, 256, 0, stream>>>(Wk_, wkt);
    castw_k<<<tg, 256, 0, stream>>>(Wv_, wvt);
    castw_k<<<tg, 256, 0, stream>>>(Wg, wgt);
    castw_k<<<tg, 256, 0, stream>>>(Wo, wot);
    tw_k<<<32, 256, 0, stream>>>(Wa, Wb, Wabt);

    // projections
    dim3 gg(HD / 128, NTOK / 128);   // (8, 32)
    gemm_bf16_k<<<gg, 256, 0, stream>>>(xb, wqt, q_pre, (int)NTOK, HD, DD);
    gemm_bf16_k<<<gg, 256, 0, stream>>>(xb, wkt, k_pre, (int)NTOK, HD, DD);
    gemm_bf16_k<<<gg, 256, 0, stream>>>(xb, wvt, v_pre, (int)NTOK, HD, DD);
    gemm_bf16_k<<<gg, 256, 0, stream>>>(xb, wgt, gatep, (int)NTOK, HD, DD);

    gbeta_k<<<(int)(NTOK / 8), 256, 0, stream>>>(x, Wabt, A_log, dt_bias, gbuf, bbuf);

    stage_k<<<BB * HH * NC, 64, 0, stream>>>(q_pre, k_pre, conv_q, conv_k, gbuf,
                                             Qc, Kc, bcumb);

    prep_k<<<BB * HH * NC, 256, 0, stream>>>(Kc, v_pre, conv_v, bcumb, bbuf, Wvb, Wkb);

    // chunked state recurrence, decomposed:
    ab_k<<<BB * HH * NC, 256, 0, stream>>>(Kc, Wvb, Wkb, bcumb, Abuf, Bbuf);
    hrec_k<<<BB * HH * VS, 64, 0, stream>>>(Abuf, Bbuf, HstB);
    wfix_k<<<BB * HH * NC, 256, 0, stream>>>(Wkb, HstB, Wvb);

    out_k<<<BB * HH * NC, 256, 0, stream>>>(Qc, Kc, Wvb, HstB, bcumb, o_scan);

    gnorm_k<<<(int)(NTOK * HH / 4), 256, 0, stream>>>(o_scan, gatep, rms_w, o2b);

    gemm_bf16_k<<<gg, 256, 0, stream>>>(o2b, wot, out, (int)NTOK, HD, DD);
}

// Round 11
// 462.605 us; speedup vs baseline: 13.9169x; 1.1260x over previous
//
#include <hip/hip_runtime.h>
#include <hip/hip_bf16.h>
#include <math.h>
#include <stdint.h>

// Problem constants
#define BB 2
#define TT 2048
#define DD 1024
#define HH 16
#define DK 64
#define HD 1024   // H*DK
#define NC 32     // chunks per sequence (TT/64)
#define CL 64     // chunk length
#define PAD 68    // padded LDS row stride (floats) to break stride-64 bank conflicts
#define VS 16     // v-splits in hrec_k

typedef short bf16x8 __attribute__((ext_vector_type(8)));     // 8 bf16 (4 VGPRs)
typedef float f32x4 __attribute__((ext_vector_type(4)));      // MFMA acc
typedef unsigned short u16x8 __attribute__((ext_vector_type(8)));
typedef unsigned short u16x4 __attribute__((ext_vector_type(4)));

#define GAS __attribute__((address_space(1)))
#define LAS __attribute__((address_space(3)))

#define DOT4(a, b) ((a).x*(b).x + (a).y*(b).y + (a).z*(b).z + (a).w*(b).w)

// acc[i][j] += kf[i-component] * wv[j-component]   (one contraction step)
#define OUT16(acc, kf, wv) \
    acc[0][0] += kf.x * wv.x; acc[0][1] += kf.x * wv.y; acc[0][2] += kf.x * wv.z; acc[0][3] += kf.x * wv.w; \
    acc[1][0] += kf.y * wv.x; acc[1][1] += kf.y * wv.y; acc[1][2] += kf.y * wv.z; acc[1][3] += kf.y * wv.w; \
    acc[2][0] += kf.z * wv.x; acc[2][1] += kf.z * wv.y; acc[2][2] += kf.z * wv.z; acc[2][3] += kf.z * wv.w; \
    acc[3][0] += kf.w * wv.x; acc[3][1] += kf.w * wv.y; acc[3][2] += kf.w * wv.z; acc[3][3] += kf.w * wv.w;

// acc[i][j] -= wa_i.c * hv[j]   (c = component selecting m)
#define WSUB(c, hv) \
    acc[0][0] -= wa0.c * hv.x; acc[0][1] -= wa0.c * hv.y; acc[0][2] -= wa0.c * hv.z; acc[0][3] -= wa0.c * hv.w; \
    acc[1][0] -= wa1.c * hv.x; acc[1][1] -= wa1.c * hv.y; acc[1][2] -= wa1.c * hv.z; acc[1][3] -= wa1.c * hv.w; \
    acc[2][0] -= wa2.c * hv.x; acc[2][1] -= wa2.c * hv.y; acc[2][2] -= wa2.c * hv.z; acc[2][3] -= wa2.c * hv.w; \
    acc[3][0] -= wa3.c * hv.x; acc[3][1] -= wa3.c * hv.y; acc[3][2] -= wa3.c * hv.z; acc[3][3] -= wa3.c * hv.w;

// acc[i][j] += sa_i.c * wv[j]   (c = component selecting the contraction idx)
#define ACC16(c, wv) \
    acc[0][0] += sa0.c * wv.x; acc[0][1] += sa0.c * wv.y; acc[0][2] += sa0.c * wv.z; acc[0][3] += sa0.c * wv.w; \
    acc[1][0] += sa1.c * wv.x; acc[1][1] += sa1.c * wv.y; acc[1][2] += sa1.c * wv.z; acc[1][3] += sa1.c * wv.w; \
    acc[2][0] += sa2.c * wv.x; acc[2][1] += sa2.c * wv.y; acc[2][2] += sa2.c * wv.z; acc[2][3] += sa2.c * wv.w; \
    acc[3][0] += sa3.c * wv.x; acc[3][1] += sa3.c * wv.y; acc[3][2] += sa3.c * wv.z; acc[3][3] += sa3.c * wv.w;

__device__ __forceinline__ float sigmoidf_(float x) { return 1.0f / (1.0f + expf(-x)); }
__device__ __forceinline__ float siluf_(float x) { return x * sigmoidf_(x); }

// round-to-nearest-even fp32 -> bf16
__device__ __forceinline__ unsigned short f2bf(float f) {
    unsigned int u = __builtin_bit_cast(unsigned int, f);
    u = (u + 0x7fffu + ((u >> 16) & 1u)) >> 16;
    return (unsigned short)u;
}

// ---------------------------------------------------------------------------
// Cast x (fp32) -> bf16, flat.
// ---------------------------------------------------------------------------
__global__ __launch_bounds__(256) void castx_k(const float* __restrict__ src,
                                               unsigned short* __restrict__ dst) {
    const size_t idx = (size_t)blockIdx.x * 256 + threadIdx.x;
    float4 a = *(const float4*)&src[idx * 8];
    float4 b = *(const float4*)&src[idx * 8 + 4];
    u16x8 o;
    o[0] = f2bf(a.x); o[1] = f2bf(a.y); o[2] = f2bf(a.z); o[3] = f2bf(a.w);
    o[4] = f2bf(b.x); o[5] = f2bf(b.y); o[6] = f2bf(b.z); o[7] = f2bf(b.w);
    *(u16x8*)&dst[idx * 8] = o;
}

// ---------------------------------------------------------------------------
// Transpose+cast weight: W[K=1024][N=1024] fp32 -> Wt[N][K] bf16.
// ---------------------------------------------------------------------------
__global__ __launch_bounds__(256) void castw_k(const float* __restrict__ W,
                                               unsigned short* __restrict__ Wt) {
    __shared__ float t_s[64][65];
    const int tid = threadIdx.x;
    const int rr = tid >> 4;
    const int cc = tid & 15;
    const int r0 = blockIdx.y * 64;
    const int c0 = blockIdx.x * 64;
#pragma unroll
    for (int i = 0; i < 4; ++i) {
        const int row = rr + i * 16;
        float4 v = *(const float4*)&W[(size_t)(r0 + row) * 1024 + c0 + cc * 4];
        t_s[row][cc * 4 + 0] = v.x;
        t_s[row][cc * 4 + 1] = v.y;
        t_s[row][cc * 4 + 2] = v.z;
        t_s[row][cc * 4 + 3] = v.w;
    }
    __syncthreads();
#pragma unroll
    for (int i = 0; i < 4; ++i) {
        const int nr = rr + i * 16;
        u16x4 o;
#pragma unroll
        for (int d = 0; d < 4; ++d) o[d] = f2bf(t_s[cc * 4 + d][nr]);
        *(u16x4*)&Wt[(size_t)(c0 + nr) * 1024 + r0 + cc * 4] = o;
    }
}

// ---------------------------------------------------------------------------
// transpose Wa|Wb [1024][16] -> Wab_t [32][1024] fp32 (R8)
// ---------------------------------------------------------------------------
__global__ __launch_bounds__(256) void tw_k(const float* __restrict__ Wa,
                                            const float* __restrict__ Wb,
                                            float* __restrict__ Wt) {
    const int o = blockIdx.x;          // 0..31
    const int h = o & 15;
    const float* W = (o < 16) ? Wa : Wb;
    const int tid = threadIdx.x;
    float4 v;
    v.x = W[(size_t)(tid * 4 + 0) * HH + h];
    v.y = W[(size_t)(tid * 4 + 1) * HH + h];
    v.z = W[(size_t)(tid * 4 + 2) * HH + h];
    v.w = W[(size_t)(tid * 4 + 3) * HH + h];
    *(float4*)&Wt[(size_t)o * DD + tid * 4] = v;
}

// ---------------------------------------------------------------------------
// bf16 MFMA GEMM (m97 structure) — generic single-output (used for Wo).
// ---------------------------------------------------------------------------
__global__ __launch_bounds__(256) void gemm_bf16_k(const unsigned short* __restrict__ A,
                                                   const unsigned short* __restrict__ Bt,
                                                   float* __restrict__ C,
                                                   int M, int N, int Kd) {
    __shared__ unsigned short a_s[128 * 32];
    __shared__ unsigned short b_s[128 * 32];

    const int tid = threadIdx.x;
    const int wave = tid >> 6;
    const int lane = tid & 63;
    const int m0 = blockIdx.y * 128;
    const int n0 = blockIdx.x * 128;

    const int quad = lane >> 4;
    const int l16 = lane & 15;
    const int wr = wave >> 1;
    const int wc = wave & 1;

    const int srow = lane >> 2;
    const int sseg = lane & 3;

    f32x4 acc[4][4];
#pragma unroll
    for (int i = 0; i < 4; ++i)
#pragma unroll
        for (int j = 0; j < 4; ++j) acc[i][j] = (f32x4){0.f, 0.f, 0.f, 0.f};

    for (int k0 = 0; k0 < Kd; k0 += 32) {
        __syncthreads();
#pragma unroll
        for (int c = 0; c < 2; ++c) {
            const int region = wave * 2 + c;
            const int r0t = region * 16;
            const int ra = r0t + srow;
            const unsigned short* ga = A + (size_t)(m0 + ra) * Kd + k0 + sseg * 8;
            const unsigned short* gb = Bt + (size_t)(n0 + ra) * Kd + k0 + sseg * 8;
            __builtin_amdgcn_global_load_lds((const GAS unsigned int*)ga,
                                             (LAS unsigned int*)&a_s[r0t * 32], 16, 0, 0);
            __builtin_amdgcn_global_load_lds((const GAS unsigned int*)gb,
                                             (LAS unsigned int*)&b_s[r0t * 32], 16, 0, 0);
        }
        __syncthreads();

        bf16x8 af[4], bfr[4];
#pragma unroll
        for (int i = 0; i < 4; ++i)
            af[i] = *(const bf16x8*)&a_s[(wr * 64 + i * 16 + l16) * 32 + quad * 8];
#pragma unroll
        for (int j = 0; j < 4; ++j)
            bfr[j] = *(const bf16x8*)&b_s[(wc * 64 + j * 16 + l16) * 32 + quad * 8];
#pragma unroll
        for (int i = 0; i < 4; ++i)
#pragma unroll
            for (int j = 0; j < 4; ++j)
                acc[i][j] = __builtin_amdgcn_mfma_f32_16x16x32_bf16(af[i], bfr[j], acc[i][j], 0, 0, 0);
    }

#pragma unroll
    for (int i = 0; i < 4; ++i)
#pragma unroll
        for (int j = 0; j < 4; ++j) {
            const int col = n0 + wc * 64 + j * 16 + l16;
#pragma unroll
            for (int r = 0; r < 4; ++r) {
                const int row = m0 + wr * 64 + i * 16 + quad * 4 + r;
                C[(size_t)row * N + col] = acc[i][j][r];
            }
        }
}

// ---------------------------------------------------------------------------
// NEW (R10): fused QKVG projection GEMM. N=4096 (wqt|wkt|wvt|wgt rows are
// contiguous); each 128-wide n-block writes into ONE of the 4 outputs
// (n0>>10), local col stride 1024 — downstream layout identical to R9.
// grid (32,32) = 1024 blocks = 4/CU (was 4 launches x 256 blocks = 1/CU).
// ---------------------------------------------------------------------------
__global__ __launch_bounds__(256) void gemm_qkvg_k(const unsigned short* __restrict__ A,
                                                   const unsigned short* __restrict__ Bt,
                                                   float* __restrict__ Oq,
                                                   float* __restrict__ Ok,
                                                   float* __restrict__ Ov,
                                                   float* __restrict__ Og) {
    __shared__ unsigned short a_s[128 * 32];
    __shared__ unsigned short b_s[128 * 32];

    const int tid = threadIdx.x;
    const int wave = tid >> 6;
    const int lane = tid & 63;
    const int m0 = blockIdx.y * 128;
    const int n0 = blockIdx.x * 128;          // 0..4095

    const int quad = lane >> 4;
    const int l16 = lane & 15;
    const int wr = wave >> 1;
    const int wc = wave & 1;

    const int srow = lane >> 2;
    const int sseg = lane & 3;

    f32x4 acc[4][4];
#pragma unroll
    for (int i = 0; i < 4; ++i)
#pragma unroll
        for (int j = 0; j < 4; ++j) acc[i][j] = (f32x4){0.f, 0.f, 0.f, 0.f};

    for (int k0 = 0; k0 < DD; k0 += 32) {
        __syncthreads();
#pragma unroll
        for (int c = 0; c < 2; ++c) {
            const int region = wave * 2 + c;
            const int r0t = region * 16;
            const int ra = r0t + srow;
            const unsigned short* ga = A + (size_t)(m0 + ra) * DD + k0 + sseg * 8;
            const unsigned short* gb = Bt + (size_t)(n0 + ra) * DD + k0 + sseg * 8;
            __builtin_amdgcn_global_load_lds((const GAS unsigned int*)ga,
                                             (LAS unsigned int*)&a_s[r0t * 32], 16, 0, 0);
            __builtin_amdgcn_global_load_lds((const GAS unsigned int*)gb,
                                             (LAS unsigned int*)&b_s[r0t * 32], 16, 0, 0);
        }
        __syncthreads();

        bf16x8 af[4], bfr[4];
#pragma unroll
        for (int i = 0; i < 4; ++i)
            af[i] = *(const bf16x8*)&a_s[(wr * 64 + i * 16 + l16) * 32 + quad * 8];
#pragma unroll
        for (int j = 0; j < 4; ++j)
            bfr[j] = *(const bf16x8*)&b_s[(wc * 64 + j * 16 + l16) * 32 + quad * 8];
#pragma unroll
        for (int i = 0; i < 4; ++i)
#pragma unroll
            for (int j = 0; j < 4; ++j)
                acc[i][j] = __builtin_amdgcn_mfma_f32_16x16x32_bf16(af[i], bfr[j], acc[i][j], 0, 0, 0);
    }

    float* Cd = (n0 < 1024) ? Oq : (n0 < 2048) ? Ok : (n0 < 3072) ? Ov : Og;
    const int nl = n0 & 1023;
#pragma unroll
    for (int i = 0; i < 4; ++i)
#pragma unroll
        for (int j = 0; j < 4; ++j) {
            const int col = nl + wc * 64 + j * 16 + l16;
#pragma unroll
            for (int r = 0; r < 4; ++r) {
                const int row = m0 + wr * 64 + i * 16 + quad * 4 + r;
                Cd[(size_t)row * HD + col] = acc[i][j][r];
            }
        }
}

// ---------------------------------------------------------------------------
// g / beta kernel (R8, unchanged)
// ---------------------------------------------------------------------------
__global__ __launch_bounds__(256) void gbeta_k(const float* __restrict__ x,
                                               const float* __restrict__ Wt,
                                               const float* __restrict__ A_log,
                                               const float* __restrict__ dt_bias,
                                               float* __restrict__ g,
                                               float* __restrict__ beta) {
    __shared__ __align__(16) float xs[8][DD];
    const int r0 = blockIdx.x * 8;
    const int tid = threadIdx.x;

#pragma unroll
    for (int i = 0; i < 8; ++i) {
        const int f = tid + i * 256;
        const int r = f >> 8;
        const int col = (f & 255) * 4;
        *(float4*)&xs[r][col] = *(const float4*)&x[((size_t)r0 + r) * DD + col];
    }
    __syncthreads();

    const int out = tid >> 3;
    const int part = tid & 7;
    const int h = out & 15;
    const float* Wrow = Wt + (size_t)out * DD;

    float a0 = 0, a1 = 0, a2 = 0, a3 = 0, a4 = 0, a5 = 0, a6 = 0, a7 = 0;
#pragma unroll 4
    for (int i = 0; i < 32; ++i) {
        const int d = i * 32 + part * 4;
        const float4 wv = *(const float4*)&Wrow[d];
        float4 x0 = *(const float4*)&xs[0][d];
        float4 x1 = *(const float4*)&xs[1][d];
        float4 x2 = *(const float4*)&xs[2][d];
        float4 x3 = *(const float4*)&xs[3][d];
        float4 x4 = *(const float4*)&xs[4][d];
        float4 x5 = *(const float4*)&xs[5][d];
        float4 x6 = *(const float4*)&xs[6][d];
        float4 x7 = *(const float4*)&xs[7][d];
        a0 += DOT4(x0, wv); a1 += DOT4(x1, wv);
        a2 += DOT4(x2, wv); a3 += DOT4(x3, wv);
        a4 += DOT4(x4, wv); a5 += DOT4(x5, wv);
        a6 += DOT4(x6, wv); a7 += DOT4(x7, wv);
    }
#pragma unroll
    for (int s = 1; s <= 4; s <<= 1) {
        a0 += __shfl_xor(a0, s); a1 += __shfl_xor(a1, s);
        a2 += __shfl_xor(a2, s); a3 += __shfl_xor(a3, s);
        a4 += __shfl_xor(a4, s); a5 += __shfl_xor(a5, s);
        a6 += __shfl_xor(a6, s); a7 += __shfl_xor(a7, s);
    }

    if (part == 0) {
        float sv[8] = {a0, a1, a2, a3, a4, a5, a6, a7};
        if (out < 16) {
            const float ae = -expf(A_log[h]);
            const float db = dt_bias[h];
#pragma unroll
            for (int r = 0; r < 8; ++r) {
                float v = sv[r] + db;
                float sp = (v > 20.0f) ? v : log1pf(expf(v));
                g[((size_t)r0 + r) * HH + h] = ae * sp;
            }
        } else {
#pragma unroll
            for (int r = 0; r < 8; ++r)
                beta[((size_t)r0 + r) * HH + h] = sigmoidf_(sv[r]);
        }
    }
}

// ---------------------------------------------------------------------------
// Phase A1: stage normalized q,k (conv+silu+l2norm) and cumsum(g). (unchanged)
// ---------------------------------------------------------------------------
__global__ __launch_bounds__(64) void stage_k(const float* __restrict__ q_pre,
                                              const float* __restrict__ k_pre,
                                              const float* __restrict__ cq,
                                              const float* __restrict__ ck,
                                              const float* __restrict__ g,
                                              float* __restrict__ Qc,
                                              float* __restrict__ Kc,
                                              float* __restrict__ bcum) {
    const int blk = blockIdx.x;
    const int bh = blk >> 5;
    const int c = blk & 31;
    const int b = bh >> 4;
    const int h = bh & 15;
    const int lane = threadIdx.x;
    const int ch = h * DK + lane;

    const float4 wq4 = *(const float4*)&cq[ch * 4];
    const float4 wk4 = *(const float4*)&ck[ch * 4];

    float qw0 = 0, qw1 = 0, qw2 = 0, kw0 = 0, kw1 = 0, kw2 = 0;
    {
        const int t0 = c * CL;
        if (t0 - 3 >= 0) { size_t bi = ((size_t)b * TT + t0 - 3) * HD + ch; qw0 = q_pre[bi]; kw0 = k_pre[bi]; }
        if (t0 - 2 >= 0) { size_t bi = ((size_t)b * TT + t0 - 2) * HD + ch; qw1 = q_pre[bi]; kw1 = k_pre[bi]; }
        if (t0 - 1 >= 0) { size_t bi = ((size_t)b * TT + t0 - 1) * HD + ch; qw2 = q_pre[bi]; kw2 = k_pre[bi]; }
    }
    float* Qo = Qc + (size_t)blk * 4096;
    float* Ko = Kc + (size_t)blk * 4096;

    for (int tt = 0; tt < CL; ++tt) {
        const int t = c * CL + tt;
        const size_t bi = ((size_t)b * TT + t) * HD + ch;
        const float qc_ = q_pre[bi];
        const float kc_ = k_pre[bi];
        float qa = qw0 * wq4.x + qw1 * wq4.y + qw2 * wq4.z + qc_ * wq4.w;
        float ka = kw0 * wk4.x + kw1 * wk4.y + kw2 * wk4.z + kc_ * wk4.w;
        qw0 = qw1; qw1 = qw2; qw2 = qc_;
        kw0 = kw1; kw1 = kw2; kw2 = kc_;
        qa = siluf_(qa);
        ka = siluf_(ka);
        float qs2 = qa * qa, ks2 = ka * ka;
#pragma unroll
        for (int s = 32; s > 0; s >>= 1) {
            qs2 += __shfl_xor(qs2, s);
            ks2 += __shfl_xor(ks2, s);
        }
        Qo[tt * 64 + lane] = qa * rsqrtf(qs2 + 1e-6f) * 0.125f;
        Ko[tt * 64 + lane] = ka * rsqrtf(ks2 + 1e-6f);
    }

    float cum = g[((size_t)b * TT + c * CL + lane) * HH + h];
#pragma unroll
    for (int s = 1; s < 64; s <<= 1) {
        float u = __shfl_up(cum, s);
        if (lane >= s) cum += u;
    }
    bcum[(size_t)blk * 64 + lane] = cum;
}

// ---------------------------------------------------------------------------
// Phase A2 (R5): scratch-free blocked triangular solve (unchanged)
// ---------------------------------------------------------------------------
__global__ __launch_bounds__(256) void prep_k(const float* __restrict__ Kc,
                                              const float* __restrict__ v_pre,
                                              const float* __restrict__ cv,
                                              const float* __restrict__ bcum,
                                              const float* __restrict__ bbuf,
                                              float* __restrict__ Wv,
                                              float* __restrict__ Wk) {
    __shared__ __align__(16) float k_s[CL * PAD];
    __shared__ __align__(16) float wv_s[CL * PAD];
    __shared__ __align__(16) float wk_s[CL * PAD];
    __shared__ __align__(16) float A_s[CL * PAD];
    __shared__ float T_s[4][16 * 17];
    __shared__ float b_s[CL], beta_s[CL], bk_s[CL];

    const int blk = blockIdx.x;
    const int bh = blk >> 5;
    const int c = blk & 31;
    const int b = bh >> 4;
    const int h = bh & 15;
    const int tid = threadIdx.x;

    if (tid < 64) {
        float bv = bcum[(size_t)blk * 64 + tid];
        float be = bbuf[((size_t)b * TT + c * CL + tid) * HH + h];
        b_s[tid] = bv;
        beta_s[tid] = be;
        bk_s[tid] = be * __expf(bv);
    }
    __syncthreads();

    {
        const float4* Kg = (const float4*)(Kc + (size_t)blk * 4096);
#pragma unroll
        for (int i = 0; i < 4; ++i) {
            int f = tid + i * 256;
            int t = f >> 4;
            int d = t * PAD + (f & 15) * 4;
            float4 kv = Kg[f];
            *(float4*)&k_s[d] = kv;
            float sk = bk_s[t];
            *(float4*)&wk_s[d] = make_float4(kv.x * sk, kv.y * sk, kv.z * sk, kv.w * sk);
        }
    }

    {
        const int lane = tid & 63;
        const int q4 = tid >> 6;
        const int ch = h * DK + lane;
        const float4 wv4 = *(const float4*)&cv[ch * 4];
        const int T0 = c * CL + q4 * 16;
        float w0 = 0, w1 = 0, w2 = 0;
        if (T0 - 3 >= 0) w0 = v_pre[((size_t)b * TT + T0 - 3) * HD + ch];
        if (T0 - 2 >= 0) w1 = v_pre[((size_t)b * TT + T0 - 2) * HD + ch];
        if (T0 - 1 >= 0) w2 = v_pre[((size_t)b * TT + T0 - 1) * HD + ch];
#pragma unroll 1
        for (int i = 0; i < 16; ++i) {
            const int t = T0 + i;
            const float vc_ = v_pre[((size_t)b * TT + t) * HD + ch];
            float va = w0 * wv4.x + w1 * wv4.y + w2 * wv4.z + vc_ * wv4.w;
            w0 = w1; w1 = w2; w2 = vc_;
            va = siluf_(va);
            wv_s[(q4 * 16 + i) * PAD + lane] = va * beta_s[q4 * 16 + i];
        }
    }
    __syncthreads();

    {
        const int t0 = (tid >> 4) * 4, s0 = (tid & 15) * 4;
        float acc[4][4] = {};
        for (int kk = 0; kk < 64; kk += 4) {
            float4 ta0 = *(const float4*)&k_s[(t0 + 0) * PAD + kk];
            float4 ta1 = *(const float4*)&k_s[(t0 + 1) * PAD + kk];
            float4 ta2 = *(const float4*)&k_s[(t0 + 2) * PAD + kk];
            float4 ta3 = *(const float4*)&k_s[(t0 + 3) * PAD + kk];
            float4 sb0 = *(const float4*)&k_s[(s0 + 0) * PAD + kk];
            float4 sb1 = *(const float4*)&k_s[(s0 + 1) * PAD + kk];
            float4 sb2 = *(const float4*)&k_s[(s0 + 2) * PAD + kk];
            float4 sb3 = *(const float4*)&k_s[(s0 + 3) * PAD + kk];
            acc[0][0] += DOT4(ta0, sb0); acc[0][1] += DOT4(ta0, sb1);
            acc[0][2] += DOT4(ta0, sb2); acc[0][3] += DOT4(ta0, sb3);
            acc[1][0] += DOT4(ta1, sb0); acc[1][1] += DOT4(ta1, sb1);
            acc[1][2] += DOT4(ta1, sb2); acc[1][3] += DOT4(ta1, sb3);
            acc[2][0] += DOT4(ta2, sb0); acc[2][1] += DOT4(ta2, sb1);
            acc[2][2] += DOT4(ta2, sb2); acc[2][3] += DOT4(ta2, sb3);
            acc[3][0] += DOT4(ta3, sb0); acc[3][1] += DOT4(ta3, sb1);
            acc[3][2] += DOT4(ta3, sb2); acc[3][3] += DOT4(ta3, sb3);
        }
#pragma unroll
        for (int i = 0; i < 4; ++i)
#pragma unroll
            for (int j = 0; j < 4; ++j) {
                const int t = t0 + i, s = s0 + j;
                A_s[t * PAD + s] = (s < t) ? acc[i][j] * beta_s[t] * __expf(b_s[t] - b_s[s]) : 0.0f;
            }
    }
    __syncthreads();

    if (tid < 64) {
        const int d = tid >> 4;
        const int col = tid & 15;
        const int base = d * 16;
        float tcol[16];
#pragma unroll
        for (int s = 0; s < 16; ++s) tcol[s] = (s == col) ? 1.0f : 0.0f;
#pragma unroll
        for (int t = 1; t < 16; ++t) {
            float a = 0.0f;
#pragma unroll
            for (int s = 0; s < 16; ++s)
                if (s < t) a += A_s[(base + t) * PAD + base + s] * tcol[s];
            tcol[t] -= a;
        }
#pragma unroll
        for (int t = 0; t < 16; ++t) T_s[d][t * 17 + col] = tcol[t];
    }
    __syncthreads();

    {
        const int r = tid >> 4;
        const int cg = tid & 15;
        float* Wc = (cg < 8) ? wv_s : wk_s;
        const int cc = (cg & 7) * 8;

        for (int tb = 0; tb < 4; ++tb) {
            const int t = tb * 16 + r;
            if (tb > 0) {
                float4 lo = *(const float4*)&Wc[t * PAD + cc];
                float4 hi = *(const float4*)&Wc[t * PAD + cc + 4];
#pragma unroll 4
                for (int s = 0; s < tb * 16; ++s) {
                    const float a = A_s[t * PAD + s];
                    float4 wlo = *(const float4*)&Wc[s * PAD + cc];
                    float4 whi = *(const float4*)&Wc[s * PAD + cc + 4];
                    lo.x -= a * wlo.x; lo.y -= a * wlo.y; lo.z -= a * wlo.z; lo.w -= a * wlo.w;
                    hi.x -= a * whi.x; hi.y -= a * whi.y; hi.z -= a * whi.z; hi.w -= a * whi.w;
                }
                *(float4*)&Wc[t * PAD + cc] = lo;
                *(float4*)&Wc[t * PAD + cc + 4] = hi;
            }
            __syncthreads();
            float4 alo = make_float4(0, 0, 0, 0);
            float4 ahi = make_float4(0, 0, 0, 0);
#pragma unroll 4
            for (int s = 0; s < 16; ++s) {
                const float tv = T_s[tb][r * 17 + s];
                float4 wlo = *(const float4*)&Wc[(tb * 16 + s) * PAD + cc];
                float4 whi = *(const float4*)&Wc[(tb * 16 + s) * PAD + cc + 4];
                alo.x += tv * wlo.x; alo.y += tv * wlo.y; alo.z += tv * wlo.z; alo.w += tv * wlo.w;
                ahi.x += tv * whi.x; ahi.y += tv * whi.y; ahi.z += tv * whi.z; ahi.w += tv * whi.w;
            }
            __syncthreads();
            *(float4*)&Wc[t * PAD + cc] = alo;
            *(float4*)&Wc[t * PAD + cc + 4] = ahi;
            __syncthreads();
        }
    }

    float4* Wvg = (float4*)(Wv + (size_t)blk * 4096);
    float4* Wkg = (float4*)(Wk + (size_t)blk * 4096);
#pragma unroll
    for (int i = 0; i < 4; ++i) {
        int f = tid + i * 256;
        int d = (f >> 4) * PAD + (f & 15) * 4;
        Wvg[f] = *(float4*)&wv_s[d];
        Wkg[f] = *(float4*)&wk_s[d];
    }
}

// ---------------------------------------------------------------------------
// Phase B1: chunk-transition operators A_c, B_c (unchanged)
// ---------------------------------------------------------------------------
__global__ __launch_bounds__(256) void ab_k(const float* __restrict__ Kc,
                                            const float* __restrict__ Wv,
                                            const float* __restrict__ Wk,
                                            const float* __restrict__ bcum,
                                            float* __restrict__ Ab,
                                            float* __restrict__ Bb) {
    __shared__ __align__(16) float kt_s[CL * PAD];
    __shared__ __align__(16) float wk_s[CL * PAD];
    __shared__ __align__(16) float wv_s[CL * PAD];
    __shared__ float e_s[CL];
    __shared__ float ebC_s;

    const int blk = blockIdx.x;
    const int tid = threadIdx.x;

    if (tid < 64) {
        float bC = bcum[(size_t)blk * 64 + 63];
        e_s[tid] = __expf(bC - bcum[(size_t)blk * 64 + tid]);
        if (tid == 63) ebC_s = __expf(bC);
    }
    __syncthreads();

    {
        const float4* Kg = (const float4*)(Kc + (size_t)blk * 4096);
        const float4* Wkg = (const float4*)(Wk + (size_t)blk * 4096);
        const float4* Wvg = (const float4*)(Wv + (size_t)blk * 4096);
#pragma unroll
        for (int i = 0; i < 4; ++i) {
            int f = tid + i * 256;
            int t = f >> 4;
            int d = t * PAD + (f & 15) * 4;
            float4 kv = Kg[f];
            float e = e_s[t];
            *(float4*)&kt_s[d] = make_float4(kv.x * e, kv.y * e, kv.z * e, kv.w * e);
            *(float4*)&wk_s[d] = Wkg[f];
            *(float4*)&wv_s[d] = Wvg[f];
        }
    }
    __syncthreads();

    const int k0 = (tid >> 4) * 4, m0 = (tid & 15) * 4;
    float aA[4][4] = {};
    float aB[4][4] = {};
    for (int ss = 0; ss < 64; ss += 4) {
        float4 kf0 = *(const float4*)&kt_s[(ss + 0) * PAD + k0];
        float4 kf1 = *(const float4*)&kt_s[(ss + 1) * PAD + k0];
        float4 kf2 = *(const float4*)&kt_s[(ss + 2) * PAD + k0];
        float4 kf3 = *(const float4*)&kt_s[(ss + 3) * PAD + k0];
        float4 wa0 = *(const float4*)&wk_s[(ss + 0) * PAD + m0];
        float4 wa1 = *(const float4*)&wk_s[(ss + 1) * PAD + m0];
        float4 wa2 = *(const float4*)&wk_s[(ss + 2) * PAD + m0];
        float4 wa3 = *(const float4*)&wk_s[(ss + 3) * PAD + m0];
        float4 wb0 = *(const float4*)&wv_s[(ss + 0) * PAD + m0];
        float4 wb1 = *(const float4*)&wv_s[(ss + 1) * PAD + m0];
        float4 wb2 = *(const float4*)&wv_s[(ss + 2) * PAD + m0];
        float4 wb3 = *(const float4*)&wv_s[(ss + 3) * PAD + m0];
        OUT16(aA, kf0, wa0); OUT16(aA, kf1, wa1); OUT16(aA, kf2, wa2); OUT16(aA, kf3, wa3);
        OUT16(aB, kf0, wb0); OUT16(aB, kf1, wb1); OUT16(aB, kf2, wb2); OUT16(aB, kf3, wb3);
    }

    const float ebC = ebC_s;
    float* Ag = Ab + (size_t)blk * 4096;
    float* Bg = Bb + (size_t)blk * 4096;
#pragma unroll
    for (int i = 0; i < 4; ++i) {
        const int kk = k0 + i;
        float4 av = make_float4(-aA[i][0], -aA[i][1], -aA[i][2], -aA[i][3]);
        if (kk - m0 == 0) av.x += ebC;
        if (kk - m0 == 1) av.y += ebC;
        if (kk - m0 == 2) av.z += ebC;
        if (kk - m0 == 3) av.w += ebC;
        *(float4*)&Ag[kk * 64 + m0] = av;
        *(float4*)&Bg[kk * 64 + m0] = make_float4(aB[i][0], aB[i][1], aB[i][2], aB[i][3]);
    }
}

// ---------------------------------------------------------------------------
// Phase B2 (R10): serial chunk recurrence h' = A_c h + B_c.
// vs-major XCD-local indexing (R9). __launch_bounds__(64,1): R10 profile
// showed VGPR_Count=80 -> the an[]/ac[] A double-buffer (128 VGPRs) was
// collapsed, defeating the prefetch; allow full VGPR budget so it
// materializes.
// ---------------------------------------------------------------------------
__global__ __launch_bounds__(64, 1) void hrec_k(const float* __restrict__ Ab,
                                                const float* __restrict__ Bb,
                                                float* __restrict__ Hst) {
    const int blk = blockIdx.x;
    const int bh = blk & 31;          // vs-major: same-bh blocks -> same XCD
    const int vs = blk >> 5;          // 0..VS-1
    const int k = threadIdx.x;

    __shared__ float h_s[4][64];
#pragma unroll
    for (int j = 0; j < 4; ++j) h_s[j][k] = 0.0f;

    float h0 = 0, h1 = 0, h2 = 0, h3 = 0;

    const float* Abase = Ab + (size_t)bh * NC * 4096 + k * 64;
    const float* Bbase = Bb + (size_t)bh * NC * 4096 + k * 64 + vs * 4;

    float4 an[16];
#pragma unroll
    for (int q = 0; q < 16; ++q) an[q] = *(const float4*)&Abase[q * 4];
    float4 bn = *(const float4*)&Bbase[0];
    __syncthreads();

    for (int c = 0; c < NC; ++c) {
        float4 ac[16];
#pragma unroll
        for (int q = 0; q < 16; ++q) ac[q] = an[q];
        float4 b0 = bn;
        if (c + 1 < NC) {
            const float* An = Abase + (size_t)(c + 1) * 4096;
            const float* Bn = Bbase + (size_t)(c + 1) * 4096;
#pragma unroll
            for (int q = 0; q < 16; ++q) an[q] = *(const float4*)&An[q * 4];
            bn = *(const float4*)&Bn[0];
        }

        // write chunk-start state
        float* Hg = Hst + ((size_t)bh * NC + c) * 4096 + k * 64 + vs * 4;
        *(float4*)&Hg[0] = make_float4(h0, h1, h2, h3);

        // h' = A h + B
        float a0 = b0.x, a1 = b0.y, a2 = b0.z, a3 = b0.w;
#pragma unroll
        for (int m4 = 0; m4 < 16; ++m4) {
            float4 av = ac[m4];
            float4 hv0 = *(const float4*)&h_s[0][m4 * 4];
            float4 hv1 = *(const float4*)&h_s[1][m4 * 4];
            float4 hv2 = *(const float4*)&h_s[2][m4 * 4];
            float4 hv3 = *(const float4*)&h_s[3][m4 * 4];
            a0 += DOT4(av, hv0); a1 += DOT4(av, hv1);
            a2 += DOT4(av, hv2); a3 += DOT4(av, hv3);
        }
        __syncthreads();
        h0 = a0; h1 = a1; h2 = a2; h3 = a3;
        h_s[0][k] = h0; h_s[1][k] = h1; h_s[2][k] = h2; h_s[3][k] = h3;
        __syncthreads();
    }
}

// ---------------------------------------------------------------------------
// Phase B3: W_c = Wv_c - Wk_c h0_c (unchanged)
// ---------------------------------------------------------------------------
__global__ __launch_bounds__(256) void wfix_k(const float* __restrict__ Wk,
                                              const float* __restrict__ Hst,
                                              float* __restrict__ Wio) {
    __shared__ __align__(16) float wk_s[CL * PAD];
    __shared__ __align__(16) float h_s[CL * PAD];

    const int blk = blockIdx.x;
    const int tid = threadIdx.x;

    {
        const float4* Wkg = (const float4*)(Wk + (size_t)blk * 4096);
        const float4* Hg = (const float4*)(Hst + (size_t)blk * 4096);
#pragma unroll
        for (int i = 0; i < 4; ++i) {
            int f = tid + i * 256;
            int d = (f >> 4) * PAD + (f & 15) * 4;
            *(float4*)&wk_s[d] = Wkg[f];
            *(float4*)&h_s[d] = Hg[f];
        }
    }
    __syncthreads();

    const int t0 = (tid >> 4) * 4, v0 = (tid & 15) * 4;
    float* Wg = Wio + (size_t)blk * 4096;

    float acc[4][4];
#pragma unroll
    for (int i = 0; i < 4; ++i) {
        float4 wv = *(const float4*)&Wg[(t0 + i) * 64 + v0];
        acc[i][0] = wv.x; acc[i][1] = wv.y; acc[i][2] = wv.z; acc[i][3] = wv.w;
    }
    for (int kk = 0; kk < 64; kk += 4) {
        float4 wa0 = *(const float4*)&wk_s[(t0 + 0) * PAD + kk];
        float4 wa1 = *(const float4*)&wk_s[(t0 + 1) * PAD + kk];
        float4 wa2 = *(const float4*)&wk_s[(t0 + 2) * PAD + kk];
        float4 wa3 = *(const float4*)&wk_s[(t0 + 3) * PAD + kk];
        float4 hb0 = *(const float4*)&h_s[(kk + 0) * PAD + v0];
        float4 hb1 = *(const float4*)&h_s[(kk + 1) * PAD + v0];
        float4 hb2 = *(const float4*)&h_s[(kk + 2) * PAD + v0];
        float4 hb3 = *(const float4*)&h_s[(kk + 3) * PAD + v0];
        WSUB(x, hb0); WSUB(y, hb1); WSUB(z, hb2); WSUB(w, hb3);
    }
#pragma unroll
    for (int i = 0; i < 4; ++i)
        *(float4*)&Wg[(t0 + i) * 64 + v0] =
            make_float4(acc[i][0], acc[i][1], acc[i][2], acc[i][3]);
}

// ---------------------------------------------------------------------------
// Phase C (R7): scratch-free + PAD-strided LDS (unchanged)
// ---------------------------------------------------------------------------
__global__ __launch_bounds__(256) void out_k(const float* __restrict__ Qc,
                                             const float* __restrict__ Kc,
                                             const float* __restrict__ Wb_,
                                             const float* __restrict__ Hst,
                                             const float* __restrict__ bcum,
                                             float* __restrict__ o_scan) {
    __shared__ __align__(16) float q_s[CL * PAD];
    __shared__ __align__(16) float s_s[CL * PAD];   // K, then S
    __shared__ __align__(16) float h_s[CL * PAD];
    __shared__ __align__(16) float w_s[CL * PAD];
    __shared__ float b_s[64];

    const int blk = blockIdx.x;
    const int bh = blk >> 5;
    const int c = blk & 31;
    const int b = bh >> 4;
    const int h = bh & 15;
    const int tid = threadIdx.x;

    if (tid < 64) b_s[tid] = bcum[(size_t)blk * 64 + tid];
    {
        const float4* Qg = (const float4*)(Qc + (size_t)blk * 4096);
        const float4* Kg = (const float4*)(Kc + (size_t)blk * 4096);
        const float4* Hg = (const float4*)(Hst + (size_t)blk * 4096);
        const float4* Wg = (const float4*)(Wb_ + (size_t)blk * 4096);
#pragma unroll
        for (int i = 0; i < 4; ++i) {
            int f = tid + i * 256;
            int d = (f >> 4) * PAD + (f & 15) * 4;
            *(float4*)&q_s[d] = Qg[f];
            *(float4*)&s_s[d] = Kg[f];
            *(float4*)&h_s[d] = Hg[f];
            *(float4*)&w_s[d] = Wg[f];
        }
    }
    __syncthreads();

    // Phase 1: S = (Q K^T) ⊙ exp(b_t - b_s) [s<=t], overwrite s_s
    {
        const int t0 = (tid >> 4) * 4, s0 = (tid & 15) * 4;
        float acc[4][4] = {};
        for (int kk = 0; kk < 64; kk += 4) {
            float4 ta0 = *(const float4*)&q_s[(t0 + 0) * PAD + kk];
            float4 ta1 = *(const float4*)&q_s[(t0 + 1) * PAD + kk];
            float4 ta2 = *(const float4*)&q_s[(t0 + 2) * PAD + kk];
            float4 ta3 = *(const float4*)&q_s[(t0 + 3) * PAD + kk];
            float4 sb0 = *(const float4*)&s_s[(s0 + 0) * PAD + kk];
            float4 sb1 = *(const float4*)&s_s[(s0 + 1) * PAD + kk];
            float4 sb2 = *(const float4*)&s_s[(s0 + 2) * PAD + kk];
            float4 sb3 = *(const float4*)&s_s[(s0 + 3) * PAD + kk];
            acc[0][0] += DOT4(ta0, sb0); acc[0][1] += DOT4(ta0, sb1);
            acc[0][2] += DOT4(ta0, sb2); acc[0][3] += DOT4(ta0, sb3);
            acc[1][0] += DOT4(ta1, sb0); acc[1][1] += DOT4(ta1, sb1);
            acc[1][2] += DOT4(ta1, sb2); acc[1][3] += DOT4(ta1, sb3);
            acc[2][0] += DOT4(ta2, sb0); acc[2][1] += DOT4(ta2, sb1);
            acc[2][2] += DOT4(ta2, sb2); acc[2][3] += DOT4(ta2, sb3);
            acc[3][0] += DOT4(ta3, sb0); acc[3][1] += DOT4(ta3, sb1);
            acc[3][2] += DOT4(ta3, sb2); acc[3][3] += DOT4(ta3, sb3);
        }
        __syncthreads();   // all Q,K reads done before overwrite
#pragma unroll
        for (int i = 0; i < 4; ++i)
#pragma unroll
            for (int j = 0; j < 4; ++j) {
                const int t = t0 + i, s = s0 + j;
                s_s[t * PAD + s] = (s <= t) ? acc[i][j] * __expf(b_s[t] - b_s[s]) : 0.0f;
            }
    }
    // scale q rows by e^{b_t}
#pragma unroll
    for (int i = 0; i < 16; ++i) {
        const int e = tid + i * 256;
        const int t = e >> 6;
        q_s[t * PAD + (e & 63)] *= __expf(b_s[t]);
    }
    __syncthreads();

    // Phase 2: O = S @ W + Qs @ H
    {
        const int t0 = (tid >> 4) * 4, v0 = (tid & 15) * 4;
        float acc[4][4] = {};
        for (int ss = 0; ss < 64; ss += 4) {
            float4 sa0 = *(const float4*)&s_s[(t0 + 0) * PAD + ss];
            float4 sa1 = *(const float4*)&s_s[(t0 + 1) * PAD + ss];
            float4 sa2 = *(const float4*)&s_s[(t0 + 2) * PAD + ss];
            float4 sa3 = *(const float4*)&s_s[(t0 + 3) * PAD + ss];
            float4 wb0 = *(const float4*)&w_s[(ss + 0) * PAD + v0];
            float4 wb1 = *(const float4*)&w_s[(ss + 1) * PAD + v0];
            float4 wb2 = *(const float4*)&w_s[(ss + 2) * PAD + v0];
            float4 wb3 = *(const float4*)&w_s[(ss + 3) * PAD + v0];
            ACC16(x, wb0); ACC16(y, wb1); ACC16(z, wb2); ACC16(w, wb3);
        }
        for (int kk = 0; kk < 64; kk += 4) {
            float4 sa0 = *(const float4*)&q_s[(t0 + 0) * PAD + kk];
            float4 sa1 = *(const float4*)&q_s[(t0 + 1) * PAD + kk];
            float4 sa2 = *(const float4*)&q_s[(t0 + 2) * PAD + kk];
            float4 sa3 = *(const float4*)&q_s[(t0 + 3) * PAD + kk];
            float4 wb0 = *(const float4*)&h_s[(kk + 0) * PAD + v0];
            float4 wb1 = *(const float4*)&h_s[(kk + 1) * PAD + v0];
            float4 wb2 = *(const float4*)&h_s[(kk + 2) * PAD + v0];
            float4 wb3 = *(const float4*)&h_s[(kk + 3) * PAD + v0];
            ACC16(x, wb0); ACC16(y, wb1); ACC16(z, wb2); ACC16(w, wb3);
        }
#pragma unroll
        for (int i = 0; i < 4; ++i) {
            const int t = c * CL + t0 + i;
            *(float4*)&o_scan[(((size_t)b * TT + t) * HH + h) * DK + v0] =
                make_float4(acc[i][0], acc[i][1], acc[i][2], acc[i][3]);
        }
    }
}

// ---------------------------------------------------------------------------
// Gated RMSNorm -> bf16 output (unchanged)
// ---------------------------------------------------------------------------
__global__ __launch_bounds__(256) void gnorm_k(const float* __restrict__ o_scan,
                                               const float* __restrict__ gate,
                                               const float* __restrict__ rms_w,
                                               unsigned short* __restrict__ o2) {
    const int tid = threadIdx.x;
    const int grp = tid >> 6;
    const int lane = tid & 63;
    const int bth = blockIdx.x * 4 + grp;
    const int h = bth & 15;
    const int row = bth >> 4;

    float ov = o_scan[(size_t)bth * DK + lane];
    float s = ov * ov;
#pragma unroll
    for (int sh = 32; sh > 0; sh >>= 1) s += __shfl_xor(s, sh);
    float r = rsqrtf(s * (1.0f / 64.0f) + 1e-5f);

    float gt = gate[(size_t)row * HD + h * DK + lane];
    o2[(size_t)row * HD + h * DK + lane] = f2bf(ov * r * rms_w[lane] * siluf_(gt));
}

// ---------------------------------------------------------------------------
extern "C" void kernel_launch(void* const* d_in, const int* in_sizes, int n_in,
                              void* d_out, int out_size, void* d_ws, size_t ws_size,
                              hipStream_t stream) {
    (void)in_sizes; (void)n_in; (void)out_size; (void)ws_size;

    const float* x       = (const float*)d_in[0];
    const float* Wq      = (const float*)d_in[1];
    const float* Wk_     = (const float*)d_in[2];
    const float* Wv_     = (const float*)d_in[3];
    const float* Wa      = (const float*)d_in[4];
    const float* Wb      = (const float*)d_in[5];
    const float* Wg      = (const float*)d_in[6];
    const float* Wo      = (const float*)d_in[7];
    const float* conv_q  = (const float*)d_in[8];
    const float* conv_k  = (const float*)d_in[9];
    const float* conv_v  = (const float*)d_in[10];
    const float* A_log   = (const float*)d_in[11];
    const float* dt_bias = (const float*)d_in[12];
    const float* rms_w   = (const float*)d_in[13];
    float* out = (float*)d_out;

    float* ws = (float*)d_ws;
    const size_t NTOK = (size_t)BB * TT;     // 4096
    const size_t BIG = NTOK * HD;            // 4 Mi floats

    float* q_pre = ws + 0 * BIG;
    float* k_pre = ws + 1 * BIG;
    float* v_pre = ws + 2 * BIG;
    float* gatep = ws + 3 * BIG;
    float* Qc    = ws + 4 * BIG;
    float* Kc    = ws + 5 * BIG;
    float* gbuf  = ws + 6 * BIG;
    float* bbuf  = gbuf + NTOK * HH;
    float* bcumb = bbuf + NTOK * HH;

    // bf16 buffers after the fp32 region (wqt..wgt contiguous = fused B matrix)
    unsigned short* xb  = (unsigned short*)(bcumb + NTOK * HH);
    unsigned short* wqt = xb + (size_t)NTOK * DD;
    unsigned short* wkt = wqt + (size_t)DD * HD;
    unsigned short* wvt = wkt + (size_t)DD * HD;
    unsigned short* wgt = wvt + (size_t)DD * HD;
    unsigned short* wot = wgt + (size_t)DD * HD;

    // fp32 buffers after bf16 region: Bb + Hst (32 MB) + Wab_t (128 KB)
    float* Bbuf = (float*)(wot + (size_t)DD * HD);
    float* HstB = Bbuf + BIG;
    float* Wabt = HstB + BIG;

    // aliases (stream-ordered lifetimes):
    float* Wvb    = q_pre;   // prep_k out; wfix_k rewrites in place to W
    float* Wkb    = k_pre;
    float* Abuf   = v_pre;   // ab_k out (v_pre dead after prep_k)
    float* o_scan = v_pre;   // out_k out (Abuf dead after hrec_k)
    unsigned short* o2b = (unsigned short*)Qc;

    // casts
    castx_k<<<(int)(NTOK * DD / (256 * 8)), 256, 0, stream>>>(x, xb);
    dim3 tg(16, 16);
    castw_k<<<tg, 256, 0, stream>>>(Wq, wqt);
    castw_k<<<tg, 256, 0, stream>>>(Wk_, wkt);
    castw_k<<<tg, 256, 0, stream>>>(Wv_, wvt);
    castw_k<<<tg, 256, 0, stream>>>(Wg, wgt);
    castw_k<<<tg, 256, 0, stream>>>(Wo, wot);
    tw_k<<<32, 256, 0, stream>>>(Wa, Wb, Wabt);

    // fused QKVG projection: one dispatch, 1024 blocks (was 4 x 256)
    gemm_qkvg_k<<<dim3(32, 32), 256, 0, stream>>>(xb, wqt, q_pre, k_pre, v_pre, gatep);

    gbeta_k<<<(int)(NTOK / 8), 256, 0, stream>>>(x, Wabt, A_log, dt_bias, gbuf, bbuf);

    stage_k<<<BB * HH * NC, 64, 0, stream>>>(q_pre, k_pre, conv_q, conv_k, gbuf,
                                             Qc, Kc, bcumb);

    prep_k<<<BB * HH * NC, 256, 0, stream>>>(Kc, v_pre, conv_v, bcumb, bbuf, Wvb, Wkb);

    // chunked state recurrence, decomposed:
    ab_k<<<BB * HH * NC, 256, 0, stream>>>(Kc, Wvb, Wkb, bcumb, Abuf, Bbuf);
    hrec_k<<<BB * HH * VS, 64, 0, stream>>>(Abuf, Bbuf, HstB);
    wfix_k<<<BB * HH * NC, 256, 0, stream>>>(Wkb, HstB, Wvb);

    out_k<<<BB * HH * NC, 256, 0, stream>>>(Qc, Kc, Wvb, HstB, bcumb, o_scan);

    gnorm_k<<<(int)(NTOK * HH / 4), 256, 0, stream>>>(o_scan, gatep, rms_w, o2b);

    gemm_bf16_k<<<dim3(HD / 128, NTOK / 128), 256, 0, stream>>>(o2b, wot, out,
                                                                (int)NTOK, HD, DD);
}